// Round 2
// baseline (4980.853 us; speedup 1.0000x reference)
//
#include <hip/hip_runtime.h>
#include <math.h>

#define N0 100000
#define N1 25000
#define N2 6250
#define FD 128

static inline int ceildiv(int a, int b){ return (a + b - 1)/b; }

__device__ __forceinline__ unsigned encf(float f){
  unsigned u = __float_as_uint(f);
  return (u & 0x80000000u) ? ~u : (u | 0x80000000u);
}
__device__ __forceinline__ float decf(unsigned u){
  return __uint_as_float((u & 0x80000000u) ? (u & 0x7fffffffu) : ~u);
}

__global__ void fill_f32(float* __restrict__ p, float v, int n){
  int i = blockIdx.x*256 + threadIdx.x;
  if (i < n) p[i] = v;
}

// out[n x 128] = (rowScale_i * A_i) @ W[128x128] + bias
__global__ __launch_bounds__(256) void gemm128(
    const float* __restrict__ A, const float* __restrict__ rowScale,
    const float* __restrict__ W, const float* __restrict__ bias,
    float* __restrict__ out, int n)
{
  __shared__ float Wl[32*128];
  __shared__ float Al[32*32];
  const int tid = threadIdx.x;
  const int row0 = blockIdx.x * 32;
  const int c0 = (tid & 31) * 4;
  const int r0 = (tid >> 5) * 4;
  float acc[4][4] = {};
  const float4* A4 = (const float4*)A;
  const float4* W4 = (const float4*)W;
  for (int kp = 0; kp < 4; ++kp) {
    float4* Wl4 = (float4*)Wl;
    #pragma unroll
    for (int i = 0; i < 4; ++i)
      Wl4[tid + 256*i] = W4[kp*1024 + tid + 256*i];
    {
      int r = tid >> 3, fc = tid & 7;
      int gr = row0 + r;
      float4 v = make_float4(0.f,0.f,0.f,0.f);
      if (gr < n) {
        v = A4[(size_t)gr*32 + kp*8 + fc];
        if (rowScale) { float s = rowScale[gr]; v.x*=s; v.y*=s; v.z*=s; v.w*=s; }
      }
      ((float4*)Al)[tid] = v;
    }
    __syncthreads();
    #pragma unroll
    for (int kq = 0; kq < 8; ++kq) {
      int k0 = kq*4;
      float4 a[4], w[4];
      #pragma unroll
      for (int i=0;i<4;++i) a[i] = *(const float4*)&Al[(r0+i)*32 + k0];
      #pragma unroll
      for (int kk=0;kk<4;++kk) w[kk] = *(const float4*)&Wl[(k0+kk)*128 + c0];
      #pragma unroll
      for (int i=0;i<4;++i){
        acc[i][0] = fmaf(a[i].x,w[0].x, fmaf(a[i].y,w[1].x, fmaf(a[i].z,w[2].x, fmaf(a[i].w,w[3].x, acc[i][0]))));
        acc[i][1] = fmaf(a[i].x,w[0].y, fmaf(a[i].y,w[1].y, fmaf(a[i].z,w[2].y, fmaf(a[i].w,w[3].y, acc[i][1]))));
        acc[i][2] = fmaf(a[i].x,w[0].z, fmaf(a[i].y,w[1].z, fmaf(a[i].z,w[2].z, fmaf(a[i].w,w[3].z, acc[i][2]))));
        acc[i][3] = fmaf(a[i].x,w[0].w, fmaf(a[i].y,w[1].w, fmaf(a[i].z,w[2].w, fmaf(a[i].w,w[3].w, acc[i][3]))));
      }
    }
    __syncthreads();
  }
  float4 bv = *(const float4*)&bias[c0];
  #pragma unroll
  for (int i=0;i<4;++i){
    int gr = row0 + r0 + i;
    if (gr < n){
      float4 o;
      o.x = acc[i][0] + bv.x; o.y = acc[i][1] + bv.y;
      o.z = acc[i][2] + bv.z; o.w = acc[i][3] + bv.w;
      *(float4*)&out[(size_t)gr*FD + c0] = o;
    }
  }
}

// s[row] = dot(qb, K[row]) * inv   (one wave per row)
__global__ __launch_bounds__(256) void score_qb(
    const float* __restrict__ K, const float* __restrict__ qb,
    float* __restrict__ s, int n, float inv)
{
  int wid = threadIdx.x >> 6, lane = threadIdx.x & 63;
  int row = blockIdx.x*4 + wid;
  if (row >= n) return;
  const float* kr = K + (size_t)row*FD;
  float a = kr[lane]*qb[lane] + kr[64+lane]*qb[64+lane];
  #pragma unroll
  for (int o = 32; o; o >>= 1) a += __shfl_xor(a, o);
  if (lane == 0) s[row] = a * inv;
}

__global__ void seg_max_k(const int* __restrict__ src, const int* __restrict__ dst,
                          const float* __restrict__ s, unsigned* __restrict__ m, int E){
  int e = blockIdx.x*256 + threadIdx.x;
  if (e >= E) return;
  atomicMax(&m[dst[e]], encf(s[src[e]]));
}

__global__ void seg_exp_k(const int* __restrict__ src, const int* __restrict__ dst,
                          const float* __restrict__ s, const unsigned* __restrict__ m,
                          float* __restrict__ ew, float* __restrict__ den, int E){
  int e = blockIdx.x*256 + threadIdx.x;
  if (e >= E) return;
  int d = dst[e];
  float x = expf(s[src[e]] - decf(m[d]));
  ew[e] = x;
  atomicAdd(&den[d], x);
}

// 32 threads per edge, 4 feats each: out[dst] += (ew/den[dst]) * V[src]
__global__ void attn_scatter(const int* __restrict__ src, const int* __restrict__ dst,
                             const float* __restrict__ ew, const float* __restrict__ den,
                             const float* __restrict__ V, float* __restrict__ out, int E){
  int t = blockIdx.x*256 + threadIdx.x;
  if (t >= E*32) return;
  int e = t >> 5, g = t & 31;
  int d = dst[e];
  float w = ew[e] / den[d];
  float4 v = *(const float4*)&V[(size_t)src[e]*FD + g*4];
  float* o = &out[(size_t)d*FD + g*4];
  atomicAdd(o+0, w*v.x);
  atomicAdd(o+1, w*v.y);
  atomicAdd(o+2, w*v.z);
  atomicAdd(o+3, w*v.w);
}

__global__ void deg_k(const int* __restrict__ src, const int* __restrict__ dst,
                      float* __restrict__ dout, float* __restrict__ din, int E){
  int e = blockIdx.x*256 + threadIdx.x;
  if (e >= E) return;
  atomicAdd(&dout[src[e]], 1.0f);
  atomicAdd(&din[dst[e]], 1.0f);
}

__global__ void rsqrt_clip(float* __restrict__ p, int n){
  int i = blockIdx.x*256 + threadIdx.x;
  if (i < n) p[i] = rsqrtf(fmaxf(p[i], 1.0f));
}

// 32 threads/edge: agg[dst] += rsO[src] * X[src]
__global__ void gcn_scatter(const int* __restrict__ src, const int* __restrict__ dst,
                            const float* __restrict__ X, const float* __restrict__ rsO,
                            float* __restrict__ agg, int E){
  int t = blockIdx.x*256 + threadIdx.x;
  if (t >= E*32) return;
  int e = t >> 5, g = t & 31;
  int sn = src[e];
  float w = rsO[sn];
  float4 v = *(const float4*)&X[(size_t)sn*FD + g*4];
  float* o = &agg[(size_t)dst[e]*FD + g*4];
  atomicAdd(o+0, w*v.x);
  atomicAdd(o+1, w*v.y);
  atomicAdd(o+2, w*v.z);
  atomicAdd(o+3, w*v.w);
}

// wave per row: softmax( concat(g,d) @ W[256x5] + b )
__global__ __launch_bounds__(256) void head_k(
    const float* __restrict__ g, const float* __restrict__ dch,
    const float* __restrict__ W, const float* __restrict__ b,
    float* __restrict__ out, int n, int rowOff)
{
  int wid = threadIdx.x >> 6, lane = threadIdx.x & 63;
  int row = blockIdx.x*4 + wid;
  if (row >= n) return;
  const float* gr = g + (size_t)row*FD;
  const float* dr = dch + (size_t)row*FD;
  float x0 = gr[lane], x1 = gr[64+lane], x2 = dr[lane], x3 = dr[64+lane];
  float acc[5];
  #pragma unroll
  for (int o = 0; o < 5; ++o)
    acc[o] = x0*W[lane*5+o] + x1*W[(64+lane)*5+o] + x2*W[(128+lane)*5+o] + x3*W[(192+lane)*5+o];
  #pragma unroll
  for (int o = 0; o < 5; ++o)
    #pragma unroll
    for (int s = 32; s; s >>= 1) acc[o] += __shfl_xor(acc[o], s);
  if (lane == 0){
    float m = -1e30f;
    #pragma unroll
    for (int o = 0; o < 5; ++o){ acc[o] += b[o]; m = fmaxf(m, acc[o]); }
    float sum = 0.f;
    #pragma unroll
    for (int o = 0; o < 5; ++o){ acc[o] = expf(acc[o]-m); sum += acc[o]; }
    float is = 1.0f/sum;
    float* op = out + (size_t)(rowOff+row)*5;
    #pragma unroll
    for (int o = 0; o < 5; ++o) op[o] = acc[o]*is;
  }
}

extern "C" void kernel_launch(void* const* d_in, const int* in_sizes, int n_in,
                              void* d_out, int out_size, void* d_ws, size_t ws_size,
                              hipStream_t stream)
{
  const float* X      = (const float*)d_in[0];
  const float* emb_W  = (const float*)d_in[1];
  const float* emb_b  = (const float*)d_in[2];
  const float* gcn_W  = (const float*)d_in[3];
  const float* gcn_b  = (const float*)d_in[4];
  const float* enc_qb = (const float*)d_in[6];
  const float* enc_kW = (const float*)d_in[7];
  const float* enc_kb = (const float*)d_in[8];
  const float* enc_vW = (const float*)d_in[9];
  const float* enc_vb = (const float*)d_in[10];
  const float* dec_qb = (const float*)d_in[12];
  const float* dec_kW = (const float*)d_in[13];
  const float* dec_kb = (const float*)d_in[14];
  const float* dec_vW = (const float*)d_in[15];
  const float* dec_vb = (const float*)d_in[16];
  const float* head_W = (const float*)d_in[17];
  const float* head_b = (const float*)d_in[18];
  const int* g0s  = (const int*)d_in[19];
  const int* g0d  = (const int*)d_in[20];
  const int* g1s  = (const int*)d_in[21];
  const int* g1d  = (const int*)d_in[22];
  const int* g2s  = (const int*)d_in[23];
  const int* g2d  = (const int*)d_in[24];
  const int* i0s  = (const int*)d_in[25];
  const int* i0d  = (const int*)d_in[26];
  const int* i1s  = (const int*)d_in[27];
  const int* i1d  = (const int*)d_in[28];
  const int* dc0s = (const int*)d_in[29];
  const int* dc0d = (const int*)d_in[30];
  const int* dc1s = (const int*)d_in[31];
  const int* dc1d = (const int*)d_in[32];

  float* ws = (float*)d_ws;
  float* bh0 = ws;                          // N0*FD : h0, later d0
  float* bkv = bh0 + (size_t)N0*FD;         // N0*FD : K then V then agg
  float* be1 = bkv + (size_t)N0*FD;         // N1*FD : e1, later d1
  float* be2 = be1 + (size_t)N1*FD;         // N2*FD : e2
  float* bg0 = be2 + (size_t)N2*FD;         // N0*FD
  float* bg1 = bg0 + (size_t)N0*FD;         // N1*FD
  float* bg2 = bg1 + (size_t)N1*FD;         // N2*FD
  float* sS  = bg2 + (size_t)N2*FD;         // N0
  unsigned* sM = (unsigned*)(sS + N0);      // N0
  float* sDen = (float*)(sM + N0);          // N0
  float* sEW  = sDen + N0;                  // 400000
  float* sRo  = sEW + 400000;               // N0
  float* sRi  = sRo + N0;                   // N0

  const float invScale = 0.17677669529663687f; // 1/sqrt(32)
  float* out = (float*)d_out;

  auto run_attn = [&](const float* srcFeat, int nSrc, const int* es, const int* ed, int E,
                      int nDst, const float* kW, const float* kb,
                      const float* vW, const float* vb, const float* qb, float* outBuf){
    gemm128<<<ceildiv(nSrc,32),256,0,stream>>>(srcFeat, nullptr, kW, kb, bkv, nSrc);
    score_qb<<<ceildiv(nSrc,4),256,0,stream>>>(bkv, qb, sS, nSrc, invScale);
    gemm128<<<ceildiv(nSrc,32),256,0,stream>>>(srcFeat, nullptr, vW, vb, bkv, nSrc);
    fill_f32<<<ceildiv(nDst,256),256,0,stream>>>((float*)sM, 0.f, nDst);
    fill_f32<<<ceildiv(nDst,256),256,0,stream>>>(sDen, 0.f, nDst);
    seg_max_k<<<ceildiv(E,256),256,0,stream>>>(es, ed, sS, sM, E);
    seg_exp_k<<<ceildiv(E,256),256,0,stream>>>(es, ed, sS, sM, sEW, sDen, E);
    fill_f32<<<ceildiv(nDst*FD,256),256,0,stream>>>(outBuf, 0.f, nDst*FD);
    attn_scatter<<<ceildiv(E*32,256),256,0,stream>>>(es, ed, sEW, sDen, bkv, outBuf, E);
  };

  auto run_gcn = [&](const float* feat, int n, const int* es, const int* ed, int E,
                     const float* W, const float* b, float* outBuf){
    fill_f32<<<ceildiv(n,256),256,0,stream>>>(sRo, 0.f, n);
    fill_f32<<<ceildiv(n,256),256,0,stream>>>(sRi, 0.f, n);
    deg_k<<<ceildiv(E,256),256,0,stream>>>(es, ed, sRo, sRi, E);
    rsqrt_clip<<<ceildiv(n,256),256,0,stream>>>(sRo, n);
    rsqrt_clip<<<ceildiv(n,256),256,0,stream>>>(sRi, n);
    fill_f32<<<ceildiv(n*FD,256),256,0,stream>>>(bkv, 0.f, n*FD);
    gcn_scatter<<<ceildiv(E*32,256),256,0,stream>>>(es, ed, feat, sRo, bkv, E);
    gemm128<<<ceildiv(n,32),256,0,stream>>>(bkv, sRi, W, b, outBuf, n);
  };

  // 1. h0 = X @ emb_W + emb_b
  gemm128<<<ceildiv(N0,32),256,0,stream>>>(X, nullptr, emb_W, emb_b, bh0, N0);
  // 2. encoder
  run_attn(bh0, N0, i0s, i0d, 400000, N1,
           enc_kW, enc_kb, enc_vW, enc_vb, enc_qb, be1);
  run_attn(be1, N1, i1s, i1d, 100000, N2,
           enc_kW+16384, enc_kb+128, enc_vW+16384, enc_vb+128, enc_qb+128, be2);
  // 3. GCNs
  run_gcn(bh0, N0, g0s, g0d, 1000000, gcn_W,        gcn_b,     bg0);
  run_gcn(be1, N1, g1s, g1d, 400000,  gcn_W+16384,  gcn_b+128, bg1);
  run_gcn(be2, N2, g2s, g2d, 100000,  gcn_W+32768,  gcn_b+256, bg2);
  // 4. decoder
  run_attn(bg2, N2, dc0s, dc0d, 100000, N1,
           dec_kW, dec_kb, dec_vW, dec_vb, dec_qb, be1);          // d1 -> be1
  run_attn(be1, N1, dc1s, dc1d, 400000, N0,
           dec_kW+16384, dec_kb+128, dec_vW+16384, dec_vb+128, dec_qb+128, bh0); // d0 -> bh0
  // 5. heads
  head_k<<<ceildiv(N0,4),256,0,stream>>>(bg0, bh0, head_W,       head_b,    out, N0, 0);
  head_k<<<ceildiv(N1,4),256,0,stream>>>(bg1, be1, head_W+1280,  head_b+5,  out, N1, N0);
  head_k<<<ceildiv(N2,4),256,0,stream>>>(bg2, bg2, head_W+2560,  head_b+10, out, N2, N0+N1);
}

// Round 3
// 1095.554 us; speedup vs baseline: 4.5464x; 4.5464x over previous
//
#include <hip/hip_runtime.h>
#include <math.h>

#define N0 100000
#define N1 25000
#define N2 6250
#define FD 128
#define SCAN_CHUNK 4096

static inline int ceildiv(int a, int b){ return (a + b - 1)/b; }

__global__ void fill_f32(float* __restrict__ p, float v, int n){
  int i = blockIdx.x*256 + threadIdx.x;
  if (i < n) p[i] = v;
}
__global__ void zero_int(int* __restrict__ p, int n){
  int i = blockIdx.x*256 + threadIdx.x;
  if (i < n) p[i] = 0;
}

// out[n x 128] = A @ W[128x128] + bias
__global__ __launch_bounds__(256) void gemm128(
    const float* __restrict__ A,
    const float* __restrict__ W, const float* __restrict__ bias,
    float* __restrict__ out, int n)
{
  __shared__ float Wl[32*128];
  __shared__ float Al[32*32];
  const int tid = threadIdx.x;
  const int row0 = blockIdx.x * 32;
  const int c0 = (tid & 31) * 4;
  const int r0 = (tid >> 5) * 4;
  float acc[4][4] = {};
  const float4* A4 = (const float4*)A;
  const float4* W4 = (const float4*)W;
  for (int kp = 0; kp < 4; ++kp) {
    float4* Wl4 = (float4*)Wl;
    #pragma unroll
    for (int i = 0; i < 4; ++i)
      Wl4[tid + 256*i] = W4[kp*1024 + tid + 256*i];
    {
      int r = tid >> 3, fc = tid & 7;
      int gr = row0 + r;
      float4 v = make_float4(0.f,0.f,0.f,0.f);
      if (gr < n) v = A4[(size_t)gr*32 + kp*8 + fc];
      ((float4*)Al)[tid] = v;
    }
    __syncthreads();
    #pragma unroll
    for (int kq = 0; kq < 8; ++kq) {
      int k0 = kq*4;
      float4 a[4], w[4];
      #pragma unroll
      for (int i=0;i<4;++i) a[i] = *(const float4*)&Al[(r0+i)*32 + k0];
      #pragma unroll
      for (int kk=0;kk<4;++kk) w[kk] = *(const float4*)&Wl[(k0+kk)*128 + c0];
      #pragma unroll
      for (int i=0;i<4;++i){
        acc[i][0] = fmaf(a[i].x,w[0].x, fmaf(a[i].y,w[1].x, fmaf(a[i].z,w[2].x, fmaf(a[i].w,w[3].x, acc[i][0]))));
        acc[i][1] = fmaf(a[i].x,w[0].y, fmaf(a[i].y,w[1].y, fmaf(a[i].z,w[2].y, fmaf(a[i].w,w[3].y, acc[i][1]))));
        acc[i][2] = fmaf(a[i].x,w[0].z, fmaf(a[i].y,w[1].z, fmaf(a[i].z,w[2].z, fmaf(a[i].w,w[3].z, acc[i][2]))));
        acc[i][3] = fmaf(a[i].x,w[0].w, fmaf(a[i].y,w[1].w, fmaf(a[i].z,w[2].w, fmaf(a[i].w,w[3].w, acc[i][3]))));
      }
    }
    __syncthreads();
  }
  float4 bv = *(const float4*)&bias[c0];
  #pragma unroll
  for (int i=0;i<4;++i){
    int gr = row0 + r0 + i;
    if (gr < n){
      float4 o;
      o.x = acc[i][0] + bv.x; o.y = acc[i][1] + bv.y;
      o.z = acc[i][2] + bv.z; o.w = acc[i][3] + bv.w;
      *(float4*)&out[(size_t)gr*FD + c0] = o;
    }
  }
}

// kvec[k] = inv * sum_j kW[k,j]*qb[j];  kvec[128] = inv * dot(kb,qb)
__global__ void kqv_k(const float* __restrict__ kW, const float* __restrict__ kb,
                      const float* __restrict__ qb, float* __restrict__ kvec, float inv){
  int k = threadIdx.x;
  float a = 0.f;
  for (int j = 0; j < 128; ++j) a = fmaf(kW[k*128+j], qb[j], a);
  kvec[k] = a * inv;
  if (k == 0){
    float c = 0.f;
    for (int j = 0; j < 128; ++j) c = fmaf(kb[j], qb[j], c);
    kvec[128] = c * inv;
  }
}

// s[row] = dot(feat[row], kvec) + kvec[128]   (one wave per row)
__global__ __launch_bounds__(256) void score_feat(
    const float* __restrict__ feat, const float* __restrict__ kvec,
    float* __restrict__ s, int n)
{
  int wid = threadIdx.x >> 6, lane = threadIdx.x & 63;
  int row = blockIdx.x*4 + wid;
  if (row >= n) return;
  const float* fr = feat + (size_t)row*FD;
  float a = fr[lane]*kvec[lane] + fr[64+lane]*kvec[64+lane];
  #pragma unroll
  for (int o = 32; o; o >>= 1) a += __shfl_xor(a, o);
  if (lane == 0) s[row] = a + kvec[128];
}

// ---------- CSR build ----------
__global__ void hist_idx(const int* __restrict__ idx, int* __restrict__ cnt, int E){
  int e = blockIdx.x*256 + threadIdx.x;
  if (e < E) atomicAdd(&cnt[idx[e]], 1);
}

__global__ __launch_bounds__(256) void scanA(const int* __restrict__ cnt, int* __restrict__ bsums, int n){
  __shared__ int sm[256];
  int base = blockIdx.x*SCAN_CHUNK + threadIdx.x*16;
  int tsum = 0;
  #pragma unroll
  for (int i = 0; i < 16; ++i){ int idx = base + i; if (idx < n) tsum += cnt[idx]; }
  sm[threadIdx.x] = tsum; __syncthreads();
  for (int o = 128; o; o >>= 1){
    if (threadIdx.x < o) sm[threadIdx.x] += sm[threadIdx.x+o];
    __syncthreads();
  }
  if (threadIdx.x == 0) bsums[blockIdx.x] = sm[0];
}

__global__ void scanB(int* __restrict__ bsums, int nb, int* __restrict__ rowp, int n, int E){
  if (threadIdx.x == 0){
    int acc = 0;
    for (int i = 0; i < nb; ++i){ int v = bsums[i]; bsums[i] = acc; acc += v; }
    rowp[n] = E;
  }
}

__global__ __launch_bounds__(256) void scanC(const int* __restrict__ cnt, const int* __restrict__ bsums,
                                             int* __restrict__ rowp, int n){
  __shared__ int sm[256];
  int base = blockIdx.x*SCAN_CHUNK + threadIdx.x*16;
  int local[16];
  int tsum = 0;
  #pragma unroll
  for (int i = 0; i < 16; ++i){
    int idx = base + i;
    int v = (idx < n) ? cnt[idx] : 0;
    local[i] = v; tsum += v;
  }
  sm[threadIdx.x] = tsum; __syncthreads();
  for (int o = 1; o < 256; o <<= 1){
    int v = sm[threadIdx.x];
    int add = (threadIdx.x >= o) ? sm[threadIdx.x - o] : 0;
    __syncthreads();
    sm[threadIdx.x] = v + add;
    __syncthreads();
  }
  int pre = (threadIdx.x ? sm[threadIdx.x-1] : 0) + bsums[blockIdx.x];
  #pragma unroll
  for (int i = 0; i < 16; ++i){
    int idx = base + i;
    if (idx < n){ rowp[idx] = pre; pre += local[i]; }
  }
}

__global__ void fill_csr(const int* __restrict__ src, const int* __restrict__ dst,
                         const int* __restrict__ rowp, int* __restrict__ cnt,
                         int* __restrict__ csr, int E){
  int e = blockIdx.x*256 + threadIdx.x;
  if (e >= E) return;
  int d = dst[e];
  int pos = atomicAdd(&cnt[d], 1);
  csr[rowp[d] + pos] = src[e];
}

// ---------- gathers (wave per dst node) ----------
__global__ __launch_bounds__(256) void attn_gather(
    const int* __restrict__ csr, const int* __restrict__ rowp,
    const float* __restrict__ s, const float* __restrict__ V,
    float* __restrict__ out, int n)
{
  int wid = threadIdx.x >> 6, lane = threadIdx.x & 63;
  int row = blockIdx.x*4 + wid;
  if (row >= n) return;
  int st = rowp[row], en = rowp[row+1];
  float2 acc = make_float2(0.f, 0.f);
  if (en > st){
    float m = -1e30f;
    for (int e = st + lane; e < en; e += 64) m = fmaxf(m, s[csr[e]]);
    #pragma unroll
    for (int o = 32; o; o >>= 1) m = fmaxf(m, __shfl_xor(m, o));
    const float2* V2 = (const float2*)V;
    float den = 0.f;
    for (int e = st; e < en; ++e){
      int sn = csr[e];
      float w = expf(s[sn] - m);
      den += w;
      float2 v = V2[(size_t)sn*64 + lane];
      acc.x = fmaf(w, v.x, acc.x);
      acc.y = fmaf(w, v.y, acc.y);
    }
    float inv = 1.0f/den;
    acc.x *= inv; acc.y *= inv;
  }
  ((float2*)out)[(size_t)row*64 + lane] = acc;
}

__global__ __launch_bounds__(256) void gcn_gather(
    const int* __restrict__ csr, const int* __restrict__ rowp,
    const float* __restrict__ rsO, const float* __restrict__ X,
    float* __restrict__ agg, int n)
{
  int wid = threadIdx.x >> 6, lane = threadIdx.x & 63;
  int row = blockIdx.x*4 + wid;
  if (row >= n) return;
  int st = rowp[row], en = rowp[row+1];
  float2 acc = make_float2(0.f, 0.f);
  const float2* X2 = (const float2*)X;
  for (int e = st; e < en; ++e){
    int sn = csr[e];
    float w = rsO[sn];
    float2 v = X2[(size_t)sn*64 + lane];
    acc.x = fmaf(w, v.x, acc.x);
    acc.y = fmaf(w, v.y, acc.y);
  }
  float sc = rsqrtf(fmaxf((float)(en - st), 1.0f));
  acc.x *= sc; acc.y *= sc;
  ((float2*)agg)[(size_t)row*64 + lane] = acc;
}

__global__ void deg_src(const int* __restrict__ src, float* __restrict__ d, int E){
  int e = blockIdx.x*256 + threadIdx.x;
  if (e < E) atomicAdd(&d[src[e]], 1.0f);
}

__global__ void rsqrt_clip(float* __restrict__ p, int n){
  int i = blockIdx.x*256 + threadIdx.x;
  if (i < n) p[i] = rsqrtf(fmaxf(p[i], 1.0f));
}

// wave per row: softmax( concat(g,d) @ W[256x5] + b )
__global__ __launch_bounds__(256) void head_k(
    const float* __restrict__ g, const float* __restrict__ dch,
    const float* __restrict__ W, const float* __restrict__ b,
    float* __restrict__ out, int n, int rowOff)
{
  int wid = threadIdx.x >> 6, lane = threadIdx.x & 63;
  int row = blockIdx.x*4 + wid;
  if (row >= n) return;
  const float* gr = g + (size_t)row*FD;
  const float* dr = dch + (size_t)row*FD;
  float x0 = gr[lane], x1 = gr[64+lane], x2 = dr[lane], x3 = dr[64+lane];
  float acc[5];
  #pragma unroll
  for (int o = 0; o < 5; ++o)
    acc[o] = x0*W[lane*5+o] + x1*W[(64+lane)*5+o] + x2*W[(128+lane)*5+o] + x3*W[(192+lane)*5+o];
  #pragma unroll
  for (int o = 0; o < 5; ++o)
    #pragma unroll
    for (int s = 32; s; s >>= 1) acc[o] += __shfl_xor(acc[o], s);
  if (lane == 0){
    float m = -1e30f;
    #pragma unroll
    for (int o = 0; o < 5; ++o){ acc[o] += b[o]; m = fmaxf(m, acc[o]); }
    float sum = 0.f;
    #pragma unroll
    for (int o = 0; o < 5; ++o){ acc[o] = expf(acc[o]-m); sum += acc[o]; }
    float is = 1.0f/sum;
    float* op = out + (size_t)(rowOff+row)*5;
    #pragma unroll
    for (int o = 0; o < 5; ++o) op[o] = acc[o]*is;
  }
}

extern "C" void kernel_launch(void* const* d_in, const int* in_sizes, int n_in,
                              void* d_out, int out_size, void* d_ws, size_t ws_size,
                              hipStream_t stream)
{
  const float* X      = (const float*)d_in[0];
  const float* emb_W  = (const float*)d_in[1];
  const float* emb_b  = (const float*)d_in[2];
  const float* gcn_W  = (const float*)d_in[3];
  const float* gcn_b  = (const float*)d_in[4];
  const float* enc_qb = (const float*)d_in[6];
  const float* enc_kW = (const float*)d_in[7];
  const float* enc_kb = (const float*)d_in[8];
  const float* enc_vW = (const float*)d_in[9];
  const float* enc_vb = (const float*)d_in[10];
  const float* dec_qb = (const float*)d_in[12];
  const float* dec_kW = (const float*)d_in[13];
  const float* dec_kb = (const float*)d_in[14];
  const float* dec_vW = (const float*)d_in[15];
  const float* dec_vb = (const float*)d_in[16];
  const float* head_W = (const float*)d_in[17];
  const float* head_b = (const float*)d_in[18];
  const int* g0s  = (const int*)d_in[19];
  const int* g0d  = (const int*)d_in[20];
  const int* g1s  = (const int*)d_in[21];
  const int* g1d  = (const int*)d_in[22];
  const int* g2s  = (const int*)d_in[23];
  const int* g2d  = (const int*)d_in[24];
  const int* i0s  = (const int*)d_in[25];
  const int* i0d  = (const int*)d_in[26];
  const int* i1s  = (const int*)d_in[27];
  const int* i1d  = (const int*)d_in[28];
  const int* dc0s = (const int*)d_in[29];
  const int* dc0d = (const int*)d_in[30];
  const int* dc1s = (const int*)d_in[31];
  const int* dc1d = (const int*)d_in[32];

  float* ws = (float*)d_ws;
  float* bh0 = ws;                          // N0*FD : h0, later d0
  float* bV  = bh0 + (size_t)N0*FD;         // N0*FD : V / agg scratch
  float* be1 = bV  + (size_t)N0*FD;         // N1*FD : e1, later d1
  float* be2 = be1 + (size_t)N1*FD;         // N2*FD : e2
  float* bg0 = be2 + (size_t)N2*FD;         // N0*FD
  float* bg1 = bg0 + (size_t)N0*FD;         // N1*FD
  float* bg2 = bg1 + (size_t)N1*FD;         // N2*FD
  float* sS  = bg2 + (size_t)N2*FD;         // N0 scores
  float* kvec = sS + N0;                    // 132
  float* rsO  = kvec + 132;                 // N0
  int* cnt  = (int*)(rsO + N0);             // N0
  int* rowp = cnt + N0;                     // N0+1
  int* bsums = rowp + N0 + 4;               // 64
  int* csr  = bsums + 64;                   // 1,000,000

  const float invScale = 0.17677669529663687f; // 1/sqrt(32)
  float* out = (float*)d_out;

  auto build_csr = [&](const int* es, const int* ed, int E, int n){
    int nb = ceildiv(n, SCAN_CHUNK);
    zero_int<<<ceildiv(n,256),256,0,stream>>>(cnt, n);
    hist_idx<<<ceildiv(E,256),256,0,stream>>>(ed, cnt, E);
    scanA<<<nb,256,0,stream>>>(cnt, bsums, n);
    scanB<<<1,64,0,stream>>>(bsums, nb, rowp, n, E);
    scanC<<<nb,256,0,stream>>>(cnt, bsums, rowp, n);
    zero_int<<<ceildiv(n,256),256,0,stream>>>(cnt, n);
    fill_csr<<<ceildiv(E,256),256,0,stream>>>(es, ed, rowp, cnt, csr, E);
  };

  auto run_attn = [&](const float* srcFeat, int nSrc, const int* es, const int* ed, int E,
                      int nDst, const float* kW, const float* kb,
                      const float* vW, const float* vb, const float* qb, float* outBuf){
    kqv_k<<<1,128,0,stream>>>(kW, kb, qb, kvec, invScale);
    score_feat<<<ceildiv(nSrc,4),256,0,stream>>>(srcFeat, kvec, sS, nSrc);
    gemm128<<<ceildiv(nSrc,32),256,0,stream>>>(srcFeat, vW, vb, bV, nSrc);
    build_csr(es, ed, E, nDst);
    attn_gather<<<ceildiv(nDst,4),256,0,stream>>>(csr, rowp, sS, bV, outBuf, nDst);
  };

  auto run_gcn = [&](const float* feat, int n, const int* es, const int* ed, int E,
                     const float* W, const float* b, float* outBuf){
    fill_f32<<<ceildiv(n,256),256,0,stream>>>(rsO, 0.f, n);
    deg_src<<<ceildiv(E,256),256,0,stream>>>(es, rsO, E);
    rsqrt_clip<<<ceildiv(n,256),256,0,stream>>>(rsO, n);
    build_csr(es, ed, E, n);
    gcn_gather<<<ceildiv(n,4),256,0,stream>>>(csr, rowp, rsO, feat, bV, n);
    gemm128<<<ceildiv(n,32),256,0,stream>>>(bV, W, b, outBuf, n);
  };

  // 1. h0 = X @ emb_W + emb_b
  gemm128<<<ceildiv(N0,32),256,0,stream>>>(X, emb_W, emb_b, bh0, N0);
  // 2. encoder
  run_attn(bh0, N0, i0s, i0d, 400000, N1,
           enc_kW, enc_kb, enc_vW, enc_vb, enc_qb, be1);
  run_attn(be1, N1, i1s, i1d, 100000, N2,
           enc_kW+16384, enc_kb+128, enc_vW+16384, enc_vb+128, enc_qb+128, be2);
  // 3. GCNs
  run_gcn(bh0, N0, g0s, g0d, 1000000, gcn_W,        gcn_b,     bg0);
  run_gcn(be1, N1, g1s, g1d, 400000,  gcn_W+16384,  gcn_b+128, bg1);
  run_gcn(be2, N2, g2s, g2d, 100000,  gcn_W+32768,  gcn_b+256, bg2);
  // 4. decoder
  run_attn(bg2, N2, dc0s, dc0d, 100000, N1,
           dec_kW, dec_kb, dec_vW, dec_vb, dec_qb, be1);          // d1 -> be1
  run_attn(be1, N1, dc1s, dc1d, 400000, N0,
           dec_kW+16384, dec_kb+128, dec_vW+16384, dec_vb+128, dec_qb+128, bh0); // d0 -> bh0
  // 5. heads
  head_k<<<ceildiv(N0,4),256,0,stream>>>(bg0, bh0, head_W,       head_b,    out, N0, 0);
  head_k<<<ceildiv(N1,4),256,0,stream>>>(bg1, be1, head_W+1280,  head_b+5,  out, N1, N0);
  head_k<<<ceildiv(N2,4),256,0,stream>>>(bg2, bg2, head_W+2560,  head_b+10, out, N2, N0+N1);
}

// Round 4
// 946.462 us; speedup vs baseline: 5.2626x; 1.1575x over previous
//
#include <hip/hip_runtime.h>
#include <math.h>

#define N0 100000
#define N1 25000
#define N2 6250
#define FD 128
#define SCAN_CHUNK 4096

typedef unsigned short u16;
typedef unsigned int u32;

static inline int ceildiv(int a, int b){ return (a + b - 1)/b; }

__device__ __forceinline__ u16 f2bf(float f){
  u32 u = __float_as_uint(f);
  u += 0x7fffu + ((u >> 16) & 1u);
  return (u16)(u >> 16);
}
__device__ __forceinline__ float bf2f(u16 h){
  return __uint_as_float(((u32)h) << 16);
}

__global__ void zero_int(int* __restrict__ p, int n){
  int i = blockIdx.x*256 + threadIdx.x;
  if (i < n) p[i] = 0;
}

// ---------------- GEMMs ----------------
// out[n x 128] = A @ W + bias (f32 out) — used for embedding only
__global__ __launch_bounds__(256) void gemm128(
    const float* __restrict__ A,
    const float* __restrict__ W, const float* __restrict__ bias,
    float* __restrict__ out, int n)
{
  __shared__ float Wl[32*128];
  __shared__ float Al[32*32];
  const int tid = threadIdx.x;
  const int row0 = blockIdx.x * 32;
  const int c0 = (tid & 31) * 4;
  const int r0 = (tid >> 5) * 4;
  float acc[4][4] = {};
  const float4* A4 = (const float4*)A;
  const float4* W4 = (const float4*)W;
  for (int kp = 0; kp < 4; ++kp) {
    float4* Wl4 = (float4*)Wl;
    #pragma unroll
    for (int i = 0; i < 4; ++i)
      Wl4[tid + 256*i] = W4[kp*1024 + tid + 256*i];
    {
      int r = tid >> 3, fc = tid & 7;
      int gr = row0 + r;
      float4 v = make_float4(0.f,0.f,0.f,0.f);
      if (gr < n) v = A4[(size_t)gr*32 + kp*8 + fc];
      ((float4*)Al)[tid] = v;
    }
    __syncthreads();
    #pragma unroll
    for (int kq = 0; kq < 8; ++kq) {
      int k0 = kq*4;
      float4 a[4], w[4];
      #pragma unroll
      for (int i=0;i<4;++i) a[i] = *(const float4*)&Al[(r0+i)*32 + k0];
      #pragma unroll
      for (int kk=0;kk<4;++kk) w[kk] = *(const float4*)&Wl[(k0+kk)*128 + c0];
      #pragma unroll
      for (int i=0;i<4;++i){
        acc[i][0] = fmaf(a[i].x,w[0].x, fmaf(a[i].y,w[1].x, fmaf(a[i].z,w[2].x, fmaf(a[i].w,w[3].x, acc[i][0]))));
        acc[i][1] = fmaf(a[i].x,w[0].y, fmaf(a[i].y,w[1].y, fmaf(a[i].z,w[2].y, fmaf(a[i].w,w[3].y, acc[i][1]))));
        acc[i][2] = fmaf(a[i].x,w[0].z, fmaf(a[i].y,w[1].z, fmaf(a[i].z,w[2].z, fmaf(a[i].w,w[3].z, acc[i][2]))));
        acc[i][3] = fmaf(a[i].x,w[0].w, fmaf(a[i].y,w[1].w, fmaf(a[i].z,w[2].w, fmaf(a[i].w,w[3].w, acc[i][3]))));
      }
    }
    __syncthreads();
  }
  float4 bv = *(const float4*)&bias[c0];
  #pragma unroll
  for (int i=0;i<4;++i){
    int gr = row0 + r0 + i;
    if (gr < n){
      float4 o;
      o.x = acc[i][0] + bv.x; o.y = acc[i][1] + bv.y;
      o.z = acc[i][2] + bv.z; o.w = acc[i][3] + bv.w;
      *(float4*)&out[(size_t)gr*FD + c0] = o;
    }
  }
}

// bf16-output GEMM. SCORE: also emit s[row]=dot(A_row,kvec)+kvec[128], add bias.
// SCALE: pre-scale A rows by rowScale (no bias).
template<int SCORE, int SCALE>
__global__ __launch_bounds__(256) void gemm_bf16(
    const float* __restrict__ A, const float* __restrict__ rowScale,
    const float* __restrict__ W, const float* __restrict__ bias,
    const float* __restrict__ kvec, float* __restrict__ sOut,
    u16* __restrict__ out, int n)
{
  __shared__ float Wl[32*128];
  __shared__ float Al[32*32];
  const int tid = threadIdx.x;
  const int row0 = blockIdx.x * 32;
  const int c0 = (tid & 31) * 4;
  const int r0 = (tid >> 5) * 4;
  const int r = tid >> 3, fc = tid & 7;
  const int gr_s = row0 + r;
  float acc[4][4] = {};
  float sacc = 0.f;
  const float4* A4 = (const float4*)A;
  const float4* W4 = (const float4*)W;
  for (int kp = 0; kp < 4; ++kp) {
    float4* Wl4 = (float4*)Wl;
    #pragma unroll
    for (int i = 0; i < 4; ++i)
      Wl4[tid + 256*i] = W4[kp*1024 + tid + 256*i];
    {
      float4 v = make_float4(0.f,0.f,0.f,0.f);
      if (gr_s < n){
        v = A4[(size_t)gr_s*32 + kp*8 + fc];
        if (SCALE){ float s = rowScale[gr_s]; v.x*=s; v.y*=s; v.z*=s; v.w*=s; }
      }
      ((float4*)Al)[tid] = v;
      if (SCORE){
        float4 kv = *(const float4*)&kvec[kp*32 + fc*4];
        sacc += v.x*kv.x + v.y*kv.y + v.z*kv.z + v.w*kv.w;
      }
    }
    __syncthreads();
    #pragma unroll
    for (int kq = 0; kq < 8; ++kq) {
      int k0 = kq*4;
      float4 a[4], w[4];
      #pragma unroll
      for (int i=0;i<4;++i) a[i] = *(const float4*)&Al[(r0+i)*32 + k0];
      #pragma unroll
      for (int kk=0;kk<4;++kk) w[kk] = *(const float4*)&Wl[(k0+kk)*128 + c0];
      #pragma unroll
      for (int i=0;i<4;++i){
        acc[i][0] = fmaf(a[i].x,w[0].x, fmaf(a[i].y,w[1].x, fmaf(a[i].z,w[2].x, fmaf(a[i].w,w[3].x, acc[i][0]))));
        acc[i][1] = fmaf(a[i].x,w[0].y, fmaf(a[i].y,w[1].y, fmaf(a[i].z,w[2].y, fmaf(a[i].w,w[3].y, acc[i][1]))));
        acc[i][2] = fmaf(a[i].x,w[0].z, fmaf(a[i].y,w[1].z, fmaf(a[i].z,w[2].z, fmaf(a[i].w,w[3].z, acc[i][2]))));
        acc[i][3] = fmaf(a[i].x,w[0].w, fmaf(a[i].y,w[1].w, fmaf(a[i].z,w[2].w, fmaf(a[i].w,w[3].w, acc[i][3]))));
      }
    }
    __syncthreads();
  }
  if (SCORE){
    sacc += __shfl_xor(sacc, 1);
    sacc += __shfl_xor(sacc, 2);
    sacc += __shfl_xor(sacc, 4);
    if (fc == 0 && gr_s < n) sOut[gr_s] = sacc + kvec[128];
  }
  float4 bv = make_float4(0.f,0.f,0.f,0.f);
  if (SCORE) bv = *(const float4*)&bias[c0];
  #pragma unroll
  for (int i=0;i<4;++i){
    int gr = row0 + r0 + i;
    if (gr < n){
      ushort4 o;
      o.x = f2bf(acc[i][0] + bv.x); o.y = f2bf(acc[i][1] + bv.y);
      o.z = f2bf(acc[i][2] + bv.z); o.w = f2bf(acc[i][3] + bv.w);
      *(ushort4*)&out[(size_t)gr*FD + c0] = o;
    }
  }
}

// kvec for all 4 attn layers: kvec[j][k] = inv*sum kW[k,:]*qb ; [j][128]=inv*dot(kb,qb)
__global__ void kqv4(const float* __restrict__ ekW, const float* __restrict__ ekb,
                     const float* __restrict__ eqb,
                     const float* __restrict__ dkW, const float* __restrict__ dkb,
                     const float* __restrict__ dqb,
                     float* __restrict__ kv, float inv){
  int j = blockIdx.x;
  const float* kW = (j < 2) ? ekW + j*16384 : dkW + (j-2)*16384;
  const float* kb = (j < 2) ? ekb + j*128   : dkb + (j-2)*128;
  const float* qb = (j < 2) ? eqb + j*128   : dqb + (j-2)*128;
  float* out = kv + j*132;
  int k = threadIdx.x;
  float a = 0.f;
  for (int t = 0; t < 128; ++t) a = fmaf(kW[k*128+t], qb[t], a);
  out[k] = a * inv;
  if (k == 0){
    float c = 0.f;
    for (int t = 0; t < 128; ++t) c = fmaf(kb[t], qb[t], c);
    out[128] = c * inv;
  }
}

// ---------------- batched CSR build ----------------
struct HistA {
  const int* idx[10];
  int* cnt[10];
  int eoff[11];
};
__global__ __launch_bounds__(256) void hist_all(HistA a){
  int e = blockIdx.x*256 + threadIdx.x;
  if (e >= a.eoff[10]) return;
  int j = 0;
  #pragma unroll
  for (int t = 1; t < 10; ++t) if (e >= a.eoff[t]) j = t;
  atomicAdd(&a.cnt[j][a.idx[j][e - a.eoff[j]]], 1);
}

struct ScanA {
  const int* cnt[7];
  int* rowp[7];
  int* fpos[7];
  int n[7];
  int E[7];
  int boff[8];
};
__global__ __launch_bounds__(256) void scanA_all(ScanA a, int* __restrict__ bsums){
  int j = 0;
  #pragma unroll
  for (int t = 1; t < 7; ++t) if ((int)blockIdx.x >= a.boff[t]) j = t;
  int lb = blockIdx.x - a.boff[j];
  const int* cnt = a.cnt[j]; int n = a.n[j];
  __shared__ int sm[256];
  int base = lb*SCAN_CHUNK + threadIdx.x*16;
  int t = 0;
  #pragma unroll
  for (int i = 0; i < 16; ++i){ int idx = base + i; if (idx < n) t += cnt[idx]; }
  sm[threadIdx.x] = t; __syncthreads();
  for (int o = 128; o; o >>= 1){
    if ((int)threadIdx.x < o) sm[threadIdx.x] += sm[threadIdx.x + o];
    __syncthreads();
  }
  if (threadIdx.x == 0) bsums[blockIdx.x] = sm[0];
}
__global__ void scanB_all(ScanA a, int* __restrict__ bsums){
  int j = threadIdx.x;
  if (j < 7){
    int acc = 0;
    for (int i = a.boff[j]; i < a.boff[j+1]; ++i){ int v = bsums[i]; bsums[i] = acc; acc += v; }
    a.rowp[j][a.n[j]] = a.E[j];
  }
}
__global__ __launch_bounds__(256) void scanC_all(ScanA a, const int* __restrict__ bsums){
  int j = 0;
  #pragma unroll
  for (int t = 1; t < 7; ++t) if ((int)blockIdx.x >= a.boff[t]) j = t;
  int lb = blockIdx.x - a.boff[j];
  const int* cnt = a.cnt[j]; int n = a.n[j];
  int* rowp = a.rowp[j]; int* fpos = a.fpos[j];
  __shared__ int sm[256];
  int base = lb*SCAN_CHUNK + threadIdx.x*16;
  int local[16]; int t = 0;
  #pragma unroll
  for (int i = 0; i < 16; ++i){
    int idx = base + i;
    int v = (idx < n) ? cnt[idx] : 0;
    local[i] = v; t += v;
  }
  sm[threadIdx.x] = t; __syncthreads();
  for (int o = 1; o < 256; o <<= 1){
    int v = sm[threadIdx.x];
    int add = ((int)threadIdx.x >= o) ? sm[threadIdx.x - o] : 0;
    __syncthreads();
    sm[threadIdx.x] = v + add;
    __syncthreads();
  }
  int pre = (threadIdx.x ? sm[threadIdx.x - 1] : 0) + bsums[blockIdx.x];
  #pragma unroll
  for (int i = 0; i < 16; ++i){
    int idx = base + i;
    if (idx < n){ rowp[idx] = pre; fpos[idx] = pre; pre += local[i]; }
  }
}
struct FillA {
  const int* src[7]; const int* dst[7];
  int* fpos[7]; int* csr[7];
  int eoff[8];
};
__global__ __launch_bounds__(256) void fill_all(FillA a){
  int e = blockIdx.x*256 + threadIdx.x;
  if (e >= a.eoff[7]) return;
  int j = 0;
  #pragma unroll
  for (int t = 1; t < 7; ++t) if (e >= a.eoff[t]) j = t;
  int le = e - a.eoff[j];
  int d = a.dst[j][le];
  int pos = atomicAdd(&a.fpos[j][d], 1);
  a.csr[j][pos] = a.src[j][le];
}

__global__ void deg2rs(const int* __restrict__ deg, float* __restrict__ rs, int n){
  int i = blockIdx.x*256 + threadIdx.x;
  if (i < n) rs[i] = rsqrtf(fmaxf((float)deg[i], 1.f));
}

// ---------------- gathers ----------------
__global__ __launch_bounds__(256) void attn_gather(
    const int* __restrict__ csr, const int* __restrict__ rowp,
    const float* __restrict__ s, const u16* __restrict__ V,
    float* __restrict__ out, int n)
{
  int wid = threadIdx.x >> 6, lane = threadIdx.x & 63;
  int row = blockIdx.x*4 + wid;
  if (row >= n) return;
  int st = rowp[row], en = rowp[row+1];
  float ax = 0.f, ay = 0.f;
  if (en > st){
    float m = -1e30f;
    for (int e = st + lane; e < en; e += 64) m = fmaxf(m, s[csr[e]]);
    #pragma unroll
    for (int o = 32; o; o >>= 1) m = fmaxf(m, __shfl_xor(m, o));
    const ushort2* V2 = (const ushort2*)V;
    float den = 0.f;
    for (int e = st; e < en; ++e){
      int sn = csr[e];
      float w = expf(s[sn] - m);
      den += w;
      ushort2 v = V2[(size_t)sn*64 + lane];
      ax = fmaf(w, bf2f(v.x), ax);
      ay = fmaf(w, bf2f(v.y), ay);
    }
    float inv = 1.f/den;
    ax *= inv; ay *= inv;
  }
  ((float2*)out)[(size_t)row*64 + lane] = make_float2(ax, ay);
}

// out = rsqrt(max(deg_in,1)) * sum Y[src] + bias
__global__ __launch_bounds__(256) void gcn_gather(
    const int* __restrict__ csr, const int* __restrict__ rowp,
    const u16* __restrict__ Y, const float* __restrict__ bias,
    float* __restrict__ out, int n)
{
  int wid = threadIdx.x >> 6, lane = threadIdx.x & 63;
  int row = blockIdx.x*4 + wid;
  if (row >= n) return;
  int st = rowp[row], en = rowp[row+1];
  float ax = 0.f, ay = 0.f;
  const ushort2* Y2 = (const ushort2*)Y;
  for (int e = st; e < en; ++e){
    int sn = csr[e];
    ushort2 v = Y2[(size_t)sn*64 + lane];
    ax += bf2f(v.x); ay += bf2f(v.y);
  }
  float sc = rsqrtf(fmaxf((float)(en - st), 1.f));
  float2 b2 = ((const float2*)bias)[lane];
  ((float2*)out)[(size_t)row*64 + lane] = make_float2(fmaf(ax, sc, b2.x), fmaf(ay, sc, b2.y));
}

// wave per row: softmax( concat(g,d) @ W[256x5] + b )
__global__ __launch_bounds__(256) void head_k(
    const float* __restrict__ g, const float* __restrict__ dch,
    const float* __restrict__ W, const float* __restrict__ b,
    float* __restrict__ out, int n, int rowOff)
{
  int wid = threadIdx.x >> 6, lane = threadIdx.x & 63;
  int row = blockIdx.x*4 + wid;
  if (row >= n) return;
  const float* gr = g + (size_t)row*FD;
  const float* dr = dch + (size_t)row*FD;
  float x0 = gr[lane], x1 = gr[64+lane], x2 = dr[lane], x3 = dr[64+lane];
  float acc[5];
  #pragma unroll
  for (int o = 0; o < 5; ++o)
    acc[o] = x0*W[lane*5+o] + x1*W[(64+lane)*5+o] + x2*W[(128+lane)*5+o] + x3*W[(192+lane)*5+o];
  #pragma unroll
  for (int o = 0; o < 5; ++o)
    #pragma unroll
    for (int s = 32; s; s >>= 1) acc[o] += __shfl_xor(acc[o], s);
  if (lane == 0){
    float m = -1e30f;
    #pragma unroll
    for (int o = 0; o < 5; ++o){ acc[o] += b[o]; m = fmaxf(m, acc[o]); }
    float sum = 0.f;
    #pragma unroll
    for (int o = 0; o < 5; ++o){ acc[o] = expf(acc[o]-m); sum += acc[o]; }
    float is = 1.0f/sum;
    float* op = out + (size_t)(rowOff+row)*5;
    #pragma unroll
    for (int o = 0; o < 5; ++o) op[o] = acc[o]*is;
  }
}

extern "C" void kernel_launch(void* const* d_in, const int* in_sizes, int n_in,
                              void* d_out, int out_size, void* d_ws, size_t ws_size,
                              hipStream_t stream)
{
  const float* X      = (const float*)d_in[0];
  const float* emb_W  = (const float*)d_in[1];
  const float* emb_b  = (const float*)d_in[2];
  const float* gcn_W  = (const float*)d_in[3];
  const float* gcn_b  = (const float*)d_in[4];
  const float* enc_qb = (const float*)d_in[6];
  const float* enc_kW = (const float*)d_in[7];
  const float* enc_kb = (const float*)d_in[8];
  const float* enc_vW = (const float*)d_in[9];
  const float* enc_vb = (const float*)d_in[10];
  const float* dec_qb = (const float*)d_in[12];
  const float* dec_kW = (const float*)d_in[13];
  const float* dec_kb = (const float*)d_in[14];
  const float* dec_vW = (const float*)d_in[15];
  const float* dec_vb = (const float*)d_in[16];
  const float* head_W = (const float*)d_in[17];
  const float* head_b = (const float*)d_in[18];
  const int* g0s  = (const int*)d_in[19];
  const int* g0d  = (const int*)d_in[20];
  const int* g1s  = (const int*)d_in[21];
  const int* g1d  = (const int*)d_in[22];
  const int* g2s  = (const int*)d_in[23];
  const int* g2d  = (const int*)d_in[24];
  const int* i0s  = (const int*)d_in[25];
  const int* i0d  = (const int*)d_in[26];
  const int* i1s  = (const int*)d_in[27];
  const int* i1d  = (const int*)d_in[28];
  const int* dc0s = (const int*)d_in[29];
  const int* dc0d = (const int*)d_in[30];
  const int* dc1s = (const int*)d_in[31];
  const int* dc1d = (const int*)d_in[32];

  // ---- workspace layout ----
  float* ws = (float*)d_ws;
  float* bh0 = ws;                          // N0*FD f32 : h0, later d0
  float* be1 = bh0 + (size_t)N0*FD;         // N1*FD : e1, later d1
  float* be2 = be1 + (size_t)N1*FD;         // N2*FD : e2
  float* bg0 = be2 + (size_t)N2*FD;         // N0*FD
  float* bg1 = bg0 + (size_t)N0*FD;         // N1*FD
  float* bg2 = bg1 + (size_t)N1*FD;         // N2*FD
  float* sS  = bg2 + (size_t)N2*FD;         // N0 scores
  float* kvec = sS + N0;                    // 4*132
  float* rsO  = kvec + 4*132;               // N0+N1+N2 (g0,g1,g2 out-deg rsqrt)
  u16*  bYB = (u16*)(rsO + (N0+N1+N2));     // N0*FD ushorts (bf16 V/Y table)
  int*  cntBlk = (int*)(bYB + (size_t)N0*FD);   // 287500 (7 dst hists)
  int*  degBlk = cntBlk + (2*N0+3*N1+2*N2);     // 131250 (3 src hists)
  int*  rowpBlk = degBlk + (N0+N1+N2);          // 287507
  int*  fposBlk = rowpBlk + (2*N0+3*N1+2*N2+7); // 287500
  int*  bsums  = fposBlk + (2*N0+3*N1+2*N2);    // 128
  int*  csrBlk = bsums + 128;                   // 2,500,000

  // per-graph n / E (order: g0,g1,g2,i0,i1,d0,d1)
  const int nArr[7] = {N0,N1,N2,N1,N2,N1,N0};
  const int EArr[7] = {1000000,400000,100000,400000,100000,100000,400000};
  int* cntP[7]; int* rowpP[7]; int* fposP[7]; int* csrP[7];
  {
    int co=0, ro=0, fo=0, cs=0;
    for (int j=0;j<7;++j){
      cntP[j]=cntBlk+co; rowpP[j]=rowpBlk+ro; fposP[j]=fposBlk+fo; csrP[j]=csrBlk+cs;
      co+=nArr[j]; ro+=nArr[j]+1; fo+=nArr[j]; cs+=EArr[j];
    }
  }
  const int* srcP[7] = {g0s,g1s,g2s,i0s,i1s,dc0s,dc1s};
  const int* dstP[7] = {g0d,g1d,g2d,i0d,i1d,dc0d,dc1d};

  const float invScale = 0.17677669529663687f; // 1/sqrt(32)
  float* out = (float*)d_out;
  float* rs0 = rsO; float* rs1 = rsO + N0; float* rs2 = rsO + N0 + N1;

  // ---- batched prep ----
  const int CNT_TOT = (2*N0+3*N1+2*N2) + (N0+N1+N2); // cnt + deg contiguous
  zero_int<<<ceildiv(CNT_TOT,256),256,0,stream>>>(cntBlk, CNT_TOT);

  HistA ha;
  {
    int off=0;
    for (int j=0;j<7;++j){ ha.idx[j]=dstP[j]; ha.cnt[j]=cntP[j]; ha.eoff[j]=off; off+=EArr[j]; }
    const int* sidx[3] = {g0s,g1s,g2s};
    int* scnt[3] = {degBlk, degBlk+N0, degBlk+N0+N1};
    const int sE[3] = {1000000,400000,100000};
    for (int j=0;j<3;++j){ ha.idx[7+j]=sidx[j]; ha.cnt[7+j]=scnt[j]; ha.eoff[7+j]=off; off+=sE[j]; }
    ha.eoff[10]=off; // 4,000,000
  }
  hist_all<<<ceildiv(4000000,256),256,0,stream>>>(ha);

  ScanA sa;
  {
    int bo=0;
    for (int j=0;j<7;++j){
      sa.cnt[j]=cntP[j]; sa.rowp[j]=rowpP[j]; sa.fpos[j]=fposP[j];
      sa.n[j]=nArr[j]; sa.E[j]=EArr[j];
      sa.boff[j]=bo; bo+=ceildiv(nArr[j],SCAN_CHUNK);
    }
    sa.boff[7]=bo; // 75
  }
  scanA_all<<<sa.boff[7],256,0,stream>>>(sa, bsums);
  scanB_all<<<1,64,0,stream>>>(sa, bsums);
  scanC_all<<<sa.boff[7],256,0,stream>>>(sa, bsums);

  FillA fa;
  {
    int off=0;
    for (int j=0;j<7;++j){
      fa.src[j]=srcP[j]; fa.dst[j]=dstP[j]; fa.fpos[j]=fposP[j]; fa.csr[j]=csrP[j];
      fa.eoff[j]=off; off+=EArr[j];
    }
    fa.eoff[7]=off; // 2,500,000
  }
  fill_all<<<ceildiv(2500000,256),256,0,stream>>>(fa);

  deg2rs<<<ceildiv(N0+N1+N2,256),256,0,stream>>>(degBlk, rsO, N0+N1+N2);
  kqv4<<<4,128,0,stream>>>(enc_kW, enc_kb, enc_qb, dec_kW, dec_kb, dec_qb, kvec, invScale);

  // ---- pipeline ----
  // 1. h0 = X @ emb_W + emb_b  (f32)
  gemm128<<<ceildiv(N0,32),256,0,stream>>>(X, emb_W, emb_b, bh0, N0);

  // 2. encoder attn 0: V=h0@vW+vb (bf16) + scores; gather into e1
  gemm_bf16<1,0><<<ceildiv(N0,32),256,0,stream>>>(bh0, nullptr, enc_vW, enc_vb, kvec, sS, bYB, N0);
  attn_gather<<<ceildiv(N1,4),256,0,stream>>>(csrP[3], rowpP[3], sS, bYB, be1, N1);
  // encoder attn 1
  gemm_bf16<1,0><<<ceildiv(N1,32),256,0,stream>>>(be1, nullptr, enc_vW+16384, enc_vb+128, kvec+132, sS, bYB, N1);
  attn_gather<<<ceildiv(N2,4),256,0,stream>>>(csrP[4], rowpP[4], sS, bYB, be2, N2);

  // 3. GCNs: Y=(rsO*X)@W (bf16), out = rsIn*sum Y[src] + b
  gemm_bf16<0,1><<<ceildiv(N0,32),256,0,stream>>>(bh0, rs0, gcn_W, nullptr, nullptr, nullptr, bYB, N0);
  gcn_gather<<<ceildiv(N0,4),256,0,stream>>>(csrP[0], rowpP[0], bYB, gcn_b, bg0, N0);
  gemm_bf16<0,1><<<ceildiv(N1,32),256,0,stream>>>(be1, rs1, gcn_W+16384, nullptr, nullptr, nullptr, bYB, N1);
  gcn_gather<<<ceildiv(N1,4),256,0,stream>>>(csrP[1], rowpP[1], bYB, gcn_b+128, bg1, N1);
  gemm_bf16<0,1><<<ceildiv(N2,32),256,0,stream>>>(be2, rs2, gcn_W+32768, nullptr, nullptr, nullptr, bYB, N2);
  gcn_gather<<<ceildiv(N2,4),256,0,stream>>>(csrP[2], rowpP[2], bYB, gcn_b+256, bg2, N2);

  // 4. decoder attn 0 (src bg2 -> d1 into be1)
  gemm_bf16<1,0><<<ceildiv(N2,32),256,0,stream>>>(bg2, nullptr, dec_vW, dec_vb, kvec+264, sS, bYB, N2);
  attn_gather<<<ceildiv(N1,4),256,0,stream>>>(csrP[5], rowpP[5], sS, bYB, be1, N1);
  // decoder attn 1 (src d1 -> d0 into bh0)
  gemm_bf16<1,0><<<ceildiv(N1,32),256,0,stream>>>(be1, nullptr, dec_vW+16384, dec_vb+128, kvec+396, sS, bYB, N1);
  attn_gather<<<ceildiv(N0,4),256,0,stream>>>(csrP[6], rowpP[6], sS, bYB, bh0, N0);

  // 5. heads
  head_k<<<ceildiv(N0,4),256,0,stream>>>(bg0, bh0, head_W,      head_b,    out, N0, 0);
  head_k<<<ceildiv(N1,4),256,0,stream>>>(bg1, be1, head_W+1280, head_b+5,  out, N1, N0);
  head_k<<<ceildiv(N2,4),256,0,stream>>>(bg2, bg2, head_W+2560, head_b+10, out, N2, N0+N1);
}

// Round 5
// 852.904 us; speedup vs baseline: 5.8399x; 1.1097x over previous
//
#include <hip/hip_runtime.h>
#include <math.h>

#define N0 100000
#define N1 25000
#define N2 6250
#define FD 128
#define SCAN_CHUNK 4096

typedef unsigned short u16;
typedef unsigned int u32;

static inline int ceildiv(int a, int b){ return (a + b - 1)/b; }

__device__ __forceinline__ u16 f2bf(float f){
  u32 u = __float_as_uint(f);
  u += 0x7fffu + ((u >> 16) & 1u);
  return (u16)(u >> 16);
}
__device__ __forceinline__ float bf2f(u16 h){
  return __uint_as_float(((u32)h) << 16);
}

// ================= device bodies =================

__device__ __forceinline__ void mm_inner(const float* Al, const float* Wl, int r0, int c0, float acc[4][4]){
  #pragma unroll
  for (int kq = 0; kq < 8; ++kq) {
    int k0 = kq*4;
    float4 a[4], w[4];
    #pragma unroll
    for (int i=0;i<4;++i) a[i] = *(const float4*)&Al[(r0+i)*32 + k0];
    #pragma unroll
    for (int kk=0;kk<4;++kk) w[kk] = *(const float4*)&Wl[(k0+kk)*128 + c0];
    #pragma unroll
    for (int i=0;i<4;++i){
      acc[i][0] = fmaf(a[i].x,w[0].x, fmaf(a[i].y,w[1].x, fmaf(a[i].z,w[2].x, fmaf(a[i].w,w[3].x, acc[i][0]))));
      acc[i][1] = fmaf(a[i].x,w[0].y, fmaf(a[i].y,w[1].y, fmaf(a[i].z,w[2].y, fmaf(a[i].w,w[3].y, acc[i][1]))));
      acc[i][2] = fmaf(a[i].x,w[0].z, fmaf(a[i].y,w[1].z, fmaf(a[i].z,w[2].z, fmaf(a[i].w,w[3].z, acc[i][2]))));
      acc[i][3] = fmaf(a[i].x,w[0].w, fmaf(a[i].y,w[1].w, fmaf(a[i].z,w[2].w, fmaf(a[i].w,w[3].w, acc[i][3]))));
    }
  }
}

__device__ __forceinline__ void dev_gemm_f32(float* Wl, float* Al, int bid,
    const float* __restrict__ A, const float* __restrict__ W, const float* __restrict__ bias,
    float* __restrict__ out, int n)
{
  const int tid = threadIdx.x;
  const int row0 = bid * 32;
  const int c0 = (tid & 31) * 4, r0 = (tid >> 5) * 4;
  float acc[4][4] = {};
  const float4* A4 = (const float4*)A;
  const float4* W4 = (const float4*)W;
  for (int kp = 0; kp < 4; ++kp) {
    float4* Wl4 = (float4*)Wl;
    #pragma unroll
    for (int i = 0; i < 4; ++i) Wl4[tid + 256*i] = W4[kp*1024 + tid + 256*i];
    { int r = tid >> 3, fc = tid & 7; int gr = row0 + r;
      float4 v = make_float4(0.f,0.f,0.f,0.f);
      if (gr < n) v = A4[(size_t)gr*32 + kp*8 + fc];
      ((float4*)Al)[tid] = v; }
    __syncthreads();
    mm_inner(Al, Wl, r0, c0, acc);
    __syncthreads();
  }
  float4 bv = *(const float4*)&bias[c0];
  #pragma unroll
  for (int i=0;i<4;++i){
    int gr = row0 + r0 + i;
    if (gr < n){
      float4 o;
      o.x = acc[i][0]+bv.x; o.y = acc[i][1]+bv.y; o.z = acc[i][2]+bv.z; o.w = acc[i][3]+bv.w;
      *(float4*)&out[(size_t)gr*FD + c0] = o;
    }
  }
}

// SCORE: emit s[row]=dot(A_row,kvec)+kvec[128], add bias to output.
// SCALE: pre-scale A rows by rowScale (no bias).
template<int SCORE, int SCALE>
__device__ __forceinline__ void dev_gemm_bf16(float* Wl, float* Al, int bid,
    const float* __restrict__ A, const float* __restrict__ rowScale,
    const float* __restrict__ W, const float* __restrict__ bias,
    const float* __restrict__ kvec, float* __restrict__ sOut,
    u16* __restrict__ out, int n)
{
  const int tid = threadIdx.x;
  const int row0 = bid * 32;
  const int c0 = (tid & 31) * 4, r0 = (tid >> 5) * 4;
  const int r = tid >> 3, fc = tid & 7;
  const int gr_s = row0 + r;
  float acc[4][4] = {};
  float sacc = 0.f;
  const float4* A4 = (const float4*)A;
  const float4* W4 = (const float4*)W;
  for (int kp = 0; kp < 4; ++kp) {
    float4* Wl4 = (float4*)Wl;
    #pragma unroll
    for (int i = 0; i < 4; ++i) Wl4[tid + 256*i] = W4[kp*1024 + tid + 256*i];
    {
      float4 v = make_float4(0.f,0.f,0.f,0.f);
      if (gr_s < n){
        v = A4[(size_t)gr_s*32 + kp*8 + fc];
        if (SCALE){ float s = rowScale[gr_s]; v.x*=s; v.y*=s; v.z*=s; v.w*=s; }
      }
      ((float4*)Al)[tid] = v;
      if (SCORE){
        float4 kv = *(const float4*)&kvec[kp*32 + fc*4];
        sacc += v.x*kv.x + v.y*kv.y + v.z*kv.z + v.w*kv.w;
      }
    }
    __syncthreads();
    mm_inner(Al, Wl, r0, c0, acc);
    __syncthreads();
  }
  if (SCORE){
    sacc += __shfl_xor(sacc, 1);
    sacc += __shfl_xor(sacc, 2);
    sacc += __shfl_xor(sacc, 4);
    if (fc == 0 && gr_s < n) sOut[gr_s] = sacc + kvec[128];
  }
  float4 bv = make_float4(0.f,0.f,0.f,0.f);
  if (SCORE) bv = *(const float4*)&bias[c0];
  #pragma unroll
  for (int i=0;i<4;++i){
    int gr = row0 + r0 + i;
    if (gr < n){
      ushort4 o;
      o.x = f2bf(acc[i][0]+bv.x); o.y = f2bf(acc[i][1]+bv.y);
      o.z = f2bf(acc[i][2]+bv.z); o.w = f2bf(acc[i][3]+bv.w);
      *(ushort4*)&out[(size_t)gr*FD + c0] = o;
    }
  }
}

struct HistA {
  const int* idx[10];
  int* cnt[10];
  int eoff[11];
};
__device__ __forceinline__ void dev_hist(const HistA& a, int bid){
  int e = bid*256 + threadIdx.x;
  if (e >= a.eoff[10]) return;
  int j = 0;
  #pragma unroll
  for (int t = 1; t < 10; ++t) if (e >= a.eoff[t]) j = t;
  atomicAdd(&a.cnt[j][a.idx[j][e - a.eoff[j]]], 1);
}

struct FillA {
  const int* src[7]; const int* dst[7];
  int* fpos[7]; int* csr[7];
  int eoff[8];
};
__device__ __forceinline__ void dev_fill(const FillA& a, int bid){
  int e = bid*256 + threadIdx.x;
  if (e >= a.eoff[7]) return;
  int j = 0;
  #pragma unroll
  for (int t = 1; t < 7; ++t) if (e >= a.eoff[t]) j = t;
  int le = e - a.eoff[j];
  int d = a.dst[j][le];
  int pos = atomicAdd(&a.fpos[j][d], 1);
  a.csr[j][pos] = a.src[j][le];
}

__device__ __forceinline__ void dev_deg2rs(int bid, const int* __restrict__ deg, float* __restrict__ rs, int n){
  int i = bid*256 + threadIdx.x;
  if (i < n) rs[i] = rsqrtf(fmaxf((float)deg[i], 1.f));
}

__device__ __forceinline__ void dev_attn_gather(int bid,
    const int* __restrict__ csr, const int* __restrict__ rowp,
    const float* __restrict__ s, const u16* __restrict__ V,
    float* __restrict__ out, int n)
{
  int wid = threadIdx.x >> 6, lane = threadIdx.x & 63;
  int row = bid*4 + wid;
  if (row >= n) return;
  int st = rowp[row], en = rowp[row+1];
  float ax = 0.f, ay = 0.f;
  if (en > st){
    float m = -1e30f;
    for (int e = st + lane; e < en; e += 64) m = fmaxf(m, s[csr[e]]);
    #pragma unroll
    for (int o = 32; o; o >>= 1) m = fmaxf(m, __shfl_xor(m, o));
    const ushort2* V2 = (const ushort2*)V;
    float den = 0.f;
    for (int e = st; e < en; ++e){
      int sn = csr[e];
      float w = expf(s[sn] - m);
      den += w;
      ushort2 v = V2[(size_t)sn*64 + lane];
      ax = fmaf(w, bf2f(v.x), ax);
      ay = fmaf(w, bf2f(v.y), ay);
    }
    float inv = 1.f/den;
    ax *= inv; ay *= inv;
  }
  ((float2*)out)[(size_t)row*64 + lane] = make_float2(ax, ay);
}

// out = rsqrt(max(deg_in,1)) * sum Y[src] + bias; OB16: bf16 output
template<int OB16>
__device__ __forceinline__ void dev_gcn_gather(int bid,
    const int* __restrict__ csr, const int* __restrict__ rowp,
    const u16* __restrict__ Y, const float* __restrict__ bias,
    void* __restrict__ out, int n)
{
  int wid = threadIdx.x >> 6, lane = threadIdx.x & 63;
  int row = bid*4 + wid;
  if (row >= n) return;
  int st = rowp[row], en = rowp[row+1];
  float ax = 0.f, ay = 0.f;
  const ushort2* Y2 = (const ushort2*)Y;
  for (int e = st; e < en; ++e){
    int sn = csr[e];
    ushort2 v = Y2[(size_t)sn*64 + lane];
    ax += bf2f(v.x); ay += bf2f(v.y);
  }
  float sc = rsqrtf(fmaxf((float)(en - st), 1.f));
  float2 b2 = ((const float2*)bias)[lane];
  float ox = fmaf(ax, sc, b2.x), oy = fmaf(ay, sc, b2.y);
  if (OB16){
    ushort2 o; o.x = f2bf(ox); o.y = f2bf(oy);
    ((ushort2*)out)[(size_t)row*64 + lane] = o;
  } else {
    ((float2*)out)[(size_t)row*64 + lane] = make_float2(ox, oy);
  }
}

// softmax( concat(g,d) @ W[256x5] + b ); GB16/DB16 select bf16 inputs
template<int GB16, int DB16>
__device__ __forceinline__ void dev_head(int bid, const void* __restrict__ g, const void* __restrict__ dch,
    const float* __restrict__ W, const float* __restrict__ b,
    float* __restrict__ out, int n, int rowOff)
{
  int wid = threadIdx.x >> 6, lane = threadIdx.x & 63;
  int row = bid*4 + wid;
  if (row >= n) return;
  float x0, x1, x2, x3;
  if (GB16){ const u16* gr = (const u16*)g + (size_t)row*FD; x0 = bf2f(gr[lane]); x1 = bf2f(gr[64+lane]); }
  else     { const float* gr = (const float*)g + (size_t)row*FD; x0 = gr[lane]; x1 = gr[64+lane]; }
  if (DB16){ const u16* dr = (const u16*)dch + (size_t)row*FD; x2 = bf2f(dr[lane]); x3 = bf2f(dr[64+lane]); }
  else     { const float* dr = (const float*)dch + (size_t)row*FD; x2 = dr[lane]; x3 = dr[64+lane]; }
  float acc[5];
  #pragma unroll
  for (int o = 0; o < 5; ++o)
    acc[o] = x0*W[lane*5+o] + x1*W[(64+lane)*5+o] + x2*W[(128+lane)*5+o] + x3*W[(192+lane)*5+o];
  #pragma unroll
  for (int o = 0; o < 5; ++o)
    #pragma unroll
    for (int s = 32; s; s >>= 1) acc[o] += __shfl_xor(acc[o], s);
  if (lane == 0){
    float m = -1e30f;
    #pragma unroll
    for (int o = 0; o < 5; ++o){ acc[o] += b[o]; m = fmaxf(m, acc[o]); }
    float sum = 0.f;
    #pragma unroll
    for (int o = 0; o < 5; ++o){ acc[o] = expf(acc[o]-m); sum += acc[o]; }
    float is = 1.0f/sum;
    float* op = out + (size_t)(rowOff+row)*5;
    #pragma unroll
    for (int o = 0; o < 5; ++o) op[o] = acc[o]*is;
  }
}

// ================= scan structs (as r4) =================
struct ScanA {
  const int* cnt[7];
  int* rowp[7];
  int* fpos[7];
  int n[7];
  int E[7];
  int boff[8];
};
__device__ __forceinline__ void dev_scanA(const ScanA& a, int bid, int* __restrict__ bsums){
  int j = 0;
  #pragma unroll
  for (int t = 1; t < 7; ++t) if (bid >= a.boff[t]) j = t;
  int lb = bid - a.boff[j];
  const int* cnt = a.cnt[j]; int n = a.n[j];
  __shared__ int sm[256];
  int base = lb*SCAN_CHUNK + threadIdx.x*16;
  int t = 0;
  #pragma unroll
  for (int i = 0; i < 16; ++i){ int idx = base + i; if (idx < n) t += cnt[idx]; }
  sm[threadIdx.x] = t; __syncthreads();
  for (int o = 128; o; o >>= 1){
    if ((int)threadIdx.x < o) sm[threadIdx.x] += sm[threadIdx.x + o];
    __syncthreads();
  }
  if (threadIdx.x == 0) bsums[bid] = sm[0];
}

__global__ void k_scanB(ScanA a, int* __restrict__ bsums){
  int j = threadIdx.x;
  if (j < 7){
    int acc = 0;
    for (int i = a.boff[j]; i < a.boff[j+1]; ++i){ int v = bsums[i]; bsums[i] = acc; acc += v; }
    a.rowp[j][a.n[j]] = a.E[j];
  }
}

__global__ __launch_bounds__(256) void k_scanC(ScanA a, const int* __restrict__ bsums){
  int bid = blockIdx.x;
  int j = 0;
  #pragma unroll
  for (int t = 1; t < 7; ++t) if (bid >= a.boff[t]) j = t;
  int lb = bid - a.boff[j];
  const int* cnt = a.cnt[j]; int n = a.n[j];
  int* rowp = a.rowp[j]; int* fpos = a.fpos[j];
  __shared__ int sm[256];
  int base = lb*SCAN_CHUNK + threadIdx.x*16;
  int local[16]; int t = 0;
  #pragma unroll
  for (int i = 0; i < 16; ++i){
    int idx = base + i;
    int v = (idx < n) ? cnt[idx] : 0;
    local[i] = v; t += v;
  }
  sm[threadIdx.x] = t; __syncthreads();
  for (int o = 1; o < 256; o <<= 1){
    int v = sm[threadIdx.x];
    int add = ((int)threadIdx.x >= o) ? sm[threadIdx.x - o] : 0;
    __syncthreads();
    sm[threadIdx.x] = v + add;
    __syncthreads();
  }
  int pre = (threadIdx.x ? sm[threadIdx.x - 1] : 0) + bsums[bid];
  #pragma unroll
  for (int i = 0; i < 16; ++i){
    int idx = base + i;
    if (idx < n){ rowp[idx] = pre; fpos[idx] = pre; pre += local[i]; }
  }
}

// ================= merged kernels =================

// K1: zero counters ∥ kvec precompute (4 blocks)
__global__ __launch_bounds__(256) void k1_zero_kqv(int* __restrict__ cntBlk, int ntot,
    const float* __restrict__ ekW, const float* __restrict__ ekb, const float* __restrict__ eqb,
    const float* __restrict__ dkW, const float* __restrict__ dkb, const float* __restrict__ dqb,
    float* __restrict__ kv, float inv)
{
  int bid = blockIdx.x;
  if (bid < 4){
    if (threadIdx.x < 128){
      int j = bid;
      const float* kW = (j < 2) ? ekW + j*16384 : dkW + (j-2)*16384;
      const float* kb = (j < 2) ? ekb + j*128   : dkb + (j-2)*128;
      const float* qb = (j < 2) ? eqb + j*128   : dqb + (j-2)*128;
      float* o = kv + j*132;
      int k = threadIdx.x;
      float a = 0.f;
      for (int t = 0; t < 128; ++t) a = fmaf(kW[k*128+t], qb[t], a);
      o[k] = a * inv;
      if (k == 0){
        float c = 0.f;
        for (int t = 0; t < 128; ++t) c = fmaf(kb[t], qb[t], c);
        o[128] = c * inv;
      }
    }
  } else {
    int i = (bid-4)*256 + threadIdx.x;
    if (i < ntot) cntBlk[i] = 0;
  }
}

// K2: gemm_f32 (h0) ∥ hist
__global__ __launch_bounds__(256) void k2_gemm_hist(HistA ha,
    const float* __restrict__ X, const float* __restrict__ W, const float* __restrict__ b,
    float* __restrict__ bh0, int ngemm)
{
  __shared__ float sm[32*128 + 32*32];
  int bid = blockIdx.x;
  if (bid < ngemm) dev_gemm_f32(sm, sm + 4096, bid, X, W, b, bh0, N0);
  else dev_hist(ha, bid - ngemm);
}

// K3: scanA ∥ deg2rs
__global__ __launch_bounds__(256) void k3_scanA_deg(ScanA sa, int* __restrict__ bsums,
    const int* __restrict__ deg, float* __restrict__ rs, int nA, int ndeg)
{
  int bid = blockIdx.x;
  if (bid < nA) dev_scanA(sa, bid, bsums);
  else dev_deg2rs(bid - nA, deg, rs, ndeg);
}

// K6: enc0 V+score gemm ∥ gcn0 Y gemm ∥ fill
__global__ __launch_bounds__(256) void k6_gemms_fill(FillA fa,
    const float* __restrict__ bh0,
    const float* __restrict__ evW, const float* __restrict__ evb,
    const float* __restrict__ kvec, float* __restrict__ sS, u16* __restrict__ bV,
    const float* __restrict__ rs0, const float* __restrict__ gW, u16* __restrict__ bY0,
    int g1, int g2)
{
  __shared__ float sm[32*128 + 32*32];
  int bid = blockIdx.x;
  if (bid < g1)      dev_gemm_bf16<1,0>(sm, sm+4096, bid,      bh0, nullptr, evW, evb, kvec, sS, bV, N0);
  else if (bid < g2) dev_gemm_bf16<0,1>(sm, sm+4096, bid - g1, bh0, rs0, gW, nullptr, nullptr, nullptr, bY0, N0);
  else dev_fill(fa, bid - g2);
}

// K7: attn_gather(i0) ∥ gcn_gather(g0, bf16 out)
__global__ __launch_bounds__(256) void k7_gathers(
    const int* __restrict__ csrA, const int* __restrict__ rowpA,
    const float* __restrict__ sS, const u16* __restrict__ bV, float* __restrict__ be1,
    const int* __restrict__ csrG, const int* __restrict__ rowpG,
    const u16* __restrict__ bY0, const float* __restrict__ gb, u16* __restrict__ bg0, int na)
{
  int bid = blockIdx.x;
  if (bid < na) dev_attn_gather(bid, csrA, rowpA, sS, bV, be1, N1);
  else dev_gcn_gather<1>(bid - na, csrG, rowpG, bY0, gb, bg0, N0);
}

// plain wrappers
__global__ __launch_bounds__(256) void k_gemm_score(
    const float* __restrict__ A, const float* __restrict__ vW, const float* __restrict__ vb,
    const float* __restrict__ kvec, float* __restrict__ sS, u16* __restrict__ out, int n)
{
  __shared__ float sm[32*128 + 32*32];
  dev_gemm_bf16<1,0>(sm, sm+4096, blockIdx.x, A, nullptr, vW, vb, kvec, sS, out, n);
}

__global__ __launch_bounds__(256) void k_attn_gather(
    const int* __restrict__ csr, const int* __restrict__ rowp,
    const float* __restrict__ s, const u16* __restrict__ V, float* __restrict__ out, int n)
{
  dev_attn_gather(blockIdx.x, csr, rowp, s, V, out, n);
}

// K10: Y-gemm for scale1 ∥ scale2
__global__ __launch_bounds__(256) void k10_ygemm(
    const float* __restrict__ be1, const float* __restrict__ rs1, const float* __restrict__ W1, u16* __restrict__ bY1,
    const float* __restrict__ be2, const float* __restrict__ rs2, const float* __restrict__ W2, u16* __restrict__ bY2,
    int ga)
{
  __shared__ float sm[32*128 + 32*32];
  int bid = blockIdx.x;
  if (bid < ga) dev_gemm_bf16<0,1>(sm, sm+4096, bid, be1, rs1, W1, nullptr, nullptr, nullptr, bY1, N1);
  else          dev_gemm_bf16<0,1>(sm, sm+4096, bid - ga, be2, rs2, W2, nullptr, nullptr, nullptr, bY2, N2);
}

// K11: gcn_gather(g1, bf16) ∥ gcn_gather(g2, f32)
__global__ __launch_bounds__(256) void k11_ggathers(
    const int* __restrict__ csr1, const int* __restrict__ rowp1, const u16* __restrict__ bY1,
    const float* __restrict__ b1, u16* __restrict__ bg1,
    const int* __restrict__ csr2, const int* __restrict__ rowp2, const u16* __restrict__ bY2,
    const float* __restrict__ b2, float* __restrict__ bg2, int na)
{
  int bid = blockIdx.x;
  if (bid < na) dev_gcn_gather<1>(bid, csr1, rowp1, bY1, b1, bg1, N1);
  else          dev_gcn_gather<0>(bid - na, csr2, rowp2, bY2, b2, bg2, N2);
}

// K12: dec0 gemm (from bg2) ∥ head2
__global__ __launch_bounds__(256) void k12_dec0_head2(
    const float* __restrict__ bg2, const float* __restrict__ vW, const float* __restrict__ vb,
    const float* __restrict__ kvec, float* __restrict__ sS, u16* __restrict__ bV,
    const float* __restrict__ hW, const float* __restrict__ hb, float* __restrict__ out, int ngemm)
{
  __shared__ float sm[32*128 + 32*32];
  int bid = blockIdx.x;
  if (bid < ngemm) dev_gemm_bf16<1,0>(sm, sm+4096, bid, bg2, nullptr, vW, vb, kvec, sS, bV, N2);
  else dev_head<0,0>(bid - ngemm, bg2, bg2, hW, hb, out, N2, N0+N1);
}

// K14: dec1 gemm (from be1) ∥ head1
__global__ __launch_bounds__(256) void k14_dec1_head1(
    const float* __restrict__ be1, const float* __restrict__ vW, const float* __restrict__ vb,
    const float* __restrict__ kvec, float* __restrict__ sS, u16* __restrict__ bV,
    const u16* __restrict__ bg1, const float* __restrict__ hW, const float* __restrict__ hb,
    float* __restrict__ out, int ngemm)
{
  __shared__ float sm[32*128 + 32*32];
  int bid = blockIdx.x;
  if (bid < ngemm) dev_gemm_bf16<1,0>(sm, sm+4096, bid, be1, nullptr, vW, vb, kvec, sS, bV, N1);
  else dev_head<1,0>(bid - ngemm, bg1, be1, hW, hb, out, N1, N0);
}

// K16: head0
__global__ __launch_bounds__(256) void k16_head0(
    const u16* __restrict__ bg0, const float* __restrict__ bh0,
    const float* __restrict__ hW, const float* __restrict__ hb, float* __restrict__ out)
{
  dev_head<1,0>(blockIdx.x, bg0, bh0, hW, hb, out, N0, 0);
}

// ================= host =================
extern "C" void kernel_launch(void* const* d_in, const int* in_sizes, int n_in,
                              void* d_out, int out_size, void* d_ws, size_t ws_size,
                              hipStream_t stream)
{
  const float* X      = (const float*)d_in[0];
  const float* emb_W  = (const float*)d_in[1];
  const float* emb_b  = (const float*)d_in[2];
  const float* gcn_W  = (const float*)d_in[3];
  const float* gcn_b  = (const float*)d_in[4];
  const float* enc_qb = (const float*)d_in[6];
  const float* enc_kW = (const float*)d_in[7];
  const float* enc_kb = (const float*)d_in[8];
  const float* enc_vW = (const float*)d_in[9];
  const float* enc_vb = (const float*)d_in[10];
  const float* dec_qb = (const float*)d_in[12];
  const float* dec_kW = (const float*)d_in[13];
  const float* dec_kb = (const float*)d_in[14];
  const float* dec_vW = (const float*)d_in[15];
  const float* dec_vb = (const float*)d_in[16];
  const float* head_W = (const float*)d_in[17];
  const float* head_b = (const float*)d_in[18];
  const int* g0s  = (const int*)d_in[19];
  const int* g0d  = (const int*)d_in[20];
  const int* g1s  = (const int*)d_in[21];
  const int* g1d  = (const int*)d_in[22];
  const int* g2s  = (const int*)d_in[23];
  const int* g2d  = (const int*)d_in[24];
  const int* i0s  = (const int*)d_in[25];
  const int* i0d  = (const int*)d_in[26];
  const int* i1s  = (const int*)d_in[27];
  const int* i1d  = (const int*)d_in[28];
  const int* dc0s = (const int*)d_in[29];
  const int* dc0d = (const int*)d_in[30];
  const int* dc1s = (const int*)d_in[31];
  const int* dc1d = (const int*)d_in[32];

  // ---- workspace layout ----
  float* ws = (float*)d_ws;
  float* bh0 = ws;                          // N0*FD f32 : h0, later d0
  float* be1 = bh0 + (size_t)N0*FD;         // N1*FD f32 : e1, later d1
  float* be2 = be1 + (size_t)N1*FD;         // N2*FD f32 : e2
  float* bg2 = be2 + (size_t)N2*FD;         // N2*FD f32 : gcn2 out
  float* sS  = bg2 + (size_t)N2*FD;         // N0 scores
  float* kvec = sS + N0;                    // 4*132
  float* rsO  = kvec + 4*132;               // N0+N1+N2
  u16*  bg0 = (u16*)(rsO + (N0+N1+N2));     // N0*FD u16 : gcn0 out (bf16)
  u16*  bg1 = bg0 + (size_t)N0*FD;          // N1*FD u16
  u16*  bV  = bg1 + (size_t)N1*FD;          // N0*FD u16 : V tables (time-shared)
  u16*  bY0 = bV  + (size_t)N0*FD;          // N0*FD u16 : gcn0 Y
  u16*  bY1 = bV + 4000000;                 // alias into bV tail (dead zone when used)
  u16*  bY2 = bV + 8000000;
  int*  cntBlk = (int*)(bY0 + (size_t)N0*FD);   // 287500
  int*  degBlk = cntBlk + (2*N0+3*N1+2*N2);     // 131250
  int*  rowpBlk = degBlk + (N0+N1+N2);          // 287507
  int*  fposBlk = rowpBlk + (2*N0+3*N1+2*N2+7); // 287500
  int*  bsums  = fposBlk + (2*N0+3*N1+2*N2);    // 128
  int*  csrBlk = bsums + 128;                   // 2,500,000

  const int nArr[7] = {N0,N1,N2,N1,N2,N1,N0};
  const int EArr[7] = {1000000,400000,100000,400000,100000,100000,400000};
  int* cntP[7]; int* rowpP[7]; int* fposP[7]; int* csrP[7];
  {
    int co=0, ro=0, fo=0, cs=0;
    for (int j=0;j<7;++j){
      cntP[j]=cntBlk+co; rowpP[j]=rowpBlk+ro; fposP[j]=fposBlk+fo; csrP[j]=csrBlk+cs;
      co+=nArr[j]; ro+=nArr[j]+1; fo+=nArr[j]; cs+=EArr[j];
    }
  }
  const int* srcP[7] = {g0s,g1s,g2s,i0s,i1s,dc0s,dc1s};
  const int* dstP[7] = {g0d,g1d,g2d,i0d,i1d,dc0d,dc1d};

  const float invScale = 0.17677669529663687f; // 1/sqrt(32)
  float* out = (float*)d_out;
  float* rs0 = rsO; float* rs1 = rsO + N0; float* rs2 = rsO + N0 + N1;

  HistA ha;
  {
    int off=0;
    for (int j=0;j<7;++j){ ha.idx[j]=dstP[j]; ha.cnt[j]=cntP[j]; ha.eoff[j]=off; off+=EArr[j]; }
    const int* sidx[3] = {g0s,g1s,g2s};
    int* scnt[3] = {degBlk, degBlk+N0, degBlk+N0+N1};
    const int sE[3] = {1000000,400000,100000};
    for (int j=0;j<3;++j){ ha.idx[7+j]=sidx[j]; ha.cnt[7+j]=scnt[j]; ha.eoff[7+j]=off; off+=sE[j]; }
    ha.eoff[10]=off; // 4,000,000
  }
  ScanA sa;
  {
    int bo=0;
    for (int j=0;j<7;++j){
      sa.cnt[j]=cntP[j]; sa.rowp[j]=rowpP[j]; sa.fpos[j]=fposP[j];
      sa.n[j]=nArr[j]; sa.E[j]=EArr[j];
      sa.boff[j]=bo; bo+=ceildiv(nArr[j],SCAN_CHUNK);
    }
    sa.boff[7]=bo; // 75
  }
  FillA fa;
  {
    int off=0;
    for (int j=0;j<7;++j){
      fa.src[j]=srcP[j]; fa.dst[j]=dstP[j]; fa.fpos[j]=fposP[j]; fa.csr[j]=csrP[j];
      fa.eoff[j]=off; off+=EArr[j];
    }
    fa.eoff[7]=off; // 2,500,000
  }

  const int CNT_TOT = (2*N0+3*N1+2*N2) + (N0+N1+N2); // 418750
  const int GH0 = ceildiv(N0,32);   // 3125
  const int GH1 = ceildiv(N1,32);   // 782
  const int GH2 = ceildiv(N2,32);   // 196
  const int GHIST = ceildiv(4000000,256); // 15625
  const int GFILL = ceildiv(2500000,256); // 9766
  const int GDEG  = ceildiv(N0+N1+N2,256); // 513
  const int GA1 = ceildiv(N1,4);    // 6250
  const int GA2 = ceildiv(N2,4);    // 1563
  const int GA0 = ceildiv(N0,4);    // 25000

  // K1: zero ∥ kvec
  k1_zero_kqv<<<4 + ceildiv(CNT_TOT,256), 256, 0, stream>>>(cntBlk, CNT_TOT,
      enc_kW, enc_kb, enc_qb, dec_kW, dec_kb, dec_qb, kvec, invScale);
  // K2: h0 gemm ∥ hist(all 10)
  k2_gemm_hist<<<GH0 + GHIST, 256, 0, stream>>>(ha, X, emb_W, emb_b, bh0, GH0);
  // K3: scanA ∥ deg2rs
  k3_scanA_deg<<<sa.boff[7] + GDEG, 256, 0, stream>>>(sa, bsums, degBlk, rsO, sa.boff[7], N0+N1+N2);
  // K4: scanB
  k_scanB<<<1, 64, 0, stream>>>(sa, bsums);
  // K5: scanC
  k_scanC<<<sa.boff[7], 256, 0, stream>>>(sa, bsums);
  // K6: enc0 V+score gemm ∥ gcn0 Y gemm ∥ fill
  k6_gemms_fill<<<GH0 + GH0 + GFILL, 256, 0, stream>>>(fa, bh0,
      enc_vW, enc_vb, kvec, sS, bV, rs0, gcn_W, bY0, GH0, 2*GH0);
  // K7: attn_gather(i0)→be1 ∥ gcn_gather(g0)→bg0
  k7_gathers<<<GA1 + GA0, 256, 0, stream>>>(csrP[3], rowpP[3], sS, bV, be1,
      csrP[0], rowpP[0], bY0, gcn_b, bg0, GA1);
  // K8: enc1 V+score gemm (from be1)
  k_gemm_score<<<GH1, 256, 0, stream>>>(be1, enc_vW+16384, enc_vb+128, kvec+132, sS, bV, N1);
  // K9: attn_gather(i1)→be2
  k_attn_gather<<<GA2, 256, 0, stream>>>(csrP[4], rowpP[4], sS, bV, be2, N2);
  // K10: gcn1 Y ∥ gcn2 Y
  k10_ygemm<<<GH1 + GH2, 256, 0, stream>>>(be1, rs1, gcn_W+16384, bY1,
      be2, rs2, gcn_W+32768, bY2, GH1);
  // K11: gcn_gather(g1)→bg1 ∥ gcn_gather(g2)→bg2
  k11_ggathers<<<GA1 + GA2, 256, 0, stream>>>(csrP[1], rowpP[1], bY1, gcn_b+128, bg1,
      csrP[2], rowpP[2], bY2, gcn_b+256, bg2, GA1);
  // K12: dec0 gemm (from bg2) ∥ head2
  k12_dec0_head2<<<GH2 + GA2, 256, 0, stream>>>(bg2, dec_vW, dec_vb, kvec+264, sS, bV,
      head_W+2560, head_b+10, out, GH2);
  // K13: attn_gather(d0)→be1 (d1)
  k_attn_gather<<<GA1, 256, 0, stream>>>(csrP[5], rowpP[5], sS, bV, be1, N1);
  // K14: dec1 gemm (from be1) ∥ head1
  k14_dec1_head1<<<GH1 + GA1, 256, 0, stream>>>(be1, dec_vW+16384, dec_vb+128, kvec+396, sS, bV,
      bg1, head_W+1280, head_b+5, out, GH1);
  // K15: attn_gather(d1)→bh0 (d0)
  k_attn_gather<<<GA0, 256, 0, stream>>>(csrP[6], rowpP[6], sS, bV, bh0, N0);
  // K16: head0
  k16_head0<<<GA0, 256, 0, stream>>>(bg0, bh0, head_W, head_b, out);
}

// Round 6
// 584.537 us; speedup vs baseline: 8.5210x; 1.4591x over previous
//
#include <hip/hip_runtime.h>
#include <math.h>

#define N0 100000
#define N1 25000
#define N2 6250
#define FD 128

typedef unsigned short u16;
typedef unsigned int u32;

static inline int ceildiv(int a, int b){ return (a + b - 1)/b; }

__device__ __forceinline__ u16 f2bf(float f){
  u32 u = __float_as_uint(f);
  u += 0x7fffu + ((u >> 16) & 1u);
  return (u16)(u >> 16);
}
__device__ __forceinline__ float bf2f(u16 h){
  return __uint_as_float(((u32)h) << 16);
}

// ================= bucket-CSR metadata =================
struct BMeta {
  const int* src[7]; const int* dst[7];
  int* rowp[7]; int* csr[7];
  int n[7], E[7], B[7], r[7];
  int eoff[8];   // global edge offsets
  int boff[8];   // bucket offsets (224 total)
  int pblk[8];   // per-graph 4096-edge block ranges (614 total)
};

// ================= GEMM bodies =================
__device__ __forceinline__ void mm_inner(const float* Al, const float* Wl, int r0, int c0, float acc[4][4]){
  #pragma unroll
  for (int kq = 0; kq < 8; ++kq) {
    int k0 = kq*4;
    float4 a[4], w[4];
    #pragma unroll
    for (int i=0;i<4;++i) a[i] = *(const float4*)&Al[(r0+i)*32 + k0];
    #pragma unroll
    for (int kk=0;kk<4;++kk) w[kk] = *(const float4*)&Wl[(k0+kk)*128 + c0];
    #pragma unroll
    for (int i=0;i<4;++i){
      acc[i][0] = fmaf(a[i].x,w[0].x, fmaf(a[i].y,w[1].x, fmaf(a[i].z,w[2].x, fmaf(a[i].w,w[3].x, acc[i][0]))));
      acc[i][1] = fmaf(a[i].x,w[0].y, fmaf(a[i].y,w[1].y, fmaf(a[i].z,w[2].y, fmaf(a[i].w,w[3].y, acc[i][1]))));
      acc[i][2] = fmaf(a[i].x,w[0].z, fmaf(a[i].y,w[1].z, fmaf(a[i].z,w[2].z, fmaf(a[i].w,w[3].z, acc[i][2]))));
      acc[i][3] = fmaf(a[i].x,w[0].w, fmaf(a[i].y,w[1].w, fmaf(a[i].z,w[2].w, fmaf(a[i].w,w[3].w, acc[i][3]))));
    }
  }
}

__device__ __forceinline__ void dev_gemm_f32(float* Wl, float* Al, int bid,
    const float* __restrict__ A, const float* __restrict__ W, const float* __restrict__ bias,
    float* __restrict__ out, int n)
{
  const int tid = threadIdx.x;
  const int row0 = bid * 32;
  const int c0 = (tid & 31) * 4, r0 = (tid >> 5) * 4;
  float acc[4][4] = {};
  const float4* A4 = (const float4*)A;
  const float4* W4 = (const float4*)W;
  for (int kp = 0; kp < 4; ++kp) {
    float4* Wl4 = (float4*)Wl;
    #pragma unroll
    for (int i = 0; i < 4; ++i) Wl4[tid + 256*i] = W4[kp*1024 + tid + 256*i];
    { int r = tid >> 3, fc = tid & 7; int gr = row0 + r;
      float4 v = make_float4(0.f,0.f,0.f,0.f);
      if (gr < n) v = A4[(size_t)gr*32 + kp*8 + fc];
      ((float4*)Al)[tid] = v; }
    __syncthreads();
    mm_inner(Al, Wl, r0, c0, acc);
    __syncthreads();
  }
  float4 bv = *(const float4*)&bias[c0];
  #pragma unroll
  for (int i=0;i<4;++i){
    int gr = row0 + r0 + i;
    if (gr < n){
      float4 o;
      o.x = acc[i][0]+bv.x; o.y = acc[i][1]+bv.y; o.z = acc[i][2]+bv.z; o.w = acc[i][3]+bv.w;
      *(float4*)&out[(size_t)gr*FD + c0] = o;
    }
  }
}

// SCORE: emit w[row]=exp(dot(A_row,kvec)+kvec[128]) (global-max-free softmax weight),
// add bias to bf16 output. SCALE: pre-scale A rows by rowScale (no bias).
template<int SCORE, int SCALE>
__device__ __forceinline__ void dev_gemm_bf16(float* Wl, float* Al, int bid,
    const float* __restrict__ A, const float* __restrict__ rowScale,
    const float* __restrict__ W, const float* __restrict__ bias,
    const float* __restrict__ kvec, float* __restrict__ sOut,
    u16* __restrict__ out, int n)
{
  const int tid = threadIdx.x;
  const int row0 = bid * 32;
  const int c0 = (tid & 31) * 4, r0 = (tid >> 5) * 4;
  const int r = tid >> 3, fc = tid & 7;
  const int gr_s = row0 + r;
  float acc[4][4] = {};
  float sacc = 0.f;
  const float4* A4 = (const float4*)A;
  const float4* W4 = (const float4*)W;
  for (int kp = 0; kp < 4; ++kp) {
    float4* Wl4 = (float4*)Wl;
    #pragma unroll
    for (int i = 0; i < 4; ++i) Wl4[tid + 256*i] = W4[kp*1024 + tid + 256*i];
    {
      float4 v = make_float4(0.f,0.f,0.f,0.f);
      if (gr_s < n){
        v = A4[(size_t)gr_s*32 + kp*8 + fc];
        if (SCALE){ float s = rowScale[gr_s]; v.x*=s; v.y*=s; v.z*=s; v.w*=s; }
      }
      ((float4*)Al)[tid] = v;
      if (SCORE){
        float4 kv = *(const float4*)&kvec[kp*32 + fc*4];
        sacc += v.x*kv.x + v.y*kv.y + v.z*kv.z + v.w*kv.w;
      }
    }
    __syncthreads();
    mm_inner(Al, Wl, r0, c0, acc);
    __syncthreads();
  }
  if (SCORE){
    sacc += __shfl_xor(sacc, 1);
    sacc += __shfl_xor(sacc, 2);
    sacc += __shfl_xor(sacc, 4);
    if (fc == 0 && gr_s < n) sOut[gr_s] = expf(sacc + kvec[128]);
  }
  float4 bv = make_float4(0.f,0.f,0.f,0.f);
  if (SCORE) bv = *(const float4*)&bias[c0];
  #pragma unroll
  for (int i=0;i<4;++i){
    int gr = row0 + r0 + i;
    if (gr < n){
      ushort4 o;
      o.x = f2bf(acc[i][0]+bv.x); o.y = f2bf(acc[i][1]+bv.y);
      o.z = f2bf(acc[i][2]+bv.z); o.w = f2bf(acc[i][3]+bv.w);
      *(ushort4*)&out[(size_t)gr*FD + c0] = o;
    }
  }
}

// ================= bucket-CSR passes =================
// P0: per-block LDS bucket histogram of dst
__device__ __forceinline__ void dev_p0(const BMeta& m, int bid, int* __restrict__ bktCnt, int* sh){
  int j = 0;
  #pragma unroll
  for (int t = 1; t < 7; ++t) if (bid >= m.pblk[t]) j = t;
  int lb = bid - m.pblk[j];
  const int* dst = m.dst[j]; int E = m.E[j], r = m.r[j], B = m.B[j];
  if (threadIdx.x < 64) sh[threadIdx.x] = 0;
  __syncthreads();
  int base = lb*4096 + threadIdx.x;
  #pragma unroll
  for (int i = 0; i < 16; ++i){ int e = base + i*256; if (e < E) atomicAdd(&sh[dst[e]/r], 1); }
  __syncthreads();
  if ((int)threadIdx.x < B) atomicAdd(&bktCnt[m.boff[j] + threadIdx.x], sh[threadIdx.x]);
}

// src-degree histograms for g0,g1,g2 (block ranges 245/98/25)
__device__ __forceinline__ void dev_srcdeg(int bid,
    const int* __restrict__ g0s, const int* __restrict__ g1s, const int* __restrict__ g2s,
    int* __restrict__ d0, int* __restrict__ d1, int* __restrict__ d2){
  const int* s; int* d; int E; int lb;
  if (bid < 245){ s = g0s; d = d0; E = 1000000; lb = bid; }
  else if (bid < 343){ s = g1s; d = d1; E = 400000; lb = bid - 245; }
  else { s = g2s; d = d2; E = 100000; lb = bid - 343; }
  int base = lb*4096 + threadIdx.x;
  #pragma unroll
  for (int i = 0; i < 16; ++i){ int e = base + i*256; if (e < E) atomicAdd(&d[s[e]], 1); }
}

// P1: scan 224 bucket counts -> bases/cursors (single block)
__device__ __forceinline__ void dev_p1(const BMeta& m, const int* __restrict__ bktCnt,
    int* __restrict__ bktBase, int* __restrict__ bktCur, int* sh){
  int tid = threadIdx.x;
  if (tid < 224) sh[tid] = bktCnt[tid];
  __syncthreads();
  if (tid < 7){
    int acc = m.eoff[tid];
    for (int b = m.boff[tid]; b < m.boff[tid+1]; ++b){ int v = sh[b]; sh[b] = acc; acc += v; }
  }
  __syncthreads();
  if (tid < 224){ bktBase[tid] = sh[tid]; bktCur[tid] = sh[tid]; }
}

// P2: scatter edges into bucket-contiguous ebuf via per-(block,bucket) chunks
__device__ __forceinline__ void dev_p2(const BMeta& m, int bid, int* __restrict__ bktCur,
    int2* __restrict__ ebuf, int* sh){
  int j = 0;
  #pragma unroll
  for (int t = 1; t < 7; ++t) if (bid >= m.pblk[t]) j = t;
  int lb = bid - m.pblk[j];
  const int* src = m.src[j]; const int* dst = m.dst[j];
  int E = m.E[j], r = m.r[j], B = m.B[j];
  int* h = sh; int* start = sh + 64;
  if (threadIdx.x < 64) h[threadIdx.x] = 0;
  __syncthreads();
  int base = lb*4096 + threadIdx.x;
  #pragma unroll
  for (int i = 0; i < 16; ++i){ int e = base + i*256; if (e < E) atomicAdd(&h[dst[e]/r], 1); }
  __syncthreads();
  if ((int)threadIdx.x < B) start[threadIdx.x] = atomicAdd(&bktCur[m.boff[j] + threadIdx.x], h[threadIdx.x]);
  __syncthreads();
  #pragma unroll
  for (int i = 0; i < 16; ++i){
    int e = base + i*256;
    if (e < E){
      int s = src[e], d = dst[e];
      int pos = atomicAdd(&start[d/r], 1);
      ebuf[pos] = make_int2(s, d);
    }
  }
}

// P3: per-bucket LDS counting sort -> rowp (coalesced) + csr (L2-local)
__device__ __forceinline__ void dev_p3(const BMeta& m, int bb,
    const int* __restrict__ bktCnt, const int* __restrict__ bktBase,
    const int2* __restrict__ ebuf, int* sh){
  int j = 0;
  #pragma unroll
  for (int t = 1; t < 7; ++t) if (bb >= m.boff[t]) j = t;
  int b = bb - m.boff[j];
  int n = m.n[j], r = m.r[j], B = m.B[j];
  int* rowp = m.rowp[j]; int* csr = m.csr[j];
  int node0 = b*r;
  int rr = min(r, n - node0);
  int gbase = bktBase[bb];
  int cnt = bktCnt[bb];
  int lbase = gbase - m.eoff[j];
  int* hist = sh; int* aux = sh + 1568;
  int tid = threadIdx.x;
  for (int i = tid; i < rr; i += 256) hist[i] = 0;
  __syncthreads();
  for (int e = tid; e < cnt; e += 256){ int2 ed = ebuf[gbase + e]; atomicAdd(&hist[ed.y - node0], 1); }
  __syncthreads();
  // exclusive scan of hist[0..rr)
  int ch = (rr + 255) >> 8;
  int i0 = tid*ch;
  int s = 0;
  for (int k = 0; k < ch; ++k){ int idx = i0 + k; if (idx < rr){ int t = hist[idx]; hist[idx] = s; s += t; } }
  aux[tid] = s; __syncthreads();
  for (int off = 1; off < 256; off <<= 1){
    int v = aux[tid]; int a = (tid >= off) ? aux[tid - off] : 0;
    __syncthreads();
    aux[tid] = v + a;
    __syncthreads();
  }
  int pre = (tid ? aux[tid-1] : 0) + lbase;
  for (int k = 0; k < ch; ++k){ int idx = i0 + k; if (idx < rr) hist[idx] += pre; }
  __syncthreads();
  for (int i = tid; i < rr; i += 256) rowp[node0 + i] = hist[i];
  if (b == B-1 && tid == 0) rowp[n] = lbase + cnt;
  __syncthreads();
  for (int e = tid; e < cnt; e += 256){
    int2 ed = ebuf[gbase + e];
    int pos = atomicAdd(&hist[ed.y - node0], 1);
    csr[pos] = ed.x;
  }
}

__device__ __forceinline__ void dev_deg2rs(int bid, const int* __restrict__ deg, float* __restrict__ rs, int n){
  int i = bid*256 + threadIdx.x;
  if (i < n) rs[i] = rsqrtf(fmaxf((float)deg[i], 1.f));
}

// ================= gathers / heads =================
// single-pass: w already exp'd; out = (sum w V)/(sum w)
__device__ __forceinline__ void dev_attn_gather(int bid,
    const int* __restrict__ csr, const int* __restrict__ rowp,
    const float* __restrict__ w, const u16* __restrict__ V,
    float* __restrict__ out, int n)
{
  int wid = threadIdx.x >> 6, lane = threadIdx.x & 63;
  int row = bid*4 + wid;
  if (row >= n) return;
  int st = rowp[row], en = rowp[row+1];
  float ax = 0.f, ay = 0.f;
  if (en > st){
    const ushort2* V2 = (const ushort2*)V;
    float den = 0.f;
    for (int e = st; e < en; ++e){
      int sn = csr[e];
      float x = w[sn];
      den += x;
      ushort2 v = V2[(size_t)sn*64 + lane];
      ax = fmaf(x, bf2f(v.x), ax);
      ay = fmaf(x, bf2f(v.y), ay);
    }
    float inv = 1.f/den;
    ax *= inv; ay *= inv;
  }
  ((float2*)out)[(size_t)row*64 + lane] = make_float2(ax, ay);
}

template<int OB16>
__device__ __forceinline__ void dev_gcn_gather(int bid,
    const int* __restrict__ csr, const int* __restrict__ rowp,
    const u16* __restrict__ Y, const float* __restrict__ bias,
    void* __restrict__ out, int n)
{
  int wid = threadIdx.x >> 6, lane = threadIdx.x & 63;
  int row = bid*4 + wid;
  if (row >= n) return;
  int st = rowp[row], en = rowp[row+1];
  float ax = 0.f, ay = 0.f;
  const ushort2* Y2 = (const ushort2*)Y;
  for (int e = st; e < en; ++e){
    int sn = csr[e];
    ushort2 v = Y2[(size_t)sn*64 + lane];
    ax += bf2f(v.x); ay += bf2f(v.y);
  }
  float sc = rsqrtf(fmaxf((float)(en - st), 1.f));
  float2 b2 = ((const float2*)bias)[lane];
  float ox = fmaf(ax, sc, b2.x), oy = fmaf(ay, sc, b2.y);
  if (OB16){
    ushort2 o; o.x = f2bf(ox); o.y = f2bf(oy);
    ((ushort2*)out)[(size_t)row*64 + lane] = o;
  } else {
    ((float2*)out)[(size_t)row*64 + lane] = make_float2(ox, oy);
  }
}

template<int GB16, int DB16>
__device__ __forceinline__ void dev_head(int bid, const void* __restrict__ g, const void* __restrict__ dch,
    const float* __restrict__ W, const float* __restrict__ b,
    float* __restrict__ out, int n, int rowOff)
{
  int wid = threadIdx.x >> 6, lane = threadIdx.x & 63;
  int row = bid*4 + wid;
  if (row >= n) return;
  float x0, x1, x2, x3;
  if (GB16){ const u16* gr = (const u16*)g + (size_t)row*FD; x0 = bf2f(gr[lane]); x1 = bf2f(gr[64+lane]); }
  else     { const float* gr = (const float*)g + (size_t)row*FD; x0 = gr[lane]; x1 = gr[64+lane]; }
  if (DB16){ const u16* dr = (const u16*)dch + (size_t)row*FD; x2 = bf2f(dr[lane]); x3 = bf2f(dr[64+lane]); }
  else     { const float* dr = (const float*)dch + (size_t)row*FD; x2 = dr[lane]; x3 = dr[64+lane]; }
  float acc[5];
  #pragma unroll
  for (int o = 0; o < 5; ++o)
    acc[o] = x0*W[lane*5+o] + x1*W[(64+lane)*5+o] + x2*W[(128+lane)*5+o] + x3*W[(192+lane)*5+o];
  #pragma unroll
  for (int o = 0; o < 5; ++o)
    #pragma unroll
    for (int s = 32; s; s >>= 1) acc[o] += __shfl_xor(acc[o], s);
  if (lane == 0){
    float m = -1e30f;
    #pragma unroll
    for (int o = 0; o < 5; ++o){ acc[o] += b[o]; m = fmaxf(m, acc[o]); }
    float sum = 0.f;
    #pragma unroll
    for (int o = 0; o < 5; ++o){ acc[o] = expf(acc[o]-m); sum += acc[o]; }
    float is = 1.0f/sum;
    float* op = out + (size_t)(rowOff+row)*5;
    #pragma unroll
    for (int o = 0; o < 5; ++o) op[o] = acc[o]*is;
  }
}

// ================= kernels =================

// K1: zero deg+bktCnt || kvec for 4 attn layers
__global__ __launch_bounds__(256) void k1_zero_kqv(int* __restrict__ zeroBlk, int ntot,
    const float* __restrict__ ekW, const float* __restrict__ ekb, const float* __restrict__ eqb,
    const float* __restrict__ dkW, const float* __restrict__ dkb, const float* __restrict__ dqb,
    float* __restrict__ kv, float inv)
{
  int bid = blockIdx.x;
  if (bid < 4){
    if (threadIdx.x < 128){
      int j = bid;
      const float* kW = (j < 2) ? ekW + j*16384 : dkW + (j-2)*16384;
      const float* kb = (j < 2) ? ekb + j*128   : dkb + (j-2)*128;
      const float* qb = (j < 2) ? eqb + j*128   : dqb + (j-2)*128;
      float* o = kv + j*132;
      int k = threadIdx.x;
      float a = 0.f;
      for (int t = 0; t < 128; ++t) a = fmaf(kW[k*128+t], qb[t], a);
      o[k] = a * inv;
      if (k == 0){
        float c = 0.f;
        for (int t = 0; t < 128; ++t) c = fmaf(kb[t], qb[t], c);
        o[128] = c * inv;
      }
    }
  } else {
    int i = (bid-4)*256 + threadIdx.x;
    if (i < ntot) zeroBlk[i] = 0;
  }
}

// K2: P0 || srcdeg || h0 gemm  (latency roles first in bid order)
__global__ __launch_bounds__(256) void k2_p0_deg_gemm(BMeta m, int* __restrict__ bktCnt,
    const int* __restrict__ g0s, const int* __restrict__ g1s, const int* __restrict__ g2s,
    int* __restrict__ d0, int* __restrict__ d1, int* __restrict__ d2,
    const float* __restrict__ X, const float* __restrict__ W, const float* __restrict__ b,
    float* __restrict__ bh0, int np0, int ndeg)
{
  __shared__ float sm[4096 + 1024];
  int bid = blockIdx.x;
  if (bid < np0) dev_p0(m, bid, bktCnt, (int*)sm);
  else if (bid < np0 + ndeg) dev_srcdeg(bid - np0, g0s, g1s, g2s, d0, d1, d2);
  else dev_gemm_f32(sm, sm + 4096, bid - np0 - ndeg, X, W, b, bh0, N0);
}

// K3: P1 || deg2rs
__global__ __launch_bounds__(256) void k3_p1_deg2rs(BMeta m,
    const int* __restrict__ bktCnt, int* __restrict__ bktBase, int* __restrict__ bktCur,
    const int* __restrict__ deg, float* __restrict__ rs, int ndeg)
{
  __shared__ int sh[256];
  int bid = blockIdx.x;
  if (bid == 0) dev_p1(m, bktCnt, bktBase, bktCur, sh);
  else dev_deg2rs(bid - 1, deg, rs, ndeg);
}

// K4: P2 || enc0 V+score gemm
__global__ __launch_bounds__(256) void k4_p2_gemm(BMeta m, int* __restrict__ bktCur, int2* __restrict__ ebuf,
    const float* __restrict__ bh0, const float* __restrict__ evW, const float* __restrict__ evb,
    const float* __restrict__ kvec, float* __restrict__ sS, u16* __restrict__ bV, int np2)
{
  __shared__ float sm[4096 + 1024];
  int bid = blockIdx.x;
  if (bid < np2) dev_p2(m, bid, bktCur, ebuf, (int*)sm);
  else dev_gemm_bf16<1,0>(sm, sm+4096, bid - np2, bh0, nullptr, evW, evb, kvec, sS, bV, N0);
}

// K5: P3 || gcn0 Y gemm
__global__ __launch_bounds__(256) void k5_p3_ygemm(BMeta m,
    const int* __restrict__ bktCnt, const int* __restrict__ bktBase, const int2* __restrict__ ebuf,
    const float* __restrict__ bh0, const float* __restrict__ rs0, const float* __restrict__ gW,
    u16* __restrict__ bY0, int np3)
{
  __shared__ float sm[4096 + 1024];
  int bid = blockIdx.x;
  if (bid < np3) dev_p3(m, bid, bktCnt, bktBase, ebuf, (int*)sm);
  else dev_gemm_bf16<0,1>(sm, sm+4096, bid - np3, bh0, rs0, gW, nullptr, nullptr, nullptr, bY0, N0);
}

// K7: attn_gather(i0) || gcn_gather(g0, bf16 out)
__global__ __launch_bounds__(256) void k7_gathers(
    const int* __restrict__ csrA, const int* __restrict__ rowpA,
    const float* __restrict__ sS, const u16* __restrict__ bV, float* __restrict__ be1,
    const int* __restrict__ csrG, const int* __restrict__ rowpG,
    const u16* __restrict__ bY0, const float* __restrict__ gb, u16* __restrict__ bg0, int na)
{
  int bid = blockIdx.x;
  if (bid < na) dev_attn_gather(bid, csrA, rowpA, sS, bV, be1, N1);
  else dev_gcn_gather<1>(bid - na, csrG, rowpG, bY0, gb, bg0, N0);
}

__global__ __launch_bounds__(256) void k_gemm_score(
    const float* __restrict__ A, const float* __restrict__ vW, const float* __restrict__ vb,
    const float* __restrict__ kvec, float* __restrict__ sS, u16* __restrict__ out, int n)
{
  __shared__ float sm[4096 + 1024];
  dev_gemm_bf16<1,0>(sm, sm+4096, blockIdx.x, A, nullptr, vW, vb, kvec, sS, out, n);
}

__global__ __launch_bounds__(256) void k_attn_gather(
    const int* __restrict__ csr, const int* __restrict__ rowp,
    const float* __restrict__ s, const u16* __restrict__ V, float* __restrict__ out, int n)
{
  dev_attn_gather(blockIdx.x, csr, rowp, s, V, out, n);
}

// K10: Y-gemm scale1 || scale2
__global__ __launch_bounds__(256) void k10_ygemm(
    const float* __restrict__ be1, const float* __restrict__ rs1, const float* __restrict__ W1, u16* __restrict__ bY1,
    const float* __restrict__ be2, const float* __restrict__ rs2, const float* __restrict__ W2, u16* __restrict__ bY2,
    int ga)
{
  __shared__ float sm[4096 + 1024];
  int bid = blockIdx.x;
  if (bid < ga) dev_gemm_bf16<0,1>(sm, sm+4096, bid, be1, rs1, W1, nullptr, nullptr, nullptr, bY1, N1);
  else          dev_gemm_bf16<0,1>(sm, sm+4096, bid - ga, be2, rs2, W2, nullptr, nullptr, nullptr, bY2, N2);
}

// K11: gcn_gather(g1, bf16) || gcn_gather(g2, f32)
__global__ __launch_bounds__(256) void k11_ggathers(
    const int* __restrict__ csr1, const int* __restrict__ rowp1, const u16* __restrict__ bY1,
    const float* __restrict__ b1, u16* __restrict__ bg1,
    const int* __restrict__ csr2, const int* __restrict__ rowp2, const u16* __restrict__ bY2,
    const float* __restrict__ b2, float* __restrict__ bg2, int na)
{
  int bid = blockIdx.x;
  if (bid < na) dev_gcn_gather<1>(bid, csr1, rowp1, bY1, b1, bg1, N1);
  else          dev_gcn_gather<0>(bid - na, csr2, rowp2, bY2, b2, bg2, N2);
}

// K12: dec0 gemm (from bg2) || head2
__global__ __launch_bounds__(256) void k12_dec0_head2(
    const float* __restrict__ bg2, const float* __restrict__ vW, const float* __restrict__ vb,
    const float* __restrict__ kvec, float* __restrict__ sS, u16* __restrict__ bV,
    const float* __restrict__ hW, const float* __restrict__ hb, float* __restrict__ out, int ngemm)
{
  __shared__ float sm[4096 + 1024];
  int bid = blockIdx.x;
  if (bid < ngemm) dev_gemm_bf16<1,0>(sm, sm+4096, bid, bg2, nullptr, vW, vb, kvec, sS, bV, N2);
  else dev_head<0,0>(bid - ngemm, bg2, bg2, hW, hb, out, N2, N0+N1);
}

// K14: dec1 gemm (from be1) || head1
__global__ __launch_bounds__(256) void k14_dec1_head1(
    const float* __restrict__ be1, const float* __restrict__ vW, const float* __restrict__ vb,
    const float* __restrict__ kvec, float* __restrict__ sS, u16* __restrict__ bV,
    const u16* __restrict__ bg1, const float* __restrict__ hW, const float* __restrict__ hb,
    float* __restrict__ out, int ngemm)
{
  __shared__ float sm[4096 + 1024];
  int bid = blockIdx.x;
  if (bid < ngemm) dev_gemm_bf16<1,0>(sm, sm+4096, bid, be1, nullptr, vW, vb, kvec, sS, bV, N1);
  else dev_head<1,0>(bid - ngemm, bg1, be1, hW, hb, out, N1, N0);
}

// K15: fused d0 gather + head0 (d0 never materialized)
__global__ __launch_bounds__(256) void k15_gather_head0(
    const int* __restrict__ csr, const int* __restrict__ rowp,
    const float* __restrict__ w, const u16* __restrict__ V,
    const u16* __restrict__ bg0,
    const float* __restrict__ hW, const float* __restrict__ hb,
    float* __restrict__ out)
{
  int wid = threadIdx.x >> 6, lane = threadIdx.x & 63;
  int row = blockIdx.x*4 + wid;
  if (row >= N0) return;
  int st = rowp[row], en = rowp[row+1];
  float ax = 0.f, ay = 0.f;
  if (en > st){
    const ushort2* V2 = (const ushort2*)V;
    float den = 0.f;
    for (int e = st; e < en; ++e){
      int sn = csr[e];
      float x = w[sn];
      den += x;
      ushort2 v = V2[(size_t)sn*64 + lane];
      ax = fmaf(x, bf2f(v.x), ax);
      ay = fmaf(x, bf2f(v.y), ay);
    }
    float inv = 1.f/den;
    ax *= inv; ay *= inv;
  }
  // lane holds d0 elements 2*lane, 2*lane+1 -> redistribute to head layout
  int hs = lane >> 1;
  float a0 = __shfl(ax, hs),      b0 = __shfl(ay, hs);
  float a1 = __shfl(ax, 32 + hs), b1 = __shfl(ay, 32 + hs);
  float x2 = (lane & 1) ? b0 : a0;
  float x3 = (lane & 1) ? b1 : a1;
  const u16* gr = bg0 + (size_t)row*FD;
  float x0 = bf2f(gr[lane]), x1 = bf2f(gr[64+lane]);
  float acc[5];
  #pragma unroll
  for (int o = 0; o < 5; ++o)
    acc[o] = x0*hW[lane*5+o] + x1*hW[(64+lane)*5+o] + x2*hW[(128+lane)*5+o] + x3*hW[(192+lane)*5+o];
  #pragma unroll
  for (int o = 0; o < 5; ++o)
    #pragma unroll
    for (int s = 32; s; s >>= 1) acc[o] += __shfl_xor(acc[o], s);
  if (lane == 0){
    float m = -1e30f;
    #pragma unroll
    for (int o = 0; o < 5; ++o){ acc[o] += hb[o]; m = fmaxf(m, acc[o]); }
    float sum = 0.f;
    #pragma unroll
    for (int o = 0; o < 5; ++o){ acc[o] = expf(acc[o]-m); sum += acc[o]; }
    float is = 1.0f/sum;
    float* op = out + (size_t)row*5;
    #pragma unroll
    for (int o = 0; o < 5; ++o) op[o] = acc[o]*is;
  }
}

// ================= host =================
extern "C" void kernel_launch(void* const* d_in, const int* in_sizes, int n_in,
                              void* d_out, int out_size, void* d_ws, size_t ws_size,
                              hipStream_t stream)
{
  const float* X      = (const float*)d_in[0];
  const float* emb_W  = (const float*)d_in[1];
  const float* emb_b  = (const float*)d_in[2];
  const float* gcn_W  = (const float*)d_in[3];
  const float* gcn_b  = (const float*)d_in[4];
  const float* enc_qb = (const float*)d_in[6];
  const float* enc_kW = (const float*)d_in[7];
  const float* enc_kb = (const float*)d_in[8];
  const float* enc_vW = (const float*)d_in[9];
  const float* enc_vb = (const float*)d_in[10];
  const float* dec_qb = (const float*)d_in[12];
  const float* dec_kW = (const float*)d_in[13];
  const float* dec_kb = (const float*)d_in[14];
  const float* dec_vW = (const float*)d_in[15];
  const float* dec_vb = (const float*)d_in[16];
  const float* head_W = (const float*)d_in[17];
  const float* head_b = (const float*)d_in[18];
  const int* g0s  = (const int*)d_in[19];
  const int* g0d  = (const int*)d_in[20];
  const int* g1s  = (const int*)d_in[21];
  const int* g1d  = (const int*)d_in[22];
  const int* g2s  = (const int*)d_in[23];
  const int* g2d  = (const int*)d_in[24];
  const int* i0s  = (const int*)d_in[25];
  const int* i0d  = (const int*)d_in[26];
  const int* i1s  = (const int*)d_in[27];
  const int* i1d  = (const int*)d_in[28];
  const int* dc0s = (const int*)d_in[29];
  const int* dc0d = (const int*)d_in[30];
  const int* dc1s = (const int*)d_in[31];
  const int* dc1d = (const int*)d_in[32];

  // ---- workspace layout ----
  float* ws = (float*)d_ws;
  float* bh0 = ws;                          // 12.8M f32 : h0
  float* be1 = bh0 + (size_t)N0*FD;         // 3.2M  f32 : e1, later d1
  float* be2 = be1 + (size_t)N1*FD;         // 0.8M  f32 : e2
  float* bg2 = be2 + (size_t)N2*FD;         // 0.8M  f32 : gcn2 out
  float* sS  = bg2 + (size_t)N2*FD;         // N0 : softmax weights w=exp(s)
  float* kvec = sS + N0;                    // 4*132
  float* rsO  = kvec + 4*132;               // N0+N1+N2 f32
  u16*  bg0 = (u16*)(rsO + (N0+N1+N2));     // N0*FD u16
  u16*  bg1 = bg0 + (size_t)N0*FD;          // N1*FD u16
  u16*  bV  = bg1 + (size_t)N1*FD;          // N0*FD u16 (V tables, time-shared)
  u16*  bY0 = bV  + (size_t)N0*FD;          // N0*FD u16
  u16*  bY1 = bV + 4000000;                 // alias into bV tail
  u16*  bY2 = bV + 8000000;
  int*  degBlk  = (int*)(bY0 + (size_t)N0*FD);  // 131250
  int*  bktCnt  = degBlk + (N0+N1+N2);          // 224
  int*  bktBase = bktCnt + 224;                 // 224
  int*  bktCur  = bktBase + 224;                // 224
  int*  rowpBlk = bktCur + 224;                 // 287507
  int*  csrBlk  = rowpBlk + 287507;             // 2,500,000
  int2* ebuf    = (int2*)(csrBlk + 2500000 + 1);// 2.5M int2 (pad int for 8B align)

  const int* srcP[7] = {g0s,g1s,g2s,i0s,i1s,dc0s,dc1s};
  const int* dstP[7] = {g0d,g1d,g2d,i0d,i1d,dc0d,dc1d};
  const int nArr[7] = {N0,N1,N2,N1,N2,N1,N0};
  const int EArr[7] = {1000000,400000,100000,400000,100000,100000,400000};
  const int BArr[7] = {64,32,8,32,8,16,64};
  const int rArr[7] = {1563,782,782,782,782,1563,1563};

  BMeta m;
  {
    int eo=0, bo=0, po=0, ro=0, co=0;
    for (int j=0;j<7;++j){
      m.src[j]=srcP[j]; m.dst[j]=dstP[j];
      m.rowp[j]=rowpBlk+ro; m.csr[j]=csrBlk+co;
      m.n[j]=nArr[j]; m.E[j]=EArr[j]; m.B[j]=BArr[j]; m.r[j]=rArr[j];
      m.eoff[j]=eo; m.boff[j]=bo; m.pblk[j]=po;
      eo+=EArr[j]; bo+=BArr[j]; po+=ceildiv(EArr[j],4096); ro+=nArr[j]+1; co+=EArr[j];
    }
    m.eoff[7]=eo; m.boff[7]=bo; m.pblk[7]=po;   // 2.5M / 224 / 614
  }

  const float invScale = 0.17677669529663687f; // 1/sqrt(32)
  float* out = (float*)d_out;
  float* rs0 = rsO; float* rs1 = rsO + N0; float* rs2 = rsO + N0 + N1;
  int* deg0 = degBlk; int* deg1 = degBlk + N0; int* deg2 = degBlk + N0 + N1;

  const int NP0 = m.pblk[7];                 // 614
  const int NDEG = 245 + 98 + 25;            // 368
  const int NP3 = m.boff[7];                 // 224
  const int ZTOT = (N0+N1+N2) + 224;         // deg + bktCnt contiguous
  const int GH0 = ceildiv(N0,32);            // 3125
  const int GH1 = ceildiv(N1,32);            // 782
  const int GH2 = ceildiv(N2,32);            // 196
  const int GA0 = ceildiv(N0,4);             // 25000
  const int GA1 = ceildiv(N1,4);             // 6250
  const int GA2 = ceildiv(N2,4);             // 1563

  // K1: zero (deg+bktCnt) || kvec
  k1_zero_kqv<<<4 + ceildiv(ZTOT,256), 256, 0, stream>>>(degBlk, ZTOT,
      enc_kW, enc_kb, enc_qb, dec_kW, dec_kb, dec_qb, kvec, invScale);
  // K2: P0 || srcdeg || h0 gemm
  k2_p0_deg_gemm<<<NP0 + NDEG + GH0, 256, 0, stream>>>(m, bktCnt,
      g0s, g1s, g2s, deg0, deg1, deg2, X, emb_W, emb_b, bh0, NP0, NDEG);
  // K3: P1 || deg2rs
  k3_p1_deg2rs<<<1 + ceildiv(N0+N1+N2,256), 256, 0, stream>>>(m, bktCnt, bktBase, bktCur,
      degBlk, rsO, N0+N1+N2);
  // K4: P2 || enc0 V+score gemm
  k4_p2_gemm<<<NP0 + GH0, 256, 0, stream>>>(m, bktCur, ebuf,
      bh0, enc_vW, enc_vb, kvec, sS, bV, NP0);
  // K5: P3 || gcn0 Y gemm
  k5_p3_ygemm<<<NP3 + GH0, 256, 0, stream>>>(m, bktCnt, bktBase, ebuf,
      bh0, rs0, gcn_W, bY0, NP3);
  // K7: attn_gather(i0)->be1 || gcn_gather(g0)->bg0
  k7_gathers<<<GA1 + GA0, 256, 0, stream>>>(m.csr[3], m.rowp[3], sS, bV, be1,
      m.csr[0], m.rowp[0], bY0, gcn_b, bg0, GA1);
  // K8: enc1 V+score gemm
  k_gemm_score<<<GH1, 256, 0, stream>>>(be1, enc_vW+16384, enc_vb+128, kvec+132, sS, bV, N1);
  // K9: attn_gather(i1)->be2
  k_attn_gather<<<GA2, 256, 0, stream>>>(m.csr[4], m.rowp[4], sS, bV, be2, N2);
  // K10: gcn1 Y || gcn2 Y
  k10_ygemm<<<GH1 + GH2, 256, 0, stream>>>(be1, rs1, gcn_W+16384, bY1,
      be2, rs2, gcn_W+32768, bY2, GH1);
  // K11: gcn_gather(g1)->bg1 || gcn_gather(g2)->bg2
  k11_ggathers<<<GA1 + GA2, 256, 0, stream>>>(m.csr[1], m.rowp[1], bY1, gcn_b+128, bg1,
      m.csr[2], m.rowp[2], bY2, gcn_b+256, bg2, GA1);
  // K12: dec0 gemm || head2
  k12_dec0_head2<<<GH2 + GA2, 256, 0, stream>>>(bg2, dec_vW, dec_vb, kvec+264, sS, bV,
      head_W+2560, head_b+10, out, GH2);
  // K13: attn_gather(d0)->be1 (d1)
  k_attn_gather<<<GA1, 256, 0, stream>>>(m.csr[5], m.rowp[5], sS, bV, be1, N1);
  // K14: dec1 gemm || head1
  k14_dec1_head1<<<GH1 + GA1, 256, 0, stream>>>(be1, dec_vW+16384, dec_vb+128, kvec+396, sS, bV,
      bg1, head_W+1280, head_b+5, out, GH1);
  // K15: fused d0 gather + head0
  k15_gather_head0<<<GA0, 256, 0, stream>>>(m.csr[6], m.rowp[6], sS, bV, bg0,
      head_W, head_b, out);
}

// Round 7
// 520.581 us; speedup vs baseline: 9.5679x; 1.1229x over previous
//
#include <hip/hip_runtime.h>
#include <math.h>

#define N0 100000
#define N1 25000
#define N2 6250
#define FD 128

typedef unsigned short u16;
typedef unsigned int u32;

static inline int ceildiv(int a, int b){ return (a + b - 1)/b; }

__device__ __forceinline__ u16 f2bf(float f){
  u32 u = __float_as_uint(f);
  u += 0x7fffu + ((u >> 16) & 1u);
  return (u16)(u >> 16);
}
__device__ __forceinline__ float bf2f(u16 h){
  return __uint_as_float(((u32)h) << 16);
}

// ================= bucket-CSR metadata =================
struct BMeta {
  const int* src[7]; const int* dst[7];
  int* rowp[7]; int* csr[7];
  int n[7], E[7], B[7], r[7];
  int eoff[8];   // global edge offsets
  int boff[8];   // bucket offsets (224 total)
  int pblk[8];   // per-graph 4096-edge block ranges (614 total)
};

// ================= GEMM bodies =================
__device__ __forceinline__ void mm_inner(const float* Al, const float* Wl, int r0, int c0, float acc[4][4]){
  #pragma unroll
  for (int kq = 0; kq < 8; ++kq) {
    int k0 = kq*4;
    float4 a[4], w[4];
    #pragma unroll
    for (int i=0;i<4;++i) a[i] = *(const float4*)&Al[(r0+i)*32 + k0];
    #pragma unroll
    for (int kk=0;kk<4;++kk) w[kk] = *(const float4*)&Wl[(k0+kk)*128 + c0];
    #pragma unroll
    for (int i=0;i<4;++i){
      acc[i][0] = fmaf(a[i].x,w[0].x, fmaf(a[i].y,w[1].x, fmaf(a[i].z,w[2].x, fmaf(a[i].w,w[3].x, acc[i][0]))));
      acc[i][1] = fmaf(a[i].x,w[0].y, fmaf(a[i].y,w[1].y, fmaf(a[i].z,w[2].y, fmaf(a[i].w,w[3].y, acc[i][1]))));
      acc[i][2] = fmaf(a[i].x,w[0].z, fmaf(a[i].y,w[1].z, fmaf(a[i].z,w[2].z, fmaf(a[i].w,w[3].z, acc[i][2]))));
      acc[i][3] = fmaf(a[i].x,w[0].w, fmaf(a[i].y,w[1].w, fmaf(a[i].z,w[2].w, fmaf(a[i].w,w[3].w, acc[i][3]))));
    }
  }
}

__device__ __forceinline__ void dev_gemm_f32(float* Wl, float* Al, int bid,
    const float* __restrict__ A, const float* __restrict__ W, const float* __restrict__ bias,
    float* __restrict__ out, int n)
{
  const int tid = threadIdx.x;
  const int row0 = bid * 32;
  const int c0 = (tid & 31) * 4, r0 = (tid >> 5) * 4;
  float acc[4][4] = {};
  const float4* A4 = (const float4*)A;
  const float4* W4 = (const float4*)W;
  for (int kp = 0; kp < 4; ++kp) {
    float4* Wl4 = (float4*)Wl;
    #pragma unroll
    for (int i = 0; i < 4; ++i) Wl4[tid + 256*i] = W4[kp*1024 + tid + 256*i];
    { int r = tid >> 3, fc = tid & 7; int gr = row0 + r;
      float4 v = make_float4(0.f,0.f,0.f,0.f);
      if (gr < n) v = A4[(size_t)gr*32 + kp*8 + fc];
      ((float4*)Al)[tid] = v; }
    __syncthreads();
    mm_inner(Al, Wl, r0, c0, acc);
    __syncthreads();
  }
  float4 bv = *(const float4*)&bias[c0];
  #pragma unroll
  for (int i=0;i<4;++i){
    int gr = row0 + r0 + i;
    if (gr < n){
      float4 o;
      o.x = acc[i][0]+bv.x; o.y = acc[i][1]+bv.y; o.z = acc[i][2]+bv.z; o.w = acc[i][3]+bv.w;
      *(float4*)&out[(size_t)gr*FD + c0] = o;
    }
  }
}

// SCORE: emit w[row]=exp(dot(A_row,kvec)+kvec[128]); add bias to bf16 out.
// SCALE: pre-scale A rows by rowScale (no bias).
template<int SCORE, int SCALE>
__device__ __forceinline__ void dev_gemm_bf16(float* Wl, float* Al, int bid,
    const float* __restrict__ A, const float* __restrict__ rowScale,
    const float* __restrict__ W, const float* __restrict__ bias,
    const float* __restrict__ kvec, float* __restrict__ sOut,
    u16* __restrict__ out, int n)
{
  const int tid = threadIdx.x;
  const int row0 = bid * 32;
  const int c0 = (tid & 31) * 4, r0 = (tid >> 5) * 4;
  const int r = tid >> 3, fc = tid & 7;
  const int gr_s = row0 + r;
  float acc[4][4] = {};
  float sacc = 0.f;
  const float4* A4 = (const float4*)A;
  const float4* W4 = (const float4*)W;
  for (int kp = 0; kp < 4; ++kp) {
    float4* Wl4 = (float4*)Wl;
    #pragma unroll
    for (int i = 0; i < 4; ++i) Wl4[tid + 256*i] = W4[kp*1024 + tid + 256*i];
    {
      float4 v = make_float4(0.f,0.f,0.f,0.f);
      if (gr_s < n){
        v = A4[(size_t)gr_s*32 + kp*8 + fc];
        if (SCALE){ float s = rowScale[gr_s]; v.x*=s; v.y*=s; v.z*=s; v.w*=s; }
      }
      ((float4*)Al)[tid] = v;
      if (SCORE){
        float4 kv = *(const float4*)&kvec[kp*32 + fc*4];
        sacc += v.x*kv.x + v.y*kv.y + v.z*kv.z + v.w*kv.w;
      }
    }
    __syncthreads();
    mm_inner(Al, Wl, r0, c0, acc);
    __syncthreads();
  }
  if (SCORE){
    sacc += __shfl_xor(sacc, 1);
    sacc += __shfl_xor(sacc, 2);
    sacc += __shfl_xor(sacc, 4);
    if (fc == 0 && gr_s < n) sOut[gr_s] = expf(sacc + kvec[128]);
  }
  float4 bv = make_float4(0.f,0.f,0.f,0.f);
  if (SCORE) bv = *(const float4*)&bias[c0];
  #pragma unroll
  for (int i=0;i<4;++i){
    int gr = row0 + r0 + i;
    if (gr < n){
      ushort4 o;
      o.x = f2bf(acc[i][0]+bv.x); o.y = f2bf(acc[i][1]+bv.y);
      o.z = f2bf(acc[i][2]+bv.z); o.w = f2bf(acc[i][3]+bv.w);
      *(ushort4*)&out[(size_t)gr*FD + c0] = o;
    }
  }
}

// ================= bucket-CSR passes =================
__device__ __forceinline__ void dev_p0(const BMeta& m, int bid, int* __restrict__ bktCnt, int* sh){
  int j = 0;
  #pragma unroll
  for (int t = 1; t < 7; ++t) if (bid >= m.pblk[t]) j = t;
  int lb = bid - m.pblk[j];
  const int* dst = m.dst[j]; int E = m.E[j], r = m.r[j], B = m.B[j];
  if (threadIdx.x < 64) sh[threadIdx.x] = 0;
  __syncthreads();
  int base = lb*4096 + threadIdx.x;
  #pragma unroll
  for (int i = 0; i < 16; ++i){ int e = base + i*256; if (e < E) atomicAdd(&sh[dst[e]/r], 1); }
  __syncthreads();
  if ((int)threadIdx.x < B) atomicAdd(&bktCnt[m.boff[j] + threadIdx.x], sh[threadIdx.x]);
}

__device__ __forceinline__ void dev_srcdeg(int bid,
    const int* __restrict__ g0s, const int* __restrict__ g1s, const int* __restrict__ g2s,
    int* __restrict__ d0, int* __restrict__ d1, int* __restrict__ d2){
  const int* s; int* d; int E; int lb;
  if (bid < 245){ s = g0s; d = d0; E = 1000000; lb = bid; }
  else if (bid < 343){ s = g1s; d = d1; E = 400000; lb = bid - 245; }
  else { s = g2s; d = d2; E = 100000; lb = bid - 343; }
  int base = lb*4096 + threadIdx.x;
  #pragma unroll
  for (int i = 0; i < 16; ++i){ int e = base + i*256; if (e < E) atomicAdd(&d[s[e]], 1); }
}

__device__ __forceinline__ void dev_p1(const BMeta& m, const int* __restrict__ bktCnt,
    int* __restrict__ bktBase, int* __restrict__ bktCur, int* sh){
  int tid = threadIdx.x;
  if (tid < 224) sh[tid] = bktCnt[tid];
  __syncthreads();
  if (tid < 7){
    int acc = m.eoff[tid];
    for (int b = m.boff[tid]; b < m.boff[tid+1]; ++b){ int v = sh[b]; sh[b] = acc; acc += v; }
  }
  __syncthreads();
  if (tid < 224){ bktBase[tid] = sh[tid]; bktCur[tid] = sh[tid]; }
}

__device__ __forceinline__ void dev_p2(const BMeta& m, int bid, int* __restrict__ bktCur,
    int2* __restrict__ ebuf, int* sh){
  int j = 0;
  #pragma unroll
  for (int t = 1; t < 7; ++t) if (bid >= m.pblk[t]) j = t;
  int lb = bid - m.pblk[j];
  const int* src = m.src[j]; const int* dst = m.dst[j];
  int E = m.E[j], r = m.r[j], B = m.B[j];
  int* h = sh; int* start = sh + 64;
  if (threadIdx.x < 64) h[threadIdx.x] = 0;
  __syncthreads();
  int base = lb*4096 + threadIdx.x;
  #pragma unroll
  for (int i = 0; i < 16; ++i){ int e = base + i*256; if (e < E) atomicAdd(&h[dst[e]/r], 1); }
  __syncthreads();
  if ((int)threadIdx.x < B) start[threadIdx.x] = atomicAdd(&bktCur[m.boff[j] + threadIdx.x], h[threadIdx.x]);
  __syncthreads();
  #pragma unroll
  for (int i = 0; i < 16; ++i){
    int e = base + i*256;
    if (e < E){
      int s = src[e], d = dst[e];
      int pos = atomicAdd(&start[d/r], 1);
      ebuf[pos] = make_int2(s, d);
    }
  }
}

__device__ __forceinline__ void dev_p3(const BMeta& m, int bb,
    const int* __restrict__ bktCnt, const int* __restrict__ bktBase,
    const int2* __restrict__ ebuf, int* sh){
  int j = 0;
  #pragma unroll
  for (int t = 1; t < 7; ++t) if (bb >= m.boff[t]) j = t;
  int b = bb - m.boff[j];
  int n = m.n[j], r = m.r[j], B = m.B[j];
  int* rowp = m.rowp[j]; int* csr = m.csr[j];
  int node0 = b*r;
  int rr = min(r, n - node0);
  int gbase = bktBase[bb];
  int cnt = bktCnt[bb];
  int lbase = gbase - m.eoff[j];
  int* hist = sh; int* aux = sh + 1568;
  int tid = threadIdx.x;
  for (int i = tid; i < rr; i += 256) hist[i] = 0;
  __syncthreads();
  for (int e = tid; e < cnt; e += 256){ int2 ed = ebuf[gbase + e]; atomicAdd(&hist[ed.y - node0], 1); }
  __syncthreads();
  int ch = (rr + 255) >> 8;
  int i0 = tid*ch;
  int s = 0;
  for (int k = 0; k < ch; ++k){ int idx = i0 + k; if (idx < rr){ int t = hist[idx]; hist[idx] = s; s += t; } }
  aux[tid] = s; __syncthreads();
  for (int off = 1; off < 256; off <<= 1){
    int v = aux[tid]; int a = (tid >= off) ? aux[tid - off] : 0;
    __syncthreads();
    aux[tid] = v + a;
    __syncthreads();
  }
  int pre = (tid ? aux[tid-1] : 0) + lbase;
  for (int k = 0; k < ch; ++k){ int idx = i0 + k; if (idx < rr) hist[idx] += pre; }
  __syncthreads();
  for (int i = tid; i < rr; i += 256) rowp[node0 + i] = hist[i];
  if (b == B-1 && tid == 0) rowp[n] = lbase + cnt;
  __syncthreads();
  for (int e = tid; e < cnt; e += 256){
    int2 ed = ebuf[gbase + e];
    int pos = atomicAdd(&hist[ed.y - node0], 1);
    csr[pos] = ed.x;
  }
}

__device__ __forceinline__ void dev_deg2rs(int bid, const int* __restrict__ deg, float* __restrict__ rs, int n){
  int i = bid*256 + threadIdx.x;
  if (i < n) rs[i] = rsqrtf(fmaxf((float)deg[i], 1.f));
}

// ================= 32-lane-per-row gathers (2 rows in flight per wave) =================
__device__ __forceinline__ void dev_attn_gather32(int bid,
    const int* __restrict__ csr, const int* __restrict__ rowp,
    const float* __restrict__ w, const u16* __restrict__ V,
    float* __restrict__ out, int n)
{
  int g = threadIdx.x >> 5, lane = threadIdx.x & 31;
  int row = bid*8 + g;
  if (row >= n) return;
  int st = rowp[row], en = rowp[row+1];
  float a0=0.f,a1=0.f,a2=0.f,a3=0.f;
  if (en > st){
    const ushort4* V4 = (const ushort4*)V;
    float den = 0.f;
    for (int e = st; e < en; ++e){
      int sn = csr[e];
      float x = w[sn];
      den += x;
      ushort4 v = V4[(size_t)sn*32 + lane];
      a0 = fmaf(x, bf2f(v.x), a0); a1 = fmaf(x, bf2f(v.y), a1);
      a2 = fmaf(x, bf2f(v.z), a2); a3 = fmaf(x, bf2f(v.w), a3);
    }
    float inv = 1.f/den;
    a0*=inv; a1*=inv; a2*=inv; a3*=inv;
  }
  ((float4*)out)[(size_t)row*32 + lane] = make_float4(a0,a1,a2,a3);
}

template<int OB16>
__device__ __forceinline__ void dev_gcn_gather32(int bid,
    const int* __restrict__ csr, const int* __restrict__ rowp,
    const u16* __restrict__ Y, const float* __restrict__ bias,
    void* __restrict__ out, int n)
{
  int g = threadIdx.x >> 5, lane = threadIdx.x & 31;
  int row = bid*8 + g;
  if (row >= n) return;
  int st = rowp[row], en = rowp[row+1];
  float a0=0.f,a1=0.f,a2=0.f,a3=0.f;
  const ushort4* Y4 = (const ushort4*)Y;
  for (int e = st; e < en; ++e){
    int sn = csr[e];
    ushort4 v = Y4[(size_t)sn*32 + lane];
    a0 += bf2f(v.x); a1 += bf2f(v.y); a2 += bf2f(v.z); a3 += bf2f(v.w);
  }
  float sc = rsqrtf(fmaxf((float)(en - st), 1.f));
  float4 b4 = ((const float4*)bias)[lane];
  float o0=fmaf(a0,sc,b4.x), o1=fmaf(a1,sc,b4.y), o2=fmaf(a2,sc,b4.z), o3=fmaf(a3,sc,b4.w);
  if (OB16){
    ushort4 o; o.x=f2bf(o0); o.y=f2bf(o1); o.z=f2bf(o2); o.w=f2bf(o3);
    ((ushort4*)out)[(size_t)row*32 + lane] = o;
  } else {
    ((float4*)out)[(size_t)row*32 + lane] = make_float4(o0,o1,o2,o3);
  }
}

// 64-lane head (for head1/head2 where inputs are materialized)
template<int GB16, int DB16>
__device__ __forceinline__ void dev_head(int bid, const void* __restrict__ g, const void* __restrict__ dch,
    const float* __restrict__ W, const float* __restrict__ b,
    float* __restrict__ out, int n, int rowOff)
{
  int wid = threadIdx.x >> 6, lane = threadIdx.x & 63;
  int row = bid*4 + wid;
  if (row >= n) return;
  float x0, x1, x2, x3;
  if (GB16){ const u16* gr = (const u16*)g + (size_t)row*FD; x0 = bf2f(gr[lane]); x1 = bf2f(gr[64+lane]); }
  else     { const float* gr = (const float*)g + (size_t)row*FD; x0 = gr[lane]; x1 = gr[64+lane]; }
  if (DB16){ const u16* dr = (const u16*)dch + (size_t)row*FD; x2 = bf2f(dr[lane]); x3 = bf2f(dr[64+lane]); }
  else     { const float* dr = (const float*)dch + (size_t)row*FD; x2 = dr[lane]; x3 = dr[64+lane]; }
  float acc[5];
  #pragma unroll
  for (int o = 0; o < 5; ++o)
    acc[o] = x0*W[lane*5+o] + x1*W[(64+lane)*5+o] + x2*W[(128+lane)*5+o] + x3*W[(192+lane)*5+o];
  #pragma unroll
  for (int o = 0; o < 5; ++o)
    #pragma unroll
    for (int s = 32; s; s >>= 1) acc[o] += __shfl_xor(acc[o], s);
  if (lane == 0){
    float m = -1e30f;
    #pragma unroll
    for (int o = 0; o < 5; ++o){ acc[o] += b[o]; m = fmaxf(m, acc[o]); }
    float sum = 0.f;
    #pragma unroll
    for (int o = 0; o < 5; ++o){ acc[o] = expf(acc[o]-m); sum += acc[o]; }
    float is = 1.0f/sum;
    float* op = out + (size_t)(rowOff+row)*5;
    #pragma unroll
    for (int o = 0; o < 5; ++o) op[o] = acc[o]*is;
  }
}

// ================= kernels =================

__global__ __launch_bounds__(256) void k1_zero_kqv(int* __restrict__ zeroBlk, int ntot,
    const float* __restrict__ ekW, const float* __restrict__ ekb, const float* __restrict__ eqb,
    const float* __restrict__ dkW, const float* __restrict__ dkb, const float* __restrict__ dqb,
    float* __restrict__ kv, float inv)
{
  int bid = blockIdx.x;
  if (bid < 4){
    if (threadIdx.x < 128){
      int j = bid;
      const float* kW = (j < 2) ? ekW + j*16384 : dkW + (j-2)*16384;
      const float* kb = (j < 2) ? ekb + j*128   : dkb + (j-2)*128;
      const float* qb = (j < 2) ? eqb + j*128   : dqb + (j-2)*128;
      float* o = kv + j*132;
      int k = threadIdx.x;
      float a = 0.f;
      for (int t = 0; t < 128; ++t) a = fmaf(kW[k*128+t], qb[t], a);
      o[k] = a * inv;
      if (k == 0){
        float c = 0.f;
        for (int t = 0; t < 128; ++t) c = fmaf(kb[t], qb[t], c);
        o[128] = c * inv;
      }
    }
  } else {
    int i = (bid-4)*256 + threadIdx.x;
    if (i < ntot) zeroBlk[i] = 0;
  }
}

__global__ __launch_bounds__(256) void k2_p0_deg_gemm(BMeta m, int* __restrict__ bktCnt,
    const int* __restrict__ g0s, const int* __restrict__ g1s, const int* __restrict__ g2s,
    int* __restrict__ d0, int* __restrict__ d1, int* __restrict__ d2,
    const float* __restrict__ X, const float* __restrict__ W, const float* __restrict__ b,
    float* __restrict__ bh0, int np0, int ndeg)
{
  __shared__ float sm[4096 + 1024];
  int bid = blockIdx.x;
  if (bid < np0) dev_p0(m, bid, bktCnt, (int*)sm);
  else if (bid < np0 + ndeg) dev_srcdeg(bid - np0, g0s, g1s, g2s, d0, d1, d2);
  else dev_gemm_f32(sm, sm + 4096, bid - np0 - ndeg, X, W, b, bh0, N0);
}

__global__ __launch_bounds__(256) void k3_p1_deg2rs(BMeta m,
    const int* __restrict__ bktCnt, int* __restrict__ bktBase, int* __restrict__ bktCur,
    const int* __restrict__ deg, float* __restrict__ rs, int ndeg)
{
  __shared__ int sh[256];
  int bid = blockIdx.x;
  if (bid == 0) dev_p1(m, bktCnt, bktBase, bktCur, sh);
  else dev_deg2rs(bid - 1, deg, rs, ndeg);
}

__global__ __launch_bounds__(256) void k4_p2_gemm(BMeta m, int* __restrict__ bktCur, int2* __restrict__ ebuf,
    const float* __restrict__ bh0, const float* __restrict__ evW, const float* __restrict__ evb,
    const float* __restrict__ kvec, float* __restrict__ sS, u16* __restrict__ bV, int np2)
{
  __shared__ float sm[4096 + 1024];
  int bid = blockIdx.x;
  if (bid < np2) dev_p2(m, bid, bktCur, ebuf, (int*)sm);
  else dev_gemm_bf16<1,0>(sm, sm+4096, bid - np2, bh0, nullptr, evW, evb, kvec, sS, bV, N0);
}

__global__ __launch_bounds__(256) void k5_p3_ygemm(BMeta m,
    const int* __restrict__ bktCnt, const int* __restrict__ bktBase, const int2* __restrict__ ebuf,
    const float* __restrict__ bh0, const float* __restrict__ rs0, const float* __restrict__ gW,
    u16* __restrict__ bY0, int np3)
{
  __shared__ float sm[4096 + 1024];
  int bid = blockIdx.x;
  if (bid < np3) dev_p3(m, bid, bktCnt, bktBase, ebuf, (int*)sm);
  else dev_gemm_bf16<0,1>(sm, sm+4096, bid - np3, bh0, rs0, gW, nullptr, nullptr, nullptr, bY0, N0);
}

// ---- mid-pipeline kernels, each carrying a slice of the g0-gather ----
// slice tail: dev_gcn_gather32<1>(sBase + bid - nMain, csr0, rowp0, bY0, gcn_b, bg0, N0)

// K6: attn_gather32(i0)->be1 || g0 slice
__global__ __launch_bounds__(256) void k6_ag_i0(
    const int* __restrict__ csrA, const int* __restrict__ rowpA,
    const float* __restrict__ sS, const u16* __restrict__ bV, float* __restrict__ be1,
    const int* __restrict__ csr0, const int* __restrict__ rowp0, const u16* __restrict__ bY0,
    const float* __restrict__ gb, u16* __restrict__ bg0, int nMain, int sBase)
{
  int bid = blockIdx.x;
  if (bid < nMain) dev_attn_gather32(bid, csrA, rowpA, sS, bV, be1, N1);
  else dev_gcn_gather32<1>(sBase + bid - nMain, csr0, rowp0, bY0, gb, bg0, N0);
}

// K7: enc1 V+score gemm || g0 slice
__global__ __launch_bounds__(256) void k7_gemm_enc1(
    const float* __restrict__ be1, const float* __restrict__ vW, const float* __restrict__ vb,
    const float* __restrict__ kvec, float* __restrict__ sS, u16* __restrict__ bV,
    const int* __restrict__ csr0, const int* __restrict__ rowp0, const u16* __restrict__ bY0,
    const float* __restrict__ gb, u16* __restrict__ bg0, int nMain, int sBase)
{
  __shared__ float sm[4096 + 1024];
  int bid = blockIdx.x;
  if (bid < nMain) dev_gemm_bf16<1,0>(sm, sm+4096, bid, be1, nullptr, vW, vb, kvec, sS, bV, N1);
  else dev_gcn_gather32<1>(sBase + bid - nMain, csr0, rowp0, bY0, gb, bg0, N0);
}

// K8: attn_gather32(i1)->be2 || g0 slice
__global__ __launch_bounds__(256) void k8_ag_i1(
    const int* __restrict__ csrA, const int* __restrict__ rowpA,
    const float* __restrict__ sS, const u16* __restrict__ bV, float* __restrict__ be2,
    const int* __restrict__ csr0, const int* __restrict__ rowp0, const u16* __restrict__ bY0,
    const float* __restrict__ gb, u16* __restrict__ bg0, int nMain, int sBase)
{
  int bid = blockIdx.x;
  if (bid < nMain) dev_attn_gather32(bid, csrA, rowpA, sS, bV, be2, N2);
  else dev_gcn_gather32<1>(sBase + bid - nMain, csr0, rowp0, bY0, gb, bg0, N0);
}

// K9: gcn1 Y gemm || gcn2 Y gemm || g0 slice
__global__ __launch_bounds__(256) void k9_ygemm(
    const float* __restrict__ be1, const float* __restrict__ rs1, const float* __restrict__ W1, u16* __restrict__ bY1,
    const float* __restrict__ be2, const float* __restrict__ rs2, const float* __restrict__ W2, u16* __restrict__ bY2,
    const int* __restrict__ csr0, const int* __restrict__ rowp0, const u16* __restrict__ bY0,
    const float* __restrict__ gb, u16* __restrict__ bg0, int ga, int nMain, int sBase)
{
  __shared__ float sm[4096 + 1024];
  int bid = blockIdx.x;
  if (bid < ga) dev_gemm_bf16<0,1>(sm, sm+4096, bid, be1, rs1, W1, nullptr, nullptr, nullptr, bY1, N1);
  else if (bid < nMain) dev_gemm_bf16<0,1>(sm, sm+4096, bid - ga, be2, rs2, W2, nullptr, nullptr, nullptr, bY2, N2);
  else dev_gcn_gather32<1>(sBase + bid - nMain, csr0, rowp0, bY0, gb, bg0, N0);
}

// K10: gcn_gather32(g1,bf16) || gcn_gather32(g2,f32) || g0 slice
__global__ __launch_bounds__(256) void k10_ggathers(
    const int* __restrict__ csr1, const int* __restrict__ rowp1, const u16* __restrict__ bY1,
    const float* __restrict__ b1, u16* __restrict__ bg1,
    const int* __restrict__ csr2, const int* __restrict__ rowp2, const u16* __restrict__ bY2,
    const float* __restrict__ b2, float* __restrict__ bg2,
    const int* __restrict__ csr0, const int* __restrict__ rowp0, const u16* __restrict__ bY0,
    const float* __restrict__ gb, u16* __restrict__ bg0, int ga, int nMain, int sBase)
{
  int bid = blockIdx.x;
  if (bid < ga) dev_gcn_gather32<1>(bid, csr1, rowp1, bY1, b1, bg1, N1);
  else if (bid < nMain) dev_gcn_gather32<0>(bid - ga, csr2, rowp2, bY2, b2, bg2, N2);
  else dev_gcn_gather32<1>(sBase + bid - nMain, csr0, rowp0, bY0, gb, bg0, N0);
}

// K11: dec0 gemm || head2 || g0 slice
__global__ __launch_bounds__(256) void k11_dec0_head2(
    const float* __restrict__ bg2, const float* __restrict__ vW, const float* __restrict__ vb,
    const float* __restrict__ kvec, float* __restrict__ sS, u16* __restrict__ bV,
    const float* __restrict__ hW, const float* __restrict__ hb, float* __restrict__ out,
    const int* __restrict__ csr0, const int* __restrict__ rowp0, const u16* __restrict__ bY0,
    const float* __restrict__ gb, u16* __restrict__ bg0, int ngemm, int nMain, int sBase)
{
  __shared__ float sm[4096 + 1024];
  int bid = blockIdx.x;
  if (bid < ngemm) dev_gemm_bf16<1,0>(sm, sm+4096, bid, bg2, nullptr, vW, vb, kvec, sS, bV, N2);
  else if (bid < nMain) dev_head<0,0>(bid - ngemm, bg2, bg2, hW, hb, out, N2, N0+N1);
  else dev_gcn_gather32<1>(sBase + bid - nMain, csr0, rowp0, bY0, gb, bg0, N0);
}

// K12: attn_gather32(dc0)->be1 (d1) || g0 slice
__global__ __launch_bounds__(256) void k12_ag_d1(
    const int* __restrict__ csrA, const int* __restrict__ rowpA,
    const float* __restrict__ sS, const u16* __restrict__ bV, float* __restrict__ be1,
    const int* __restrict__ csr0, const int* __restrict__ rowp0, const u16* __restrict__ bY0,
    const float* __restrict__ gb, u16* __restrict__ bg0, int nMain, int sBase)
{
  int bid = blockIdx.x;
  if (bid < nMain) dev_attn_gather32(bid, csrA, rowpA, sS, bV, be1, N1);
  else dev_gcn_gather32<1>(sBase + bid - nMain, csr0, rowp0, bY0, gb, bg0, N0);
}

// K13: dec1 gemm || head1 || g0 slice
__global__ __launch_bounds__(256) void k13_dec1_head1(
    const float* __restrict__ be1, const float* __restrict__ vW, const float* __restrict__ vb,
    const float* __restrict__ kvec, float* __restrict__ sS, u16* __restrict__ bV,
    const u16* __restrict__ bg1, const float* __restrict__ hW, const float* __restrict__ hb,
    float* __restrict__ out,
    const int* __restrict__ csr0, const int* __restrict__ rowp0, const u16* __restrict__ bY0,
    const float* __restrict__ gb, u16* __restrict__ bg0, int ngemm, int nMain, int sBase)
{
  __shared__ float sm[4096 + 1024];
  int bid = blockIdx.x;
  if (bid < ngemm) dev_gemm_bf16<1,0>(sm, sm+4096, bid, be1, nullptr, vW, vb, kvec, sS, bV, N1);
  else if (bid < nMain) dev_head<1,0>(bid - ngemm, bg1, be1, hW, hb, out, N1, N0);
  else dev_gcn_gather32<1>(sBase + bid - nMain, csr0, rowp0, bY0, gb, bg0, N0);
}

// K14: fused d0 gather + head0, 32-lane groups (8 rows/block)
__global__ __launch_bounds__(256) void k14_gather_head0(
    const int* __restrict__ csr, const int* __restrict__ rowp,
    const float* __restrict__ w, const u16* __restrict__ V,
    const u16* __restrict__ bg0,
    const float* __restrict__ hW, const float* __restrict__ hb,
    float* __restrict__ out)
{
  int g = threadIdx.x >> 5, lane = threadIdx.x & 31;
  int row = blockIdx.x*8 + g;
  if (row >= N0) return;
  int st = rowp[row], en = rowp[row+1];
  float a0=0.f,a1=0.f,a2=0.f,a3=0.f;
  if (en > st){
    const ushort4* V4 = (const ushort4*)V;
    float den = 0.f;
    for (int e = st; e < en; ++e){
      int sn = csr[e];
      float x = w[sn];
      den += x;
      ushort4 v = V4[(size_t)sn*32 + lane];
      a0 = fmaf(x, bf2f(v.x), a0); a1 = fmaf(x, bf2f(v.y), a1);
      a2 = fmaf(x, bf2f(v.z), a2); a3 = fmaf(x, bf2f(v.w), a3);
    }
    float inv = 1.f/den;
    a0*=inv; a1*=inv; a2*=inv; a3*=inv;
  }
  // lane owns d0 cols 4l..4l+3 (= a0..a3) and g cols 4l..4l+3
  ushort4 gv = ((const ushort4*)(bg0 + (size_t)row*FD))[lane];
  float g0 = bf2f(gv.x), g1 = bf2f(gv.y), g2 = bf2f(gv.z), g3 = bf2f(gv.w);
  int j = 4*lane;
  float acc[5];
  #pragma unroll
  for (int o = 0; o < 5; ++o){
    acc[o] = g0*hW[(j+0)*5+o] + g1*hW[(j+1)*5+o] + g2*hW[(j+2)*5+o] + g3*hW[(j+3)*5+o]
           + a0*hW[(128+j+0)*5+o] + a1*hW[(128+j+1)*5+o] + a2*hW[(128+j+2)*5+o] + a3*hW[(128+j+3)*5+o];
  }
  #pragma unroll
  for (int o = 0; o < 5; ++o)
    #pragma unroll
    for (int s = 16; s; s >>= 1) acc[o] += __shfl_xor(acc[o], s, 32);
  if (lane == 0){
    float m = -1e30f;
    #pragma unroll
    for (int o = 0; o < 5; ++o){ acc[o] += hb[o]; m = fmaxf(m, acc[o]); }
    float sum = 0.f;
    #pragma unroll
    for (int o = 0; o < 5; ++o){ acc[o] = expf(acc[o]-m); sum += acc[o]; }
    float is = 1.0f/sum;
    float* op = out + (size_t)row*5;
    #pragma unroll
    for (int o = 0; o < 5; ++o) op[o] = acc[o]*is;
  }
}

// ================= host =================
extern "C" void kernel_launch(void* const* d_in, const int* in_sizes, int n_in,
                              void* d_out, int out_size, void* d_ws, size_t ws_size,
                              hipStream_t stream)
{
  const float* X      = (const float*)d_in[0];
  const float* emb_W  = (const float*)d_in[1];
  const float* emb_b  = (const float*)d_in[2];
  const float* gcn_W  = (const float*)d_in[3];
  const float* gcn_b  = (const float*)d_in[4];
  const float* enc_qb = (const float*)d_in[6];
  const float* enc_kW = (const float*)d_in[7];
  const float* enc_kb = (const float*)d_in[8];
  const float* enc_vW = (const float*)d_in[9];
  const float* enc_vb = (const float*)d_in[10];
  const float* dec_qb = (const float*)d_in[12];
  const float* dec_kW = (const float*)d_in[13];
  const float* dec_kb = (const float*)d_in[14];
  const float* dec_vW = (const float*)d_in[15];
  const float* dec_vb = (const float*)d_in[16];
  const float* head_W = (const float*)d_in[17];
  const float* head_b = (const float*)d_in[18];
  const int* g0s  = (const int*)d_in[19];
  const int* g0d  = (const int*)d_in[20];
  const int* g1s  = (const int*)d_in[21];
  const int* g1d  = (const int*)d_in[22];
  const int* g2s  = (const int*)d_in[23];
  const int* g2d  = (const int*)d_in[24];
  const int* i0s  = (const int*)d_in[25];
  const int* i0d  = (const int*)d_in[26];
  const int* i1s  = (const int*)d_in[27];
  const int* i1d  = (const int*)d_in[28];
  const int* dc0s = (const int*)d_in[29];
  const int* dc0d = (const int*)d_in[30];
  const int* dc1s = (const int*)d_in[31];
  const int* dc1d = (const int*)d_in[32];

  // ---- workspace layout (as round 6) ----
  float* ws = (float*)d_ws;
  float* bh0 = ws;
  float* be1 = bh0 + (size_t)N0*FD;
  float* be2 = be1 + (size_t)N1*FD;
  float* bg2 = be2 + (size_t)N2*FD;
  float* sS  = bg2 + (size_t)N2*FD;
  float* kvec = sS + N0;
  float* rsO  = kvec + 4*132;
  u16*  bg0 = (u16*)(rsO + (N0+N1+N2));
  u16*  bg1 = bg0 + (size_t)N0*FD;
  u16*  bV  = bg1 + (size_t)N1*FD;
  u16*  bY0 = bV  + (size_t)N0*FD;
  u16*  bY1 = bV + 4000000;
  u16*  bY2 = bV + 8000000;
  int*  degBlk  = (int*)(bY0 + (size_t)N0*FD);
  int*  bktCnt  = degBlk + (N0+N1+N2);
  int*  bktBase = bktCnt + 224;
  int*  bktCur  = bktBase + 224;
  int*  rowpBlk = bktCur + 224;
  int*  csrBlk  = rowpBlk + 287507;
  int2* ebuf    = (int2*)(csrBlk + 2500000 + 1);

  const int* srcP[7] = {g0s,g1s,g2s,i0s,i1s,dc0s,dc1s};
  const int* dstP[7] = {g0d,g1d,g2d,i0d,i1d,dc0d,dc1d};
  const int nArr[7] = {N0,N1,N2,N1,N2,N1,N0};
  const int EArr[7] = {1000000,400000,100000,400000,100000,100000,400000};
  const int BArr[7] = {64,32,8,32,8,16,64};
  const int rArr[7] = {1563,782,782,782,782,1563,1563};

  BMeta m;
  {
    int eo=0, bo=0, po=0, ro=0, co=0;
    for (int j=0;j<7;++j){
      m.src[j]=srcP[j]; m.dst[j]=dstP[j];
      m.rowp[j]=rowpBlk+ro; m.csr[j]=csrBlk+co;
      m.n[j]=nArr[j]; m.E[j]=EArr[j]; m.B[j]=BArr[j]; m.r[j]=rArr[j];
      m.eoff[j]=eo; m.boff[j]=bo; m.pblk[j]=po;
      eo+=EArr[j]; bo+=BArr[j]; po+=ceildiv(EArr[j],4096); ro+=nArr[j]+1; co+=EArr[j];
    }
    m.eoff[7]=eo; m.boff[7]=bo; m.pblk[7]=po;
  }

  const float invScale = 0.17677669529663687f;
  float* out = (float*)d_out;
  float* rs0 = rsO; float* rs1 = rsO + N0; float* rs2 = rsO + N0 + N1;
  int* deg0 = degBlk; int* deg1 = degBlk + N0; int* deg2 = degBlk + N0 + N1;

  const int NP0 = m.pblk[7];
  const int NDEG = 245 + 98 + 25;
  const int NP3 = m.boff[7];
  const int ZTOT = (N0+N1+N2) + 224;
  const int GH0 = ceildiv(N0,32);           // 3125
  const int GH1 = ceildiv(N1,32);           // 782
  const int GH2 = ceildiv(N2,32);           // 196
  const int GA1_32 = ceildiv(N1,8);         // 3125
  const int GA2_32 = ceildiv(N2,8);         // 782
  const int G0B = ceildiv(N0,8);            // 12500 (g0-gather blocks)
  const int GH2H = ceildiv(N2,4);           // 1563 (head2, 64-lane)
  const int GH1H = ceildiv(N1,4);           // 6250 (head1, 64-lane)

  // slice bounds for g0-gather across 8 mid-kernels
  int ss[9];
  for (int i = 0; i <= 8; ++i) ss[i] = (int)(((long long)G0B * i) / 8);

  // K1: zero || kvec
  k1_zero_kqv<<<4 + ceildiv(ZTOT,256), 256, 0, stream>>>(degBlk, ZTOT,
      enc_kW, enc_kb, enc_qb, dec_kW, dec_kb, dec_qb, kvec, invScale);
  // K2: P0 || srcdeg || h0 gemm
  k2_p0_deg_gemm<<<NP0 + NDEG + GH0, 256, 0, stream>>>(m, bktCnt,
      g0s, g1s, g2s, deg0, deg1, deg2, X, emb_W, emb_b, bh0, NP0, NDEG);
  // K3: P1 || deg2rs
  k3_p1_deg2rs<<<1 + ceildiv(N0+N1+N2,256), 256, 0, stream>>>(m, bktCnt, bktBase, bktCur,
      degBlk, rsO, N0+N1+N2);
  // K4: P2 || enc0 V+score gemm
  k4_p2_gemm<<<NP0 + GH0, 256, 0, stream>>>(m, bktCur, ebuf,
      bh0, enc_vW, enc_vb, kvec, sS, bV, NP0);
  // K5: P3 || gcn0 Y gemm
  k5_p3_ygemm<<<NP3 + GH0, 256, 0, stream>>>(m, bktCnt, bktBase, ebuf,
      bh0, rs0, gcn_W, bY0, NP3);
  // K6: attn_gather(i0)->be1 || g0[0]
  k6_ag_i0<<<GA1_32 + (ss[1]-ss[0]), 256, 0, stream>>>(m.csr[3], m.rowp[3], sS, bV, be1,
      m.csr[0], m.rowp[0], bY0, gcn_b, bg0, GA1_32, ss[0]);
  // K7: enc1 gemm || g0[1]
  k7_gemm_enc1<<<GH1 + (ss[2]-ss[1]), 256, 0, stream>>>(be1, enc_vW+16384, enc_vb+128, kvec+132, sS, bV,
      m.csr[0], m.rowp[0], bY0, gcn_b, bg0, GH1, ss[1]);
  // K8: attn_gather(i1)->be2 || g0[2]
  k8_ag_i1<<<GA2_32 + (ss[3]-ss[2]), 256, 0, stream>>>(m.csr[4], m.rowp[4], sS, bV, be2,
      m.csr[0], m.rowp[0], bY0, gcn_b, bg0, GA2_32, ss[2]);
  // K9: gcn1 Y || gcn2 Y || g0[3]
  k9_ygemm<<<GH1 + GH2 + (ss[4]-ss[3]), 256, 0, stream>>>(be1, rs1, gcn_W+16384, bY1,
      be2, rs2, gcn_W+32768, bY2,
      m.csr[0], m.rowp[0], bY0, gcn_b, bg0, GH1, GH1+GH2, ss[3]);
  // K10: gather(g1) || gather(g2) || g0[4]
  k10_ggathers<<<GA1_32 + GA2_32 + (ss[5]-ss[4]), 256, 0, stream>>>(
      m.csr[1], m.rowp[1], bY1, gcn_b+128, bg1,
      m.csr[2], m.rowp[2], bY2, gcn_b+256, bg2,
      m.csr[0], m.rowp[0], bY0, gcn_b, bg0, GA1_32, GA1_32+GA2_32, ss[4]);
  // K11: dec0 gemm || head2 || g0[5]
  k11_dec0_head2<<<GH2 + GH2H + (ss[6]-ss[5]), 256, 0, stream>>>(bg2, dec_vW, dec_vb, kvec+264, sS, bV,
      head_W+2560, head_b+10, out,
      m.csr[0], m.rowp[0], bY0, gcn_b, bg0, GH2, GH2+GH2H, ss[5]);
  // K12: attn_gather(dc0)->be1 (d1) || g0[6]
  k12_ag_d1<<<GA1_32 + (ss[7]-ss[6]), 256, 0, stream>>>(m.csr[5], m.rowp[5], sS, bV, be1,
      m.csr[0], m.rowp[0], bY0, gcn_b, bg0, GA1_32, ss[6]);
  // K13: dec1 gemm || head1 || g0[7]
  k13_dec1_head1<<<GH1 + GH1H + (ss[8]-ss[7]), 256, 0, stream>>>(be1, dec_vW+16384, dec_vb+128, kvec+396, sS, bV,
      bg1, head_W+1280, head_b+5, out,
      m.csr[0], m.rowp[0], bY0, gcn_b, bg0, GH1, GH1+GH1H, ss[7]);
  // K14: fused d0 gather + head0
  k14_gather_head0<<<G0B, 256, 0, stream>>>(m.csr[6], m.rowp[6], sS, bV, bg0,
      head_W, head_b, out);
}

// Round 8
// 505.526 us; speedup vs baseline: 9.8528x; 1.0298x over previous
//
#include <hip/hip_runtime.h>
#include <math.h>

#define N0 100000
#define N1 25000
#define N2 6250
#define FD 128

typedef unsigned short u16;
typedef unsigned int u32;

static inline int ceildiv(int a, int b){ return (a + b - 1)/b; }

__device__ __forceinline__ u16 f2bf(float f){
  u32 u = __float_as_uint(f);
  u += 0x7fffu + ((u >> 16) & 1u);
  return (u16)(u >> 16);
}
__device__ __forceinline__ float bf2f(u16 h){
  return __uint_as_float(((u32)h) << 16);
}

// ================= bucket-CSR metadata =================
struct BMeta {
  const int* src[7]; const int* dst[7];
  int* rowp[7]; int* csr[7];
  int* degp[7];                 // src-degree hist target (g0,g1,g2 only)
  int n[7], E[7], B[7], r[7];
  int eoff[8];
  int boff[8];
  int pblk[8];
};

// ================= GEMM =================
__device__ __forceinline__ void mm_inner(const float* Al, const float* Wl, int r0, int c0, float acc[4][4]){
  #pragma unroll
  for (int kq = 0; kq < 8; ++kq) {
    int k0 = kq*4;
    float4 a[4], w[4];
    #pragma unroll
    for (int i=0;i<4;++i) a[i] = *(const float4*)&Al[(r0+i)*32 + k0];
    #pragma unroll
    for (int kk=0;kk<4;++kk) w[kk] = *(const float4*)&Wl[(k0+kk)*128 + c0];
    #pragma unroll
    for (int i=0;i<4;++i){
      acc[i][0] = fmaf(a[i].x,w[0].x, fmaf(a[i].y,w[1].x, fmaf(a[i].z,w[2].x, fmaf(a[i].w,w[3].x, acc[i][0]))));
      acc[i][1] = fmaf(a[i].x,w[0].y, fmaf(a[i].y,w[1].y, fmaf(a[i].z,w[2].y, fmaf(a[i].w,w[3].y, acc[i][1]))));
      acc[i][2] = fmaf(a[i].x,w[0].z, fmaf(a[i].y,w[1].z, fmaf(a[i].z,w[2].z, fmaf(a[i].w,w[3].z, acc[i][2]))));
      acc[i][3] = fmaf(a[i].x,w[0].w, fmaf(a[i].y,w[1].w, fmaf(a[i].z,w[2].w, fmaf(a[i].w,w[3].w, acc[i][3]))));
    }
  }
}

// A(f32 or bf16, optional deg-rsqrt row scale) @ W + (bias?) -> bf16 out.
// SCORE: also emit w[row] = exp(dot(A_row,kvec)+kvec[128]).
template<int SCORE, int SCALEDEG, int AB16>
__device__ __forceinline__ void dev_gemm(float* Wl, float* Al, int bid,
    const void* __restrict__ Ap, const int* __restrict__ deg,
    const float* __restrict__ W, const float* __restrict__ bias,
    const float* __restrict__ kvec, float* __restrict__ sOut,
    u16* __restrict__ out, int n)
{
  const int tid = threadIdx.x;
  const int row0 = bid * 32;
  const int c0 = (tid & 31) * 4, r0 = (tid >> 5) * 4;
  const int r = tid >> 3, fc = tid & 7;
  const int gr_s = row0 + r;
  float acc[4][4] = {};
  float sacc = 0.f;
  const float4* W4 = (const float4*)W;
  float rsc = 1.f;
  if (SCALEDEG && gr_s < n) rsc = rsqrtf(fmaxf((float)deg[gr_s], 1.f));
  for (int kp = 0; kp < 4; ++kp) {
    float4* Wl4 = (float4*)Wl;
    #pragma unroll
    for (int i = 0; i < 4; ++i) Wl4[tid + 256*i] = W4[kp*1024 + tid + 256*i];
    {
      float4 v = make_float4(0.f,0.f,0.f,0.f);
      if (gr_s < n){
        if (AB16){
          ushort4 h = ((const ushort4*)Ap)[(size_t)gr_s*32 + kp*8 + fc];
          v = make_float4(bf2f(h.x), bf2f(h.y), bf2f(h.z), bf2f(h.w));
        } else {
          v = ((const float4*)Ap)[(size_t)gr_s*32 + kp*8 + fc];
        }
        if (SCALEDEG){ v.x*=rsc; v.y*=rsc; v.z*=rsc; v.w*=rsc; }
      }
      ((float4*)Al)[tid] = v;
      if (SCORE){
        float4 kv = *(const float4*)&kvec[kp*32 + fc*4];
        sacc += v.x*kv.x + v.y*kv.y + v.z*kv.z + v.w*kv.w;
      }
    }
    __syncthreads();
    mm_inner(Al, Wl, r0, c0, acc);
    __syncthreads();
  }
  if (SCORE){
    sacc += __shfl_xor(sacc, 1);
    sacc += __shfl_xor(sacc, 2);
    sacc += __shfl_xor(sacc, 4);
    if (fc == 0 && gr_s < n) sOut[gr_s] = expf(sacc + kvec[128]);
  }
  float4 bv = make_float4(0.f,0.f,0.f,0.f);
  if (bias) bv = *(const float4*)&bias[c0];
  #pragma unroll
  for (int i=0;i<4;++i){
    int gr = row0 + r0 + i;
    if (gr < n){
      ushort4 o;
      o.x = f2bf(acc[i][0]+bv.x); o.y = f2bf(acc[i][1]+bv.y);
      o.z = f2bf(acc[i][2]+bv.z); o.w = f2bf(acc[i][3]+bv.w);
      *(ushort4*)&out[(size_t)gr*FD + c0] = o;
    }
  }
}

// ================= bucket-CSR passes =================
__device__ __forceinline__ void dev_p0(const BMeta& m, int bid, int* __restrict__ bktCnt, int* sh){
  int j = 0;
  #pragma unroll
  for (int t = 1; t < 7; ++t) if (bid >= m.pblk[t]) j = t;
  int lb = bid - m.pblk[j];
  const int* dst = m.dst[j]; int E = m.E[j], r = m.r[j], B = m.B[j];
  if (threadIdx.x < 64) sh[threadIdx.x] = 0;
  __syncthreads();
  int base = lb*4096 + threadIdx.x;
  #pragma unroll
  for (int i = 0; i < 16; ++i){ int e = base + i*256; if (e < E) atomicAdd(&sh[dst[e]/r], 1); }
  __syncthreads();
  if ((int)threadIdx.x < B) atomicAdd(&bktCnt[m.boff[j] + threadIdx.x], sh[threadIdx.x]);
}

__device__ __forceinline__ void dev_p1(const BMeta& m, const int* __restrict__ bktCnt,
    int* __restrict__ bktBase, int* __restrict__ bktCur, int* sh){
  int tid = threadIdx.x;
  if (tid < 224) sh[tid] = bktCnt[tid];
  __syncthreads();
  if (tid < 7){
    int acc = m.eoff[tid];
    for (int b = m.boff[tid]; b < m.boff[tid+1]; ++b){ int v = sh[b]; sh[b] = acc; acc += v; }
  }
  __syncthreads();
  if (tid < 224){ bktBase[tid] = sh[tid]; bktCur[tid] = sh[tid]; }
}

// P2: scatter into bucket-contiguous ebuf; also src-degree hist for g0/g1/g2
__device__ __forceinline__ void dev_p2(const BMeta& m, int bid, int* __restrict__ bktCur,
    int2* __restrict__ ebuf, int* sh){
  int j = 0;
  #pragma unroll
  for (int t = 1; t < 7; ++t) if (bid >= m.pblk[t]) j = t;
  int lb = bid - m.pblk[j];
  const int* src = m.src[j]; const int* dst = m.dst[j];
  int* dp = m.degp[j];
  int E = m.E[j], r = m.r[j], B = m.B[j];
  int* h = sh; int* start = sh + 64;
  if (threadIdx.x < 64) h[threadIdx.x] = 0;
  __syncthreads();
  int base = lb*4096 + threadIdx.x;
  #pragma unroll
  for (int i = 0; i < 16; ++i){ int e = base + i*256; if (e < E) atomicAdd(&h[dst[e]/r], 1); }
  __syncthreads();
  if ((int)threadIdx.x < B) start[threadIdx.x] = atomicAdd(&bktCur[m.boff[j] + threadIdx.x], h[threadIdx.x]);
  __syncthreads();
  #pragma unroll
  for (int i = 0; i < 16; ++i){
    int e = base + i*256;
    if (e < E){
      int s = src[e], d = dst[e];
      if (dp) atomicAdd(&dp[s], 1);
      int pos = atomicAdd(&start[d/r], 1);
      ebuf[pos] = make_int2(s, d);
    }
  }
}

__device__ __forceinline__ void dev_p3(const BMeta& m, int bb,
    const int* __restrict__ bktCnt, const int* __restrict__ bktBase,
    const int2* __restrict__ ebuf, int* sh){
  int j = 0;
  #pragma unroll
  for (int t = 1; t < 7; ++t) if (bb >= m.boff[t]) j = t;
  int b = bb - m.boff[j];
  int n = m.n[j], r = m.r[j], B = m.B[j];
  int* rowp = m.rowp[j]; int* csr = m.csr[j];
  int node0 = b*r;
  int rr = min(r, n - node0);
  int gbase = bktBase[bb];
  int cnt = bktCnt[bb];
  int lbase = gbase - m.eoff[j];
  int* hist = sh; int* aux = sh + 1568;
  int tid = threadIdx.x;
  for (int i = tid; i < rr; i += 256) hist[i] = 0;
  __syncthreads();
  for (int e = tid; e < cnt; e += 256){ int2 ed = ebuf[gbase + e]; atomicAdd(&hist[ed.y - node0], 1); }
  __syncthreads();
  int ch = (rr + 255) >> 8;
  int i0 = tid*ch;
  int s = 0;
  for (int k = 0; k < ch; ++k){ int idx = i0 + k; if (idx < rr){ int t = hist[idx]; hist[idx] = s; s += t; } }
  aux[tid] = s; __syncthreads();
  for (int off = 1; off < 256; off <<= 1){
    int v = aux[tid]; int a = (tid >= off) ? aux[tid - off] : 0;
    __syncthreads();
    aux[tid] = v + a;
    __syncthreads();
  }
  int pre = (tid ? aux[tid-1] : 0) + lbase;
  for (int k = 0; k < ch; ++k){ int idx = i0 + k; if (idx < rr) hist[idx] += pre; }
  __syncthreads();
  for (int i = tid; i < rr; i += 256) rowp[node0 + i] = hist[i];
  if (b == B-1 && tid == 0) rowp[n] = lbase + cnt;
  __syncthreads();
  for (int e = tid; e < cnt; e += 256){
    int2 ed = ebuf[gbase + e];
    int pos = atomicAdd(&hist[ed.y - node0], 1);
    csr[pos] = ed.x;
  }
}

// ================= 32-lane gathers =================
template<int OB16>
__device__ __forceinline__ void dev_attn_gather32(int bid,
    const int* __restrict__ csr, const int* __restrict__ rowp,
    const float* __restrict__ w, const u16* __restrict__ V,
    void* __restrict__ out, int n)
{
  int g = threadIdx.x >> 5, lane = threadIdx.x & 31;
  int row = bid*8 + g;
  if (row >= n) return;
  int st = rowp[row], en = rowp[row+1];
  float a0=0.f,a1=0.f,a2=0.f,a3=0.f;
  if (en > st){
    const ushort4* V4 = (const ushort4*)V;
    float den = 0.f;
    for (int e = st; e < en; ++e){
      int sn = csr[e];
      float x = w[sn];
      den += x;
      ushort4 v = V4[(size_t)sn*32 + lane];
      a0 = fmaf(x, bf2f(v.x), a0); a1 = fmaf(x, bf2f(v.y), a1);
      a2 = fmaf(x, bf2f(v.z), a2); a3 = fmaf(x, bf2f(v.w), a3);
    }
    float inv = 1.f/den;
    a0*=inv; a1*=inv; a2*=inv; a3*=inv;
  }
  if (OB16){
    ushort4 o; o.x=f2bf(a0); o.y=f2bf(a1); o.z=f2bf(a2); o.w=f2bf(a3);
    ((ushort4*)out)[(size_t)row*32 + lane] = o;
  } else {
    ((float4*)out)[(size_t)row*32 + lane] = make_float4(a0,a1,a2,a3);
  }
}

template<int OB16>
__device__ __forceinline__ void dev_gcn_gather32(int bid,
    const int* __restrict__ csr, const int* __restrict__ rowp,
    const u16* __restrict__ Y, const float* __restrict__ bias,
    void* __restrict__ out, int n)
{
  int g = threadIdx.x >> 5, lane = threadIdx.x & 31;
  int row = bid*8 + g;
  if (row >= n) return;
  int st = rowp[row], en = rowp[row+1];
  float a0=0.f,a1=0.f,a2=0.f,a3=0.f;
  const ushort4* Y4 = (const ushort4*)Y;
  for (int e = st; e < en; ++e){
    int sn = csr[e];
    ushort4 v = Y4[(size_t)sn*32 + lane];
    a0 += bf2f(v.x); a1 += bf2f(v.y); a2 += bf2f(v.z); a3 += bf2f(v.w);
  }
  float sc = rsqrtf(fmaxf((float)(en - st), 1.f));
  float4 b4 = ((const float4*)bias)[lane];
  float o0=fmaf(a0,sc,b4.x), o1=fmaf(a1,sc,b4.y), o2=fmaf(a2,sc,b4.z), o3=fmaf(a3,sc,b4.w);
  if (OB16){
    ushort4 o; o.x=f2bf(o0); o.y=f2bf(o1); o.z=f2bf(o2); o.w=f2bf(o3);
    ((ushort4*)out)[(size_t)row*32 + lane] = o;
  } else {
    ((float4*)out)[(size_t)row*32 + lane] = make_float4(o0,o1,o2,o3);
  }
}

// 64-lane head; GB16/DB16 select bf16 inputs
template<int GB16, int DB16>
__device__ __forceinline__ void dev_head(int bid, const void* __restrict__ g, const void* __restrict__ dch,
    const float* __restrict__ W, const float* __restrict__ b,
    float* __restrict__ out, int n, int rowOff)
{
  int wid = threadIdx.x >> 6, lane = threadIdx.x & 63;
  int row = bid*4 + wid;
  if (row >= n) return;
  float x0, x1, x2, x3;
  if (GB16){ const u16* gr = (const u16*)g + (size_t)row*FD; x0 = bf2f(gr[lane]); x1 = bf2f(gr[64+lane]); }
  else     { const float* gr = (const float*)g + (size_t)row*FD; x0 = gr[lane]; x1 = gr[64+lane]; }
  if (DB16){ const u16* dr = (const u16*)dch + (size_t)row*FD; x2 = bf2f(dr[lane]); x3 = bf2f(dr[64+lane]); }
  else     { const float* dr = (const float*)dch + (size_t)row*FD; x2 = dr[lane]; x3 = dr[64+lane]; }
  float acc[5];
  #pragma unroll
  for (int o = 0; o < 5; ++o)
    acc[o] = x0*W[lane*5+o] + x1*W[(64+lane)*5+o] + x2*W[(128+lane)*5+o] + x3*W[(192+lane)*5+o];
  #pragma unroll
  for (int o = 0; o < 5; ++o)
    #pragma unroll
    for (int s = 32; s; s >>= 1) acc[o] += __shfl_xor(acc[o], s);
  if (lane == 0){
    float m = -1e30f;
    #pragma unroll
    for (int o = 0; o < 5; ++o){ acc[o] += b[o]; m = fmaxf(m, acc[o]); }
    float sum = 0.f;
    #pragma unroll
    for (int o = 0; o < 5; ++o){ acc[o] = expf(acc[o]-m); sum += acc[o]; }
    float is = 1.0f/sum;
    float* op = out + (size_t)(rowOff+row)*5;
    #pragma unroll
    for (int o = 0; o < 5; ++o) op[o] = acc[o]*is;
  }
}

// ================= kernels =================

__global__ __launch_bounds__(256) void k1_zero_kqv(int* __restrict__ zeroBlk, int ntot,
    const float* __restrict__ ekW, const float* __restrict__ ekb, const float* __restrict__ eqb,
    const float* __restrict__ dkW, const float* __restrict__ dkb, const float* __restrict__ dqb,
    float* __restrict__ kv, float inv)
{
  int bid = blockIdx.x;
  if (bid < 4){
    if (threadIdx.x < 128){
      int j = bid;
      const float* kW = (j < 2) ? ekW + j*16384 : dkW + (j-2)*16384;
      const float* kb = (j < 2) ? ekb + j*128   : dkb + (j-2)*128;
      const float* qb = (j < 2) ? eqb + j*128   : dqb + (j-2)*128;
      float* o = kv + j*132;
      int k = threadIdx.x;
      float a = 0.f;
      for (int t = 0; t < 128; ++t) a = fmaf(kW[k*128+t], qb[t], a);
      o[k] = a * inv;
      if (k == 0){
        float c = 0.f;
        for (int t = 0; t < 128; ++t) c = fmaf(kb[t], qb[t], c);
        o[128] = c * inv;
      }
    }
  } else {
    int i = (bid-4)*256 + threadIdx.x;
    if (i < ntot) zeroBlk[i] = 0;
  }
}

// K2: P0 || h0 gemm (f32 A -> bf16 out, with bias)
__global__ __launch_bounds__(256) void k2_p0_gemm(BMeta m, int* __restrict__ bktCnt,
    const float* __restrict__ X, const float* __restrict__ W, const float* __restrict__ b,
    u16* __restrict__ bh0, int np0)
{
  __shared__ float sm[4096 + 1024];
  int bid = blockIdx.x;
  if (bid < np0) dev_p0(m, bid, bktCnt, (int*)sm);
  else dev_gemm<0,0,0>(sm, sm+4096, bid - np0, X, nullptr, W, b, nullptr, nullptr, bh0, N0);
}

// K3: P1 (single block)
__global__ __launch_bounds__(256) void k3_p1(BMeta m,
    const int* __restrict__ bktCnt, int* __restrict__ bktBase, int* __restrict__ bktCur)
{
  __shared__ int sh[256];
  dev_p1(m, bktCnt, bktBase, bktCur, sh);
}

// K4: P2(+srcdeg) || enc0 V+score gemm (bf16 A)
__global__ __launch_bounds__(256) void k4_p2_gemm(BMeta m, int* __restrict__ bktCur, int2* __restrict__ ebuf,
    const u16* __restrict__ bh0, const float* __restrict__ evW, const float* __restrict__ evb,
    const float* __restrict__ kvec, float* __restrict__ sS, u16* __restrict__ bV, int np2)
{
  __shared__ float sm[4096 + 1024];
  int bid = blockIdx.x;
  if (bid < np2) dev_p2(m, bid, bktCur, ebuf, (int*)sm);
  else dev_gemm<1,0,1>(sm, sm+4096, bid - np2, bh0, nullptr, evW, evb, kvec, sS, bV, N0);
}

// K5: P3 || gcn0 Y gemm (bf16 A, deg-scale)
__global__ __launch_bounds__(256) void k5_p3_ygemm(BMeta m,
    const int* __restrict__ bktCnt, const int* __restrict__ bktBase, const int2* __restrict__ ebuf,
    const u16* __restrict__ bh0, const int* __restrict__ deg0, const float* __restrict__ gW,
    u16* __restrict__ bY0, int np3)
{
  __shared__ float sm[4096 + 1024];
  int bid = blockIdx.x;
  if (bid < np3) dev_p3(m, bid, bktCnt, bktBase, ebuf, (int*)sm);
  else dev_gemm<0,1,1>(sm, sm+4096, bid - np3, bh0, deg0, gW, nullptr, nullptr, nullptr, bY0, N0);
}

// ---- mid-pipeline kernels with g0-gather slices ----

__global__ __launch_bounds__(256) void k6_ag_i0(
    const int* __restrict__ csrA, const int* __restrict__ rowpA,
    const float* __restrict__ sS, const u16* __restrict__ bV, u16* __restrict__ be1,
    const int* __restrict__ csr0, const int* __restrict__ rowp0, const u16* __restrict__ bY0,
    const float* __restrict__ gb, u16* __restrict__ bg0, int nMain, int sBase)
{
  int bid = blockIdx.x;
  if (bid < nMain) dev_attn_gather32<1>(bid, csrA, rowpA, sS, bV, be1, N1);
  else dev_gcn_gather32<1>(sBase + bid - nMain, csr0, rowp0, bY0, gb, bg0, N0);
}

__global__ __launch_bounds__(256) void k7_gemm_enc1(
    const u16* __restrict__ be1, const float* __restrict__ vW, const float* __restrict__ vb,
    const float* __restrict__ kvec, float* __restrict__ sS, u16* __restrict__ bV,
    const int* __restrict__ csr0, const int* __restrict__ rowp0, const u16* __restrict__ bY0,
    const float* __restrict__ gb, u16* __restrict__ bg0, int nMain, int sBase)
{
  __shared__ float sm[4096 + 1024];
  int bid = blockIdx.x;
  if (bid < nMain) dev_gemm<1,0,1>(sm, sm+4096, bid, be1, nullptr, vW, vb, kvec, sS, bV, N1);
  else dev_gcn_gather32<1>(sBase + bid - nMain, csr0, rowp0, bY0, gb, bg0, N0);
}

__global__ __launch_bounds__(256) void k8_ag_i1(
    const int* __restrict__ csrA, const int* __restrict__ rowpA,
    const float* __restrict__ sS, const u16* __restrict__ bV, float* __restrict__ be2,
    const int* __restrict__ csr0, const int* __restrict__ rowp0, const u16* __restrict__ bY0,
    const float* __restrict__ gb, u16* __restrict__ bg0, int nMain, int sBase)
{
  int bid = blockIdx.x;
  if (bid < nMain) dev_attn_gather32<0>(bid, csrA, rowpA, sS, bV, be2, N2);
  else dev_gcn_gather32<1>(sBase + bid - nMain, csr0, rowp0, bY0, gb, bg0, N0);
}

__global__ __launch_bounds__(256) void k9_ygemm(
    const u16* __restrict__ be1, const int* __restrict__ deg1, const float* __restrict__ W1, u16* __restrict__ bY1,
    const float* __restrict__ be2, const int* __restrict__ deg2, const float* __restrict__ W2, u16* __restrict__ bY2,
    const int* __restrict__ csr0, const int* __restrict__ rowp0, const u16* __restrict__ bY0,
    const float* __restrict__ gb, u16* __restrict__ bg0, int ga, int nMain, int sBase)
{
  __shared__ float sm[4096 + 1024];
  int bid = blockIdx.x;
  if (bid < ga) dev_gemm<0,1,1>(sm, sm+4096, bid, be1, deg1, W1, nullptr, nullptr, nullptr, bY1, N1);
  else if (bid < nMain) dev_gemm<0,1,0>(sm, sm+4096, bid - ga, be2, deg2, W2, nullptr, nullptr, nullptr, bY2, N2);
  else dev_gcn_gather32<1>(sBase + bid - nMain, csr0, rowp0, bY0, gb, bg0, N0);
}

__global__ __launch_bounds__(256) void k10_ggathers(
    const int* __restrict__ csr1, const int* __restrict__ rowp1, const u16* __restrict__ bY1,
    const float* __restrict__ b1, u16* __restrict__ bg1,
    const int* __restrict__ csr2, const int* __restrict__ rowp2, const u16* __restrict__ bY2,
    const float* __restrict__ b2, float* __restrict__ bg2,
    const int* __restrict__ csr0, const int* __restrict__ rowp0, const u16* __restrict__ bY0,
    const float* __restrict__ gb, u16* __restrict__ bg0, int ga, int nMain, int sBase)
{
  int bid = blockIdx.x;
  if (bid < ga) dev_gcn_gather32<1>(bid, csr1, rowp1, bY1, b1, bg1, N1);
  else if (bid < nMain) dev_gcn_gather32<0>(bid - ga, csr2, rowp2, bY2, b2, bg2, N2);
  else dev_gcn_gather32<1>(sBase + bid - nMain, csr0, rowp0, bY0, gb, bg0, N0);
}

__global__ __launch_bounds__(256) void k11_dec0_head2(
    const float* __restrict__ bg2, const float* __restrict__ vW, const float* __restrict__ vb,
    const float* __restrict__ kvec, float* __restrict__ sS, u16* __restrict__ bV,
    const float* __restrict__ hW, const float* __restrict__ hb, float* __restrict__ out,
    const int* __restrict__ csr0, const int* __restrict__ rowp0, const u16* __restrict__ bY0,
    const float* __restrict__ gb, u16* __restrict__ bg0, int ngemm, int nMain, int sBase)
{
  __shared__ float sm[4096 + 1024];
  int bid = blockIdx.x;
  if (bid < ngemm) dev_gemm<1,0,0>(sm, sm+4096, bid, bg2, nullptr, vW, vb, kvec, sS, bV, N2);
  else if (bid < nMain) dev_head<0,0>(bid - ngemm, bg2, bg2, hW, hb, out, N2, N0+N1);
  else dev_gcn_gather32<1>(sBase + bid - nMain, csr0, rowp0, bY0, gb, bg0, N0);
}

__global__ __launch_bounds__(256) void k12_ag_d1(
    const int* __restrict__ csrA, const int* __restrict__ rowpA,
    const float* __restrict__ sS, const u16* __restrict__ bV, u16* __restrict__ be1,
    const int* __restrict__ csr0, const int* __restrict__ rowp0, const u16* __restrict__ bY0,
    const float* __restrict__ gb, u16* __restrict__ bg0, int nMain, int sBase)
{
  int bid = blockIdx.x;
  if (bid < nMain) dev_attn_gather32<1>(bid, csrA, rowpA, sS, bV, be1, N1);
  else dev_gcn_gather32<1>(sBase + bid - nMain, csr0, rowp0, bY0, gb, bg0, N0);
}

__global__ __launch_bounds__(256) void k13_dec1_head1(
    const u16* __restrict__ be1, const float* __restrict__ vW, const float* __restrict__ vb,
    const float* __restrict__ kvec, float* __restrict__ sS, u16* __restrict__ bV,
    const u16* __restrict__ bg1, const float* __restrict__ hW, const float* __restrict__ hb,
    float* __restrict__ out,
    const int* __restrict__ csr0, const int* __restrict__ rowp0, const u16* __restrict__ bY0,
    const float* __restrict__ gb, u16* __restrict__ bg0, int ngemm, int nMain, int sBase)
{
  __shared__ float sm[4096 + 1024];
  int bid = blockIdx.x;
  if (bid < ngemm) dev_gemm<1,0,1>(sm, sm+4096, bid, be1, nullptr, vW, vb, kvec, sS, bV, N1);
  else if (bid < nMain) dev_head<1,1>(bid - ngemm, bg1, be1, hW, hb, out, N1, N0);
  else dev_gcn_gather32<1>(sBase + bid - nMain, csr0, rowp0, bY0, gb, bg0, N0);
}

__global__ __launch_bounds__(256) void k14_gather_head0(
    const int* __restrict__ csr, const int* __restrict__ rowp,
    const float* __restrict__ w, const u16* __restrict__ V,
    const u16* __restrict__ bg0,
    const float* __restrict__ hW, const float* __restrict__ hb,
    float* __restrict__ out)
{
  int g = threadIdx.x >> 5, lane = threadIdx.x & 31;
  int row = blockIdx.x*8 + g;
  if (row >= N0) return;
  int st = rowp[row], en = rowp[row+1];
  float a0=0.f,a1=0.f,a2=0.f,a3=0.f;
  if (en > st){
    const ushort4* V4 = (const ushort4*)V;
    float den = 0.f;
    for (int e = st; e < en; ++e){
      int sn = csr[e];
      float x = w[sn];
      den += x;
      ushort4 v = V4[(size_t)sn*32 + lane];
      a0 = fmaf(x, bf2f(v.x), a0); a1 = fmaf(x, bf2f(v.y), a1);
      a2 = fmaf(x, bf2f(v.z), a2); a3 = fmaf(x, bf2f(v.w), a3);
    }
    float inv = 1.f/den;
    a0*=inv; a1*=inv; a2*=inv; a3*=inv;
  }
  ushort4 gv = ((const ushort4*)(bg0 + (size_t)row*FD))[lane];
  float g0 = bf2f(gv.x), g1 = bf2f(gv.y), g2 = bf2f(gv.z), g3 = bf2f(gv.w);
  int j = 4*lane;
  float acc[5];
  #pragma unroll
  for (int o = 0; o < 5; ++o){
    acc[o] = g0*hW[(j+0)*5+o] + g1*hW[(j+1)*5+o] + g2*hW[(j+2)*5+o] + g3*hW[(j+3)*5+o]
           + a0*hW[(128+j+0)*5+o] + a1*hW[(128+j+1)*5+o] + a2*hW[(128+j+2)*5+o] + a3*hW[(128+j+3)*5+o];
  }
  #pragma unroll
  for (int o = 0; o < 5; ++o)
    #pragma unroll
    for (int s = 16; s; s >>= 1) acc[o] += __shfl_xor(acc[o], s, 32);
  if (lane == 0){
    float m = -1e30f;
    #pragma unroll
    for (int o = 0; o < 5; ++o){ acc[o] += hb[o]; m = fmaxf(m, acc[o]); }
    float sum = 0.f;
    #pragma unroll
    for (int o = 0; o < 5; ++o){ acc[o] = expf(acc[o]-m); sum += acc[o]; }
    float is = 1.0f/sum;
    float* op = out + (size_t)row*5;
    #pragma unroll
    for (int o = 0; o < 5; ++o) op[o] = acc[o]*is;
  }
}

// ================= host =================
extern "C" void kernel_launch(void* const* d_in, const int* in_sizes, int n_in,
                              void* d_out, int out_size, void* d_ws, size_t ws_size,
                              hipStream_t stream)
{
  const float* X      = (const float*)d_in[0];
  const float* emb_W  = (const float*)d_in[1];
  const float* emb_b  = (const float*)d_in[2];
  const float* gcn_W  = (const float*)d_in[3];
  const float* gcn_b  = (const float*)d_in[4];
  const float* enc_qb = (const float*)d_in[6];
  const float* enc_kW = (const float*)d_in[7];
  const float* enc_kb = (const float*)d_in[8];
  const float* enc_vW = (const float*)d_in[9];
  const float* enc_vb = (const float*)d_in[10];
  const float* dec_qb = (const float*)d_in[12];
  const float* dec_kW = (const float*)d_in[13];
  const float* dec_kb = (const float*)d_in[14];
  const float* dec_vW = (const float*)d_in[15];
  const float* dec_vb = (const float*)d_in[16];
  const float* head_W = (const float*)d_in[17];
  const float* head_b = (const float*)d_in[18];
  const int* g0s  = (const int*)d_in[19];
  const int* g0d  = (const int*)d_in[20];
  const int* g1s  = (const int*)d_in[21];
  const int* g1d  = (const int*)d_in[22];
  const int* g2s  = (const int*)d_in[23];
  const int* g2d  = (const int*)d_in[24];
  const int* i0s  = (const int*)d_in[25];
  const int* i0d  = (const int*)d_in[26];
  const int* i1s  = (const int*)d_in[27];
  const int* i1d  = (const int*)d_in[28];
  const int* dc0s = (const int*)d_in[29];
  const int* dc0d = (const int*)d_in[30];
  const int* dc1s = (const int*)d_in[31];
  const int* dc1d = (const int*)d_in[32];

  // ---- workspace layout ----
  float* ws = (float*)d_ws;
  float* sS  = ws;                          // N0
  float* kvec = sS + N0;                    // 4*132
  float* be2 = kvec + 4*132;                // N2*FD f32
  float* bg2 = be2 + (size_t)N2*FD;         // N2*FD f32
  // pad to 8B boundary for ushort4 region (float count so far: N0+528+2*N2*FD = 1700528, even)
  u16*  bh0 = (u16*)(bg2 + (size_t)N2*FD);  // N0*FD u16 (h0 bf16)
  u16*  be1 = bh0 + (size_t)N0*FD;          // N1*FD u16 (e1/d1 bf16)
  u16*  bg0 = be1 + (size_t)N1*FD;          // N0*FD u16
  u16*  bg1 = bg0 + (size_t)N0*FD;          // N1*FD u16
  u16*  bV  = bg1 + (size_t)N1*FD;          // N0*FD u16 (V tables, time-shared)
  u16*  bY0 = bV  + (size_t)N0*FD;          // N0*FD u16
  u16*  bY1 = bV + 4000000;                 // alias into bV tail (safe: V<=3.2M u16 when used)
  u16*  bY2 = bV + 8000000;
  int*  degBlk  = (int*)(bY0 + (size_t)N0*FD);  // N0+N1+N2
  int*  bktCnt  = degBlk + (N0+N1+N2);          // 224
  int*  bktBase = bktCnt + 224;                 // 224
  int*  bktCur  = bktBase + 224;                // 224
  int*  rowpBlk = bktCur + 224;                 // 287507
  int*  csrBlk  = rowpBlk + 287507;             // 2,500,000
  int2* ebuf    = (int2*)(csrBlk + 2500000 + 1);// 2.5M int2

  const int* srcP[7] = {g0s,g1s,g2s,i0s,i1s,dc0s,dc1s};
  const int* dstP[7] = {g0d,g1d,g2d,i0d,i1d,dc0d,dc1d};
  const int nArr[7] = {N0,N1,N2,N1,N2,N1,N0};
  const int EArr[7] = {1000000,400000,100000,400000,100000,100000,400000};
  const int BArr[7] = {64,32,8,32,8,16,64};
  const int rArr[7] = {1563,782,782,782,782,1563,1563};
  int* deg0 = degBlk; int* deg1 = degBlk + N0; int* deg2 = degBlk + N0 + N1;
  int* degP[7] = {deg0, deg1, deg2, nullptr, nullptr, nullptr, nullptr};

  BMeta m;
  {
    int eo=0, bo=0, po=0, ro=0, co=0;
    for (int j=0;j<7;++j){
      m.src[j]=srcP[j]; m.dst[j]=dstP[j]; m.degp[j]=degP[j];
      m.rowp[j]=rowpBlk+ro; m.csr[j]=csrBlk+co;
      m.n[j]=nArr[j]; m.E[j]=EArr[j]; m.B[j]=BArr[j]; m.r[j]=rArr[j];
      m.eoff[j]=eo; m.boff[j]=bo; m.pblk[j]=po;
      eo+=EArr[j]; bo+=BArr[j]; po+=ceildiv(EArr[j],4096); ro+=nArr[j]+1; co+=EArr[j];
    }
    m.eoff[7]=eo; m.boff[7]=bo; m.pblk[7]=po;   // 2.5M / 224 / 614
  }

  const float invScale = 0.17677669529663687f;
  float* out = (float*)d_out;

  const int NP0 = m.pblk[7];                // 614
  const int NP3 = m.boff[7];                // 224
  const int ZTOT = (N0+N1+N2) + 224;
  const int GH0 = ceildiv(N0,32);           // 3125
  const int GH1 = ceildiv(N1,32);           // 782
  const int GH2 = ceildiv(N2,32);           // 196
  const int GA1_32 = ceildiv(N1,8);         // 3125
  const int GA2_32 = ceildiv(N2,8);         // 782
  const int G0B = ceildiv(N0,8);            // 12500
  const int GH2H = ceildiv(N2,4);           // 1563
  const int GH1H = ceildiv(N1,4);           // 6250

  int ss[9];
  for (int i = 0; i <= 8; ++i) ss[i] = (int)(((long long)G0B * i) / 8);

  // K1: zero (deg+bktCnt) || kvec
  k1_zero_kqv<<<4 + ceildiv(ZTOT,256), 256, 0, stream>>>(degBlk, ZTOT,
      enc_kW, enc_kb, enc_qb, dec_kW, dec_kb, dec_qb, kvec, invScale);
  // K2: P0 || h0 gemm (f32 -> bf16)
  k2_p0_gemm<<<NP0 + GH0, 256, 0, stream>>>(m, bktCnt, X, emb_W, emb_b, bh0, NP0);
  // K3: P1
  k3_p1<<<1, 256, 0, stream>>>(m, bktCnt, bktBase, bktCur);
  // K4: P2(+srcdeg) || enc0 V+score gemm
  k4_p2_gemm<<<NP0 + GH0, 256, 0, stream>>>(m, bktCur, ebuf,
      bh0, enc_vW, enc_vb, kvec, sS, bV, NP0);
  // K5: P3 || gcn0 Y gemm
  k5_p3_ygemm<<<NP3 + GH0, 256, 0, stream>>>(m, bktCnt, bktBase, ebuf,
      bh0, deg0, gcn_W, bY0, NP3);
  // K6: attn_gather(i0)->be1 || g0[0]
  k6_ag_i0<<<GA1_32 + (ss[1]-ss[0]), 256, 0, stream>>>(m.csr[3], m.rowp[3], sS, bV, be1,
      m.csr[0], m.rowp[0], bY0, gcn_b, bg0, GA1_32, ss[0]);
  // K7: enc1 gemm || g0[1]
  k7_gemm_enc1<<<GH1 + (ss[2]-ss[1]), 256, 0, stream>>>(be1, enc_vW+16384, enc_vb+128, kvec+132, sS, bV,
      m.csr[0], m.rowp[0], bY0, gcn_b, bg0, GH1, ss[1]);
  // K8: attn_gather(i1)->be2 || g0[2]
  k8_ag_i1<<<GA2_32 + (ss[3]-ss[2]), 256, 0, stream>>>(m.csr[4], m.rowp[4], sS, bV, be2,
      m.csr[0], m.rowp[0], bY0, gcn_b, bg0, GA2_32, ss[2]);
  // K9: gcn1 Y || gcn2 Y || g0[3]
  k9_ygemm<<<GH1 + GH2 + (ss[4]-ss[3]), 256, 0, stream>>>(be1, deg1, gcn_W+16384, bY1,
      be2, deg2, gcn_W+32768, bY2,
      m.csr[0], m.rowp[0], bY0, gcn_b, bg0, GH1, GH1+GH2, ss[3]);
  // K10: gather(g1) || gather(g2) || g0[4]
  k10_ggathers<<<GA1_32 + GA2_32 + (ss[5]-ss[4]), 256, 0, stream>>>(
      m.csr[1], m.rowp[1], bY1, gcn_b+128, bg1,
      m.csr[2], m.rowp[2], bY2, gcn_b+256, bg2,
      m.csr[0], m.rowp[0], bY0, gcn_b, bg0, GA1_32, GA1_32+GA2_32, ss[4]);
  // K11: dec0 gemm || head2 || g0[5]
  k11_dec0_head2<<<GH2 + GH2H + (ss[6]-ss[5]), 256, 0, stream>>>(bg2, dec_vW, dec_vb, kvec+264, sS, bV,
      head_W+2560, head_b+10, out,
      m.csr[0], m.rowp[0], bY0, gcn_b, bg0, GH2, GH2+GH2H, ss[5]);
  // K12: attn_gather(dc0)->be1 (d1) || g0[6]
  k12_ag_d1<<<GA1_32 + (ss[7]-ss[6]), 256, 0, stream>>>(m.csr[5], m.rowp[5], sS, bV, be1,
      m.csr[0], m.rowp[0], bY0, gcn_b, bg0, GA1_32, ss[6]);
  // K13: dec1 gemm || head1 || g0[7]
  k13_dec1_head1<<<GH1 + GH1H + (ss[8]-ss[7]), 256, 0, stream>>>(be1, dec_vW+16384, dec_vb+128, kvec+396, sS, bV,
      bg1, head_W+1280, head_b+5, out,
      m.csr[0], m.rowp[0], bY0, gcn_b, bg0, GH1, GH1+GH1H, ss[7]);
  // K14: fused d0 gather + head0
  k14_gather_head0<<<G0B, 256, 0, stream>>>(m.csr[6], m.rowp[6], sS, bV, bg0,
      head_W, head_b, out);
}

// Round 9
// 471.649 us; speedup vs baseline: 10.5605x; 1.0718x over previous
//
#include <hip/hip_runtime.h>
#include <math.h>

#define N0 100000
#define N1 25000
#define N2 6250
#define FD 128

typedef unsigned short u16;
typedef unsigned int u32;

static inline int ceildiv(int a, int b){ return (a + b - 1)/b; }

__device__ __forceinline__ u16 f2bf(float f){
  u32 u = __float_as_uint(f);
  u += 0x7fffu + ((u >> 16) & 1u);
  return (u16)(u >> 16);
}
__device__ __forceinline__ float bf2f(u16 h){
  return __uint_as_float(((u32)h) << 16);
}
__device__ __forceinline__ float blo(u32 u){ return __uint_as_float(u << 16); }
__device__ __forceinline__ float bhi(u32 u){ return __uint_as_float(u & 0xffff0000u); }
__device__ __forceinline__ u32 pk2(float a, float b){ return (u32)f2bf(a) | ((u32)f2bf(b) << 16); }

// ================= bucket-CSR metadata =================
struct BMeta {
  const int* src[7]; const int* dst[7];
  int* rowp[7]; int* csr[7];
  int* degp[7];                 // src-degree hist (g0,g1,g2 only)
  int n[7], E[7], B[7], r[7];
  int eoff[8];
  int boff[8];
  int pblk[8];
};

// ================= GEMM =================
__device__ __forceinline__ void mm_inner(const float* Al, const float* Wl, int r0, int c0, float acc[4][4]){
  #pragma unroll
  for (int kq = 0; kq < 8; ++kq) {
    int k0 = kq*4;
    float4 a[4], w[4];
    #pragma unroll
    for (int i=0;i<4;++i) a[i] = *(const float4*)&Al[(r0+i)*32 + k0];
    #pragma unroll
    for (int kk=0;kk<4;++kk) w[kk] = *(const float4*)&Wl[(k0+kk)*128 + c0];
    #pragma unroll
    for (int i=0;i<4;++i){
      acc[i][0] = fmaf(a[i].x,w[0].x, fmaf(a[i].y,w[1].x, fmaf(a[i].z,w[2].x, fmaf(a[i].w,w[3].x, acc[i][0]))));
      acc[i][1] = fmaf(a[i].x,w[0].y, fmaf(a[i].y,w[1].y, fmaf(a[i].z,w[2].y, fmaf(a[i].w,w[3].y, acc[i][1]))));
      acc[i][2] = fmaf(a[i].x,w[0].z, fmaf(a[i].y,w[1].z, fmaf(a[i].z,w[2].z, fmaf(a[i].w,w[3].z, acc[i][2]))));
      acc[i][3] = fmaf(a[i].x,w[0].w, fmaf(a[i].y,w[1].w, fmaf(a[i].z,w[2].w, fmaf(a[i].w,w[3].w, acc[i][3]))));
    }
  }
}

// single-output GEMM: A(f32/bf16) @ W (+bias) -> bf16; SCORE emits w=exp(s);
// SCALEDEG row-scales by rsqrt(max(deg,1))
template<int SCORE, int SCALEDEG, int AB16>
__device__ __forceinline__ void dev_gemm(float* Wl, float* Al, int bid,
    const void* __restrict__ Ap, const int* __restrict__ deg,
    const float* __restrict__ W, const float* __restrict__ bias,
    const float* __restrict__ kvec, float* __restrict__ sOut,
    u16* __restrict__ out, int n)
{
  const int tid = threadIdx.x;
  const int row0 = bid * 32;
  const int c0 = (tid & 31) * 4, r0 = (tid >> 5) * 4;
  const int r = tid >> 3, fc = tid & 7;
  const int gr_s = row0 + r;
  float acc[4][4] = {};
  float sacc = 0.f;
  const float4* W4 = (const float4*)W;
  for (int kp = 0; kp < 4; ++kp) {
    float4* Wl4 = (float4*)Wl;
    #pragma unroll
    for (int i = 0; i < 4; ++i) Wl4[tid + 256*i] = W4[kp*1024 + tid + 256*i];
    {
      float4 v = make_float4(0.f,0.f,0.f,0.f);
      if (gr_s < n){
        if (AB16){
          ushort4 h = ((const ushort4*)Ap)[(size_t)gr_s*32 + kp*8 + fc];
          v = make_float4(bf2f(h.x), bf2f(h.y), bf2f(h.z), bf2f(h.w));
        } else {
          v = ((const float4*)Ap)[(size_t)gr_s*32 + kp*8 + fc];
        }
      }
      ((float4*)Al)[tid] = v;
      if (SCORE){
        float4 kv = *(const float4*)&kvec[kp*32 + fc*4];
        sacc += v.x*kv.x + v.y*kv.y + v.z*kv.z + v.w*kv.w;
      }
    }
    __syncthreads();
    mm_inner(Al, Wl, r0, c0, acc);
    __syncthreads();
  }
  if (SCORE){
    sacc += __shfl_xor(sacc, 1);
    sacc += __shfl_xor(sacc, 2);
    sacc += __shfl_xor(sacc, 4);
    if (fc == 0 && gr_s < n) sOut[gr_s] = expf(sacc + kvec[128]);
  }
  float4 bv = make_float4(0.f,0.f,0.f,0.f);
  if (bias) bv = *(const float4*)&bias[c0];
  #pragma unroll
  for (int i=0;i<4;++i){
    int gr = row0 + r0 + i;
    if (gr < n){
      float rs = 1.f;
      if (SCALEDEG) rs = rsqrtf(fmaxf((float)deg[gr], 1.f));
      ushort4 o;
      o.x = f2bf(acc[i][0]*rs+bv.x); o.y = f2bf(acc[i][1]*rs+bv.y);
      o.z = f2bf(acc[i][2]*rs+bv.z); o.w = f2bf(acc[i][3]*rs+bv.w);
      *(ushort4*)&out[(size_t)gr*FD + c0] = o;
    }
  }
}

// dual-output GEMM: V = A@Wv + vb (+score), Y = rsqrt(deg)*(A@Wg). A staged once.
template<int AB16>
__device__ __forceinline__ void dev_dualgemm(float* sm, int bid,
    const void* __restrict__ Ap, const int* __restrict__ deg,
    const float* __restrict__ Wv, const float* __restrict__ vb,
    const float* __restrict__ Wg,
    const float* __restrict__ kvec, float* __restrict__ sOut,
    u16* __restrict__ Vout, u16* __restrict__ Yout, int n)
{
  float* WvL = sm; float* WgL = sm + 4096; float* Al = sm + 8192;
  const int tid = threadIdx.x;
  const int row0 = bid * 32;
  const int c0 = (tid & 31) * 4, r0 = (tid >> 5) * 4;
  const int r = tid >> 3, fc = tid & 7;
  const int gr_s = row0 + r;
  float accV[4][4] = {};
  float accY[4][4] = {};
  float sacc = 0.f;
  const float4* Wv4 = (const float4*)Wv;
  const float4* Wg4 = (const float4*)Wg;
  for (int kp = 0; kp < 4; ++kp) {
    #pragma unroll
    for (int i = 0; i < 4; ++i) ((float4*)WvL)[tid + 256*i] = Wv4[kp*1024 + tid + 256*i];
    #pragma unroll
    for (int i = 0; i < 4; ++i) ((float4*)WgL)[tid + 256*i] = Wg4[kp*1024 + tid + 256*i];
    {
      float4 v = make_float4(0.f,0.f,0.f,0.f);
      if (gr_s < n){
        if (AB16){
          ushort4 h = ((const ushort4*)Ap)[(size_t)gr_s*32 + kp*8 + fc];
          v = make_float4(bf2f(h.x), bf2f(h.y), bf2f(h.z), bf2f(h.w));
        } else {
          v = ((const float4*)Ap)[(size_t)gr_s*32 + kp*8 + fc];
        }
      }
      ((float4*)Al)[tid] = v;
      float4 kv = *(const float4*)&kvec[kp*32 + fc*4];
      sacc += v.x*kv.x + v.y*kv.y + v.z*kv.z + v.w*kv.w;
    }
    __syncthreads();
    mm_inner(Al, WvL, r0, c0, accV);
    mm_inner(Al, WgL, r0, c0, accY);
    __syncthreads();
  }
  sacc += __shfl_xor(sacc, 1);
  sacc += __shfl_xor(sacc, 2);
  sacc += __shfl_xor(sacc, 4);
  if (fc == 0 && gr_s < n) sOut[gr_s] = expf(sacc + kvec[128]);
  float4 bv = *(const float4*)&vb[c0];
  #pragma unroll
  for (int i=0;i<4;++i){
    int gr = row0 + r0 + i;
    if (gr < n){
      ushort4 o;
      o.x = f2bf(accV[i][0]+bv.x); o.y = f2bf(accV[i][1]+bv.y);
      o.z = f2bf(accV[i][2]+bv.z); o.w = f2bf(accV[i][3]+bv.w);
      *(ushort4*)&Vout[(size_t)gr*FD + c0] = o;
      float rs = rsqrtf(fmaxf((float)deg[gr], 1.f));
      ushort4 y;
      y.x = f2bf(accY[i][0]*rs); y.y = f2bf(accY[i][1]*rs);
      y.z = f2bf(accY[i][2]*rs); y.w = f2bf(accY[i][3]*rs);
      *(ushort4*)&Yout[(size_t)gr*FD + c0] = y;
    }
  }
}

// ================= bucket-CSR passes =================
// P0: bucket histogram of dst (+src-degree for g0/g1/g2)
__device__ __forceinline__ void dev_p0(const BMeta& m, int bid, int* __restrict__ bktCnt, int* sh){
  int j = 0;
  #pragma unroll
  for (int t = 1; t < 7; ++t) if (bid >= m.pblk[t]) j = t;
  int lb = bid - m.pblk[j];
  const int* dst = m.dst[j]; const int* src = m.src[j];
  int* dp = m.degp[j];
  int E = m.E[j], r = m.r[j], B = m.B[j];
  if (threadIdx.x < 64) sh[threadIdx.x] = 0;
  __syncthreads();
  int base = lb*4096 + threadIdx.x;
  #pragma unroll
  for (int i = 0; i < 16; ++i){
    int e = base + i*256;
    if (e < E){
      atomicAdd(&sh[dst[e]/r], 1);
      if (dp) atomicAdd(&dp[src[e]], 1);
    }
  }
  __syncthreads();
  if ((int)threadIdx.x < B) atomicAdd(&bktCnt[m.boff[j] + threadIdx.x], sh[threadIdx.x]);
}

__device__ __forceinline__ void dev_p1(const BMeta& m, const int* __restrict__ bktCnt,
    int* __restrict__ bktBase, int* __restrict__ bktCur, int* sh){
  int tid = threadIdx.x;
  if (tid < 224) sh[tid] = bktCnt[tid];
  __syncthreads();
  if (tid < 7){
    int acc = m.eoff[tid];
    for (int b = m.boff[tid]; b < m.boff[tid+1]; ++b){ int v = sh[b]; sh[b] = acc; acc += v; }
  }
  __syncthreads();
  if (tid < 224){ bktBase[tid] = sh[tid]; bktCur[tid] = sh[tid]; }
}

// P2: scatter packed (localDst<<17 | src) into bucket-contiguous ebuf
__device__ __forceinline__ void dev_p2(const BMeta& m, int bid, int* __restrict__ bktCur,
    u32* __restrict__ ebuf, int* sh){
  int j = 0;
  #pragma unroll
  for (int t = 1; t < 7; ++t) if (bid >= m.pblk[t]) j = t;
  int lb = bid - m.pblk[j];
  const int* src = m.src[j]; const int* dst = m.dst[j];
  int E = m.E[j], r = m.r[j], B = m.B[j];
  int* h = sh; int* start = sh + 64;
  if (threadIdx.x < 64) h[threadIdx.x] = 0;
  __syncthreads();
  int base = lb*4096 + threadIdx.x;
  #pragma unroll
  for (int i = 0; i < 16; ++i){ int e = base + i*256; if (e < E) atomicAdd(&h[dst[e]/r], 1); }
  __syncthreads();
  if ((int)threadIdx.x < B) start[threadIdx.x] = atomicAdd(&bktCur[m.boff[j] + threadIdx.x], h[threadIdx.x]);
  __syncthreads();
  #pragma unroll
  for (int i = 0; i < 16; ++i){
    int e = base + i*256;
    if (e < E){
      int s = src[e], d = dst[e];
      int b = d / r;
      int pos = atomicAdd(&start[b], 1);
      ebuf[pos] = ((u32)(d - b*r) << 17) | (u32)s;
    }
  }
}

__device__ __forceinline__ void dev_p3(const BMeta& m, int bb,
    const int* __restrict__ bktCnt, const int* __restrict__ bktBase,
    const u32* __restrict__ ebuf, int* sh){
  int j = 0;
  #pragma unroll
  for (int t = 1; t < 7; ++t) if (bb >= m.boff[t]) j = t;
  int b = bb - m.boff[j];
  int n = m.n[j], r = m.r[j], B = m.B[j];
  int* rowp = m.rowp[j]; int* csr = m.csr[j];
  int node0 = b*r;
  int rr = min(r, n - node0);
  int gbase = bktBase[bb];
  int cnt = bktCnt[bb];
  int lbase = gbase - m.eoff[j];
  int* hist = sh; int* aux = sh + 1568;
  int tid = threadIdx.x;
  for (int i = tid; i < rr; i += 256) hist[i] = 0;
  __syncthreads();
  for (int e = tid; e < cnt; e += 256){ u32 pk = ebuf[gbase + e]; atomicAdd(&hist[pk >> 17], 1); }
  __syncthreads();
  int ch = (rr + 255) >> 8;
  int i0 = tid*ch;
  int s = 0;
  for (int k = 0; k < ch; ++k){ int idx = i0 + k; if (idx < rr){ int t = hist[idx]; hist[idx] = s; s += t; } }
  aux[tid] = s; __syncthreads();
  for (int off = 1; off < 256; off <<= 1){
    int v = aux[tid]; int a = (tid >= off) ? aux[tid - off] : 0;
    __syncthreads();
    aux[tid] = v + a;
    __syncthreads();
  }
  int pre = (tid ? aux[tid-1] : 0) + lbase;
  for (int k = 0; k < ch; ++k){ int idx = i0 + k; if (idx < rr) hist[idx] += pre; }
  __syncthreads();
  for (int i = tid; i < rr; i += 256) rowp[node0 + i] = hist[i];
  if (b == B-1 && tid == 0) rowp[n] = lbase + cnt;
  __syncthreads();
  for (int e = tid; e < cnt; e += 256){
    u32 pk = ebuf[gbase + e];
    int pos = atomicAdd(&hist[pk >> 17], 1);
    csr[pos] = (int)(pk & 0x1FFFFu);
  }
}

// ================= 16-lane gathers (uint4 = 8 bf16/lane) =================
template<int OB16>
__device__ __forceinline__ void dev_attn_gather16(int bid,
    const int* __restrict__ csr, const int* __restrict__ rowp,
    const float* __restrict__ w, const u16* __restrict__ V,
    void* __restrict__ out, int n)
{
  int g = threadIdx.x >> 4, lane = threadIdx.x & 15;
  int row = bid*16 + g;
  if (row >= n) return;
  int st = rowp[row], en = rowp[row+1];
  float a0=0,a1=0,a2=0,a3=0,a4=0,a5=0,a6=0,a7=0;
  if (en > st){
    const uint4* V8 = (const uint4*)V;
    float den = 0.f;
    for (int e = st; e < en; ++e){
      int sn = csr[e];
      float x = w[sn];
      uint4 v = V8[(size_t)sn*16 + lane];
      den += x;
      a0 = fmaf(x, blo(v.x), a0); a1 = fmaf(x, bhi(v.x), a1);
      a2 = fmaf(x, blo(v.y), a2); a3 = fmaf(x, bhi(v.y), a3);
      a4 = fmaf(x, blo(v.z), a4); a5 = fmaf(x, bhi(v.z), a5);
      a6 = fmaf(x, blo(v.w), a6); a7 = fmaf(x, bhi(v.w), a7);
    }
    float inv = 1.f/den;
    a0*=inv; a1*=inv; a2*=inv; a3*=inv; a4*=inv; a5*=inv; a6*=inv; a7*=inv;
  }
  if (OB16){
    uint4 o; o.x = pk2(a0,a1); o.y = pk2(a2,a3); o.z = pk2(a4,a5); o.w = pk2(a6,a7);
    ((uint4*)out)[(size_t)row*16 + lane] = o;
  } else {
    float4* o4 = (float4*)out;
    o4[(size_t)row*32 + lane*2]     = make_float4(a0,a1,a2,a3);
    o4[(size_t)row*32 + lane*2 + 1] = make_float4(a4,a5,a6,a7);
  }
}

template<int OB16>
__device__ __forceinline__ void dev_gcn_gather16(int bid,
    const int* __restrict__ csr, const int* __restrict__ rowp,
    const u16* __restrict__ Y, const float* __restrict__ bias,
    void* __restrict__ out, int n)
{
  int g = threadIdx.x >> 4, lane = threadIdx.x & 15;
  int row = bid*16 + g;
  if (row >= n) return;
  int st = rowp[row], en = rowp[row+1];
  float a0=0,a1=0,a2=0,a3=0,a4=0,a5=0,a6=0,a7=0;
  const uint4* Y8 = (const uint4*)Y;
  for (int e = st; e < en; ++e){
    int sn = csr[e];
    uint4 v = Y8[(size_t)sn*16 + lane];
    a0 += blo(v.x); a1 += bhi(v.x);
    a2 += blo(v.y); a3 += bhi(v.y);
    a4 += blo(v.z); a5 += bhi(v.z);
    a6 += blo(v.w); a7 += bhi(v.w);
  }
  float sc = rsqrtf(fmaxf((float)(en - st), 1.f));
  const float4* b4 = (const float4*)bias;
  float4 ba = b4[lane*2], bb = b4[lane*2+1];
  float o0=fmaf(a0,sc,ba.x), o1=fmaf(a1,sc,ba.y), o2=fmaf(a2,sc,ba.z), o3=fmaf(a3,sc,ba.w);
  float o4v=fmaf(a4,sc,bb.x), o5=fmaf(a5,sc,bb.y), o6=fmaf(a6,sc,bb.z), o7=fmaf(a7,sc,bb.w);
  if (OB16){
    uint4 o; o.x = pk2(o0,o1); o.y = pk2(o2,o3); o.z = pk2(o4v,o5); o.w = pk2(o6,o7);
    ((uint4*)out)[(size_t)row*16 + lane] = o;
  } else {
    float4* o4 = (float4*)out;
    o4[(size_t)row*32 + lane*2]     = make_float4(o0,o1,o2,o3);
    o4[(size_t)row*32 + lane*2 + 1] = make_float4(o4v,o5,o6,o7);
  }
}

// 64-lane head for head1/head2
template<int GB16, int DB16>
__device__ __forceinline__ void dev_head(int bid, const void* __restrict__ g, const void* __restrict__ dch,
    const float* __restrict__ W, const float* __restrict__ b,
    float* __restrict__ out, int n, int rowOff)
{
  int wid = threadIdx.x >> 6, lane = threadIdx.x & 63;
  int row = bid*4 + wid;
  if (row >= n) return;
  float x0, x1, x2, x3;
  if (GB16){ const u16* gr = (const u16*)g + (size_t)row*FD; x0 = bf2f(gr[lane]); x1 = bf2f(gr[64+lane]); }
  else     { const float* gr = (const float*)g + (size_t)row*FD; x0 = gr[lane]; x1 = gr[64+lane]; }
  if (DB16){ const u16* dr = (const u16*)dch + (size_t)row*FD; x2 = bf2f(dr[lane]); x3 = bf2f(dr[64+lane]); }
  else     { const float* dr = (const float*)dch + (size_t)row*FD; x2 = dr[lane]; x3 = dr[64+lane]; }
  float acc[5];
  #pragma unroll
  for (int o = 0; o < 5; ++o)
    acc[o] = x0*W[lane*5+o] + x1*W[(64+lane)*5+o] + x2*W[(128+lane)*5+o] + x3*W[(192+lane)*5+o];
  #pragma unroll
  for (int o = 0; o < 5; ++o)
    #pragma unroll
    for (int s = 32; s; s >>= 1) acc[o] += __shfl_xor(acc[o], s);
  if (lane == 0){
    float m = -1e30f;
    #pragma unroll
    for (int o = 0; o < 5; ++o){ acc[o] += b[o]; m = fmaxf(m, acc[o]); }
    float sum = 0.f;
    #pragma unroll
    for (int o = 0; o < 5; ++o){ acc[o] = expf(acc[o]-m); sum += acc[o]; }
    float is = 1.0f/sum;
    float* op = out + (size_t)(rowOff+row)*5;
    #pragma unroll
    for (int o = 0; o < 5; ++o) op[o] = acc[o]*is;
  }
}

// ================= kernels =================

__global__ __launch_bounds__(256) void k1_zero_kqv(int* __restrict__ zeroBlk, int ntot,
    const float* __restrict__ ekW, const float* __restrict__ ekb, const float* __restrict__ eqb,
    const float* __restrict__ dkW, const float* __restrict__ dkb, const float* __restrict__ dqb,
    float* __restrict__ kv, float inv)
{
  int bid = blockIdx.x;
  if (bid < 4){
    if (threadIdx.x < 128){
      int j = bid;
      const float* kW = (j < 2) ? ekW + j*16384 : dkW + (j-2)*16384;
      const float* kb = (j < 2) ? ekb + j*128   : dkb + (j-2)*128;
      const float* qb = (j < 2) ? eqb + j*128   : dqb + (j-2)*128;
      float* o = kv + j*132;
      int k = threadIdx.x;
      float a = 0.f;
      for (int t = 0; t < 128; ++t) a = fmaf(kW[k*128+t], qb[t], a);
      o[k] = a * inv;
      if (k == 0){
        float c = 0.f;
        for (int t = 0; t < 128; ++t) c = fmaf(kb[t], qb[t], c);
        o[128] = c * inv;
      }
    }
  } else {
    int i = (bid-4)*256 + threadIdx.x;
    if (i < ntot) zeroBlk[i] = 0;
  }
}

// K2: P0(+srcdeg) || h0 gemm (f32 -> bf16)
__global__ __launch_bounds__(256) void k2_p0_gemm(BMeta m, int* __restrict__ bktCnt,
    const float* __restrict__ X, const float* __restrict__ W, const float* __restrict__ b,
    u16* __restrict__ bh0, int np0)
{
  __shared__ float sm[5120];
  int bid = blockIdx.x;
  if (bid < np0) dev_p0(m, bid, bktCnt, (int*)sm);
  else dev_gemm<0,0,0>(sm, sm+4096, bid - np0, X, nullptr, W, b, nullptr, nullptr, bh0, N0);
}

// K3: P1
__global__ __launch_bounds__(256) void k3_p1(BMeta m,
    const int* __restrict__ bktCnt, int* __restrict__ bktBase, int* __restrict__ bktCur)
{
  __shared__ int sh[256];
  dev_p1(m, bktCnt, bktBase, bktCur, sh);
}

// K4: P2 || dualGEMM(h0) part 1
__global__ __launch_bounds__(256) void k4_p2_dual(BMeta m, int* __restrict__ bktCur, u32* __restrict__ ebuf,
    const u16* __restrict__ bh0, const int* __restrict__ deg0,
    const float* __restrict__ evW, const float* __restrict__ evb, const float* __restrict__ gW,
    const float* __restrict__ kvec, float* __restrict__ sS, u16* __restrict__ bV, u16* __restrict__ bY0,
    int np2, int gOff)
{
  __shared__ float sm[9216];
  int bid = blockIdx.x;
  if (bid < np2) dev_p2(m, bid, bktCur, ebuf, (int*)sm);
  else dev_dualgemm<1>(sm, gOff + bid - np2, bh0, deg0, evW, evb, gW, kvec, sS, bV, bY0, N0);
}

// K5: P3 || dualGEMM(h0) part 2
__global__ __launch_bounds__(256) void k5_p3_dual(BMeta m,
    const int* __restrict__ bktCnt, const int* __restrict__ bktBase, const u32* __restrict__ ebuf,
    const u16* __restrict__ bh0, const int* __restrict__ deg0,
    const float* __restrict__ evW, const float* __restrict__ evb, const float* __restrict__ gW,
    const float* __restrict__ kvec, float* __restrict__ sS, u16* __restrict__ bV, u16* __restrict__ bY0,
    int np3, int gOff)
{
  __shared__ float sm[9216];
  int bid = blockIdx.x;
  if (bid < np3) dev_p3(m, bid, bktCnt, bktBase, ebuf, (int*)sm);
  else dev_dualgemm<1>(sm, gOff + bid - np3, bh0, deg0, evW, evb, gW, kvec, sS, bV, bY0, N0);
}

// K6: attn_gather16(i0)->be1 || g0 slice
__global__ __launch_bounds__(256) void k6_ag_i0(
    const int* __restrict__ csrA, const int* __restrict__ rowpA,
    const float* __restrict__ sS, const u16* __restrict__ bV, u16* __restrict__ be1,
    const int* __restrict__ csr0, const int* __restrict__ rowp0, const u16* __restrict__ bY0,
    const float* __restrict__ gb, u16* __restrict__ bg0, int nMain, int sBase)
{
  int bid = blockIdx.x;
  if (bid < nMain) dev_attn_gather16<1>(bid, csrA, rowpA, sS, bV, be1, N1);
  else dev_gcn_gather16<1>(sBase + bid - nMain, csr0, rowp0, bY0, gb, bg0, N0);
}

// K7: dualGEMM(be1 -> V1+score, Y1) || g0 slice
__global__ __launch_bounds__(256) void k7_dual_enc1(
    const u16* __restrict__ be1, const int* __restrict__ deg1,
    const float* __restrict__ vW, const float* __restrict__ vb, const float* __restrict__ gW,
    const float* __restrict__ kvec, float* __restrict__ sS, u16* __restrict__ bV, u16* __restrict__ bY1,
    const int* __restrict__ csr0, const int* __restrict__ rowp0, const u16* __restrict__ bY0,
    const float* __restrict__ gb, u16* __restrict__ bg0, int nMain, int sBase)
{
  __shared__ float sm[9216];
  int bid = blockIdx.x;
  if (bid < nMain) dev_dualgemm<1>(sm, bid, be1, deg1, vW, vb, gW, kvec, sS, bV, bY1, N1);
  else dev_gcn_gather16<1>(sBase + bid - nMain, csr0, rowp0, bY0, gb, bg0, N0);
}

// K8: attn_gather16(i1)->be2(f32) || g0 slice
__global__ __launch_bounds__(256) void k8_ag_i1(
    const int* __restrict__ csrA, const int* __restrict__ rowpA,
    const float* __restrict__ sS, const u16* __restrict__ bV, float* __restrict__ be2,
    const int* __restrict__ csr0, const int* __restrict__ rowp0, const u16* __restrict__ bY0,
    const float* __restrict__ gb, u16* __restrict__ bg0, int nMain, int sBase)
{
  int bid = blockIdx.x;
  if (bid < nMain) dev_attn_gather16<0>(bid, csrA, rowpA, sS, bV, be2, N2);
  else dev_gcn_gather16<1>(sBase + bid - nMain, csr0, rowp0, bY0, gb, bg0, N0);
}

// K9: gcn2-Y gemm (f32 A) || gcn_gather16(g1)->bg1 || g0 slice
__global__ __launch_bounds__(256) void k9_y2_g1(
    const float* __restrict__ be2, const int* __restrict__ deg2, const float* __restrict__ W2, u16* __restrict__ bY2,
    const int* __restrict__ csr1, const int* __restrict__ rowp1, const u16* __restrict__ bY1,
    const float* __restrict__ b1, u16* __restrict__ bg1,
    const int* __restrict__ csr0, const int* __restrict__ rowp0, const u16* __restrict__ bY0,
    const float* __restrict__ gb, u16* __restrict__ bg0, int ngemm, int nMain, int sBase)
{
  __shared__ float sm[5120];
  int bid = blockIdx.x;
  if (bid < ngemm) dev_gemm<0,1,0>(sm, sm+4096, bid, be2, deg2, W2, nullptr, nullptr, nullptr, bY2, N2);
  else if (bid < nMain) dev_gcn_gather16<1>(bid - ngemm, csr1, rowp1, bY1, b1, bg1, N1);
  else dev_gcn_gather16<1>(sBase + bid - nMain, csr0, rowp0, bY0, gb, bg0, N0);
}

// K10: gcn_gather16(g2)->bg2(f32) || g0 slice
__global__ __launch_bounds__(256) void k10_g2(
    const int* __restrict__ csr2, const int* __restrict__ rowp2, const u16* __restrict__ bY2,
    const float* __restrict__ b2, float* __restrict__ bg2,
    const int* __restrict__ csr0, const int* __restrict__ rowp0, const u16* __restrict__ bY0,
    const float* __restrict__ gb, u16* __restrict__ bg0, int nMain, int sBase)
{
  int bid = blockIdx.x;
  if (bid < nMain) dev_gcn_gather16<0>(bid, csr2, rowp2, bY2, b2, bg2, N2);
  else dev_gcn_gather16<1>(sBase + bid - nMain, csr0, rowp0, bY0, gb, bg0, N0);
}

// K11: dec0 gemm (f32 A) || head2 || g0 slice
__global__ __launch_bounds__(256) void k11_dec0_head2(
    const float* __restrict__ bg2, const float* __restrict__ vW, const float* __restrict__ vb,
    const float* __restrict__ kvec, float* __restrict__ sS, u16* __restrict__ bV,
    const float* __restrict__ hW, const float* __restrict__ hb, float* __restrict__ out,
    const int* __restrict__ csr0, const int* __restrict__ rowp0, const u16* __restrict__ bY0,
    const float* __restrict__ gb, u16* __restrict__ bg0, int ngemm, int nMain, int sBase)
{
  __shared__ float sm[5120];
  int bid = blockIdx.x;
  if (bid < ngemm) dev_gemm<1,0,0>(sm, sm+4096, bid, bg2, nullptr, vW, vb, kvec, sS, bV, N2);
  else if (bid < nMain) dev_head<0,0>(bid - ngemm, bg2, bg2, hW, hb, out, N2, N0+N1);
  else dev_gcn_gather16<1>(sBase + bid - nMain, csr0, rowp0, bY0, gb, bg0, N0);
}

// K12: attn_gather16(dc0)->be1 (d1) || g0 slice
__global__ __launch_bounds__(256) void k12_ag_d1(
    const int* __restrict__ csrA, const int* __restrict__ rowpA,
    const float* __restrict__ sS, const u16* __restrict__ bV, u16* __restrict__ be1,
    const int* __restrict__ csr0, const int* __restrict__ rowp0, const u16* __restrict__ bY0,
    const float* __restrict__ gb, u16* __restrict__ bg0, int nMain, int sBase)
{
  int bid = blockIdx.x;
  if (bid < nMain) dev_attn_gather16<1>(bid, csrA, rowpA, sS, bV, be1, N1);
  else dev_gcn_gather16<1>(sBase + bid - nMain, csr0, rowp0, bY0, gb, bg0, N0);
}

// K13: dec1 gemm (bf16 A) || head1 || g0 slice
__global__ __launch_bounds__(256) void k13_dec1_head1(
    const u16* __restrict__ be1, const float* __restrict__ vW, const float* __restrict__ vb,
    const float* __restrict__ kvec, float* __restrict__ sS, u16* __restrict__ bV,
    const u16* __restrict__ bg1, const float* __restrict__ hW, const float* __restrict__ hb,
    float* __restrict__ out,
    const int* __restrict__ csr0, const int* __restrict__ rowp0, const u16* __restrict__ bY0,
    const float* __restrict__ gb, u16* __restrict__ bg0, int ngemm, int nMain, int sBase)
{
  __shared__ float sm[5120];
  int bid = blockIdx.x;
  if (bid < ngemm) dev_gemm<1,0,1>(sm, sm+4096, bid, be1, nullptr, vW, vb, kvec, sS, bV, N1);
  else if (bid < nMain) dev_head<1,1>(bid - ngemm, bg1, be1, hW, hb, out, N1, N0);
  else dev_gcn_gather16<1>(sBase + bid - nMain, csr0, rowp0, bY0, gb, bg0, N0);
}

// K14: fused d0 gather + head0 (16-lane)
__global__ __launch_bounds__(256) void k14_gather_head0(
    const int* __restrict__ csr, const int* __restrict__ rowp,
    const float* __restrict__ w, const u16* __restrict__ V,
    const u16* __restrict__ bg0,
    const float* __restrict__ hW, const float* __restrict__ hb,
    float* __restrict__ out)
{
  int g = threadIdx.x >> 4, lane = threadIdx.x & 15;
  int row = blockIdx.x*16 + g;
  if (row >= N0) return;
  int st = rowp[row], en = rowp[row+1];
  float a0=0,a1=0,a2=0,a3=0,a4=0,a5=0,a6=0,a7=0;
  if (en > st){
    const uint4* V8 = (const uint4*)V;
    float den = 0.f;
    for (int e = st; e < en; ++e){
      int sn = csr[e];
      float x = w[sn];
      uint4 v = V8[(size_t)sn*16 + lane];
      den += x;
      a0 = fmaf(x, blo(v.x), a0); a1 = fmaf(x, bhi(v.x), a1);
      a2 = fmaf(x, blo(v.y), a2); a3 = fmaf(x, bhi(v.y), a3);
      a4 = fmaf(x, blo(v.z), a4); a5 = fmaf(x, bhi(v.z), a5);
      a6 = fmaf(x, blo(v.w), a6); a7 = fmaf(x, bhi(v.w), a7);
    }
    float inv = 1.f/den;
    a0*=inv; a1*=inv; a2*=inv; a3*=inv; a4*=inv; a5*=inv; a6*=inv; a7*=inv;
  }
  uint4 gv = ((const uint4*)(bg0 + (size_t)row*FD))[lane];
  float g0 = blo(gv.x), g1 = bhi(gv.x), g2 = blo(gv.y), g3 = bhi(gv.y);
  float g4 = blo(gv.z), g5 = bhi(gv.z), g6 = blo(gv.w), g7 = bhi(gv.w);
  int j = 8*lane;
  float acc[5];
  #pragma unroll
  for (int o = 0; o < 5; ++o){
    acc[o] = g0*hW[(j+0)*5+o] + g1*hW[(j+1)*5+o] + g2*hW[(j+2)*5+o] + g3*hW[(j+3)*5+o]
           + g4*hW[(j+4)*5+o] + g5*hW[(j+5)*5+o] + g6*hW[(j+6)*5+o] + g7*hW[(j+7)*5+o]
           + a0*hW[(128+j+0)*5+o] + a1*hW[(128+j+1)*5+o] + a2*hW[(128+j+2)*5+o] + a3*hW[(128+j+3)*5+o]
           + a4*hW[(128+j+4)*5+o] + a5*hW[(128+j+5)*5+o] + a6*hW[(128+j+6)*5+o] + a7*hW[(128+j+7)*5+o];
  }
  #pragma unroll
  for (int o = 0; o < 5; ++o)
    #pragma unroll
    for (int s = 8; s; s >>= 1) acc[o] += __shfl_xor(acc[o], s, 16);
  if (lane == 0){
    float m = -1e30f;
    #pragma unroll
    for (int o = 0; o < 5; ++o){ acc[o] += hb[o]; m = fmaxf(m, acc[o]); }
    float sum = 0.f;
    #pragma unroll
    for (int o = 0; o < 5; ++o){ acc[o] = expf(acc[o]-m); sum += acc[o]; }
    float is = 1.0f/sum;
    float* op = out + (size_t)row*5;
    #pragma unroll
    for (int o = 0; o < 5; ++o) op[o] = acc[o]*is;
  }
}

// ================= host =================
extern "C" void kernel_launch(void* const* d_in, const int* in_sizes, int n_in,
                              void* d_out, int out_size, void* d_ws, size_t ws_size,
                              hipStream_t stream)
{
  const float* X      = (const float*)d_in[0];
  const float* emb_W  = (const float*)d_in[1];
  const float* emb_b  = (const float*)d_in[2];
  const float* gcn_W  = (const float*)d_in[3];
  const float* gcn_b  = (const float*)d_in[4];
  const float* enc_qb = (const float*)d_in[6];
  const float* enc_kW = (const float*)d_in[7];
  const float* enc_kb = (const float*)d_in[8];
  const float* enc_vW = (const float*)d_in[9];
  const float* enc_vb = (const float*)d_in[10];
  const float* dec_qb = (const float*)d_in[12];
  const float* dec_kW = (const float*)d_in[13];
  const float* dec_kb = (const float*)d_in[14];
  const float* dec_vW = (const float*)d_in[15];
  const float* dec_vb = (const float*)d_in[16];
  const float* head_W = (const float*)d_in[17];
  const float* head_b = (const float*)d_in[18];
  const int* g0s  = (const int*)d_in[19];
  const int* g0d  = (const int*)d_in[20];
  const int* g1s  = (const int*)d_in[21];
  const int* g1d  = (const int*)d_in[22];
  const int* g2s  = (const int*)d_in[23];
  const int* g2d  = (const int*)d_in[24];
  const int* i0s  = (const int*)d_in[25];
  const int* i0d  = (const int*)d_in[26];
  const int* i1s  = (const int*)d_in[27];
  const int* i1d  = (const int*)d_in[28];
  const int* dc0s = (const int*)d_in[29];
  const int* dc0d = (const int*)d_in[30];
  const int* dc1s = (const int*)d_in[31];
  const int* dc1d = (const int*)d_in[32];

  // ---- workspace layout ----
  float* ws = (float*)d_ws;
  float* sS  = ws;                          // N0
  float* kvec = sS + N0;                    // 4*132
  float* be2 = kvec + 4*132;                // N2*FD f32
  float* bg2 = be2 + (size_t)N2*FD;         // N2*FD f32
  u16*  bh0 = (u16*)(bg2 + (size_t)N2*FD);  // N0*FD u16
  u16*  be1 = bh0 + (size_t)N0*FD;          // N1*FD u16
  u16*  bg0 = be1 + (size_t)N1*FD;          // N0*FD u16
  u16*  bg1 = bg0 + (size_t)N0*FD;          // N1*FD u16
  u16*  bV  = bg1 + (size_t)N1*FD;          // N0*FD u16 (V tables, time-shared)
  u16*  bY0 = bV  + (size_t)N0*FD;          // N0*FD u16
  u16*  bY1 = bV + 4000000;                 // alias into bV tail
  u16*  bY2 = bV + 8000000;
  int*  degBlk  = (int*)(bY0 + (size_t)N0*FD);  // N0+N1+N2
  int*  bktCnt  = degBlk + (N0+N1+N2);          // 224
  int*  bktBase = bktCnt + 224;                 // 224
  int*  bktCur  = bktBase + 224;                // 224
  int*  rowpBlk = bktCur + 224;                 // 287507
  int*  csrBlk  = rowpBlk + 287507;             // 2,500,000
  u32*  ebuf    = (u32*)(csrBlk + 2500000);     // 2.5M u32

  const int* srcP[7] = {g0s,g1s,g2s,i0s,i1s,dc0s,dc1s};
  const int* dstP[7] = {g0d,g1d,g2d,i0d,i1d,dc0d,dc1d};
  const int nArr[7] = {N0,N1,N2,N1,N2,N1,N0};
  const int EArr[7] = {1000000,400000,100000,400000,100000,100000,400000};
  const int BArr[7] = {64,32,8,32,8,16,64};
  const int rArr[7] = {1563,782,782,782,782,1563,1563};
  int* deg0 = degBlk; int* deg1 = degBlk + N0; int* deg2 = degBlk + N0 + N1;
  int* degP[7] = {deg0, deg1, deg2, nullptr, nullptr, nullptr, nullptr};

  BMeta m;
  {
    int eo=0, bo=0, po=0, ro=0, co=0;
    for (int j=0;j<7;++j){
      m.src[j]=srcP[j]; m.dst[j]=dstP[j]; m.degp[j]=degP[j];
      m.rowp[j]=rowpBlk+ro; m.csr[j]=csrBlk+co;
      m.n[j]=nArr[j]; m.E[j]=EArr[j]; m.B[j]=BArr[j]; m.r[j]=rArr[j];
      m.eoff[j]=eo; m.boff[j]=bo; m.pblk[j]=po;
      eo+=EArr[j]; bo+=BArr[j]; po+=ceildiv(EArr[j],4096); ro+=nArr[j]+1; co+=EArr[j];
    }
    m.eoff[7]=eo; m.boff[7]=bo; m.pblk[7]=po;   // 2.5M / 224 / 614
  }

  const float invScale = 0.17677669529663687f;
  float* out = (float*)d_out;

  const int NP0 = m.pblk[7];                // 614
  const int NP3 = m.boff[7];                // 224
  const int ZTOT = (N0+N1+N2) + 224;
  const int GH0 = ceildiv(N0,32);           // 3125
  const int GH1 = ceildiv(N1,32);           // 782
  const int GH2 = ceildiv(N2,32);           // 196
  const int GS1 = 1250;                     // dual(h0) share in K4
  const int GA1_16 = ceildiv(N1,16);        // 1563
  const int GA2_16 = ceildiv(N2,16);        // 391
  const int G0B16  = ceildiv(N0,16);        // 6250
  const int GH2H = ceildiv(N2,4);           // 1563
  const int GH1H = ceildiv(N1,4);           // 6250

  int ss[9];
  for (int i = 0; i <= 8; ++i) ss[i] = (int)(((long long)G0B16 * i) / 8);

  // K1: zero (deg+bktCnt) || kvec
  k1_zero_kqv<<<4 + ceildiv(ZTOT,256), 256, 0, stream>>>(degBlk, ZTOT,
      enc_kW, enc_kb, enc_qb, dec_kW, dec_kb, dec_qb, kvec, invScale);
  // K2: P0(+srcdeg) || h0 gemm
  k2_p0_gemm<<<NP0 + GH0, 256, 0, stream>>>(m, bktCnt, X, emb_W, emb_b, bh0, NP0);
  // K3: P1
  k3_p1<<<1, 256, 0, stream>>>(m, bktCnt, bktBase, bktCur);
  // K4: P2 || dual(h0) part 1
  k4_p2_dual<<<NP0 + GS1, 256, 0, stream>>>(m, bktCur, ebuf,
      bh0, deg0, enc_vW, enc_vb, gcn_W, kvec, sS, bV, bY0, NP0, 0);
  // K5: P3 || dual(h0) part 2
  k5_p3_dual<<<NP3 + (GH0 - GS1), 256, 0, stream>>>(m, bktCnt, bktBase, ebuf,
      bh0, deg0, enc_vW, enc_vb, gcn_W, kvec, sS, bV, bY0, NP3, GS1);
  // K6: attn_gather(i0)->be1 || g0[0]
  k6_ag_i0<<<GA1_16 + (ss[1]-ss[0]), 256, 0, stream>>>(m.csr[3], m.rowp[3], sS, bV, be1,
      m.csr[0], m.rowp[0], bY0, gcn_b, bg0, GA1_16, ss[0]);
  // K7: dual(be1 -> V1, Y1) || g0[1]
  k7_dual_enc1<<<GH1 + (ss[2]-ss[1]), 256, 0, stream>>>(be1, deg1,
      enc_vW+16384, enc_vb+128, gcn_W+16384, kvec+132, sS, bV, bY1,
      m.csr[0], m.rowp[0], bY0, gcn_b, bg0, GH1, ss[1]);
  // K8: attn_gather(i1)->be2 || g0[2]
  k8_ag_i1<<<GA2_16 + (ss[3]-ss[2]), 256, 0, stream>>>(m.csr[4], m.rowp[4], sS, bV, be2,
      m.csr[0], m.rowp[0], bY0, gcn_b, bg0, GA2_16, ss[2]);
  // K9: gcn2-Y || gather(g1)->bg1 || g0[3]
  k9_y2_g1<<<GH2 + GA1_16 + (ss[4]-ss[3]), 256, 0, stream>>>(be2, deg2, gcn_W+32768, bY2,
      m.csr[1], m.rowp[1], bY1, gcn_b+128, bg1,
      m.csr[0], m.rowp[0], bY0, gcn_b, bg0, GH2, GH2+GA1_16, ss[3]);
  // K10: gather(g2)->bg2 || g0[4]
  k10_g2<<<GA2_16 + (ss[5]-ss[4]), 256, 0, stream>>>(m.csr[2], m.rowp[2], bY2, gcn_b+256, bg2,
      m.csr[0], m.rowp[0], bY0, gcn_b, bg0, GA2_16, ss[4]);
  // K11: dec0 gemm || head2 || g0[5]
  k11_dec0_head2<<<GH2 + GH2H + (ss[6]-ss[5]), 256, 0, stream>>>(bg2, dec_vW, dec_vb, kvec+264, sS, bV,
      head_W+2560, head_b+10, out,
      m.csr[0], m.rowp[0], bY0, gcn_b, bg0, GH2, GH2+GH2H, ss[5]);
  // K12: attn_gather(dc0)->be1 (d1) || g0[6]
  k12_ag_d1<<<GA1_16 + (ss[7]-ss[6]), 256, 0, stream>>>(m.csr[5], m.rowp[5], sS, bV, be1,
      m.csr[0], m.rowp[0], bY0, gcn_b, bg0, GA1_16, ss[6]);
  // K13: dec1 gemm || head1 || g0[7]
  k13_dec1_head1<<<GH1 + GH1H + (ss[8]-ss[7]), 256, 0, stream>>>(be1, dec_vW+16384, dec_vb+128, kvec+396, sS, bV,
      bg1, head_W+1280, head_b+5, out,
      m.csr[0], m.rowp[0], bY0, gcn_b, bg0, GH1, GH1+GH1H, ss[7]);
  // K14: fused d0 gather + head0
  k14_gather_head0<<<G0B16, 256, 0, stream>>>(m.csr[6], m.rowp[6], sS, bV, bg0,
      head_W, head_b, out);
}

// Round 10
// 457.069 us; speedup vs baseline: 10.8974x; 1.0319x over previous
//
#include <hip/hip_runtime.h>
#include <math.h>

#define N0 100000
#define N1 25000
#define N2 6250
#define FD 128

typedef unsigned short u16;
typedef unsigned int u32;

static inline int ceildiv(int a, int b){ return (a + b - 1)/b; }

__device__ __forceinline__ u16 f2bf(float f){
  u32 u = __float_as_uint(f);
  u += 0x7fffu + ((u >> 16) & 1u);
  return (u16)(u >> 16);
}
__device__ __forceinline__ float bf2f(u16 h){
  return __uint_as_float(((u32)h) << 16);
}
__device__ __forceinline__ float blo(u32 u){ return __uint_as_float(u << 16); }
__device__ __forceinline__ float bhi(u32 u){ return __uint_as_float(u & 0xffff0000u); }
__device__ __forceinline__ u32 pk2(float a, float b){ return (u32)f2bf(a) | ((u32)f2bf(b) << 16); }

// ================= bucket metadata: 10 jobs =================
// jobs 0-6: dst-CSR builds (g0,g1,g2,i0,i1,dc0,dc1)
// jobs 7-9: src-degree counts for g0,g1,g2 -> rs = rsqrt(max(deg,1))
struct BMeta {
  const int* key[10];           // dst (0-6) or src (7-9)
  const int* src[7];            // payload for CSR jobs
  int* rowp[7]; int* csr[7];
  float* rsout[3];
  int n[10], E[10], B[10], r[10];
  int eoff[8];                  // u32 ebuf offsets, jobs 0-6
  int soff[4];                  // u16 ebuf16 offsets, jobs 7-9
  int boff[11];                 // bucket offsets (328 total)
  int pblk[11];                 // 4096-edge block ranges (982 total)
};

// ================= GEMM =================
__device__ __forceinline__ void mm_inner(const float* Al, const float* Wl, int r0, int c0, float acc[4][4]){
  #pragma unroll
  for (int kq = 0; kq < 8; ++kq) {
    int k0 = kq*4;
    float4 a[4], w[4];
    #pragma unroll
    for (int i=0;i<4;++i) a[i] = *(const float4*)&Al[(r0+i)*32 + k0];
    #pragma unroll
    for (int kk=0;kk<4;++kk) w[kk] = *(const float4*)&Wl[(k0+kk)*128 + c0];
    #pragma unroll
    for (int i=0;i<4;++i){
      acc[i][0] = fmaf(a[i].x,w[0].x, fmaf(a[i].y,w[1].x, fmaf(a[i].z,w[2].x, fmaf(a[i].w,w[3].x, acc[i][0]))));
      acc[i][1] = fmaf(a[i].x,w[0].y, fmaf(a[i].y,w[1].y, fmaf(a[i].z,w[2].y, fmaf(a[i].w,w[3].y, acc[i][1]))));
      acc[i][2] = fmaf(a[i].x,w[0].z, fmaf(a[i].y,w[1].z, fmaf(a[i].z,w[2].z, fmaf(a[i].w,w[3].z, acc[i][2]))));
      acc[i][3] = fmaf(a[i].x,w[0].w, fmaf(a[i].y,w[1].w, fmaf(a[i].z,w[2].w, fmaf(a[i].w,w[3].w, acc[i][3]))));
    }
  }
}

// single-output GEMM: A(f32/bf16) @ W (+bias) -> bf16; SCORE emits w=exp(s)
template<int SCORE, int AB16>
__device__ __forceinline__ void dev_gemm(float* Wl, float* Al, int bid,
    const void* __restrict__ Ap,
    const float* __restrict__ W, const float* __restrict__ bias,
    const float* __restrict__ kvec, float* __restrict__ sOut,
    u16* __restrict__ out, int n)
{
  const int tid = threadIdx.x;
  const int row0 = bid * 32;
  const int c0 = (tid & 31) * 4, r0 = (tid >> 5) * 4;
  const int r = tid >> 3, fc = tid & 7;
  const int gr_s = row0 + r;
  float acc[4][4] = {};
  float sacc = 0.f;
  const float4* W4 = (const float4*)W;
  for (int kp = 0; kp < 4; ++kp) {
    float4* Wl4 = (float4*)Wl;
    #pragma unroll
    for (int i = 0; i < 4; ++i) Wl4[tid + 256*i] = W4[kp*1024 + tid + 256*i];
    {
      float4 v = make_float4(0.f,0.f,0.f,0.f);
      if (gr_s < n){
        if (AB16){
          ushort4 h = ((const ushort4*)Ap)[(size_t)gr_s*32 + kp*8 + fc];
          v = make_float4(bf2f(h.x), bf2f(h.y), bf2f(h.z), bf2f(h.w));
        } else {
          v = ((const float4*)Ap)[(size_t)gr_s*32 + kp*8 + fc];
        }
      }
      ((float4*)Al)[tid] = v;
      if (SCORE){
        float4 kv = *(const float4*)&kvec[kp*32 + fc*4];
        sacc += v.x*kv.x + v.y*kv.y + v.z*kv.z + v.w*kv.w;
      }
    }
    __syncthreads();
    mm_inner(Al, Wl, r0, c0, acc);
    __syncthreads();
  }
  if (SCORE){
    sacc += __shfl_xor(sacc, 1);
    sacc += __shfl_xor(sacc, 2);
    sacc += __shfl_xor(sacc, 4);
    if (fc == 0 && gr_s < n) sOut[gr_s] = expf(sacc + kvec[128]);
  }
  float4 bv = make_float4(0.f,0.f,0.f,0.f);
  if (bias) bv = *(const float4*)&bias[c0];
  #pragma unroll
  for (int i=0;i<4;++i){
    int gr = row0 + r0 + i;
    if (gr < n){
      ushort4 o;
      o.x = f2bf(acc[i][0]+bv.x); o.y = f2bf(acc[i][1]+bv.y);
      o.z = f2bf(acc[i][2]+bv.z); o.w = f2bf(acc[i][3]+bv.w);
      *(ushort4*)&out[(size_t)gr*FD + c0] = o;
    }
  }
}

// dual-output GEMM: V = A@Wv + vb (+score), Y = A@Wg (unscaled). A staged once.
template<int AB16>
__device__ __forceinline__ void dev_dualgemm(float* sm, int bid,
    const void* __restrict__ Ap,
    const float* __restrict__ Wv, const float* __restrict__ vb,
    const float* __restrict__ Wg,
    const float* __restrict__ kvec, float* __restrict__ sOut,
    u16* __restrict__ Vout, u16* __restrict__ Yout, int n)
{
  float* WvL = sm; float* WgL = sm + 4096; float* Al = sm + 8192;
  const int tid = threadIdx.x;
  const int row0 = bid * 32;
  const int c0 = (tid & 31) * 4, r0 = (tid >> 5) * 4;
  const int r = tid >> 3, fc = tid & 7;
  const int gr_s = row0 + r;
  float accV[4][4] = {};
  float accY[4][4] = {};
  float sacc = 0.f;
  const float4* Wv4 = (const float4*)Wv;
  const float4* Wg4 = (const float4*)Wg;
  for (int kp = 0; kp < 4; ++kp) {
    #pragma unroll
    for (int i = 0; i < 4; ++i) ((float4*)WvL)[tid + 256*i] = Wv4[kp*1024 + tid + 256*i];
    #pragma unroll
    for (int i = 0; i < 4; ++i) ((float4*)WgL)[tid + 256*i] = Wg4[kp*1024 + tid + 256*i];
    {
      float4 v = make_float4(0.f,0.f,0.f,0.f);
      if (gr_s < n){
        if (AB16){
          ushort4 h = ((const ushort4*)Ap)[(size_t)gr_s*32 + kp*8 + fc];
          v = make_float4(bf2f(h.x), bf2f(h.y), bf2f(h.z), bf2f(h.w));
        } else {
          v = ((const float4*)Ap)[(size_t)gr_s*32 + kp*8 + fc];
        }
      }
      ((float4*)Al)[tid] = v;
      float4 kv = *(const float4*)&kvec[kp*32 + fc*4];
      sacc += v.x*kv.x + v.y*kv.y + v.z*kv.z + v.w*kv.w;
    }
    __syncthreads();
    mm_inner(Al, WvL, r0, c0, accV);
    mm_inner(Al, WgL, r0, c0, accY);
    __syncthreads();
  }
  sacc += __shfl_xor(sacc, 1);
  sacc += __shfl_xor(sacc, 2);
  sacc += __shfl_xor(sacc, 4);
  if (fc == 0 && gr_s < n) sOut[gr_s] = expf(sacc + kvec[128]);
  float4 bv = *(const float4*)&vb[c0];
  #pragma unroll
  for (int i=0;i<4;++i){
    int gr = row0 + r0 + i;
    if (gr < n){
      ushort4 o;
      o.x = f2bf(accV[i][0]+bv.x); o.y = f2bf(accV[i][1]+bv.y);
      o.z = f2bf(accV[i][2]+bv.z); o.w = f2bf(accV[i][3]+bv.w);
      *(ushort4*)&Vout[(size_t)gr*FD + c0] = o;
      ushort4 y;
      y.x = f2bf(accY[i][0]); y.y = f2bf(accY[i][1]);
      y.z = f2bf(accY[i][2]); y.w = f2bf(accY[i][3]);
      *(ushort4*)&Yout[(size_t)gr*FD + c0] = y;
    }
  }
}

// ================= bucket passes =================
__device__ __forceinline__ int job_of_blk(const BMeta& m, int bid){
  int j = 0;
  #pragma unroll
  for (int t = 1; t < 10; ++t) if (bid >= m.pblk[t]) j = t;
  return j;
}

// P0: LDS bucket histogram of key (all 10 jobs)
__device__ __forceinline__ void dev_p0(const BMeta& m, int bid, int* __restrict__ bktCnt, int* sh){
  int j = job_of_blk(m, bid);
  int lb = bid - m.pblk[j];
  const int* key = m.key[j]; int E = m.E[j], r = m.r[j], B = m.B[j];
  if (threadIdx.x < 64) sh[threadIdx.x] = 0;
  __syncthreads();
  int base = lb*4096 + threadIdx.x;
  #pragma unroll
  for (int i = 0; i < 16; ++i){ int e = base + i*256; if (e < E) atomicAdd(&sh[key[e]/r], 1); }
  __syncthreads();
  if ((int)threadIdx.x < B) atomicAdd(&bktCnt[m.boff[j] + threadIdx.x], sh[threadIdx.x]);
}

// P1: scan 328 buckets across 10 jobs
__device__ __forceinline__ void dev_p1(const BMeta& m, const int* __restrict__ bktCnt,
    int* __restrict__ bktBase, int* __restrict__ bktCur, int* sh){
  int tid = threadIdx.x;
  for (int i = tid; i < 328; i += 256) sh[i] = bktCnt[i];
  __syncthreads();
  if (tid < 10){
    int acc = (tid < 7) ? m.eoff[tid] : m.soff[tid-7];
    for (int b = m.boff[tid]; b < m.boff[tid+1]; ++b){ int v = sh[b]; sh[b] = acc; acc += v; }
  }
  __syncthreads();
  for (int i = tid; i < 328; i += 256){ bktBase[i] = sh[i]; bktCur[i] = sh[i]; }
}

// P2: CSR jobs scatter packed u32 (localDst<<17|src); deg jobs scatter u16 localSrc
__device__ __forceinline__ void dev_p2(const BMeta& m, int bid, int* __restrict__ bktCur,
    u32* __restrict__ ebuf, u16* __restrict__ ebuf16, int* sh){
  int j = job_of_blk(m, bid);
  int lb = bid - m.pblk[j];
  const int* key = m.key[j];
  int E = m.E[j], r = m.r[j], B = m.B[j];
  int* h = sh; int* start = sh + 64;
  if (threadIdx.x < 64) h[threadIdx.x] = 0;
  __syncthreads();
  int base = lb*4096 + threadIdx.x;
  #pragma unroll
  for (int i = 0; i < 16; ++i){ int e = base + i*256; if (e < E) atomicAdd(&h[key[e]/r], 1); }
  __syncthreads();
  if ((int)threadIdx.x < B) start[threadIdx.x] = atomicAdd(&bktCur[m.boff[j] + threadIdx.x], h[threadIdx.x]);
  __syncthreads();
  if (j < 7){
    const int* src = m.src[j];
    #pragma unroll
    for (int i = 0; i < 16; ++i){
      int e = base + i*256;
      if (e < E){
        int s = src[e], d = key[e];
        int b = d / r;
        int pos = atomicAdd(&start[b], 1);
        ebuf[pos] = ((u32)(d - b*r) << 17) | (u32)s;
      }
    }
  } else {
    #pragma unroll
    for (int i = 0; i < 16; ++i){
      int e = base + i*256;
      if (e < E){
        int k = key[e];
        int b = k / r;
        int pos = atomicAdd(&start[b], 1);
        ebuf16[pos] = (u16)(k - b*r);
      }
    }
  }
}

// P3: CSR jobs -> counting sort; deg jobs -> histogram + rsqrt write
__device__ __forceinline__ void dev_p3(const BMeta& m, int bb,
    const int* __restrict__ bktCnt, const int* __restrict__ bktBase,
    const u32* __restrict__ ebuf, const u16* __restrict__ ebuf16, int* sh){
  int j = 0;
  #pragma unroll
  for (int t = 1; t < 10; ++t) if (bb >= m.boff[t]) j = t;
  int b = bb - m.boff[j];
  int n = m.n[j], r = m.r[j];
  int node0 = b*r;
  int rr = min(r, n - node0);
  int gbase = bktBase[bb];
  int cnt = bktCnt[bb];
  int tid = threadIdx.x;
  if (j >= 7){
    int* hist = sh;
    for (int i = tid; i < rr; i += 256) hist[i] = 0;
    __syncthreads();
    for (int e = tid; e < cnt; e += 256) atomicAdd(&hist[ebuf16[gbase + e]], 1);
    __syncthreads();
    float* rs = m.rsout[j-7];
    for (int i = tid; i < rr; i += 256) rs[node0 + i] = rsqrtf(fmaxf((float)hist[i], 1.f));
    return;
  }
  int B = m.B[j];
  int* rowp = m.rowp[j]; int* csr = m.csr[j];
  int lbase = gbase - m.eoff[j];
  int* hist = sh; int* aux = sh + 1568;
  for (int i = tid; i < rr; i += 256) hist[i] = 0;
  __syncthreads();
  for (int e = tid; e < cnt; e += 256){ u32 pk = ebuf[gbase + e]; atomicAdd(&hist[pk >> 17], 1); }
  __syncthreads();
  int ch = (rr + 255) >> 8;
  int i0 = tid*ch;
  int s = 0;
  for (int k = 0; k < ch; ++k){ int idx = i0 + k; if (idx < rr){ int t = hist[idx]; hist[idx] = s; s += t; } }
  aux[tid] = s; __syncthreads();
  for (int off = 1; off < 256; off <<= 1){
    int v = aux[tid]; int a = (tid >= off) ? aux[tid - off] : 0;
    __syncthreads();
    aux[tid] = v + a;
    __syncthreads();
  }
  int pre = (tid ? aux[tid-1] : 0) + lbase;
  for (int k = 0; k < ch; ++k){ int idx = i0 + k; if (idx < rr) hist[idx] += pre; }
  __syncthreads();
  for (int i = tid; i < rr; i += 256) rowp[node0 + i] = hist[i];
  if (b == B-1 && tid == 0) rowp[n] = lbase + cnt;
  __syncthreads();
  for (int e = tid; e < cnt; e += 256){
    u32 pk = ebuf[gbase + e];
    int pos = atomicAdd(&hist[pk >> 17], 1);
    csr[pos] = (int)(pk & 0x1FFFFu);
  }
}

// ================= 16-lane gathers =================
template<int OB16>
__device__ __forceinline__ void dev_attn_gather16(int bid,
    const int* __restrict__ csr, const int* __restrict__ rowp,
    const float* __restrict__ w, const u16* __restrict__ V,
    void* __restrict__ out, int n)
{
  int g = threadIdx.x >> 4, lane = threadIdx.x & 15;
  int row = bid*16 + g;
  if (row >= n) return;
  int st = rowp[row], en = rowp[row+1];
  float a0=0,a1=0,a2=0,a3=0,a4=0,a5=0,a6=0,a7=0;
  if (en > st){
    const uint4* V8 = (const uint4*)V;
    float den = 0.f;
    for (int e = st; e < en; ++e){
      int sn = csr[e];
      float x = w[sn];
      uint4 v = V8[(size_t)sn*16 + lane];
      den += x;
      a0 = fmaf(x, blo(v.x), a0); a1 = fmaf(x, bhi(v.x), a1);
      a2 = fmaf(x, blo(v.y), a2); a3 = fmaf(x, bhi(v.y), a3);
      a4 = fmaf(x, blo(v.z), a4); a5 = fmaf(x, bhi(v.z), a5);
      a6 = fmaf(x, blo(v.w), a6); a7 = fmaf(x, bhi(v.w), a7);
    }
    float inv = 1.f/den;
    a0*=inv; a1*=inv; a2*=inv; a3*=inv; a4*=inv; a5*=inv; a6*=inv; a7*=inv;
  }
  if (OB16){
    uint4 o; o.x = pk2(a0,a1); o.y = pk2(a2,a3); o.z = pk2(a4,a5); o.w = pk2(a6,a7);
    ((uint4*)out)[(size_t)row*16 + lane] = o;
  } else {
    float4* o4 = (float4*)out;
    o4[(size_t)row*32 + lane*2]     = make_float4(a0,a1,a2,a3);
    o4[(size_t)row*32 + lane*2 + 1] = make_float4(a4,a5,a6,a7);
  }
}

// gcn gather: out = rsqrt(deg_in) * sum rs[src]*Y[src] + bias
template<int OB16>
__device__ __forceinline__ void dev_gcn_gather16(int bid,
    const int* __restrict__ csr, const int* __restrict__ rowp,
    const float* __restrict__ rs, const u16* __restrict__ Y,
    const float* __restrict__ bias, void* __restrict__ out, int n)
{
  int g = threadIdx.x >> 4, lane = threadIdx.x & 15;
  int row = bid*16 + g;
  if (row >= n) return;
  int st = rowp[row], en = rowp[row+1];
  float a0=0,a1=0,a2=0,a3=0,a4=0,a5=0,a6=0,a7=0;
  const uint4* Y8 = (const uint4*)Y;
  for (int e = st; e < en; ++e){
    int sn = csr[e];
    float x = rs[sn];
    uint4 v = Y8[(size_t)sn*16 + lane];
    a0 = fmaf(x, blo(v.x), a0); a1 = fmaf(x, bhi(v.x), a1);
    a2 = fmaf(x, blo(v.y), a2); a3 = fmaf(x, bhi(v.y), a3);
    a4 = fmaf(x, blo(v.z), a4); a5 = fmaf(x, bhi(v.z), a5);
    a6 = fmaf(x, blo(v.w), a6); a7 = fmaf(x, bhi(v.w), a7);
  }
  float sc = rsqrtf(fmaxf((float)(en - st), 1.f));
  const float4* b4 = (const float4*)bias;
  float4 ba = b4[lane*2], bb = b4[lane*2+1];
  float o0=fmaf(a0,sc,ba.x), o1=fmaf(a1,sc,ba.y), o2=fmaf(a2,sc,ba.z), o3=fmaf(a3,sc,ba.w);
  float o4v=fmaf(a4,sc,bb.x), o5=fmaf(a5,sc,bb.y), o6=fmaf(a6,sc,bb.z), o7=fmaf(a7,sc,bb.w);
  if (OB16){
    uint4 o; o.x = pk2(o0,o1); o.y = pk2(o2,o3); o.z = pk2(o4v,o5); o.w = pk2(o6,o7);
    ((uint4*)out)[(size_t)row*16 + lane] = o;
  } else {
    float4* o4 = (float4*)out;
    o4[(size_t)row*32 + lane*2]     = make_float4(o0,o1,o2,o3);
    o4[(size_t)row*32 + lane*2 + 1] = make_float4(o4v,o5,o6,o7);
  }
}

// 64-lane head for head1/head2
template<int GB16, int DB16>
__device__ __forceinline__ void dev_head(int bid, const void* __restrict__ g, const void* __restrict__ dch,
    const float* __restrict__ W, const float* __restrict__ b,
    float* __restrict__ out, int n, int rowOff)
{
  int wid = threadIdx.x >> 6, lane = threadIdx.x & 63;
  int row = bid*4 + wid;
  if (row >= n) return;
  float x0, x1, x2, x3;
  if (GB16){ const u16* gr = (const u16*)g + (size_t)row*FD; x0 = bf2f(gr[lane]); x1 = bf2f(gr[64+lane]); }
  else     { const float* gr = (const float*)g + (size_t)row*FD; x0 = gr[lane]; x1 = gr[64+lane]; }
  if (DB16){ const u16* dr = (const u16*)dch + (size_t)row*FD; x2 = bf2f(dr[lane]); x3 = bf2f(dr[64+lane]); }
  else     { const float* dr = (const float*)dch + (size_t)row*FD; x2 = dr[lane]; x3 = dr[64+lane]; }
  float acc[5];
  #pragma unroll
  for (int o = 0; o < 5; ++o)
    acc[o] = x0*W[lane*5+o] + x1*W[(64+lane)*5+o] + x2*W[(128+lane)*5+o] + x3*W[(192+lane)*5+o];
  #pragma unroll
  for (int o = 0; o < 5; ++o)
    #pragma unroll
    for (int s = 32; s; s >>= 1) acc[o] += __shfl_xor(acc[o], s);
  if (lane == 0){
    float m = -1e30f;
    #pragma unroll
    for (int o = 0; o < 5; ++o){ acc[o] += b[o]; m = fmaxf(m, acc[o]); }
    float sum = 0.f;
    #pragma unroll
    for (int o = 0; o < 5; ++o){ acc[o] = expf(acc[o]-m); sum += acc[o]; }
    float is = 1.0f/sum;
    float* op = out + (size_t)(rowOff+row)*5;
    #pragma unroll
    for (int o = 0; o < 5; ++o) op[o] = acc[o]*is;
  }
}

// ================= kernels =================

__global__ __launch_bounds__(256) void k1_zero_kqv(int* __restrict__ zeroBlk, int ntot,
    const float* __restrict__ ekW, const float* __restrict__ ekb, const float* __restrict__ eqb,
    const float* __restrict__ dkW, const float* __restrict__ dkb, const float* __restrict__ dqb,
    float* __restrict__ kv, float inv)
{
  int bid = blockIdx.x;
  if (bid < 4){
    if (threadIdx.x < 128){
      int j = bid;
      const float* kW = (j < 2) ? ekW + j*16384 : dkW + (j-2)*16384;
      const float* kb = (j < 2) ? ekb + j*128   : dkb + (j-2)*128;
      const float* qb = (j < 2) ? eqb + j*128   : dqb + (j-2)*128;
      float* o = kv + j*132;
      int k = threadIdx.x;
      float a = 0.f;
      for (int t = 0; t < 128; ++t) a = fmaf(kW[k*128+t], qb[t], a);
      o[k] = a * inv;
      if (k == 0){
        float c = 0.f;
        for (int t = 0; t < 128; ++t) c = fmaf(kb[t], qb[t], c);
        o[128] = c * inv;
      }
    }
  } else {
    int i = (bid-4)*256 + threadIdx.x;
    if (i < ntot) zeroBlk[i] = 0;
  }
}

// K2: P0 (10 jobs, LDS-only hist) || h0 gemm
__global__ __launch_bounds__(256) void k2_p0_gemm(BMeta m, int* __restrict__ bktCnt,
    const float* __restrict__ X, const float* __restrict__ W, const float* __restrict__ b,
    u16* __restrict__ bh0, int np0)
{
  __shared__ float sm[5120];
  int bid = blockIdx.x;
  if (bid < np0) dev_p0(m, bid, bktCnt, (int*)sm);
  else dev_gemm<0,0>(sm, sm+4096, bid - np0, X, W, b, nullptr, nullptr, bh0, N0);
}

// K3: P1
__global__ __launch_bounds__(256) void k3_p1(BMeta m,
    const int* __restrict__ bktCnt, int* __restrict__ bktBase, int* __restrict__ bktCur)
{
  __shared__ int sh[384];
  dev_p1(m, bktCnt, bktBase, bktCur, sh);
}

// K4: P2 (10 jobs) || dual(h0) part 1
__global__ __launch_bounds__(256) void k4_p2_dual(BMeta m, int* __restrict__ bktCur,
    u32* __restrict__ ebuf, u16* __restrict__ ebuf16,
    const u16* __restrict__ bh0,
    const float* __restrict__ evW, const float* __restrict__ evb, const float* __restrict__ gW,
    const float* __restrict__ kvec, float* __restrict__ sS, u16* __restrict__ bV, u16* __restrict__ bY0,
    int np2, int gOff)
{
  __shared__ float sm[9216];
  int bid = blockIdx.x;
  if (bid < np2) dev_p2(m, bid, bktCur, ebuf, ebuf16, (int*)sm);
  else dev_dualgemm<1>(sm, gOff + bid - np2, bh0, evW, evb, gW, kvec, sS, bV, bY0, N0);
}

// K5: P3 (328 buckets, incl deg->rs) || dual(h0) part 2
__global__ __launch_bounds__(256) void k5_p3_dual(BMeta m,
    const int* __restrict__ bktCnt, const int* __restrict__ bktBase,
    const u32* __restrict__ ebuf, const u16* __restrict__ ebuf16,
    const u16* __restrict__ bh0,
    const float* __restrict__ evW, const float* __restrict__ evb, const float* __restrict__ gW,
    const float* __restrict__ kvec, float* __restrict__ sS, u16* __restrict__ bV, u16* __restrict__ bY0,
    int np3, int gOff)
{
  __shared__ float sm[9216];
  int bid = blockIdx.x;
  if (bid < np3) dev_p3(m, bid, bktCnt, bktBase, ebuf, ebuf16, (int*)sm);
  else dev_dualgemm<1>(sm, gOff + bid - np3, bh0, evW, evb, gW, kvec, sS, bV, bY0, N0);
}

// K6: attn_gather16(i0)->be1 || g0 slice
__global__ __launch_bounds__(256) void k6_ag_i0(
    const int* __restrict__ csrA, const int* __restrict__ rowpA,
    const float* __restrict__ sS, const u16* __restrict__ bV, u16* __restrict__ be1,
    const int* __restrict__ csr0, const int* __restrict__ rowp0, const float* __restrict__ rs0,
    const u16* __restrict__ bY0, const float* __restrict__ gb, u16* __restrict__ bg0, int nMain, int sBase)
{
  int bid = blockIdx.x;
  if (bid < nMain) dev_attn_gather16<1>(bid, csrA, rowpA, sS, bV, be1, N1);
  else dev_gcn_gather16<1>(sBase + bid - nMain, csr0, rowp0, rs0, bY0, gb, bg0, N0);
}

// K7: dualGEMM(be1 -> V1+score, Y1) || g0 slice
__global__ __launch_bounds__(256) void k7_dual_enc1(
    const u16* __restrict__ be1,
    const float* __restrict__ vW, const float* __restrict__ vb, const float* __restrict__ gW,
    const float* __restrict__ kvec, float* __restrict__ sS, u16* __restrict__ bV, u16* __restrict__ bY1,
    const int* __restrict__ csr0, const int* __restrict__ rowp0, const float* __restrict__ rs0,
    const u16* __restrict__ bY0, const float* __restrict__ gb, u16* __restrict__ bg0, int nMain, int sBase)
{
  __shared__ float sm[9216];
  int bid = blockIdx.x;
  if (bid < nMain) dev_dualgemm<1>(sm, bid, be1, vW, vb, gW, kvec, sS, bV, bY1, N1);
  else dev_gcn_gather16<1>(sBase + bid - nMain, csr0, rowp0, rs0, bY0, gb, bg0, N0);
}

// K8: attn_gather16(i1)->be2(f32) || g0 slice
__global__ __launch_bounds__(256) void k8_ag_i1(
    const int* __restrict__ csrA, const int* __restrict__ rowpA,
    const float* __restrict__ sS, const u16* __restrict__ bV, float* __restrict__ be2,
    const int* __restrict__ csr0, const int* __restrict__ rowp0, const float* __restrict__ rs0,
    const u16* __restrict__ bY0, const float* __restrict__ gb, u16* __restrict__ bg0, int nMain, int sBase)
{
  int bid = blockIdx.x;
  if (bid < nMain) dev_attn_gather16<0>(bid, csrA, rowpA, sS, bV, be2, N2);
  else dev_gcn_gather16<1>(sBase + bid - nMain, csr0, rowp0, rs0, bY0, gb, bg0, N0);
}

// K9: gcn2-Y gemm (f32 A) || gcn_gather16(g1)->bg1 || g0 slice
__global__ __launch_bounds__(256) void k9_y2_g1(
    const float* __restrict__ be2, const float* __restrict__ W2, u16* __restrict__ bY2,
    const int* __restrict__ csr1, const int* __restrict__ rowp1, const float* __restrict__ rs1,
    const u16* __restrict__ bY1, const float* __restrict__ b1, u16* __restrict__ bg1,
    const int* __restrict__ csr0, const int* __restrict__ rowp0, const float* __restrict__ rs0,
    const u16* __restrict__ bY0, const float* __restrict__ gb, u16* __restrict__ bg0,
    int ngemm, int nMain, int sBase)
{
  __shared__ float sm[5120];
  int bid = blockIdx.x;
  if (bid < ngemm) dev_gemm<0,0>(sm, sm+4096, bid, be2, W2, nullptr, nullptr, nullptr, bY2, N2);
  else if (bid < nMain) dev_gcn_gather16<1>(bid - ngemm, csr1, rowp1, rs1, bY1, b1, bg1, N1);
  else dev_gcn_gather16<1>(sBase + bid - nMain, csr0, rowp0, rs0, bY0, gb, bg0, N0);
}

// K10: gcn_gather16(g2)->bg2(f32) || g0 slice
__global__ __launch_bounds__(256) void k10_g2(
    const int* __restrict__ csr2, const int* __restrict__ rowp2, const float* __restrict__ rs2,
    const u16* __restrict__ bY2, const float* __restrict__ b2, float* __restrict__ bg2,
    const int* __restrict__ csr0, const int* __restrict__ rowp0, const float* __restrict__ rs0,
    const u16* __restrict__ bY0, const float* __restrict__ gb, u16* __restrict__ bg0, int nMain, int sBase)
{
  int bid = blockIdx.x;
  if (bid < nMain) dev_gcn_gather16<0>(bid, csr2, rowp2, rs2, bY2, b2, bg2, N2);
  else dev_gcn_gather16<1>(sBase + bid - nMain, csr0, rowp0, rs0, bY0, gb, bg0, N0);
}

// K11: dec0 gemm (f32 A) || head2 || g0 slice
__global__ __launch_bounds__(256) void k11_dec0_head2(
    const float* __restrict__ bg2, const float* __restrict__ vW, const float* __restrict__ vb,
    const float* __restrict__ kvec, float* __restrict__ sS, u16* __restrict__ bV,
    const float* __restrict__ hW, const float* __restrict__ hb, float* __restrict__ out,
    const int* __restrict__ csr0, const int* __restrict__ rowp0, const float* __restrict__ rs0,
    const u16* __restrict__ bY0, const float* __restrict__ gb, u16* __restrict__ bg0,
    int ngemm, int nMain, int sBase)
{
  __shared__ float sm[5120];
  int bid = blockIdx.x;
  if (bid < ngemm) dev_gemm<1,0>(sm, sm+4096, bid, bg2, vW, vb, kvec, sS, bV, N2);
  else if (bid < nMain) dev_head<0,0>(bid - ngemm, bg2, bg2, hW, hb, out, N2, N0+N1);
  else dev_gcn_gather16<1>(sBase + bid - nMain, csr0, rowp0, rs0, bY0, gb, bg0, N0);
}

// K12: attn_gather16(dc0)->be1 (d1) || g0 slice
__global__ __launch_bounds__(256) void k12_ag_d1(
    const int* __restrict__ csrA, const int* __restrict__ rowpA,
    const float* __restrict__ sS, const u16* __restrict__ bV, u16* __restrict__ be1,
    const int* __restrict__ csr0, const int* __restrict__ rowp0, const float* __restrict__ rs0,
    const u16* __restrict__ bY0, const float* __restrict__ gb, u16* __restrict__ bg0, int nMain, int sBase)
{
  int bid = blockIdx.x;
  if (bid < nMain) dev_attn_gather16<1>(bid, csrA, rowpA, sS, bV, be1, N1);
  else dev_gcn_gather16<1>(sBase + bid - nMain, csr0, rowp0, rs0, bY0, gb, bg0, N0);
}

// K13: dec1 gemm (bf16 A) || head1 || g0 slice
__global__ __launch_bounds__(256) void k13_dec1_head1(
    const u16* __restrict__ be1, const float* __restrict__ vW, const float* __restrict__ vb,
    const float* __restrict__ kvec, float* __restrict__ sS, u16* __restrict__ bV,
    const u16* __restrict__ bg1, const float* __restrict__ hW, const float* __restrict__ hb,
    float* __restrict__ out,
    const int* __restrict__ csr0, const int* __restrict__ rowp0, const float* __restrict__ rs0,
    const u16* __restrict__ bY0, const float* __restrict__ gb, u16* __restrict__ bg0,
    int ngemm, int nMain, int sBase)
{
  __shared__ float sm[5120];
  int bid = blockIdx.x;
  if (bid < ngemm) dev_gemm<1,1>(sm, sm+4096, bid, be1, vW, vb, kvec, sS, bV, N1);
  else if (bid < nMain) dev_head<1,1>(bid - ngemm, bg1, be1, hW, hb, out, N1, N0);
  else dev_gcn_gather16<1>(sBase + bid - nMain, csr0, rowp0, rs0, bY0, gb, bg0, N0);
}

// K14: fused d0 gather + head0 (16-lane)
__global__ __launch_bounds__(256) void k14_gather_head0(
    const int* __restrict__ csr, const int* __restrict__ rowp,
    const float* __restrict__ w, const u16* __restrict__ V,
    const u16* __restrict__ bg0,
    const float* __restrict__ hW, const float* __restrict__ hb,
    float* __restrict__ out)
{
  int g = threadIdx.x >> 4, lane = threadIdx.x & 15;
  int row = blockIdx.x*16 + g;
  if (row >= N0) return;
  int st = rowp[row], en = rowp[row+1];
  float a0=0,a1=0,a2=0,a3=0,a4=0,a5=0,a6=0,a7=0;
  if (en > st){
    const uint4* V8 = (const uint4*)V;
    float den = 0.f;
    for (int e = st; e < en; ++e){
      int sn = csr[e];
      float x = w[sn];
      uint4 v = V8[(size_t)sn*16 + lane];
      den += x;
      a0 = fmaf(x, blo(v.x), a0); a1 = fmaf(x, bhi(v.x), a1);
      a2 = fmaf(x, blo(v.y), a2); a3 = fmaf(x, bhi(v.y), a3);
      a4 = fmaf(x, blo(v.z), a4); a5 = fmaf(x, bhi(v.z), a5);
      a6 = fmaf(x, blo(v.w), a6); a7 = fmaf(x, bhi(v.w), a7);
    }
    float inv = 1.f/den;
    a0*=inv; a1*=inv; a2*=inv; a3*=inv; a4*=inv; a5*=inv; a6*=inv; a7*=inv;
  }
  uint4 gv = ((const uint4*)(bg0 + (size_t)row*FD))[lane];
  float g0 = blo(gv.x), g1 = bhi(gv.x), g2 = blo(gv.y), g3 = bhi(gv.y);
  float g4 = blo(gv.z), g5 = bhi(gv.z), g6 = blo(gv.w), g7 = bhi(gv.w);
  int j = 8*lane;
  float acc[5];
  #pragma unroll
  for (int o = 0; o < 5; ++o){
    acc[o] = g0*hW[(j+0)*5+o] + g1*hW[(j+1)*5+o] + g2*hW[(j+2)*5+o] + g3*hW[(j+3)*5+o]
           + g4*hW[(j+4)*5+o] + g5*hW[(j+5)*5+o] + g6*hW[(j+6)*5+o] + g7*hW[(j+7)*5+o]
           + a0*hW[(128+j+0)*5+o] + a1*hW[(128+j+1)*5+o] + a2*hW[(128+j+2)*5+o] + a3*hW[(128+j+3)*5+o]
           + a4*hW[(128+j+4)*5+o] + a5*hW[(128+j+5)*5+o] + a6*hW[(128+j+6)*5+o] + a7*hW[(128+j+7)*5+o];
  }
  #pragma unroll
  for (int o = 0; o < 5; ++o)
    #pragma unroll
    for (int s = 8; s; s >>= 1) acc[o] += __shfl_xor(acc[o], s, 16);
  if (lane == 0){
    float m = -1e30f;
    #pragma unroll
    for (int o = 0; o < 5; ++o){ acc[o] += hb[o]; m = fmaxf(m, acc[o]); }
    float sum = 0.f;
    #pragma unroll
    for (int o = 0; o < 5; ++o){ acc[o] = expf(acc[o]-m); sum += acc[o]; }
    float is = 1.0f/sum;
    float* op = out + (size_t)row*5;
    #pragma unroll
    for (int o = 0; o < 5; ++o) op[o] = acc[o]*is;
  }
}

// ================= host =================
extern "C" void kernel_launch(void* const* d_in, const int* in_sizes, int n_in,
                              void* d_out, int out_size, void* d_ws, size_t ws_size,
                              hipStream_t stream)
{
  const float* X      = (const float*)d_in[0];
  const float* emb_W  = (const float*)d_in[1];
  const float* emb_b  = (const float*)d_in[2];
  const float* gcn_W  = (const float*)d_in[3];
  const float* gcn_b  = (const float*)d_in[4];
  const float* enc_qb = (const float*)d_in[6];
  const float* enc_kW = (const float*)d_in[7];
  const float* enc_kb = (const float*)d_in[8];
  const float* enc_vW = (const float*)d_in[9];
  const float* enc_vb = (const float*)d_in[10];
  const float* dec_qb = (const float*)d_in[12];
  const float* dec_kW = (const float*)d_in[13];
  const float* dec_kb = (const float*)d_in[14];
  const float* dec_vW = (const float*)d_in[15];
  const float* dec_vb = (const float*)d_in[16];
  const float* head_W = (const float*)d_in[17];
  const float* head_b = (const float*)d_in[18];
  const int* g0s  = (const int*)d_in[19];
  const int* g0d  = (const int*)d_in[20];
  const int* g1s  = (const int*)d_in[21];
  const int* g1d  = (const int*)d_in[22];
  const int* g2s  = (const int*)d_in[23];
  const int* g2d  = (const int*)d_in[24];
  const int* i0s  = (const int*)d_in[25];
  const int* i0d  = (const int*)d_in[26];
  const int* i1s  = (const int*)d_in[27];
  const int* i1d  = (const int*)d_in[28];
  const int* dc0s = (const int*)d_in[29];
  const int* dc0d = (const int*)d_in[30];
  const int* dc1s = (const int*)d_in[31];
  const int* dc1d = (const int*)d_in[32];

  // ---- workspace layout ----
  float* ws = (float*)d_ws;
  float* sS  = ws;                          // N0
  float* kvec = sS + N0;                    // 4*132
  float* be2 = kvec + 4*132;                // N2*FD f32
  float* bg2 = be2 + (size_t)N2*FD;         // N2*FD f32
  float* rs0 = bg2 + (size_t)N2*FD;         // N0
  float* rs1 = rs0 + N0;                    // N1
  float* rs2 = rs1 + N1;                    // N2 (+2 pad for 16B alignment)
  u16*  bh0 = (u16*)(rs2 + N2 + 2);         // N0*FD u16
  u16*  be1 = bh0 + (size_t)N0*FD;          // N1*FD u16
  u16*  bg0 = be1 + (size_t)N1*FD;          // N0*FD u16
  u16*  bg1 = bg0 + (size_t)N0*FD;          // N1*FD u16
  u16*  bV  = bg1 + (size_t)N1*FD;          // N0*FD u16 (V tables, time-shared)
  u16*  bY0 = bV  + (size_t)N0*FD;          // N0*FD u16
  u16*  bY1 = bV + 4000000;                 // alias into bV tail
  u16*  bY2 = bV + 8000000;
  int*  bktCnt  = (int*)(bY0 + (size_t)N0*FD);  // 328
  int*  bktBase = bktCnt + 328;                 // 328
  int*  bktCur  = bktBase + 328;                // 328
  int*  rowpBlk = bktCur + 328;                 // 287507
  int*  csrBlk  = rowpBlk + 287507;             // 2,500,000
  u32*  ebuf    = (u32*)(csrBlk + 2500000);     // 2.5M u32
  u16*  ebuf16  = (u16*)(ebuf + 2500000);       // 1.5M u16

  const int* keyP[10] = {g0d,g1d,g2d,i0d,i1d,dc0d,dc1d, g0s,g1s,g2s};
  const int* srcP[7]  = {g0s,g1s,g2s,i0s,i1s,dc0s,dc1s};
  const int nArr[10] = {N0,N1,N2,N1,N2,N1,N0, N0,N1,N2};
  const int EArr[10] = {1000000,400000,100000,400000,100000,100000,400000, 1000000,400000,100000};
  const int BArr[10] = {64,32,8,32,8,16,64, 64,32,8};
  const int rArr[10] = {1563,782,782,782,782,1563,1563, 1563,782,782};

  BMeta m;
  {
    int eo=0, so=0, bo=0, po=0, ro=0, co=0;
    for (int j=0;j<10;++j){
      m.key[j]=keyP[j];
      m.n[j]=nArr[j]; m.E[j]=EArr[j]; m.B[j]=BArr[j]; m.r[j]=rArr[j];
      m.boff[j]=bo; m.pblk[j]=po;
      bo+=BArr[j]; po+=ceildiv(EArr[j],4096);
      if (j < 7){
        m.src[j]=srcP[j]; m.rowp[j]=rowpBlk+ro; m.csr[j]=csrBlk+co;
        m.eoff[j]=eo; eo+=EArr[j]; ro+=nArr[j]+1; co+=EArr[j];
      } else {
        m.soff[j-7]=so; so+=EArr[j];
      }
    }
    m.eoff[7]=eo; m.soff[3]=so; m.boff[10]=bo; m.pblk[10]=po; // 2.5M / 1.5M / 328 / 982
  }
  m.rsout[0]=rs0; m.rsout[1]=rs1; m.rsout[2]=rs2;

  const float invScale = 0.17677669529663687f;
  float* out = (float*)d_out;

  const int NP = m.pblk[10];                // 982
  const int NB = m.boff[10];                // 328
  const int GH0 = ceildiv(N0,32);           // 3125
  const int GH1 = ceildiv(N1,32);           // 782
  const int GH2 = ceildiv(N2,32);           // 196
  const int GS1 = 1250;                     // dual(h0) share in K4
  const int GA1_16 = ceildiv(N1,16);        // 1563
  const int GA2_16 = ceildiv(N2,16);        // 391
  const int G0B16  = ceildiv(N0,16);        // 6250
  const int GH2H = ceildiv(N2,4);           // 1563
  const int GH1H = ceildiv(N1,4);           // 6250

  int ss[9];
  for (int i = 0; i <= 8; ++i) ss[i] = (int)(((long long)G0B16 * i) / 8);

  // K1: zero bktCnt || kvec
  k1_zero_kqv<<<4 + ceildiv(NB,256), 256, 0, stream>>>(bktCnt, NB,
      enc_kW, enc_kb, enc_qb, dec_kW, dec_kb, dec_qb, kvec, invScale);
  // K2: P0 || h0 gemm
  k2_p0_gemm<<<NP + GH0, 256, 0, stream>>>(m, bktCnt, X, emb_W, emb_b, bh0, NP);
  // K3: P1
  k3_p1<<<1, 256, 0, stream>>>(m, bktCnt, bktBase, bktCur);
  // K4: P2 || dual(h0) part 1
  k4_p2_dual<<<NP + GS1, 256, 0, stream>>>(m, bktCur, ebuf, ebuf16,
      bh0, enc_vW, enc_vb, gcn_W, kvec, sS, bV, bY0, NP, 0);
  // K5: P3 || dual(h0) part 2
  k5_p3_dual<<<NB + (GH0 - GS1), 256, 0, stream>>>(m, bktCnt, bktBase, ebuf, ebuf16,
      bh0, enc_vW, enc_vb, gcn_W, kvec, sS, bV, bY0, NB, GS1);
  // K6: attn_gather(i0)->be1 || g0[0]
  k6_ag_i0<<<GA1_16 + (ss[1]-ss[0]), 256, 0, stream>>>(m.csr[3], m.rowp[3], sS, bV, be1,
      m.csr[0], m.rowp[0], rs0, bY0, gcn_b, bg0, GA1_16, ss[0]);
  // K7: dual(be1 -> V1, Y1) || g0[1]
  k7_dual_enc1<<<GH1 + (ss[2]-ss[1]), 256, 0, stream>>>(be1,
      enc_vW+16384, enc_vb+128, gcn_W+16384, kvec+132, sS, bV, bY1,
      m.csr[0], m.rowp[0], rs0, bY0, gcn_b, bg0, GH1, ss[1]);
  // K8: attn_gather(i1)->be2 || g0[2]
  k8_ag_i1<<<GA2_16 + (ss[3]-ss[2]), 256, 0, stream>>>(m.csr[4], m.rowp[4], sS, bV, be2,
      m.csr[0], m.rowp[0], rs0, bY0, gcn_b, bg0, GA2_16, ss[2]);
  // K9: gcn2-Y || gather(g1)->bg1 || g0[3]
  k9_y2_g1<<<GH2 + GA1_16 + (ss[4]-ss[3]), 256, 0, stream>>>(be2, gcn_W+32768, bY2,
      m.csr[1], m.rowp[1], rs1, bY1, gcn_b+128, bg1,
      m.csr[0], m.rowp[0], rs0, bY0, gcn_b, bg0, GH2, GH2+GA1_16, ss[3]);
  // K10: gather(g2)->bg2 || g0[4]
  k10_g2<<<GA2_16 + (ss[5]-ss[4]), 256, 0, stream>>>(m.csr[2], m.rowp[2], rs2, bY2, gcn_b+256, bg2,
      m.csr[0], m.rowp[0], rs0, bY0, gcn_b, bg0, GA2_16, ss[4]);
  // K11: dec0 gemm || head2 || g0[5]
  k11_dec0_head2<<<GH2 + GH2H + (ss[6]-ss[5]), 256, 0, stream>>>(bg2, dec_vW, dec_vb, kvec+264, sS, bV,
      head_W+2560, head_b+10, out,
      m.csr[0], m.rowp[0], rs0, bY0, gcn_b, bg0, GH2, GH2+GH2H, ss[5]);
  // K12: attn_gather(dc0)->be1 (d1) || g0[6]
  k12_ag_d1<<<GA1_16 + (ss[7]-ss[6]), 256, 0, stream>>>(m.csr[5], m.rowp[5], sS, bV, be1,
      m.csr[0], m.rowp[0], rs0, bY0, gcn_b, bg0, GA1_16, ss[6]);
  // K13: dec1 gemm || head1 || g0[7]
  k13_dec1_head1<<<GH1 + GH1H + (ss[8]-ss[7]), 256, 0, stream>>>(be1, dec_vW+16384, dec_vb+128, kvec+396, sS, bV,
      bg1, head_W+1280, head_b+5, out,
      m.csr[0], m.rowp[0], rs0, bY0, gcn_b, bg0, GH1, GH1+GH1H, ss[7]);
  // K14: fused d0 gather + head0
  k14_gather_head0<<<G0B16, 256, 0, stream>>>(m.csr[6], m.rowp[6], sS, bV, bg0,
      head_W, head_b, out);
}

// Round 11
// 447.843 us; speedup vs baseline: 11.1219x; 1.0206x over previous
//
#include <hip/hip_runtime.h>
#include <math.h>
#include <stdint.h>

#define N0 100000
#define N1 25000
#define N2 6250
#define FD 128

typedef unsigned short u16;
typedef unsigned int u32;
typedef short bf16x8 __attribute__((ext_vector_type(8)));
typedef float f32x4 __attribute__((ext_vector_type(4)));

static inline int ceildiv(int a, int b){ return (a + b - 1)/b; }

__device__ __forceinline__ u16 f2bf(float f){
  u32 u = __float_as_uint(f);
  u += 0x7fffu + ((u >> 16) & 1u);
  return (u16)(u >> 16);
}
__device__ __forceinline__ float bf2f(u16 h){
  return __uint_as_float(((u32)h) << 16);
}
__device__ __forceinline__ float blo(u32 u){ return __uint_as_float(u << 16); }
__device__ __forceinline__ float bhi(u32 u){ return __uint_as_float(u & 0xffff0000u); }
__device__ __forceinline__ u32 pk2(float a, float b){ return (u32)f2bf(a) | ((u32)f2bf(b) << 16); }

// ================= bucket metadata: 10 jobs =================
struct BMeta {
  const int* key[10];
  const int* src[7];
  int* rowp[7]; int* csr[7];
  float* rsout[3];
  int n[10], E[10], B[10], r[10];
  int eoff[8];
  int soff[4];
  int boff[11];
  int pblk[11];
};

// ================= FMA GEMM (f32/bf16 A, small cases) =================
__device__ __forceinline__ void mm_inner(const float* Al, const float* Wl, int r0, int c0, float acc[4][4]){
  #pragma unroll
  for (int kq = 0; kq < 8; ++kq) {
    int k0 = kq*4;
    float4 a[4], w[4];
    #pragma unroll
    for (int i=0;i<4;++i) a[i] = *(const float4*)&Al[(r0+i)*32 + k0];
    #pragma unroll
    for (int kk=0;kk<4;++kk) w[kk] = *(const float4*)&Wl[(k0+kk)*128 + c0];
    #pragma unroll
    for (int i=0;i<4;++i){
      acc[i][0] = fmaf(a[i].x,w[0].x, fmaf(a[i].y,w[1].x, fmaf(a[i].z,w[2].x, fmaf(a[i].w,w[3].x, acc[i][0]))));
      acc[i][1] = fmaf(a[i].x,w[0].y, fmaf(a[i].y,w[1].y, fmaf(a[i].z,w[2].y, fmaf(a[i].w,w[3].y, acc[i][1]))));
      acc[i][2] = fmaf(a[i].x,w[0].z, fmaf(a[i].y,w[1].z, fmaf(a[i].z,w[2].z, fmaf(a[i].w,w[3].z, acc[i][2]))));
      acc[i][3] = fmaf(a[i].x,w[0].w, fmaf(a[i].y,w[1].w, fmaf(a[i].z,w[2].w, fmaf(a[i].w,w[3].w, acc[i][3]))));
    }
  }
}

template<int SCORE, int AB16>
__device__ __forceinline__ void dev_gemm(float* Wl, float* Al, int bid,
    const void* __restrict__ Ap,
    const float* __restrict__ W, const float* __restrict__ bias,
    const float* __restrict__ kvec, float* __restrict__ sOut,
    u16* __restrict__ out, int n)
{
  const int tid = threadIdx.x;
  const int row0 = bid * 32;
  const int c0 = (tid & 31) * 4, r0 = (tid >> 5) * 4;
  const int r = tid >> 3, fc = tid & 7;
  const int gr_s = row0 + r;
  float acc[4][4] = {};
  float sacc = 0.f;
  const float4* W4 = (const float4*)W;
  for (int kp = 0; kp < 4; ++kp) {
    float4* Wl4 = (float4*)Wl;
    #pragma unroll
    for (int i = 0; i < 4; ++i) Wl4[tid + 256*i] = W4[kp*1024 + tid + 256*i];
    {
      float4 v = make_float4(0.f,0.f,0.f,0.f);
      if (gr_s < n){
        if (AB16){
          ushort4 h = ((const ushort4*)Ap)[(size_t)gr_s*32 + kp*8 + fc];
          v = make_float4(bf2f(h.x), bf2f(h.y), bf2f(h.z), bf2f(h.w));
        } else {
          v = ((const float4*)Ap)[(size_t)gr_s*32 + kp*8 + fc];
        }
      }
      ((float4*)Al)[tid] = v;
      if (SCORE){
        float4 kv = *(const float4*)&kvec[kp*32 + fc*4];
        sacc += v.x*kv.x + v.y*kv.y + v.z*kv.z + v.w*kv.w;
      }
    }
    __syncthreads();
    mm_inner(Al, Wl, r0, c0, acc);
    __syncthreads();
  }
  if (SCORE){
    sacc += __shfl_xor(sacc, 1);
    sacc += __shfl_xor(sacc, 2);
    sacc += __shfl_xor(sacc, 4);
    if (fc == 0 && gr_s < n) sOut[gr_s] = expf(sacc + kvec[128]);
  }
  float4 bv = make_float4(0.f,0.f,0.f,0.f);
  if (bias) bv = *(const float4*)&bias[c0];
  #pragma unroll
  for (int i=0;i<4;++i){
    int gr = row0 + r0 + i;
    if (gr < n){
      ushort4 o;
      o.x = f2bf(acc[i][0]+bv.x); o.y = f2bf(acc[i][1]+bv.y);
      o.z = f2bf(acc[i][2]+bv.z); o.w = f2bf(acc[i][3]+bv.w);
      *(ushort4*)&out[(size_t)gr*FD + c0] = o;
    }
  }
}

// ================= MFMA dual GEMM (LDS-free) =================
// block: rows [bid*32, +32) x 128 cols; V = A@Wv + vb (+score), Y = A@Wg.
// A bf16 row-major; WvT/WgT col-major bf16 (Wt[c][k]).
// Fragments (16x16x32): A: lane l holds A[l&15][(l>>4)*8+j]; B: B[(l>>4)*8+j][l&15].
// C/D: col=l&15, row=(l>>4)*4+reg  [verified mapping].
__device__ __forceinline__ void dev_dual_mfma(int bid,
    const u16* __restrict__ A, const u16* __restrict__ WvT, const u16* __restrict__ WgT,
    const float* __restrict__ vb, const float* __restrict__ kvec, float* __restrict__ sOut,
    u16* __restrict__ Vout, u16* __restrict__ Yout, int n)
{
  const int tid = threadIdx.x;
  const int wid = tid >> 6, lane = tid & 63;
  const int l15 = lane & 15, lg = lane >> 4;
  const int rt = wid & 1;
  const int cbase = (wid >> 1) * 64;
  const int row0 = bid * 32;
  const int arow = row0 + rt*16 + l15;
  const int arowc = min(arow, n-1);
  f32x4 accV[4] = {{0.f,0.f,0.f,0.f},{0.f,0.f,0.f,0.f},{0.f,0.f,0.f,0.f},{0.f,0.f,0.f,0.f}};
  f32x4 accY[4] = {{0.f,0.f,0.f,0.f},{0.f,0.f,0.f,0.f},{0.f,0.f,0.f,0.f},{0.f,0.f,0.f,0.f}};
  float sacc = 0.f;
  #pragma unroll
  for (int ks = 0; ks < 4; ++ks){
    const int ko = ks*32 + lg*8;
    bf16x8 a = *(const bf16x8*)(A + (size_t)arowc*FD + ko);
    if (wid < 2){
      float4 k0 = *(const float4*)(kvec + ko);
      float4 k1 = *(const float4*)(kvec + ko + 4);
      sacc += bf2f((u16)a[0])*k0.x + bf2f((u16)a[1])*k0.y + bf2f((u16)a[2])*k0.z + bf2f((u16)a[3])*k0.w
            + bf2f((u16)a[4])*k1.x + bf2f((u16)a[5])*k1.y + bf2f((u16)a[6])*k1.z + bf2f((u16)a[7])*k1.w;
    }
    #pragma unroll
    for (int ct = 0; ct < 4; ++ct){
      const int col = cbase + ct*16 + l15;
      bf16x8 bv = *(const bf16x8*)(WvT + (size_t)col*FD + ko);
      bf16x8 bg = *(const bf16x8*)(WgT + (size_t)col*FD + ko);
      accV[ct] = __builtin_amdgcn_mfma_f32_16x16x32_bf16(a, bv, accV[ct], 0, 0, 0);
      accY[ct] = __builtin_amdgcn_mfma_f32_16x16x32_bf16(a, bg, accY[ct], 0, 0, 0);
    }
  }
  if (wid < 2){
    sacc += __shfl_xor(sacc, 16);
    sacc += __shfl_xor(sacc, 32);
    if (lane < 16 && arow < n) sOut[arow] = expf(sacc + kvec[128]);
  }
  #pragma unroll
  for (int ct = 0; ct < 4; ++ct){
    const int col = cbase + ct*16 + l15;
    const float bvv = vb[col];
    #pragma unroll
    for (int i = 0; i < 4; ++i){
      int gr = row0 + rt*16 + lg*4 + i;
      if (gr < n){
        Vout[(size_t)gr*FD + col] = f2bf(accV[ct][i] + bvv);
        Yout[(size_t)gr*FD + col] = f2bf(accY[ct][i]);
      }
    }
  }
}

// ================= bucket passes =================
__device__ __forceinline__ int job_of_blk(const BMeta& m, int bid){
  int j = 0;
  #pragma unroll
  for (int t = 1; t < 10; ++t) if (bid >= m.pblk[t]) j = t;
  return j;
}

__device__ __forceinline__ void dev_p0(const BMeta& m, int bid, int* __restrict__ bktCnt, int* sh){
  int j = job_of_blk(m, bid);
  int lb = bid - m.pblk[j];
  const int* key = m.key[j]; int E = m.E[j], r = m.r[j], B = m.B[j];
  if (threadIdx.x < 64) sh[threadIdx.x] = 0;
  __syncthreads();
  int base = lb*4096 + threadIdx.x;
  #pragma unroll
  for (int i = 0; i < 16; ++i){ int e = base + i*256; if (e < E) atomicAdd(&sh[key[e]/r], 1); }
  __syncthreads();
  if ((int)threadIdx.x < B) atomicAdd(&bktCnt[m.boff[j] + threadIdx.x], sh[threadIdx.x]);
}

__device__ __forceinline__ void dev_p1(const BMeta& m, const int* __restrict__ bktCnt,
    int* __restrict__ bktBase, int* __restrict__ bktCur, int* sh){
  int tid = threadIdx.x;
  for (int i = tid; i < 328; i += 256) sh[i] = bktCnt[i];
  __syncthreads();
  if (tid < 10){
    int acc = (tid < 7) ? m.eoff[tid] : m.soff[tid-7];
    for (int b = m.boff[tid]; b < m.boff[tid+1]; ++b){ int v = sh[b]; sh[b] = acc; acc += v; }
  }
  __syncthreads();
  for (int i = tid; i < 328; i += 256){ bktBase[i] = sh[i]; bktCur[i] = sh[i]; }
}

__device__ __forceinline__ void dev_p2(const BMeta& m, int bid, int* __restrict__ bktCur,
    u32* __restrict__ ebuf, u16* __restrict__ ebuf16, int* sh){
  int j = job_of_blk(m, bid);
  int lb = bid - m.pblk[j];
  const int* key = m.key[j];
  int E = m.E[j], r = m.r[j], B = m.B[j];
  int* h = sh; int* start = sh + 64;
  if (threadIdx.x < 64) h[threadIdx.x] = 0;
  __syncthreads();
  int base = lb*4096 + threadIdx.x;
  #pragma unroll
  for (int i = 0; i < 16; ++i){ int e = base + i*256; if (e < E) atomicAdd(&h[key[e]/r], 1); }
  __syncthreads();
  if ((int)threadIdx.x < B) start[threadIdx.x] = atomicAdd(&bktCur[m.boff[j] + threadIdx.x], h[threadIdx.x]);
  __syncthreads();
  if (j < 7){
    const int* src = m.src[j];
    #pragma unroll
    for (int i = 0; i < 16; ++i){
      int e = base + i*256;
      if (e < E){
        int s = src[e], d = key[e];
        int b = d / r;
        int pos = atomicAdd(&start[b], 1);
        ebuf[pos] = ((u32)(d - b*r) << 17) | (u32)s;
      }
    }
  } else {
    #pragma unroll
    for (int i = 0; i < 16; ++i){
      int e = base + i*256;
      if (e < E){
        int k = key[e];
        int b = k / r;
        int pos = atomicAdd(&start[b], 1);
        ebuf16[pos] = (u16)(k - b*r);
      }
    }
  }
}

__device__ __forceinline__ void dev_p3(const BMeta& m, int bb,
    const int* __restrict__ bktCnt, const int* __restrict__ bktBase,
    const u32* __restrict__ ebuf, const u16* __restrict__ ebuf16, int* sh){
  int j = 0;
  #pragma unroll
  for (int t = 1; t < 10; ++t) if (bb >= m.boff[t]) j = t;
  int b = bb - m.boff[j];
  int n = m.n[j], r = m.r[j];
  int node0 = b*r;
  int rr = min(r, n - node0);
  int gbase = bktBase[bb];
  int cnt = bktCnt[bb];
  int tid = threadIdx.x;
  if (j >= 7){
    int* hist = sh;
    for (int i = tid; i < rr; i += 256) hist[i] = 0;
    __syncthreads();
    for (int e = tid; e < cnt; e += 256) atomicAdd(&hist[ebuf16[gbase + e]], 1);
    __syncthreads();
    float* rs = m.rsout[j-7];
    for (int i = tid; i < rr; i += 256) rs[node0 + i] = rsqrtf(fmaxf((float)hist[i], 1.f));
    return;
  }
  int B = m.B[j];
  int* rowp = m.rowp[j]; int* csr = m.csr[j];
  int lbase = gbase - m.eoff[j];
  int* hist = sh; int* aux = sh + 1568;
  for (int i = tid; i < rr; i += 256) hist[i] = 0;
  __syncthreads();
  for (int e = tid; e < cnt; e += 256){ u32 pk = ebuf[gbase + e]; atomicAdd(&hist[pk >> 17], 1); }
  __syncthreads();
  int ch = (rr + 255) >> 8;
  int i0 = tid*ch;
  int s = 0;
  for (int k = 0; k < ch; ++k){ int idx = i0 + k; if (idx < rr){ int t = hist[idx]; hist[idx] = s; s += t; } }
  aux[tid] = s; __syncthreads();
  for (int off = 1; off < 256; off <<= 1){
    int v = aux[tid]; int a = (tid >= off) ? aux[tid - off] : 0;
    __syncthreads();
    aux[tid] = v + a;
    __syncthreads();
  }
  int pre = (tid ? aux[tid-1] : 0) + lbase;
  for (int k = 0; k < ch; ++k){ int idx = i0 + k; if (idx < rr) hist[idx] += pre; }
  __syncthreads();
  for (int i = tid; i < rr; i += 256) rowp[node0 + i] = hist[i];
  if (b == B-1 && tid == 0) rowp[n] = lbase + cnt;
  __syncthreads();
  for (int e = tid; e < cnt; e += 256){
    u32 pk = ebuf[gbase + e];
    int pos = atomicAdd(&hist[pk >> 17], 1);
    csr[pos] = (int)(pk & 0x1FFFFu);
  }
}

// ================= 16-lane gathers =================
template<int OB16>
__device__ __forceinline__ void dev_attn_gather16(int bid,
    const int* __restrict__ csr, const int* __restrict__ rowp,
    const float* __restrict__ w, const u16* __restrict__ V,
    void* __restrict__ out, int n)
{
  int g = threadIdx.x >> 4, lane = threadIdx.x & 15;
  int row = bid*16 + g;
  if (row >= n) return;
  int st = rowp[row], en = rowp[row+1];
  float a0=0,a1=0,a2=0,a3=0,a4=0,a5=0,a6=0,a7=0;
  if (en > st){
    const uint4* V8 = (const uint4*)V;
    float den = 0.f;
    for (int e = st; e < en; ++e){
      int sn = csr[e];
      float x = w[sn];
      uint4 v = V8[(size_t)sn*16 + lane];
      den += x;
      a0 = fmaf(x, blo(v.x), a0); a1 = fmaf(x, bhi(v.x), a1);
      a2 = fmaf(x, blo(v.y), a2); a3 = fmaf(x, bhi(v.y), a3);
      a4 = fmaf(x, blo(v.z), a4); a5 = fmaf(x, bhi(v.z), a5);
      a6 = fmaf(x, blo(v.w), a6); a7 = fmaf(x, bhi(v.w), a7);
    }
    float inv = 1.f/den;
    a0*=inv; a1*=inv; a2*=inv; a3*=inv; a4*=inv; a5*=inv; a6*=inv; a7*=inv;
  }
  if (OB16){
    uint4 o; o.x = pk2(a0,a1); o.y = pk2(a2,a3); o.z = pk2(a4,a5); o.w = pk2(a6,a7);
    ((uint4*)out)[(size_t)row*16 + lane] = o;
  } else {
    float4* o4 = (float4*)out;
    o4[(size_t)row*32 + lane*2]     = make_float4(a0,a1,a2,a3);
    o4[(size_t)row*32 + lane*2 + 1] = make_float4(a4,a5,a6,a7);
  }
}

template<int OB16>
__device__ __forceinline__ void dev_gcn_gather16(int bid,
    const int* __restrict__ csr, const int* __restrict__ rowp,
    const float* __restrict__ rs, const u16* __restrict__ Y,
    const float* __restrict__ bias, void* __restrict__ out, int n)
{
  int g = threadIdx.x >> 4, lane = threadIdx.x & 15;
  int row = bid*16 + g;
  if (row >= n) return;
  int st = rowp[row], en = rowp[row+1];
  float a0=0,a1=0,a2=0,a3=0,a4=0,a5=0,a6=0,a7=0;
  const uint4* Y8 = (const uint4*)Y;
  for (int e = st; e < en; ++e){
    int sn = csr[e];
    float x = rs[sn];
    uint4 v = Y8[(size_t)sn*16 + lane];
    a0 = fmaf(x, blo(v.x), a0); a1 = fmaf(x, bhi(v.x), a1);
    a2 = fmaf(x, blo(v.y), a2); a3 = fmaf(x, bhi(v.y), a3);
    a4 = fmaf(x, blo(v.z), a4); a5 = fmaf(x, bhi(v.z), a5);
    a6 = fmaf(x, blo(v.w), a6); a7 = fmaf(x, bhi(v.w), a7);
  }
  float sc = rsqrtf(fmaxf((float)(en - st), 1.f));
  const float4* b4 = (const float4*)bias;
  float4 ba = b4[lane*2], bb = b4[lane*2+1];
  float o0=fmaf(a0,sc,ba.x), o1=fmaf(a1,sc,ba.y), o2=fmaf(a2,sc,ba.z), o3=fmaf(a3,sc,ba.w);
  float o4v=fmaf(a4,sc,bb.x), o5=fmaf(a5,sc,bb.y), o6=fmaf(a6,sc,bb.z), o7=fmaf(a7,sc,bb.w);
  if (OB16){
    uint4 o; o.x = pk2(o0,o1); o.y = pk2(o2,o3); o.z = pk2(o4v,o5); o.w = pk2(o6,o7);
    ((uint4*)out)[(size_t)row*16 + lane] = o;
  } else {
    float4* o4 = (float4*)out;
    o4[(size_t)row*32 + lane*2]     = make_float4(o0,o1,o2,o3);
    o4[(size_t)row*32 + lane*2 + 1] = make_float4(o4v,o5,o6,o7);
  }
}

template<int GB16, int DB16>
__device__ __forceinline__ void dev_head(int bid, const void* __restrict__ g, const void* __restrict__ dch,
    const float* __restrict__ W, const float* __restrict__ b,
    float* __restrict__ out, int n, int rowOff)
{
  int wid = threadIdx.x >> 6, lane = threadIdx.x & 63;
  int row = bid*4 + wid;
  if (row >= n) return;
  float x0, x1, x2, x3;
  if (GB16){ const u16* gr = (const u16*)g + (size_t)row*FD; x0 = bf2f(gr[lane]); x1 = bf2f(gr[64+lane]); }
  else     { const float* gr = (const float*)g + (size_t)row*FD; x0 = gr[lane]; x1 = gr[64+lane]; }
  if (DB16){ const u16* dr = (const u16*)dch + (size_t)row*FD; x2 = bf2f(dr[lane]); x3 = bf2f(dr[64+lane]); }
  else     { const float* dr = (const float*)dch + (size_t)row*FD; x2 = dr[lane]; x3 = dr[64+lane]; }
  float acc[5];
  #pragma unroll
  for (int o = 0; o < 5; ++o)
    acc[o] = x0*W[lane*5+o] + x1*W[(64+lane)*5+o] + x2*W[(128+lane)*5+o] + x3*W[(192+lane)*5+o];
  #pragma unroll
  for (int o = 0; o < 5; ++o)
    #pragma unroll
    for (int s = 32; s; s >>= 1) acc[o] += __shfl_xor(acc[o], s);
  if (lane == 0){
    float m = -1e30f;
    #pragma unroll
    for (int o = 0; o < 5; ++o){ acc[o] += b[o]; m = fmaxf(m, acc[o]); }
    float sum = 0.f;
    #pragma unroll
    for (int o = 0; o < 5; ++o){ acc[o] = expf(acc[o]-m); sum += acc[o]; }
    float is = 1.0f/sum;
    float* op = out + (size_t)(rowOff+row)*5;
    #pragma unroll
    for (int o = 0; o < 5; ++o) op[o] = acc[o]*is;
  }
}

// ================= kernels =================

// K1: kvec (4 blocks) || W->bf16 col-major transpose (4 blocks) || zero bktCnt
__global__ __launch_bounds__(256) void k1_prep(int* __restrict__ zeroBlk, int ntot,
    const float* __restrict__ ekW, const float* __restrict__ ekb, const float* __restrict__ eqb,
    const float* __restrict__ dkW, const float* __restrict__ dkb, const float* __restrict__ dqb,
    float* __restrict__ kv, float inv,
    const float* __restrict__ evW, const float* __restrict__ gW,
    u16* __restrict__ wvt0, u16* __restrict__ wgt0, u16* __restrict__ wvt1, u16* __restrict__ wgt1)
{
  int bid = blockIdx.x;
  if (bid < 4){
    if (threadIdx.x < 128){
      int j = bid;
      const float* kW = (j < 2) ? ekW + j*16384 : dkW + (j-2)*16384;
      const float* kb = (j < 2) ? ekb + j*128   : dkb + (j-2)*128;
      const float* qb = (j < 2) ? eqb + j*128   : dqb + (j-2)*128;
      float* o = kv + j*132;
      int k = threadIdx.x;
      float a = 0.f;
      for (int t = 0; t < 128; ++t) a = fmaf(kW[k*128+t], qb[t], a);
      o[k] = a * inv;
      if (k == 0){
        float c = 0.f;
        for (int t = 0; t < 128; ++t) c = fmaf(kb[t], qb[t], c);
        o[128] = c * inv;
      }
    }
  } else if (bid < 8){
    const float* Ws; u16* Wd;
    if (bid == 4){ Ws = evW;          Wd = wvt0; }
    else if (bid == 5){ Ws = gW;      Wd = wgt0; }
    else if (bid == 6){ Ws = evW+16384; Wd = wvt1; }
    else { Ws = gW+16384; Wd = wgt1; }
    for (int i = threadIdx.x; i < 16384; i += 256){
      int k = i >> 7, c = i & 127;
      Wd[c*128 + k] = f2bf(Ws[i]);
    }
  } else {
    int i = (bid-8)*256 + threadIdx.x;
    if (i < ntot) zeroBlk[i] = 0;
  }
}

// K2: P0 || h0 gemm (f32 A)
__global__ __launch_bounds__(256) void k2_p0_gemm(BMeta m, int* __restrict__ bktCnt,
    const float* __restrict__ X, const float* __restrict__ W, const float* __restrict__ b,
    u16* __restrict__ bh0, int np0)
{
  __shared__ float sm[5120];
  int bid = blockIdx.x;
  if (bid < np0) dev_p0(m, bid, bktCnt, (int*)sm);
  else dev_gemm<0,0>(sm, sm+4096, bid - np0, X, W, b, nullptr, nullptr, bh0, N0);
}

// K3: P1
__global__ __launch_bounds__(256) void k3_p1(BMeta m,
    const int* __restrict__ bktCnt, int* __restrict__ bktBase, int* __restrict__ bktCur)
{
  __shared__ int sh[384];
  dev_p1(m, bktCnt, bktBase, bktCur, sh);
}

// K4: P2 || MFMA dual(h0) part 1
__global__ __launch_bounds__(256) void k4_p2_dual(BMeta m, int* __restrict__ bktCur,
    u32* __restrict__ ebuf, u16* __restrict__ ebuf16,
    const u16* __restrict__ bh0,
    const u16* __restrict__ wvt0, const u16* __restrict__ wgt0, const float* __restrict__ evb,
    const float* __restrict__ kvec, float* __restrict__ sS, u16* __restrict__ bV, u16* __restrict__ bY0,
    int np2, int gOff)
{
  __shared__ int sh[1824];
  int bid = blockIdx.x;
  if (bid < np2) dev_p2(m, bid, bktCur, ebuf, ebuf16, sh);
  else dev_dual_mfma(gOff + bid - np2, bh0, wvt0, wgt0, evb, kvec, sS, bV, bY0, N0);
}

// K5: P3 || MFMA dual(h0) part 2
__global__ __launch_bounds__(256) void k5_p3_dual(BMeta m,
    const int* __restrict__ bktCnt, const int* __restrict__ bktBase,
    const u32* __restrict__ ebuf, const u16* __restrict__ ebuf16,
    const u16* __restrict__ bh0,
    const u16* __restrict__ wvt0, const u16* __restrict__ wgt0, const float* __restrict__ evb,
    const float* __restrict__ kvec, float* __restrict__ sS, u16* __restrict__ bV, u16* __restrict__ bY0,
    int np3, int gOff)
{
  __shared__ int sh[1824];
  int bid = blockIdx.x;
  if (bid < np3) dev_p3(m, bid, bktCnt, bktBase, ebuf, ebuf16, sh);
  else dev_dual_mfma(gOff + bid - np3, bh0, wvt0, wgt0, evb, kvec, sS, bV, bY0, N0);
}

// K6: attn_gather16(i0)->be1 || g0 slice
__global__ __launch_bounds__(256) void k6_ag_i0(
    const int* __restrict__ csrA, const int* __restrict__ rowpA,
    const float* __restrict__ sS, const u16* __restrict__ bV, u16* __restrict__ be1,
    const int* __restrict__ csr0, const int* __restrict__ rowp0, const float* __restrict__ rs0,
    const u16* __restrict__ bY0, const float* __restrict__ gb, u16* __restrict__ bg0, int nMain, int sBase)
{
  int bid = blockIdx.x;
  if (bid < nMain) dev_attn_gather16<1>(bid, csrA, rowpA, sS, bV, be1, N1);
  else dev_gcn_gather16<1>(sBase + bid - nMain, csr0, rowp0, rs0, bY0, gb, bg0, N0);
}

// K7: MFMA dual(be1 -> V1+score, Y1) || g0 slice
__global__ __launch_bounds__(256) void k7_dual_enc1(
    const u16* __restrict__ be1,
    const u16* __restrict__ wvt1, const u16* __restrict__ wgt1, const float* __restrict__ vb,
    const float* __restrict__ kvec, float* __restrict__ sS, u16* __restrict__ bV, u16* __restrict__ bY1,
    const int* __restrict__ csr0, const int* __restrict__ rowp0, const float* __restrict__ rs0,
    const u16* __restrict__ bY0, const float* __restrict__ gb, u16* __restrict__ bg0, int nMain, int sBase)
{
  int bid = blockIdx.x;
  if (bid < nMain) dev_dual_mfma(bid, be1, wvt1, wgt1, vb, kvec, sS, bV, bY1, N1);
  else dev_gcn_gather16<1>(sBase + bid - nMain, csr0, rowp0, rs0, bY0, gb, bg0, N0);
}

// K8: attn_gather16(i1)->be2(f32) || g0 slice
__global__ __launch_bounds__(256) void k8_ag_i1(
    const int* __restrict__ csrA, const int* __restrict__ rowpA,
    const float* __restrict__ sS, const u16* __restrict__ bV, float* __restrict__ be2,
    const int* __restrict__ csr0, const int* __restrict__ rowp0, const float* __restrict__ rs0,
    const u16* __restrict__ bY0, const float* __restrict__ gb, u16* __restrict__ bg0, int nMain, int sBase)
{
  int bid = blockIdx.x;
  if (bid < nMain) dev_attn_gather16<0>(bid, csrA, rowpA, sS, bV, be2, N2);
  else dev_gcn_gather16<1>(sBase + bid - nMain, csr0, rowp0, rs0, bY0, gb, bg0, N0);
}

// K9: gcn2-Y gemm (f32 A) || gcn_gather16(g1)->bg1 || g0 slice
__global__ __launch_bounds__(256) void k9_y2_g1(
    const float* __restrict__ be2, const float* __restrict__ W2, u16* __restrict__ bY2,
    const int* __restrict__ csr1, const int* __restrict__ rowp1, const float* __restrict__ rs1,
    const u16* __restrict__ bY1, const float* __restrict__ b1, u16* __restrict__ bg1,
    const int* __restrict__ csr0, const int* __restrict__ rowp0, const float* __restrict__ rs0,
    const u16* __restrict__ bY0, const float* __restrict__ gb, u16* __restrict__ bg0,
    int ngemm, int nMain, int sBase)
{
  __shared__ float sm[5120];
  int bid = blockIdx.x;
  if (bid < ngemm) dev_gemm<0,0>(sm, sm+4096, bid, be2, W2, nullptr, nullptr, nullptr, bY2, N2);
  else if (bid < nMain) dev_gcn_gather16<1>(bid - ngemm, csr1, rowp1, rs1, bY1, b1, bg1, N1);
  else dev_gcn_gather16<1>(sBase + bid - nMain, csr0, rowp0, rs0, bY0, gb, bg0, N0);
}

// K10: gcn_gather16(g2)->bg2(f32) || g0 slice
__global__ __launch_bounds__(256) void k10_g2(
    const int* __restrict__ csr2, const int* __restrict__ rowp2, const float* __restrict__ rs2,
    const u16* __restrict__ bY2, const float* __restrict__ b2, float* __restrict__ bg2,
    const int* __restrict__ csr0, const int* __restrict__ rowp0, const float* __restrict__ rs0,
    const u16* __restrict__ bY0, const float* __restrict__ gb, u16* __restrict__ bg0, int nMain, int sBase)
{
  int bid = blockIdx.x;
  if (bid < nMain) dev_gcn_gather16<0>(bid, csr2, rowp2, rs2, bY2, b2, bg2, N2);
  else dev_gcn_gather16<1>(sBase + bid - nMain, csr0, rowp0, rs0, bY0, gb, bg0, N0);
}

// K11: dec0 gemm (f32 A) || head2 || g0 slice
__global__ __launch_bounds__(256) void k11_dec0_head2(
    const float* __restrict__ bg2, const float* __restrict__ vW, const float* __restrict__ vb,
    const float* __restrict__ kvec, float* __restrict__ sS, u16* __restrict__ bV,
    const float* __restrict__ hW, const float* __restrict__ hb, float* __restrict__ out,
    const int* __restrict__ csr0, const int* __restrict__ rowp0, const float* __restrict__ rs0,
    const u16* __restrict__ bY0, const float* __restrict__ gb, u16* __restrict__ bg0,
    int ngemm, int nMain, int sBase)
{
  __shared__ float sm[5120];
  int bid = blockIdx.x;
  if (bid < ngemm) dev_gemm<1,0>(sm, sm+4096, bid, bg2, vW, vb, kvec, sS, bV, N2);
  else if (bid < nMain) dev_head<0,0>(bid - ngemm, bg2, bg2, hW, hb, out, N2, N0+N1);
  else dev_gcn_gather16<1>(sBase + bid - nMain, csr0, rowp0, rs0, bY0, gb, bg0, N0);
}

// K12: attn_gather16(dc0)->be1 (d1) || g0 slice
__global__ __launch_bounds__(256) void k12_ag_d1(
    const int* __restrict__ csrA, const int* __restrict__ rowpA,
    const float* __restrict__ sS, const u16* __restrict__ bV, u16* __restrict__ be1,
    const int* __restrict__ csr0, const int* __restrict__ rowp0, const float* __restrict__ rs0,
    const u16* __restrict__ bY0, const float* __restrict__ gb, u16* __restrict__ bg0, int nMain, int sBase)
{
  int bid = blockIdx.x;
  if (bid < nMain) dev_attn_gather16<1>(bid, csrA, rowpA, sS, bV, be1, N1);
  else dev_gcn_gather16<1>(sBase + bid - nMain, csr0, rowp0, rs0, bY0, gb, bg0, N0);
}

// K13: dec1 gemm (bf16 A) || head1 || g0 slice
__global__ __launch_bounds__(256) void k13_dec1_head1(
    const u16* __restrict__ be1, const float* __restrict__ vW, const float* __restrict__ vb,
    const float* __restrict__ kvec, float* __restrict__ sS, u16* __restrict__ bV,
    const u16* __restrict__ bg1, const float* __restrict__ hW, const float* __restrict__ hb,
    float* __restrict__ out,
    const int* __restrict__ csr0, const int* __restrict__ rowp0, const float* __restrict__ rs0,
    const u16* __restrict__ bY0, const float* __restrict__ gb, u16* __restrict__ bg0,
    int ngemm, int nMain, int sBase)
{
  __shared__ float sm[5120];
  int bid = blockIdx.x;
  if (bid < ngemm) dev_gemm<1,1>(sm, sm+4096, bid, be1, vW, vb, kvec, sS, bV, N1);
  else if (bid < nMain) dev_head<1,1>(bid - ngemm, bg1, be1, hW, hb, out, N1, N0);
  else dev_gcn_gather16<1>(sBase + bid - nMain, csr0, rowp0, rs0, bY0, gb, bg0, N0);
}

// K14: fused d0 gather + head0 (16-lane)
__global__ __launch_bounds__(256) void k14_gather_head0(
    const int* __restrict__ csr, const int* __restrict__ rowp,
    const float* __restrict__ w, const u16* __restrict__ V,
    const u16* __restrict__ bg0,
    const float* __restrict__ hW, const float* __restrict__ hb,
    float* __restrict__ out)
{
  int g = threadIdx.x >> 4, lane = threadIdx.x & 15;
  int row = blockIdx.x*16 + g;
  if (row >= N0) return;
  int st = rowp[row], en = rowp[row+1];
  float a0=0,a1=0,a2=0,a3=0,a4=0,a5=0,a6=0,a7=0;
  if (en > st){
    const uint4* V8 = (const uint4*)V;
    float den = 0.f;
    for (int e = st; e < en; ++e){
      int sn = csr[e];
      float x = w[sn];
      uint4 v = V8[(size_t)sn*16 + lane];
      den += x;
      a0 = fmaf(x, blo(v.x), a0); a1 = fmaf(x, bhi(v.x), a1);
      a2 = fmaf(x, blo(v.y), a2); a3 = fmaf(x, bhi(v.y), a3);
      a4 = fmaf(x, blo(v.z), a4); a5 = fmaf(x, bhi(v.z), a5);
      a6 = fmaf(x, blo(v.w), a6); a7 = fmaf(x, bhi(v.w), a7);
    }
    float inv = 1.f/den;
    a0*=inv; a1*=inv; a2*=inv; a3*=inv; a4*=inv; a5*=inv; a6*=inv; a7*=inv;
  }
  uint4 gv = ((const uint4*)(bg0 + (size_t)row*FD))[lane];
  float g0 = blo(gv.x), g1 = bhi(gv.x), g2 = blo(gv.y), g3 = bhi(gv.y);
  float g4 = blo(gv.z), g5 = bhi(gv.z), g6 = blo(gv.w), g7 = bhi(gv.w);
  int j = 8*lane;
  float acc[5];
  #pragma unroll
  for (int o = 0; o < 5; ++o){
    acc[o] = g0*hW[(j+0)*5+o] + g1*hW[(j+1)*5+o] + g2*hW[(j+2)*5+o] + g3*hW[(j+3)*5+o]
           + g4*hW[(j+4)*5+o] + g5*hW[(j+5)*5+o] + g6*hW[(j+6)*5+o] + g7*hW[(j+7)*5+o]
           + a0*hW[(128+j+0)*5+o] + a1*hW[(128+j+1)*5+o] + a2*hW[(128+j+2)*5+o] + a3*hW[(128+j+3)*5+o]
           + a4*hW[(128+j+4)*5+o] + a5*hW[(128+j+5)*5+o] + a6*hW[(128+j+6)*5+o] + a7*hW[(128+j+7)*5+o];
  }
  #pragma unroll
  for (int o = 0; o < 5; ++o)
    #pragma unroll
    for (int s = 8; s; s >>= 1) acc[o] += __shfl_xor(acc[o], s, 16);
  if (lane == 0){
    float m = -1e30f;
    #pragma unroll
    for (int o = 0; o < 5; ++o){ acc[o] += hb[o]; m = fmaxf(m, acc[o]); }
    float sum = 0.f;
    #pragma unroll
    for (int o = 0; o < 5; ++o){ acc[o] = expf(acc[o]-m); sum += acc[o]; }
    float is = 1.0f/sum;
    float* op = out + (size_t)row*5;
    #pragma unroll
    for (int o = 0; o < 5; ++o) op[o] = acc[o]*is;
  }
}

// ================= host =================
extern "C" void kernel_launch(void* const* d_in, const int* in_sizes, int n_in,
                              void* d_out, int out_size, void* d_ws, size_t ws_size,
                              hipStream_t stream)
{
  const float* X      = (const float*)d_in[0];
  const float* emb_W  = (const float*)d_in[1];
  const float* emb_b  = (const float*)d_in[2];
  const float* gcn_W  = (const float*)d_in[3];
  const float* gcn_b  = (const float*)d_in[4];
  const float* enc_qb = (const float*)d_in[6];
  const float* enc_kW = (const float*)d_in[7];
  const float* enc_kb = (const float*)d_in[8];
  const float* enc_vW = (const float*)d_in[9];
  const float* enc_vb = (const float*)d_in[10];
  const float* dec_qb = (const float*)d_in[12];
  const float* dec_kW = (const float*)d_in[13];
  const float* dec_kb = (const float*)d_in[14];
  const float* dec_vW = (const float*)d_in[15];
  const float* dec_vb = (const float*)d_in[16];
  const float* head_W = (const float*)d_in[17];
  const float* head_b = (const float*)d_in[18];
  const int* g0s  = (const int*)d_in[19];
  const int* g0d  = (const int*)d_in[20];
  const int* g1s  = (const int*)d_in[21];
  const int* g1d  = (const int*)d_in[22];
  const int* g2s  = (const int*)d_in[23];
  const int* g2d  = (const int*)d_in[24];
  const int* i0s  = (const int*)d_in[25];
  const int* i0d  = (const int*)d_in[26];
  const int* i1s  = (const int*)d_in[27];
  const int* i1d  = (const int*)d_in[28];
  const int* dc0s = (const int*)d_in[29];
  const int* dc0d = (const int*)d_in[30];
  const int* dc1s = (const int*)d_in[31];
  const int* dc1d = (const int*)d_in[32];

  // ---- workspace layout ----
  float* ws = (float*)d_ws;
  float* sS  = ws;                          // N0
  float* kvec = sS + N0;                    // 4*132
  float* be2 = kvec + 4*132;                // N2*FD f32
  float* bg2 = be2 + (size_t)N2*FD;         // N2*FD f32
  float* rs0 = bg2 + (size_t)N2*FD;         // N0
  float* rs1 = rs0 + N0;                    // N1
  float* rs2 = rs1 + N1;                    // N2 (+2 pad -> 16B-aligned u16 region)
  u16*  bh0 = (u16*)(rs2 + N2 + 2);         // N0*FD u16
  u16*  be1 = bh0 + (size_t)N0*FD;          // N1*FD u16
  u16*  bg0 = be1 + (size_t)N1*FD;          // N0*FD u16
  u16*  bg1 = bg0 + (size_t)N0*FD;          // N1*FD u16
  u16*  bV  = bg1 + (size_t)N1*FD;          // N0*FD u16 (V tables, time-shared)
  u16*  bY0 = bV  + (size_t)N0*FD;          // N0*FD u16
  u16*  bY1 = bV + 4000000;                 // alias into bV tail
  u16*  bY2 = bV + 8000000;
  int*  bktCnt  = (int*)(bY0 + (size_t)N0*FD);  // 328
  int*  bktBase = bktCnt + 328;                 // 328
  int*  bktCur  = bktBase + 328;                // 328
  int*  rowpBlk = bktCur + 328;                 // 287507
  int*  csrBlk  = rowpBlk + 287507;             // 2,500,000
  u32*  ebuf    = (u32*)(csrBlk + 2500000);     // 2.5M u32
  u16*  ebuf16  = (u16*)(ebuf + 2500000);       // 1.5M u16
  uintptr_t wtp = ((uintptr_t)(ebuf16 + 1500000) + 15) & ~(uintptr_t)15;
  u16* wvt0 = (u16*)wtp;                        // 16384 each (col-major bf16 W)
  u16* wgt0 = wvt0 + 16384;
  u16* wvt1 = wgt0 + 16384;
  u16* wgt1 = wvt1 + 16384;

  const int* keyP[10] = {g0d,g1d,g2d,i0d,i1d,dc0d,dc1d, g0s,g1s,g2s};
  const int* srcP[7]  = {g0s,g1s,g2s,i0s,i1s,dc0s,dc1s};
  const int nArr[10] = {N0,N1,N2,N1,N2,N1,N0, N0,N1,N2};
  const int EArr[10] = {1000000,400000,100000,400000,100000,100000,400000, 1000000,400000,100000};
  const int BArr[10] = {64,32,8,32,8,16,64, 64,32,8};
  const int rArr[10] = {1563,782,782,782,782,1563,1563, 1563,782,782};

  BMeta m;
  {
    int eo=0, so=0, bo=0, po=0, ro=0, co=0;
    for (int j=0;j<10;++j){
      m.key[j]=keyP[j];
      m.n[j]=nArr[j]; m.E[j]=EArr[j]; m.B[j]=BArr[j]; m.r[j]=rArr[j];
      m.boff[j]=bo; m.pblk[j]=po;
      bo+=BArr[j]; po+=ceildiv(EArr[j],4096);
      if (j < 7){
        m.src[j]=srcP[j]; m.rowp[j]=rowpBlk+ro; m.csr[j]=csrBlk+co;
        m.eoff[j]=eo; eo+=EArr[j]; ro+=nArr[j]+1; co+=EArr[j];
      } else {
        m.soff[j-7]=so; so+=EArr[j];
      }
    }
    m.eoff[7]=eo; m.soff[3]=so; m.boff[10]=bo; m.pblk[10]=po;
  }
  m.rsout[0]=rs0; m.rsout[1]=rs1; m.rsout[2]=rs2;

  const float invScale = 0.17677669529663687f;
  float* out = (float*)d_out;

  const int NP = m.pblk[10];                // 982
  const int NB = m.boff[10];                // 328
  const int GH0 = ceildiv(N0,32);           // 3125
  const int GH1 = ceildiv(N1,32);           // 782
  const int GH2 = ceildiv(N2,32);           // 196
  const int GS1 = 1563;                     // dual(h0) share in K4
  const int GA1_16 = ceildiv(N1,16);        // 1563
  const int GA2_16 = ceildiv(N2,16);        // 391
  const int G0B16  = ceildiv(N0,16);        // 6250
  const int GH2H = ceildiv(N2,4);           // 1563
  const int GH1H = ceildiv(N1,4);           // 6250

  int ss[9];
  for (int i = 0; i <= 8; ++i) ss[i] = (int)(((long long)G0B16 * i) / 8);

  // K1: kvec || W transposes || zero bktCnt
  k1_prep<<<8 + ceildiv(NB,256), 256, 0, stream>>>(bktCnt, NB,
      enc_kW, enc_kb, enc_qb, dec_kW, dec_kb, dec_qb, kvec, invScale,
      enc_vW, gcn_W, wvt0, wgt0, wvt1, wgt1);
  // K2: P0 || h0 gemm
  k2_p0_gemm<<<NP + GH0, 256, 0, stream>>>(m, bktCnt, X, emb_W, emb_b, bh0, NP);
  // K3: P1
  k3_p1<<<1, 256, 0, stream>>>(m, bktCnt, bktBase, bktCur);
  // K4: P2 || MFMA dual(h0) part 1
  k4_p2_dual<<<NP + GS1, 256, 0, stream>>>(m, bktCur, ebuf, ebuf16,
      bh0, wvt0, wgt0, enc_vb, kvec, sS, bV, bY0, NP, 0);
  // K5: P3 || MFMA dual(h0) part 2
  k5_p3_dual<<<NB + (GH0 - GS1), 256, 0, stream>>>(m, bktCnt, bktBase, ebuf, ebuf16,
      bh0, wvt0, wgt0, enc_vb, kvec, sS, bV, bY0, NB, GS1);
  // K6: attn_gather(i0)->be1 || g0[0]
  k6_ag_i0<<<GA1_16 + (ss[1]-ss[0]), 256, 0, stream>>>(m.csr[3], m.rowp[3], sS, bV, be1,
      m.csr[0], m.rowp[0], rs0, bY0, gcn_b, bg0, GA1_16, ss[0]);
  // K7: MFMA dual(be1 -> V1, Y1) || g0[1]
  k7_dual_enc1<<<GH1 + (ss[2]-ss[1]), 256, 0, stream>>>(be1,
      wvt1, wgt1, enc_vb+128, kvec+132, sS, bV, bY1,
      m.csr[0], m.rowp[0], rs0, bY0, gcn_b, bg0, GH1, ss[1]);
  // K8: attn_gather(i1)->be2 || g0[2]
  k8_ag_i1<<<GA2_16 + (ss[3]-ss[2]), 256, 0, stream>>>(m.csr[4], m.rowp[4], sS, bV, be2,
      m.csr[0], m.rowp[0], rs0, bY0, gcn_b, bg0, GA2_16, ss[2]);
  // K9: gcn2-Y || gather(g1)->bg1 || g0[3]
  k9_y2_g1<<<GH2 + GA1_16 + (ss[4]-ss[3]), 256, 0, stream>>>(be2, gcn_W+32768, bY2,
      m.csr[1], m.rowp[1], rs1, bY1, gcn_b+128, bg1,
      m.csr[0], m.rowp[0], rs0, bY0, gcn_b, bg0, GH2, GH2+GA1_16, ss[3]);
  // K10: gather(g2)->bg2 || g0[4]
  k10_g2<<<GA2_16 + (ss[5]-ss[4]), 256, 0, stream>>>(m.csr[2], m.rowp[2], rs2, bY2, gcn_b+256, bg2,
      m.csr[0], m.rowp[0], rs0, bY0, gcn_b, bg0, GA2_16, ss[4]);
  // K11: dec0 gemm || head2 || g0[5]
  k11_dec0_head2<<<GH2 + GH2H + (ss[6]-ss[5]), 256, 0, stream>>>(bg2, dec_vW, dec_vb, kvec+264, sS, bV,
      head_W+2560, head_b+10, out,
      m.csr[0], m.rowp[0], rs0, bY0, gcn_b, bg0, GH2, GH2+GH2H, ss[5]);
  // K12: attn_gather(dc0)->be1 (d1) || g0[6]
  k12_ag_d1<<<GA1_16 + (ss[7]-ss[6]), 256, 0, stream>>>(m.csr[5], m.rowp[5], sS, bV, be1,
      m.csr[0], m.rowp[0], rs0, bY0, gcn_b, bg0, GA1_16, ss[6]);
  // K13: dec1 gemm || head1 || g0[7]
  k13_dec1_head1<<<GH1 + GH1H + (ss[8]-ss[7]), 256, 0, stream>>>(be1, dec_vW+16384, dec_vb+128, kvec+396, sS, bV,
      bg1, head_W+1280, head_b+5, out,
      m.csr[0], m.rowp[0], rs0, bY0, gcn_b, bg0, GH1, GH1+GH1H, ss[7]);
  // K14: fused d0 gather + head0
  k14_gather_head0<<<G0B16, 256, 0, stream>>>(m.csr[6], m.rowp[6], sS, bV, bg0,
      head_W, head_b, out);
}

// Round 12
// 447.305 us; speedup vs baseline: 11.1352x; 1.0012x over previous
//
#include <hip/hip_runtime.h>
#include <math.h>
#include <stdint.h>

#define N0 100000
#define N1 25000
#define N2 6250
#define FD 128

typedef unsigned short u16;
typedef unsigned int u32;
typedef short bf16x8 __attribute__((ext_vector_type(8)));
typedef float f32x4 __attribute__((ext_vector_type(4)));

static inline int ceildiv(int a, int b){ return (a + b - 1)/b; }

__device__ __forceinline__ u16 f2bf(float f){
  u32 u = __float_as_uint(f);
  u += 0x7fffu + ((u >> 16) & 1u);
  return (u16)(u >> 16);
}
__device__ __forceinline__ float bf2f(u16 h){
  return __uint_as_float(((u32)h) << 16);
}
__device__ __forceinline__ float blo(u32 u){ return __uint_as_float(u << 16); }
__device__ __forceinline__ float bhi(u32 u){ return __uint_as_float(u & 0xffff0000u); }
__device__ __forceinline__ u32 pk2(float a, float b){ return (u32)f2bf(a) | ((u32)f2bf(b) << 16); }

// ================= bucket metadata: 10 jobs =================
struct BMeta {
  const int* key[10];
  const int* src[7];
  int* rowp[7]; int* csr[7];
  float* rsout[3];
  int n[10], E[10], B[10], r[10];
  int eoff[8];
  int soff[4];
  int boff[11];
  int pblk[11];
};

// ================= FMA GEMM (small cases: k9/k11) =================
__device__ __forceinline__ void mm_inner(const float* Al, const float* Wl, int r0, int c0, float acc[4][4]){
  #pragma unroll
  for (int kq = 0; kq < 8; ++kq) {
    int k0 = kq*4;
    float4 a[4], w[4];
    #pragma unroll
    for (int i=0;i<4;++i) a[i] = *(const float4*)&Al[(r0+i)*32 + k0];
    #pragma unroll
    for (int kk=0;kk<4;++kk) w[kk] = *(const float4*)&Wl[(k0+kk)*128 + c0];
    #pragma unroll
    for (int i=0;i<4;++i){
      acc[i][0] = fmaf(a[i].x,w[0].x, fmaf(a[i].y,w[1].x, fmaf(a[i].z,w[2].x, fmaf(a[i].w,w[3].x, acc[i][0]))));
      acc[i][1] = fmaf(a[i].x,w[0].y, fmaf(a[i].y,w[1].y, fmaf(a[i].z,w[2].y, fmaf(a[i].w,w[3].y, acc[i][1]))));
      acc[i][2] = fmaf(a[i].x,w[0].z, fmaf(a[i].y,w[1].z, fmaf(a[i].z,w[2].z, fmaf(a[i].w,w[3].z, acc[i][2]))));
      acc[i][3] = fmaf(a[i].x,w[0].w, fmaf(a[i].y,w[1].w, fmaf(a[i].z,w[2].w, fmaf(a[i].w,w[3].w, acc[i][3]))));
    }
  }
}

template<int SCORE, int AB16>
__device__ __forceinline__ void dev_gemm(float* Wl, float* Al, int bid,
    const void* __restrict__ Ap,
    const float* __restrict__ W, const float* __restrict__ bias,
    const float* __restrict__ kvec, float* __restrict__ sOut,
    u16* __restrict__ out, int n)
{
  const int tid = threadIdx.x;
  const int row0 = bid * 32;
  const int c0 = (tid & 31) * 4, r0 = (tid >> 5) * 4;
  const int r = tid >> 3, fc = tid & 7;
  const int gr_s = row0 + r;
  float acc[4][4] = {};
  float sacc = 0.f;
  const float4* W4 = (const float4*)W;
  for (int kp = 0; kp < 4; ++kp) {
    float4* Wl4 = (float4*)Wl;
    #pragma unroll
    for (int i = 0; i < 4; ++i) Wl4[tid + 256*i] = W4[kp*1024 + tid + 256*i];
    {
      float4 v = make_float4(0.f,0.f,0.f,0.f);
      if (gr_s < n){
        if (AB16){
          ushort4 h = ((const ushort4*)Ap)[(size_t)gr_s*32 + kp*8 + fc];
          v = make_float4(bf2f(h.x), bf2f(h.y), bf2f(h.z), bf2f(h.w));
        } else {
          v = ((const float4*)Ap)[(size_t)gr_s*32 + kp*8 + fc];
        }
      }
      ((float4*)Al)[tid] = v;
      if (SCORE){
        float4 kv = *(const float4*)&kvec[kp*32 + fc*4];
        sacc += v.x*kv.x + v.y*kv.y + v.z*kv.z + v.w*kv.w;
      }
    }
    __syncthreads();
    mm_inner(Al, Wl, r0, c0, acc);
    __syncthreads();
  }
  if (SCORE){
    sacc += __shfl_xor(sacc, 1);
    sacc += __shfl_xor(sacc, 2);
    sacc += __shfl_xor(sacc, 4);
    if (fc == 0 && gr_s < n) sOut[gr_s] = expf(sacc + kvec[128]);
  }
  float4 bv = make_float4(0.f,0.f,0.f,0.f);
  if (bias) bv = *(const float4*)&bias[c0];
  #pragma unroll
  for (int i=0;i<4;++i){
    int gr = row0 + r0 + i;
    if (gr < n){
      ushort4 o;
      o.x = f2bf(acc[i][0]+bv.x); o.y = f2bf(acc[i][1]+bv.y);
      o.z = f2bf(acc[i][2]+bv.z); o.w = f2bf(acc[i][3]+bv.w);
      *(ushort4*)&out[(size_t)gr*FD + c0] = o;
    }
  }
}

// ================= MFMA GEMMs (LDS-free) =================
// Geometry: block = 32 rows x 128 cols; 4 waves: rt=wid&1 row-tile, cbase=(wid>>1)*64.
// Fragments 16x16x32: A lane l holds A[l&15][lg*8+j]; B[lg*8+j][l&15]; C/D col=l&15,row=lg*4+reg.

// dual: V = A@Wv + vb (+score), Y = A@Wg. A bf16.
__device__ __forceinline__ void dev_dual_mfma(int bid,
    const u16* __restrict__ A, const u16* __restrict__ WvT, const u16* __restrict__ WgT,
    const float* __restrict__ vb, const float* __restrict__ kvec, float* __restrict__ sOut,
    u16* __restrict__ Vout, u16* __restrict__ Yout, int n)
{
  const int tid = threadIdx.x;
  const int wid = tid >> 6, lane = tid & 63;
  const int l15 = lane & 15, lg = lane >> 4;
  const int rt = wid & 1;
  const int cbase = (wid >> 1) * 64;
  const int row0 = bid * 32;
  const int arow = row0 + rt*16 + l15;
  const int arowc = min(arow, n-1);
  f32x4 accV[4] = {{0.f,0.f,0.f,0.f},{0.f,0.f,0.f,0.f},{0.f,0.f,0.f,0.f},{0.f,0.f,0.f,0.f}};
  f32x4 accY[4] = {{0.f,0.f,0.f,0.f},{0.f,0.f,0.f,0.f},{0.f,0.f,0.f,0.f},{0.f,0.f,0.f,0.f}};
  float sacc = 0.f;
  #pragma unroll
  for (int ks = 0; ks < 4; ++ks){
    const int ko = ks*32 + lg*8;
    bf16x8 a = *(const bf16x8*)(A + (size_t)arowc*FD + ko);
    if (wid < 2){
      float4 k0 = *(const float4*)(kvec + ko);
      float4 k1 = *(const float4*)(kvec + ko + 4);
      sacc += bf2f((u16)a[0])*k0.x + bf2f((u16)a[1])*k0.y + bf2f((u16)a[2])*k0.z + bf2f((u16)a[3])*k0.w
            + bf2f((u16)a[4])*k1.x + bf2f((u16)a[5])*k1.y + bf2f((u16)a[6])*k1.z + bf2f((u16)a[7])*k1.w;
    }
    #pragma unroll
    for (int ct = 0; ct < 4; ++ct){
      const int col = cbase + ct*16 + l15;
      bf16x8 bv = *(const bf16x8*)(WvT + (size_t)col*FD + ko);
      bf16x8 bg = *(const bf16x8*)(WgT + (size_t)col*FD + ko);
      accV[ct] = __builtin_amdgcn_mfma_f32_16x16x32_bf16(a, bv, accV[ct], 0, 0, 0);
      accY[ct] = __builtin_amdgcn_mfma_f32_16x16x32_bf16(a, bg, accY[ct], 0, 0, 0);
    }
  }
  if (wid < 2){
    sacc += __shfl_xor(sacc, 16);
    sacc += __shfl_xor(sacc, 32);
    if (lane < 16 && arow < n) sOut[arow] = expf(sacc + kvec[128]);
  }
  #pragma unroll
  for (int ct = 0; ct < 4; ++ct){
    const int col = cbase + ct*16 + l15;
    const float bvv = vb[col];
    #pragma unroll
    for (int i = 0; i < 4; ++i){
      int gr = row0 + rt*16 + lg*4 + i;
      if (gr < n){
        Vout[(size_t)gr*FD + col] = f2bf(accV[ct][i] + bvv);
        Yout[(size_t)gr*FD + col] = f2bf(accY[ct][i]);
      }
    }
  }
}

// single: out = A@W + bias (+score). AF32: A is f32 (packed to bf16 in-register).
template<int AF32, int SCORE>
__device__ __forceinline__ void dev_single_mfma(int bid,
    const void* __restrict__ Ap, const u16* __restrict__ WT,
    const float* __restrict__ bias,
    const float* __restrict__ kvec, float* __restrict__ sOut,
    u16* __restrict__ out, int n)
{
  const int tid = threadIdx.x;
  const int wid = tid >> 6, lane = tid & 63;
  const int l15 = lane & 15, lg = lane >> 4;
  const int rt = wid & 1;
  const int cbase = (wid >> 1) * 64;
  const int row0 = bid * 32;
  const int arow = row0 + rt*16 + l15;
  const int arowc = min(arow, n-1);
  f32x4 acc[4] = {{0.f,0.f,0.f,0.f},{0.f,0.f,0.f,0.f},{0.f,0.f,0.f,0.f},{0.f,0.f,0.f,0.f}};
  float sacc = 0.f;
  #pragma unroll
  for (int ks = 0; ks < 4; ++ks){
    const int ko = ks*32 + lg*8;
    bf16x8 a;
    if (AF32){
      const float* Af = (const float*)Ap + (size_t)arowc*FD + ko;
      float4 f0 = *(const float4*)Af;
      float4 f1 = *(const float4*)(Af + 4);
      a[0]=(short)f2bf(f0.x); a[1]=(short)f2bf(f0.y); a[2]=(short)f2bf(f0.z); a[3]=(short)f2bf(f0.w);
      a[4]=(short)f2bf(f1.x); a[5]=(short)f2bf(f1.y); a[6]=(short)f2bf(f1.z); a[7]=(short)f2bf(f1.w);
      if (SCORE && wid < 2){
        float4 k0 = *(const float4*)(kvec + ko);
        float4 k1 = *(const float4*)(kvec + ko + 4);
        sacc += f0.x*k0.x + f0.y*k0.y + f0.z*k0.z + f0.w*k0.w
              + f1.x*k1.x + f1.y*k1.y + f1.z*k1.z + f1.w*k1.w;
      }
    } else {
      a = *(const bf16x8*)((const u16*)Ap + (size_t)arowc*FD + ko);
      if (SCORE && wid < 2){
        float4 k0 = *(const float4*)(kvec + ko);
        float4 k1 = *(const float4*)(kvec + ko + 4);
        sacc += bf2f((u16)a[0])*k0.x + bf2f((u16)a[1])*k0.y + bf2f((u16)a[2])*k0.z + bf2f((u16)a[3])*k0.w
              + bf2f((u16)a[4])*k1.x + bf2f((u16)a[5])*k1.y + bf2f((u16)a[6])*k1.z + bf2f((u16)a[7])*k1.w;
      }
    }
    #pragma unroll
    for (int ct = 0; ct < 4; ++ct){
      const int col = cbase + ct*16 + l15;
      bf16x8 bv = *(const bf16x8*)(WT + (size_t)col*FD + ko);
      acc[ct] = __builtin_amdgcn_mfma_f32_16x16x32_bf16(a, bv, acc[ct], 0, 0, 0);
    }
  }
  if (SCORE && wid < 2){
    sacc += __shfl_xor(sacc, 16);
    sacc += __shfl_xor(sacc, 32);
    if (lane < 16 && arow < n) sOut[arow] = expf(sacc + kvec[128]);
  }
  #pragma unroll
  for (int ct = 0; ct < 4; ++ct){
    const int col = cbase + ct*16 + l15;
    const float bvv = bias[col];
    #pragma unroll
    for (int i = 0; i < 4; ++i){
      int gr = row0 + rt*16 + lg*4 + i;
      if (gr < n) out[(size_t)gr*FD + col] = f2bf(acc[ct][i] + bvv);
    }
  }
}

// ================= bucket passes =================
__device__ __forceinline__ int job_of_blk(const BMeta& m, int bid){
  int j = 0;
  #pragma unroll
  for (int t = 1; t < 10; ++t) if (bid >= m.pblk[t]) j = t;
  return j;
}

__device__ __forceinline__ void dev_p0(const BMeta& m, int bid, int* __restrict__ bktCnt, int* sh){
  int j = job_of_blk(m, bid);
  int lb = bid - m.pblk[j];
  const int* key = m.key[j]; int E = m.E[j], r = m.r[j], B = m.B[j];
  if (threadIdx.x < 64) sh[threadIdx.x] = 0;
  __syncthreads();
  int base = lb*4096 + threadIdx.x;
  #pragma unroll
  for (int i = 0; i < 16; ++i){ int e = base + i*256; if (e < E) atomicAdd(&sh[key[e]/r], 1); }
  __syncthreads();
  if ((int)threadIdx.x < B) atomicAdd(&bktCnt[m.boff[j] + threadIdx.x], sh[threadIdx.x]);
}

__device__ __forceinline__ void dev_p1(const BMeta& m, const int* __restrict__ bktCnt,
    int* __restrict__ bktBase, int* __restrict__ bktCur, int* sh){
  int tid = threadIdx.x;
  for (int i = tid; i < 328; i += 256) sh[i] = bktCnt[i];
  __syncthreads();
  if (tid < 10){
    int acc = (tid < 7) ? m.eoff[tid] : m.soff[tid-7];
    for (int b = m.boff[tid]; b < m.boff[tid+1]; ++b){ int v = sh[b]; sh[b] = acc; acc += v; }
  }
  __syncthreads();
  for (int i = tid; i < 328; i += 256){ bktBase[i] = sh[i]; bktCur[i] = sh[i]; }
}

__device__ __forceinline__ void dev_p2(const BMeta& m, int bid, int* __restrict__ bktCur,
    u32* __restrict__ ebuf, u16* __restrict__ ebuf16, int* sh){
  int j = job_of_blk(m, bid);
  int lb = bid - m.pblk[j];
  const int* key = m.key[j];
  int E = m.E[j], r = m.r[j], B = m.B[j];
  int* h = sh; int* start = sh + 64;
  if (threadIdx.x < 64) h[threadIdx.x] = 0;
  __syncthreads();
  int base = lb*4096 + threadIdx.x;
  #pragma unroll
  for (int i = 0; i < 16; ++i){ int e = base + i*256; if (e < E) atomicAdd(&h[key[e]/r], 1); }
  __syncthreads();
  if ((int)threadIdx.x < B) start[threadIdx.x] = atomicAdd(&bktCur[m.boff[j] + threadIdx.x], h[threadIdx.x]);
  __syncthreads();
  if (j < 7){
    const int* src = m.src[j];
    #pragma unroll
    for (int i = 0; i < 16; ++i){
      int e = base + i*256;
      if (e < E){
        int s = src[e], d = key[e];
        int b = d / r;
        int pos = atomicAdd(&start[b], 1);
        ebuf[pos] = ((u32)(d - b*r) << 17) | (u32)s;
      }
    }
  } else {
    #pragma unroll
    for (int i = 0; i < 16; ++i){
      int e = base + i*256;
      if (e < E){
        int k = key[e];
        int b = k / r;
        int pos = atomicAdd(&start[b], 1);
        ebuf16[pos] = (u16)(k - b*r);
      }
    }
  }
}

__device__ __forceinline__ void dev_p3(const BMeta& m, int bb,
    const int* __restrict__ bktCnt, const int* __restrict__ bktBase,
    const u32* __restrict__ ebuf, const u16* __restrict__ ebuf16, int* sh){
  int j = 0;
  #pragma unroll
  for (int t = 1; t < 10; ++t) if (bb >= m.boff[t]) j = t;
  int b = bb - m.boff[j];
  int n = m.n[j], r = m.r[j];
  int node0 = b*r;
  int rr = min(r, n - node0);
  int gbase = bktBase[bb];
  int cnt = bktCnt[bb];
  int tid = threadIdx.x;
  if (j >= 7){
    int* hist = sh;
    for (int i = tid; i < rr; i += 256) hist[i] = 0;
    __syncthreads();
    for (int e = tid; e < cnt; e += 256) atomicAdd(&hist[ebuf16[gbase + e]], 1);
    __syncthreads();
    float* rs = m.rsout[j-7];
    for (int i = tid; i < rr; i += 256) rs[node0 + i] = rsqrtf(fmaxf((float)hist[i], 1.f));
    return;
  }
  int B = m.B[j];
  int* rowp = m.rowp[j]; int* csr = m.csr[j];
  int lbase = gbase - m.eoff[j];
  int* hist = sh; int* aux = sh + 1568;
  for (int i = tid; i < rr; i += 256) hist[i] = 0;
  __syncthreads();
  for (int e = tid; e < cnt; e += 256){ u32 pk = ebuf[gbase + e]; atomicAdd(&hist[pk >> 17], 1); }
  __syncthreads();
  int ch = (rr + 255) >> 8;
  int i0 = tid*ch;
  int s = 0;
  for (int k = 0; k < ch; ++k){ int idx = i0 + k; if (idx < rr){ int t = hist[idx]; hist[idx] = s; s += t; } }
  aux[tid] = s; __syncthreads();
  for (int off = 1; off < 256; off <<= 1){
    int v = aux[tid]; int a = (tid >= off) ? aux[tid - off] : 0;
    __syncthreads();
    aux[tid] = v + a;
    __syncthreads();
  }
  int pre = (tid ? aux[tid-1] : 0) + lbase;
  for (int k = 0; k < ch; ++k){ int idx = i0 + k; if (idx < rr) hist[idx] += pre; }
  __syncthreads();
  for (int i = tid; i < rr; i += 256) rowp[node0 + i] = hist[i];
  if (b == B-1 && tid == 0) rowp[n] = lbase + cnt;
  __syncthreads();
  for (int e = tid; e < cnt; e += 256){
    u32 pk = ebuf[gbase + e];
    int pos = atomicAdd(&hist[pk >> 17], 1);
    csr[pos] = (int)(pk & 0x1FFFFu);
  }
}

// ================= 16-lane gathers =================
template<int OB16>
__device__ __forceinline__ void dev_attn_gather16(int bid,
    const int* __restrict__ csr, const int* __restrict__ rowp,
    const float* __restrict__ w, const u16* __restrict__ V,
    void* __restrict__ out, int n)
{
  int g = threadIdx.x >> 4, lane = threadIdx.x & 15;
  int row = bid*16 + g;
  if (row >= n) return;
  int st = rowp[row], en = rowp[row+1];
  float a0=0,a1=0,a2=0,a3=0,a4=0,a5=0,a6=0,a7=0;
  if (en > st){
    const uint4* V8 = (const uint4*)V;
    float den = 0.f;
    for (int e = st; e < en; ++e){
      int sn = csr[e];
      float x = w[sn];
      uint4 v = V8[(size_t)sn*16 + lane];
      den += x;
      a0 = fmaf(x, blo(v.x), a0); a1 = fmaf(x, bhi(v.x), a1);
      a2 = fmaf(x, blo(v.y), a2); a3 = fmaf(x, bhi(v.y), a3);
      a4 = fmaf(x, blo(v.z), a4); a5 = fmaf(x, bhi(v.z), a5);
      a6 = fmaf(x, blo(v.w), a6); a7 = fmaf(x, bhi(v.w), a7);
    }
    float inv = 1.f/den;
    a0*=inv; a1*=inv; a2*=inv; a3*=inv; a4*=inv; a5*=inv; a6*=inv; a7*=inv;
  }
  if (OB16){
    uint4 o; o.x = pk2(a0,a1); o.y = pk2(a2,a3); o.z = pk2(a4,a5); o.w = pk2(a6,a7);
    ((uint4*)out)[(size_t)row*16 + lane] = o;
  } else {
    float4* o4 = (float4*)out;
    o4[(size_t)row*32 + lane*2]     = make_float4(a0,a1,a2,a3);
    o4[(size_t)row*32 + lane*2 + 1] = make_float4(a4,a5,a6,a7);
  }
}

template<int OB16>
__device__ __forceinline__ void dev_gcn_gather16(int bid,
    const int* __restrict__ csr, const int* __restrict__ rowp,
    const float* __restrict__ rs, const u16* __restrict__ Y,
    const float* __restrict__ bias, void* __restrict__ out, int n)
{
  int g = threadIdx.x >> 4, lane = threadIdx.x & 15;
  int row = bid*16 + g;
  if (row >= n) return;
  int st = rowp[row], en = rowp[row+1];
  float a0=0,a1=0,a2=0,a3=0,a4=0,a5=0,a6=0,a7=0;
  const uint4* Y8 = (const uint4*)Y;
  for (int e = st; e < en; ++e){
    int sn = csr[e];
    float x = rs[sn];
    uint4 v = Y8[(size_t)sn*16 + lane];
    a0 = fmaf(x, blo(v.x), a0); a1 = fmaf(x, bhi(v.x), a1);
    a2 = fmaf(x, blo(v.y), a2); a3 = fmaf(x, bhi(v.y), a3);
    a4 = fmaf(x, blo(v.z), a4); a5 = fmaf(x, bhi(v.z), a5);
    a6 = fmaf(x, blo(v.w), a6); a7 = fmaf(x, bhi(v.w), a7);
  }
  float sc = rsqrtf(fmaxf((float)(en - st), 1.f));
  const float4* b4 = (const float4*)bias;
  float4 ba = b4[lane*2], bb = b4[lane*2+1];
  float o0=fmaf(a0,sc,ba.x), o1=fmaf(a1,sc,ba.y), o2=fmaf(a2,sc,ba.z), o3=fmaf(a3,sc,ba.w);
  float o4v=fmaf(a4,sc,bb.x), o5=fmaf(a5,sc,bb.y), o6=fmaf(a6,sc,bb.z), o7=fmaf(a7,sc,bb.w);
  if (OB16){
    uint4 o; o.x = pk2(o0,o1); o.y = pk2(o2,o3); o.z = pk2(o4v,o5); o.w = pk2(o6,o7);
    ((uint4*)out)[(size_t)row*16 + lane] = o;
  } else {
    float4* o4 = (float4*)out;
    o4[(size_t)row*32 + lane*2]     = make_float4(o0,o1,o2,o3);
    o4[(size_t)row*32 + lane*2 + 1] = make_float4(o4v,o5,o6,o7);
  }
}

template<int GB16, int DB16>
__device__ __forceinline__ void dev_head(int bid, const void* __restrict__ g, const void* __restrict__ dch,
    const float* __restrict__ W, const float* __restrict__ b,
    float* __restrict__ out, int n, int rowOff)
{
  int wid = threadIdx.x >> 6, lane = threadIdx.x & 63;
  int row = bid*4 + wid;
  if (row >= n) return;
  float x0, x1, x2, x3;
  if (GB16){ const u16* gr = (const u16*)g + (size_t)row*FD; x0 = bf2f(gr[lane]); x1 = bf2f(gr[64+lane]); }
  else     { const float* gr = (const float*)g + (size_t)row*FD; x0 = gr[lane]; x1 = gr[64+lane]; }
  if (DB16){ const u16* dr = (const u16*)dch + (size_t)row*FD; x2 = bf2f(dr[lane]); x3 = bf2f(dr[64+lane]); }
  else     { const float* dr = (const float*)dch + (size_t)row*FD; x2 = dr[lane]; x3 = dr[64+lane]; }
  float acc[5];
  #pragma unroll
  for (int o = 0; o < 5; ++o)
    acc[o] = x0*W[lane*5+o] + x1*W[(64+lane)*5+o] + x2*W[(128+lane)*5+o] + x3*W[(192+lane)*5+o];
  #pragma unroll
  for (int o = 0; o < 5; ++o)
    #pragma unroll
    for (int s = 32; s; s >>= 1) acc[o] += __shfl_xor(acc[o], s);
  if (lane == 0){
    float m = -1e30f;
    #pragma unroll
    for (int o = 0; o < 5; ++o){ acc[o] += b[o]; m = fmaxf(m, acc[o]); }
    float sum = 0.f;
    #pragma unroll
    for (int o = 0; o < 5; ++o){ acc[o] = expf(acc[o]-m); sum += acc[o]; }
    float is = 1.0f/sum;
    float* op = out + (size_t)(rowOff+row)*5;
    #pragma unroll
    for (int o = 0; o < 5; ++o) op[o] = acc[o]*is;
  }
}

// ================= kernels =================

// K1: kvec (4) || W->bf16 col-major transposes (6) || zero bktCnt
__global__ __launch_bounds__(256) void k1_prep(int* __restrict__ zeroBlk, int ntot,
    const float* __restrict__ ekW, const float* __restrict__ ekb, const float* __restrict__ eqb,
    const float* __restrict__ dkW, const float* __restrict__ dkb, const float* __restrict__ dqb,
    float* __restrict__ kv, float inv,
    const float* __restrict__ evW, const float* __restrict__ gW,
    const float* __restrict__ embW, const float* __restrict__ dvW,
    u16* __restrict__ wvt0, u16* __restrict__ wgt0, u16* __restrict__ wvt1, u16* __restrict__ wgt1,
    u16* __restrict__ wembT, u16* __restrict__ wvtd1)
{
  int bid = blockIdx.x;
  if (bid < 4){
    if (threadIdx.x < 128){
      int j = bid;
      const float* kW = (j < 2) ? ekW + j*16384 : dkW + (j-2)*16384;
      const float* kb = (j < 2) ? ekb + j*128   : dkb + (j-2)*128;
      const float* qb = (j < 2) ? eqb + j*128   : dqb + (j-2)*128;
      float* o = kv + j*132;
      int k = threadIdx.x;
      float a = 0.f;
      for (int t = 0; t < 128; ++t) a = fmaf(kW[k*128+t], qb[t], a);
      o[k] = a * inv;
      if (k == 0){
        float c = 0.f;
        for (int t = 0; t < 128; ++t) c = fmaf(kb[t], qb[t], c);
        o[128] = c * inv;
      }
    }
  } else if (bid < 10){
    const float* Ws; u16* Wd;
    if (bid == 4){ Ws = evW;            Wd = wvt0; }
    else if (bid == 5){ Ws = gW;        Wd = wgt0; }
    else if (bid == 6){ Ws = evW+16384; Wd = wvt1; }
    else if (bid == 7){ Ws = gW+16384;  Wd = wgt1; }
    else if (bid == 8){ Ws = embW;      Wd = wembT; }
    else              { Ws = dvW+16384; Wd = wvtd1; }
    for (int i = threadIdx.x; i < 16384; i += 256){
      int k = i >> 7, c = i & 127;
      Wd[c*128 + k] = f2bf(Ws[i]);
    }
  } else {
    int i = (bid-10)*256 + threadIdx.x;
    if (i < ntot) zeroBlk[i] = 0;
  }
}

// K2: P0 || MFMA h0 gemm (f32 A)
__global__ __launch_bounds__(256) void k2_p0_gemm(BMeta m, int* __restrict__ bktCnt,
    const float* __restrict__ X, const u16* __restrict__ wembT, const float* __restrict__ b,
    u16* __restrict__ bh0, int np0)
{
  __shared__ int sh[64];
  int bid = blockIdx.x;
  if (bid < np0) dev_p0(m, bid, bktCnt, sh);
  else dev_single_mfma<1,0>(bid - np0, X, wembT, b, nullptr, nullptr, bh0, N0);
}

// K3: P1
__global__ __launch_bounds__(256) void k3_p1(BMeta m,
    const int* __restrict__ bktCnt, int* __restrict__ bktBase, int* __restrict__ bktCur)
{
  __shared__ int sh[384];
  dev_p1(m, bktCnt, bktBase, bktCur, sh);
}

// K4: P2 || MFMA dual(h0) part 1
__global__ __launch_bounds__(256) void k4_p2_dual(BMeta m, int* __restrict__ bktCur,
    u32* __restrict__ ebuf, u16* __restrict__ ebuf16,
    const u16* __restrict__ bh0,
    const u16* __restrict__ wvt0, const u16* __restrict__ wgt0, const float* __restrict__ evb,
    const float* __restrict__ kvec, float* __restrict__ sS, u16* __restrict__ bV, u16* __restrict__ bY0,
    int np2, int gOff)
{
  __shared__ int sh[1824];
  int bid = blockIdx.x;
  if (bid < np2) dev_p2(m, bid, bktCur, ebuf, ebuf16, sh);
  else dev_dual_mfma(gOff + bid - np2, bh0, wvt0, wgt0, evb, kvec, sS, bV, bY0, N0);
}

// K5: P3 || MFMA dual(h0) part 2
__global__ __launch_bounds__(256) void k5_p3_dual(BMeta m,
    const int* __restrict__ bktCnt, const int* __restrict__ bktBase,
    const u32* __restrict__ ebuf, const u16* __restrict__ ebuf16,
    const u16* __restrict__ bh0,
    const u16* __restrict__ wvt0, const u16* __restrict__ wgt0, const float* __restrict__ evb,
    const float* __restrict__ kvec, float* __restrict__ sS, u16* __restrict__ bV, u16* __restrict__ bY0,
    int np3, int gOff)
{
  __shared__ int sh[1824];
  int bid = blockIdx.x;
  if (bid < np3) dev_p3(m, bid, bktCnt, bktBase, ebuf, ebuf16, sh);
  else dev_dual_mfma(gOff + bid - np3, bh0, wvt0, wgt0, evb, kvec, sS, bV, bY0, N0);
}

// K6: attn_gather16(i0)->be1 || g0 slice
__global__ __launch_bounds__(256) void k6_ag_i0(
    const int* __restrict__ csrA, const int* __restrict__ rowpA,
    const float* __restrict__ sS, const u16* __restrict__ bV, u16* __restrict__ be1,
    const int* __restrict__ csr0, const int* __restrict__ rowp0, const float* __restrict__ rs0,
    const u16* __restrict__ bY0, const float* __restrict__ gb, u16* __restrict__ bg0, int nMain, int sBase)
{
  int bid = blockIdx.x;
  if (bid < nMain) dev_attn_gather16<1>(bid, csrA, rowpA, sS, bV, be1, N1);
  else dev_gcn_gather16<1>(sBase + bid - nMain, csr0, rowp0, rs0, bY0, gb, bg0, N0);
}

// K7: MFMA dual(be1 -> V1+score, Y1) || g0 slice
__global__ __launch_bounds__(256) void k7_dual_enc1(
    const u16* __restrict__ be1,
    const u16* __restrict__ wvt1, const u16* __restrict__ wgt1, const float* __restrict__ vb,
    const float* __restrict__ kvec, float* __restrict__ sS, u16* __restrict__ bV, u16* __restrict__ bY1,
    const int* __restrict__ csr0, const int* __restrict__ rowp0, const float* __restrict__ rs0,
    const u16* __restrict__ bY0, const float* __restrict__ gb, u16* __restrict__ bg0, int nMain, int sBase)
{
  int bid = blockIdx.x;
  if (bid < nMain) dev_dual_mfma(bid, be1, wvt1, wgt1, vb, kvec, sS, bV, bY1, N1);
  else dev_gcn_gather16<1>(sBase + bid - nMain, csr0, rowp0, rs0, bY0, gb, bg0, N0);
}

// K8: attn_gather16(i1)->be2(f32) || g0 slice
__global__ __launch_bounds__(256) void k8_ag_i1(
    const int* __restrict__ csrA, const int* __restrict__ rowpA,
    const float* __restrict__ sS, const u16* __restrict__ bV, float* __restrict__ be2,
    const int* __restrict__ csr0, const int* __restrict__ rowp0, const float* __restrict__ rs0,
    const u16* __restrict__ bY0, const float* __restrict__ gb, u16* __restrict__ bg0, int nMain, int sBase)
{
  int bid = blockIdx.x;
  if (bid < nMain) dev_attn_gather16<0>(bid, csrA, rowpA, sS, bV, be2, N2);
  else dev_gcn_gather16<1>(sBase + bid - nMain, csr0, rowp0, rs0, bY0, gb, bg0, N0);
}

// K9: gcn2-Y gemm (f32 A) || gcn_gather16(g1)->bg1 || g0 slice
__global__ __launch_bounds__(256) void k9_y2_g1(
    const float* __restrict__ be2, const float* __restrict__ W2, u16* __restrict__ bY2,
    const int* __restrict__ csr1, const int* __restrict__ rowp1, const float* __restrict__ rs1,
    const u16* __restrict__ bY1, const float* __restrict__ b1, u16* __restrict__ bg1,
    const int* __restrict__ csr0, const int* __restrict__ rowp0, const float* __restrict__ rs0,
    const u16* __restrict__ bY0, const float* __restrict__ gb, u16* __restrict__ bg0,
    int ngemm, int nMain, int sBase)
{
  __shared__ float sm[5120];
  int bid = blockIdx.x;
  if (bid < ngemm) dev_gemm<0,0>(sm, sm+4096, bid, be2, W2, nullptr, nullptr, nullptr, bY2, N2);
  else if (bid < nMain) dev_gcn_gather16<1>(bid - ngemm, csr1, rowp1, rs1, bY1, b1, bg1, N1);
  else dev_gcn_gather16<1>(sBase + bid - nMain, csr0, rowp0, rs0, bY0, gb, bg0, N0);
}

// K10: gcn_gather16(g2)->bg2(f32) || g0 slice
__global__ __launch_bounds__(256) void k10_g2(
    const int* __restrict__ csr2, const int* __restrict__ rowp2, const float* __restrict__ rs2,
    const u16* __restrict__ bY2, const float* __restrict__ b2, float* __restrict__ bg2,
    const int* __restrict__ csr0, const int* __restrict__ rowp0, const float* __restrict__ rs0,
    const u16* __restrict__ bY0, const float* __restrict__ gb, u16* __restrict__ bg0, int nMain, int sBase)
{
  int bid = blockIdx.x;
  if (bid < nMain) dev_gcn_gather16<0>(bid, csr2, rowp2, rs2, bY2, b2, bg2, N2);
  else dev_gcn_gather16<1>(sBase + bid - nMain, csr0, rowp0, rs0, bY0, gb, bg0, N0);
}

// K11: dec0 gemm (f32 A) || head2 || g0 slice
__global__ __launch_bounds__(256) void k11_dec0_head2(
    const float* __restrict__ bg2, const float* __restrict__ vW, const float* __restrict__ vb,
    const float* __restrict__ kvec, float* __restrict__ sS, u16* __restrict__ bV,
    const float* __restrict__ hW, const float* __restrict__ hb, float* __restrict__ out,
    const int* __restrict__ csr0, const int* __restrict__ rowp0, const float* __restrict__ rs0,
    const u16* __restrict__ bY0, const float* __restrict__ gb, u16* __restrict__ bg0,
    int ngemm, int nMain, int sBase)
{
  __shared__ float sm[5120];
  int bid = blockIdx.x;
  if (bid < ngemm) dev_gemm<1,0>(sm, sm+4096, bid, bg2, vW, vb, kvec, sS, bV, N2);
  else if (bid < nMain) dev_head<0,0>(bid - ngemm, bg2, bg2, hW, hb, out, N2, N0+N1);
  else dev_gcn_gather16<1>(sBase + bid - nMain, csr0, rowp0, rs0, bY0, gb, bg0, N0);
}

// K12: attn_gather16(dc0)->be1 (d1) || g0 slice
__global__ __launch_bounds__(256) void k12_ag_d1(
    const int* __restrict__ csrA, const int* __restrict__ rowpA,
    const float* __restrict__ sS, const u16* __restrict__ bV, u16* __restrict__ be1,
    const int* __restrict__ csr0, const int* __restrict__ rowp0, const float* __restrict__ rs0,
    const u16* __restrict__ bY0, const float* __restrict__ gb, u16* __restrict__ bg0, int nMain, int sBase)
{
  int bid = blockIdx.x;
  if (bid < nMain) dev_attn_gather16<1>(bid, csrA, rowpA, sS, bV, be1, N1);
  else dev_gcn_gather16<1>(sBase + bid - nMain, csr0, rowp0, rs0, bY0, gb, bg0, N0);
}

// K13: MFMA dec1 gemm (bf16 A, +score) || head1 || g0 slice
__global__ __launch_bounds__(256) void k13_dec1_head1(
    const u16* __restrict__ be1, const u16* __restrict__ wvtd1, const float* __restrict__ vb,
    const float* __restrict__ kvec, float* __restrict__ sS, u16* __restrict__ bV,
    const u16* __restrict__ bg1, const float* __restrict__ hW, const float* __restrict__ hb,
    float* __restrict__ out,
    const int* __restrict__ csr0, const int* __restrict__ rowp0, const float* __restrict__ rs0,
    const u16* __restrict__ bY0, const float* __restrict__ gb, u16* __restrict__ bg0,
    int ngemm, int nMain, int sBase)
{
  int bid = blockIdx.x;
  if (bid < ngemm) dev_single_mfma<0,1>(bid, be1, wvtd1, vb, kvec, sS, bV, N1);
  else if (bid < nMain) dev_head<1,1>(bid - ngemm, bg1, be1, hW, hb, out, N1, N0);
  else dev_gcn_gather16<1>(sBase + bid - nMain, csr0, rowp0, rs0, bY0, gb, bg0, N0);
}

// K14: fused d0 gather + head0 (16-lane)
__global__ __launch_bounds__(256) void k14_gather_head0(
    const int* __restrict__ csr, const int* __restrict__ rowp,
    const float* __restrict__ w, const u16* __restrict__ V,
    const u16* __restrict__ bg0,
    const float* __restrict__ hW, const float* __restrict__ hb,
    float* __restrict__ out)
{
  int g = threadIdx.x >> 4, lane = threadIdx.x & 15;
  int row = blockIdx.x*16 + g;
  if (row >= N0) return;
  int st = rowp[row], en = rowp[row+1];
  float a0=0,a1=0,a2=0,a3=0,a4=0,a5=0,a6=0,a7=0;
  if (en > st){
    const uint4* V8 = (const uint4*)V;
    float den = 0.f;
    for (int e = st; e < en; ++e){
      int sn = csr[e];
      float x = w[sn];
      uint4 v = V8[(size_t)sn*16 + lane];
      den += x;
      a0 = fmaf(x, blo(v.x), a0); a1 = fmaf(x, bhi(v.x), a1);
      a2 = fmaf(x, blo(v.y), a2); a3 = fmaf(x, bhi(v.y), a3);
      a4 = fmaf(x, blo(v.z), a4); a5 = fmaf(x, bhi(v.z), a5);
      a6 = fmaf(x, blo(v.w), a6); a7 = fmaf(x, bhi(v.w), a7);
    }
    float inv = 1.f/den;
    a0*=inv; a1*=inv; a2*=inv; a3*=inv; a4*=inv; a5*=inv; a6*=inv; a7*=inv;
  }
  uint4 gv = ((const uint4*)(bg0 + (size_t)row*FD))[lane];
  float g0 = blo(gv.x), g1 = bhi(gv.x), g2 = blo(gv.y), g3 = bhi(gv.y);
  float g4 = blo(gv.z), g5 = bhi(gv.z), g6 = blo(gv.w), g7 = bhi(gv.w);
  int j = 8*lane;
  float acc[5];
  #pragma unroll
  for (int o = 0; o < 5; ++o){
    acc[o] = g0*hW[(j+0)*5+o] + g1*hW[(j+1)*5+o] + g2*hW[(j+2)*5+o] + g3*hW[(j+3)*5+o]
           + g4*hW[(j+4)*5+o] + g5*hW[(j+5)*5+o] + g6*hW[(j+6)*5+o] + g7*hW[(j+7)*5+o]
           + a0*hW[(128+j+0)*5+o] + a1*hW[(128+j+1)*5+o] + a2*hW[(128+j+2)*5+o] + a3*hW[(128+j+3)*5+o]
           + a4*hW[(128+j+4)*5+o] + a5*hW[(128+j+5)*5+o] + a6*hW[(128+j+6)*5+o] + a7*hW[(128+j+7)*5+o];
  }
  #pragma unroll
  for (int o = 0; o < 5; ++o)
    #pragma unroll
    for (int s = 8; s; s >>= 1) acc[o] += __shfl_xor(acc[o], s, 16);
  if (lane == 0){
    float m = -1e30f;
    #pragma unroll
    for (int o = 0; o < 5; ++o){ acc[o] += hb[o]; m = fmaxf(m, acc[o]); }
    float sum = 0.f;
    #pragma unroll
    for (int o = 0; o < 5; ++o){ acc[o] = expf(acc[o]-m); sum += acc[o]; }
    float is = 1.0f/sum;
    float* op = out + (size_t)row*5;
    #pragma unroll
    for (int o = 0; o < 5; ++o) op[o] = acc[o]*is;
  }
}

// ================= host =================
extern "C" void kernel_launch(void* const* d_in, const int* in_sizes, int n_in,
                              void* d_out, int out_size, void* d_ws, size_t ws_size,
                              hipStream_t stream)
{
  const float* X      = (const float*)d_in[0];
  const float* emb_W  = (const float*)d_in[1];
  const float* emb_b  = (const float*)d_in[2];
  const float* gcn_W  = (const float*)d_in[3];
  const float* gcn_b  = (const float*)d_in[4];
  const float* enc_qb = (const float*)d_in[6];
  const float* enc_kW = (const float*)d_in[7];
  const float* enc_kb = (const float*)d_in[8];
  const float* enc_vW = (const float*)d_in[9];
  const float* enc_vb = (const float*)d_in[10];
  const float* dec_qb = (const float*)d_in[12];
  const float* dec_kW = (const float*)d_in[13];
  const float* dec_kb = (const float*)d_in[14];
  const float* dec_vW = (const float*)d_in[15];
  const float* dec_vb = (const float*)d_in[16];
  const float* head_W = (const float*)d_in[17];
  const float* head_b = (const float*)d_in[18];
  const int* g0s  = (const int*)d_in[19];
  const int* g0d  = (const int*)d_in[20];
  const int* g1s  = (const int*)d_in[21];
  const int* g1d  = (const int*)d_in[22];
  const int* g2s  = (const int*)d_in[23];
  const int* g2d  = (const int*)d_in[24];
  const int* i0s  = (const int*)d_in[25];
  const int* i0d  = (const int*)d_in[26];
  const int* i1s  = (const int*)d_in[27];
  const int* i1d  = (const int*)d_in[28];
  const int* dc0s = (const int*)d_in[29];
  const int* dc0d = (const int*)d_in[30];
  const int* dc1s = (const int*)d_in[31];
  const int* dc1d = (const int*)d_in[32];

  // ---- workspace layout ----
  float* ws = (float*)d_ws;
  float* sS  = ws;                          // N0
  float* kvec = sS + N0;                    // 4*132
  float* be2 = kvec + 4*132;                // N2*FD f32
  float* bg2 = be2 + (size_t)N2*FD;         // N2*FD f32
  float* rs0 = bg2 + (size_t)N2*FD;         // N0
  float* rs1 = rs0 + N0;                    // N1
  float* rs2 = rs1 + N1;                    // N2 (+2 pad -> 16B-aligned u16 region)
  u16*  bh0 = (u16*)(rs2 + N2 + 2);         // N0*FD u16
  u16*  be1 = bh0 + (size_t)N0*FD;          // N1*FD u16
  u16*  bg0 = be1 + (size_t)N1*FD;          // N0*FD u16
  u16*  bg1 = bg0 + (size_t)N0*FD;          // N1*FD u16
  u16*  bV  = bg1 + (size_t)N1*FD;          // N0*FD u16 (V tables, time-shared)
  u16*  bY0 = bV  + (size_t)N0*FD;          // N0*FD u16
  u16*  bY1 = bV + 4000000;                 // alias into bV tail
  u16*  bY2 = bV + 8000000;
  int*  bktCnt  = (int*)(bY0 + (size_t)N0*FD);  // 328
  int*  bktBase = bktCnt + 328;                 // 328
  int*  bktCur  = bktBase + 328;                // 328
  int*  rowpBlk = bktCur + 328;                 // 287507
  int*  csrBlk  = rowpBlk + 287507;             // 2,500,000
  u32*  ebuf    = (u32*)(csrBlk + 2500000);     // 2.5M u32
  u16*  ebuf16  = (u16*)(ebuf + 2500000);       // 1.5M u16
  uintptr_t wtp = ((uintptr_t)(ebuf16 + 1500000) + 15) & ~(uintptr_t)15;
  u16* wvt0 = (u16*)wtp;                        // 16384 each (col-major bf16 W)
  u16* wgt0 = wvt0 + 16384;
  u16* wvt1 = wgt0 + 16384;
  u16* wgt1 = wvt1 + 16384;
  u16* wembT = wgt1 + 16384;
  u16* wvtd1 = wembT + 16384;

  const int* keyP[10] = {g0d,g1d,g2d,i0d,i1d,dc0d,dc1d, g0s,g1s,g2s};
  const int* srcP[7]  = {g0s,g1s,g2s,i0s,i1s,dc0s,dc1s};
  const int nArr[10] = {N0,N1,N2,N1,N2,N1,N0, N0,N1,N2};
  const int EArr[10] = {1000000,400000,100000,400000,100000,100000,400000, 1000000,400000,100000};
  const int BArr[10] = {64,32,8,32,8,16,64, 64,32,8};
  const int rArr[10] = {1563,782,782,782,782,1563,1563, 1563,782,782};

  BMeta m;
  {
    int eo=0, so=0, bo=0, po=0, ro=0, co=0;
    for (int j=0;j<10;++j){
      m.key[j]=keyP[j];
      m.n[j]=nArr[j]; m.E[j]=EArr[j]; m.B[j]=BArr[j]; m.r[j]=rArr[j];
      m.boff[j]=bo; m.pblk[j]=po;
      bo+=BArr[j]; po+=ceildiv(EArr[j],4096);
      if (j < 7){
        m.src[j]=srcP[j]; m.rowp[j]=rowpBlk+ro; m.csr[j]=csrBlk+co;
        m.eoff[j]=eo; eo+=EArr[j]; ro+=nArr[j]+1; co+=EArr[j];
      } else {
        m.soff[j-7]=so; so+=EArr[j];
      }
    }
    m.eoff[7]=eo; m.soff[3]=so; m.boff[10]=bo; m.pblk[10]=po;
  }
  m.rsout[0]=rs0; m.rsout[1]=rs1; m.rsout[2]=rs2;

  const float invScale = 0.17677669529663687f;
  float* out = (float*)d_out;

  const int NP = m.pblk[10];                // 982
  const int NB = m.boff[10];                // 328
  const int GH0 = ceildiv(N0,32);           // 3125
  const int GH1 = ceildiv(N1,32);           // 782
  const int GH2 = ceildiv(N2,32);           // 196
  const int GS1 = 1563;                     // dual(h0) share in K4
  const int GA1_16 = ceildiv(N1,16);        // 1563
  const int GA2_16 = ceildiv(N2,16);        // 391
  const int G0B16  = ceildiv(N0,16);        // 6250
  const int GH2H = ceildiv(N2,4);           // 1563
  const int GH1H = ceildiv(N1,4);           // 6250

  int ss[9];
  for (int i = 0; i <= 8; ++i) ss[i] = (int)(((long long)G0B16 * i) / 8);

  // K1: kvec || W transposes || zero bktCnt
  k1_prep<<<10 + ceildiv(NB,256), 256, 0, stream>>>(bktCnt, NB,
      enc_kW, enc_kb, enc_qb, dec_kW, dec_kb, dec_qb, kvec, invScale,
      enc_vW, gcn_W, emb_W, dec_vW, wvt0, wgt0, wvt1, wgt1, wembT, wvtd1);
  // K2: P0 || MFMA h0 gemm
  k2_p0_gemm<<<NP + GH0, 256, 0, stream>>>(m, bktCnt, X, wembT, emb_b, bh0, NP);
  // K3: P1
  k3_p1<<<1, 256, 0, stream>>>(m, bktCnt, bktBase, bktCur);
  // K4: P2 || MFMA dual(h0) part 1
  k4_p2_dual<<<NP + GS1, 256, 0, stream>>>(m, bktCur, ebuf, ebuf16,
      bh0, wvt0, wgt0, enc_vb, kvec, sS, bV, bY0, NP, 0);
  // K5: P3 || MFMA dual(h0) part 2
  k5_p3_dual<<<NB + (GH0 - GS1), 256, 0, stream>>>(m, bktCnt, bktBase, ebuf, ebuf16,
      bh0, wvt0, wgt0, enc_vb, kvec, sS, bV, bY0, NB, GS1);
  // K6: attn_gather(i0)->be1 || g0[0]
  k6_ag_i0<<<GA1_16 + (ss[1]-ss[0]), 256, 0, stream>>>(m.csr[3], m.rowp[3], sS, bV, be1,
      m.csr[0], m.rowp[0], rs0, bY0, gcn_b, bg0, GA1_16, ss[0]);
  // K7: MFMA dual(be1 -> V1, Y1) || g0[1]
  k7_dual_enc1<<<GH1 + (ss[2]-ss[1]), 256, 0, stream>>>(be1,
      wvt1, wgt1, enc_vb+128, kvec+132, sS, bV, bY1,
      m.csr[0], m.rowp[0], rs0, bY0, gcn_b, bg0, GH1, ss[1]);
  // K8: attn_gather(i1)->be2 || g0[2]
  k8_ag_i1<<<GA2_16 + (ss[3]-ss[2]), 256, 0, stream>>>(m.csr[4], m.rowp[4], sS, bV, be2,
      m.csr[0], m.rowp[0], rs0, bY0, gcn_b, bg0, GA2_16, ss[2]);
  // K9: gcn2-Y || gather(g1)->bg1 || g0[3]
  k9_y2_g1<<<GH2 + GA1_16 + (ss[4]-ss[3]), 256, 0, stream>>>(be2, gcn_W+32768, bY2,
      m.csr[1], m.rowp[1], rs1, bY1, gcn_b+128, bg1,
      m.csr[0], m.rowp[0], rs0, bY0, gcn_b, bg0, GH2, GH2+GA1_16, ss[3]);
  // K10: gather(g2)->bg2 || g0[4]
  k10_g2<<<GA2_16 + (ss[5]-ss[4]), 256, 0, stream>>>(m.csr[2], m.rowp[2], rs2, bY2, gcn_b+256, bg2,
      m.csr[0], m.rowp[0], rs0, bY0, gcn_b, bg0, GA2_16, ss[4]);
  // K11: dec0 gemm || head2 || g0[5]
  k11_dec0_head2<<<GH2 + GH2H + (ss[6]-ss[5]), 256, 0, stream>>>(bg2, dec_vW, dec_vb, kvec+264, sS, bV,
      head_W+2560, head_b+10, out,
      m.csr[0], m.rowp[0], rs0, bY0, gcn_b, bg0, GH2, GH2+GH2H, ss[5]);
  // K12: attn_gather(dc0)->be1 (d1) || g0[6]
  k12_ag_d1<<<GA1_16 + (ss[7]-ss[6]), 256, 0, stream>>>(m.csr[5], m.rowp[5], sS, bV, be1,
      m.csr[0], m.rowp[0], rs0, bY0, gcn_b, bg0, GA1_16, ss[6]);
  // K13: MFMA dec1 gemm || head1 || g0[7]
  k13_dec1_head1<<<GH1 + GH1H + (ss[8]-ss[7]), 256, 0, stream>>>(be1, wvtd1, dec_vb+128, kvec+396, sS, bV,
      bg1, head_W+1280, head_b+5, out,
      m.csr[0], m.rowp[0], rs0, bY0, gcn_b, bg0, GH1, GH1+GH1H, ss[7]);
  // K14: fused d0 gather + head0
  k14_gather_head0<<<G0B16, 256, 0, stream>>>(m.csr[6], m.rowp[6], sS, bV, bg0,
      head_W, head_b, out);
}

// Round 14
// 417.102 us; speedup vs baseline: 11.9416x; 1.0724x over previous
//
#include <hip/hip_runtime.h>
#include <math.h>
#include <stdint.h>

#define N0 100000
#define N1 25000
#define N2 6250
#define FD 128

typedef unsigned short u16;
typedef unsigned int u32;
typedef short bf16x8 __attribute__((ext_vector_type(8)));
typedef float f32x4 __attribute__((ext_vector_type(4)));

static inline int ceildiv(int a, int b){ return (a + b - 1)/b; }

__device__ __forceinline__ u16 f2bf(float f){
  u32 u = __float_as_uint(f);
  u += 0x7fffu + ((u >> 16) & 1u);
  return (u16)(u >> 16);
}
__device__ __forceinline__ float bf2f(u16 h){
  return __uint_as_float(((u32)h) << 16);
}
__device__ __forceinline__ float blo(u32 u){ return __uint_as_float(u << 16); }
__device__ __forceinline__ float bhi(u32 u){ return __uint_as_float(u & 0xffff0000u); }
__device__ __forceinline__ u32 pk2(float a, float b){ return (u32)f2bf(a) | ((u32)f2bf(b) << 16); }

// ================= bucket metadata: 10 jobs =================
struct BMeta {
  const int* key[10];
  const int* src[7];
  int* rowp[7]; int* csr[7];
  float* rsout[3];
  int n[10], E[10], B[10], r[10];
  int eoff[8];
  int soff[4];
  int boff[11];
  int pblk[11];
};

// ================= FMA GEMM (small cases: k9/k11) =================
__device__ __forceinline__ void mm_inner(const float* Al, const float* Wl, int r0, int c0, float acc[4][4]){
  #pragma unroll
  for (int kq = 0; kq < 8; ++kq) {
    int k0 = kq*4;
    float4 a[4], w[4];
    #pragma unroll
    for (int i=0;i<4;++i) a[i] = *(const float4*)&Al[(r0+i)*32 + k0];
    #pragma unroll
    for (int kk=0;kk<4;++kk) w[kk] = *(const float4*)&Wl[(k0+kk)*128 + c0];
    #pragma unroll
    for (int i=0;i<4;++i){
      acc[i][0] = fmaf(a[i].x,w[0].x, fmaf(a[i].y,w[1].x, fmaf(a[i].z,w[2].x, fmaf(a[i].w,w[3].x, acc[i][0]))));
      acc[i][1] = fmaf(a[i].x,w[0].y, fmaf(a[i].y,w[1].y, fmaf(a[i].z,w[2].y, fmaf(a[i].w,w[3].y, acc[i][1]))));
      acc[i][2] = fmaf(a[i].x,w[0].z, fmaf(a[i].y,w[1].z, fmaf(a[i].z,w[2].z, fmaf(a[i].w,w[3].z, acc[i][2]))));
      acc[i][3] = fmaf(a[i].x,w[0].w, fmaf(a[i].y,w[1].w, fmaf(a[i].z,w[2].w, fmaf(a[i].w,w[3].w, acc[i][3]))));
    }
  }
}

template<int SCORE, int AB16>
__device__ __forceinline__ void dev_gemm(float* Wl, float* Al, int bid,
    const void* __restrict__ Ap,
    const float* __restrict__ W, const float* __restrict__ bias,
    const float* __restrict__ kvec, float* __restrict__ sOut,
    u16* __restrict__ out, int n)
{
  const int tid = threadIdx.x;
  const int row0 = bid * 32;
  const int c0 = (tid & 31) * 4, r0 = (tid >> 5) * 4;
  const int r = tid >> 3, fc = tid & 7;
  const int gr_s = row0 + r;
  float acc[4][4] = {};
  float sacc = 0.f;
  const float4* W4 = (const float4*)W;
  for (int kp = 0; kp < 4; ++kp) {
    float4* Wl4 = (float4*)Wl;
    #pragma unroll
    for (int i = 0; i < 4; ++i) Wl4[tid + 256*i] = W4[kp*1024 + tid + 256*i];
    {
      float4 v = make_float4(0.f,0.f,0.f,0.f);
      if (gr_s < n){
        if (AB16){
          ushort4 h = ((const ushort4*)Ap)[(size_t)gr_s*32 + kp*8 + fc];
          v = make_float4(bf2f(h.x), bf2f(h.y), bf2f(h.z), bf2f(h.w));
        } else {
          v = ((const float4*)Ap)[(size_t)gr_s*32 + kp*8 + fc];
        }
      }
      ((float4*)Al)[tid] = v;
      if (SCORE){
        float4 kv = *(const float4*)&kvec[kp*32 + fc*4];
        sacc += v.x*kv.x + v.y*kv.y + v.z*kv.z + v.w*kv.w;
      }
    }
    __syncthreads();
    mm_inner(Al, Wl, r0, c0, acc);
    __syncthreads();
  }
  if (SCORE){
    sacc += __shfl_xor(sacc, 1);
    sacc += __shfl_xor(sacc, 2);
    sacc += __shfl_xor(sacc, 4);
    if (fc == 0 && gr_s < n) sOut[gr_s] = expf(sacc + kvec[128]);
  }
  float4 bv = make_float4(0.f,0.f,0.f,0.f);
  if (bias) bv = *(const float4*)&bias[c0];
  #pragma unroll
  for (int i=0;i<4;++i){
    int gr = row0 + r0 + i;
    if (gr < n){
      ushort4 o;
      o.x = f2bf(acc[i][0]+bv.x); o.y = f2bf(acc[i][1]+bv.y);
      o.z = f2bf(acc[i][2]+bv.z); o.w = f2bf(acc[i][3]+bv.w);
      *(ushort4*)&out[(size_t)gr*FD + c0] = o;
    }
  }
}

// ================= MFMA GEMMs (LDS-free) =================
__device__ __forceinline__ void dev_dual_mfma(int bid,
    const u16* __restrict__ A, const u16* __restrict__ WvT, const u16* __restrict__ WgT,
    const float* __restrict__ vb, const float* __restrict__ kvec, float* __restrict__ sOut,
    u16* __restrict__ Vout, u16* __restrict__ Yout, int n)
{
  const int tid = threadIdx.x;
  const int wid = tid >> 6, lane = tid & 63;
  const int l15 = lane & 15, lg = lane >> 4;
  const int rt = wid & 1;
  const int cbase = (wid >> 1) * 64;
  const int row0 = bid * 32;
  const int arow = row0 + rt*16 + l15;
  const int arowc = min(arow, n-1);
  f32x4 accV[4] = {{0.f,0.f,0.f,0.f},{0.f,0.f,0.f,0.f},{0.f,0.f,0.f,0.f},{0.f,0.f,0.f,0.f}};
  f32x4 accY[4] = {{0.f,0.f,0.f,0.f},{0.f,0.f,0.f,0.f},{0.f,0.f,0.f,0.f},{0.f,0.f,0.f,0.f}};
  float sacc = 0.f;
  #pragma unroll
  for (int ks = 0; ks < 4; ++ks){
    const int ko = ks*32 + lg*8;
    bf16x8 a = *(const bf16x8*)(A + (size_t)arowc*FD + ko);
    if (wid < 2){
      float4 k0 = *(const float4*)(kvec + ko);
      float4 k1 = *(const float4*)(kvec + ko + 4);
      sacc += bf2f((u16)a[0])*k0.x + bf2f((u16)a[1])*k0.y + bf2f((u16)a[2])*k0.z + bf2f((u16)a[3])*k0.w
            + bf2f((u16)a[4])*k1.x + bf2f((u16)a[5])*k1.y + bf2f((u16)a[6])*k1.z + bf2f((u16)a[7])*k1.w;
    }
    #pragma unroll
    for (int ct = 0; ct < 4; ++ct){
      const int col = cbase + ct*16 + l15;
      bf16x8 bv = *(const bf16x8*)(WvT + (size_t)col*FD + ko);
      bf16x8 bg = *(const bf16x8*)(WgT + (size_t)col*FD + ko);
      accV[ct] = __builtin_amdgcn_mfma_f32_16x16x32_bf16(a, bv, accV[ct], 0, 0, 0);
      accY[ct] = __builtin_amdgcn_mfma_f32_16x16x32_bf16(a, bg, accY[ct], 0, 0, 0);
    }
  }
  if (wid < 2){
    sacc += __shfl_xor(sacc, 16);
    sacc += __shfl_xor(sacc, 32);
    if (lane < 16 && arow < n) sOut[arow] = expf(sacc + kvec[128]);
  }
  #pragma unroll
  for (int ct = 0; ct < 4; ++ct){
    const int col = cbase + ct*16 + l15;
    const float bvv = vb[col];
    #pragma unroll
    for (int i = 0; i < 4; ++i){
      int gr = row0 + rt*16 + lg*4 + i;
      if (gr < n){
        Vout[(size_t)gr*FD + col] = f2bf(accV[ct][i] + bvv);
        Yout[(size_t)gr*FD + col] = f2bf(accY[ct][i]);
      }
    }
  }
}

template<int AF32, int SCORE>
__device__ __forceinline__ void dev_single_mfma(int bid,
    const void* __restrict__ Ap, const u16* __restrict__ WT,
    const float* __restrict__ bias,
    const float* __restrict__ kvec, float* __restrict__ sOut,
    u16* __restrict__ out, int n)
{
  const int tid = threadIdx.x;
  const int wid = tid >> 6, lane = tid & 63;
  const int l15 = lane & 15, lg = lane >> 4;
  const int rt = wid & 1;
  const int cbase = (wid >> 1) * 64;
  const int row0 = bid * 32;
  const int arow = row0 + rt*16 + l15;
  const int arowc = min(arow, n-1);
  f32x4 acc[4] = {{0.f,0.f,0.f,0.f},{0.f,0.f,0.f,0.f},{0.f,0.f,0.f,0.f},{0.f,0.f,0.f,0.f}};
  float sacc = 0.f;
  #pragma unroll
  for (int ks = 0; ks < 4; ++ks){
    const int ko = ks*32 + lg*8;
    bf16x8 a;
    if (AF32){
      const float* Af = (const float*)Ap + (size_t)arowc*FD + ko;
      float4 f0 = *(const float4*)Af;
      float4 f1 = *(const float4*)(Af + 4);
      a[0]=(short)f2bf(f0.x); a[1]=(short)f2bf(f0.y); a[2]=(short)f2bf(f0.z); a[3]=(short)f2bf(f0.w);
      a[4]=(short)f2bf(f1.x); a[5]=(short)f2bf(f1.y); a[6]=(short)f2bf(f1.z); a[7]=(short)f2bf(f1.w);
      if (SCORE && wid < 2){
        float4 k0 = *(const float4*)(kvec + ko);
        float4 k1 = *(const float4*)(kvec + ko + 4);
        sacc += f0.x*k0.x + f0.y*k0.y + f0.z*k0.z + f0.w*k0.w
              + f1.x*k1.x + f1.y*k1.y + f1.z*k1.z + f1.w*k1.w;
      }
    } else {
      a = *(const bf16x8*)((const u16*)Ap + (size_t)arowc*FD + ko);
      if (SCORE && wid < 2){
        float4 k0 = *(const float4*)(kvec + ko);
        float4 k1 = *(const float4*)(kvec + ko + 4);
        sacc += bf2f((u16)a[0])*k0.x + bf2f((u16)a[1])*k0.y + bf2f((u16)a[2])*k0.z + bf2f((u16)a[3])*k0.w
              + bf2f((u16)a[4])*k1.x + bf2f((u16)a[5])*k1.y + bf2f((u16)a[6])*k1.z + bf2f((u16)a[7])*k1.w;
      }
    }
    #pragma unroll
    for (int ct = 0; ct < 4; ++ct){
      const int col = cbase + ct*16 + l15;
      bf16x8 bv = *(const bf16x8*)(WT + (size_t)col*FD + ko);
      acc[ct] = __builtin_amdgcn_mfma_f32_16x16x32_bf16(a, bv, acc[ct], 0, 0, 0);
    }
  }
  if (SCORE && wid < 2){
    sacc += __shfl_xor(sacc, 16);
    sacc += __shfl_xor(sacc, 32);
    if (lane < 16 && arow < n) sOut[arow] = expf(sacc + kvec[128]);
  }
  #pragma unroll
  for (int ct = 0; ct < 4; ++ct){
    const int col = cbase + ct*16 + l15;
    const float bvv = bias[col];
    #pragma unroll
    for (int i = 0; i < 4; ++i){
      int gr = row0 + rt*16 + lg*4 + i;
      if (gr < n) out[(size_t)gr*FD + col] = f2bf(acc[ct][i] + bvv);
    }
  }
}

// ================= bucket passes =================
__device__ __forceinline__ int job_of_blk(const BMeta& m, int bid){
  int j = 0;
  #pragma unroll
  for (int t = 1; t < 10; ++t) if (bid >= m.pblk[t]) j = t;
  return j;
}

// P0: per-wave LDS histograms (4x64), merged at end. sh: 256 ints.
__device__ __forceinline__ void dev_p0(const BMeta& m, int bid, int* __restrict__ bktCnt, int* sh){
  int j = job_of_blk(m, bid);
  int lb = bid - m.pblk[j];
  const int* key = m.key[j]; int E = m.E[j], r = m.r[j], B = m.B[j];
  int tid = threadIdx.x, wid = tid >> 6;
  sh[tid] = 0;
  __syncthreads();
  int base = lb*4096 + tid;
  int* wh = sh + wid*64;
  #pragma unroll
  for (int i = 0; i < 16; ++i){ int e = base + i*256; if (e < E) atomicAdd(&wh[key[e]/r], 1); }
  __syncthreads();
  if (tid < B) atomicAdd(&bktCnt[m.boff[j] + tid], sh[tid] + sh[64+tid] + sh[128+tid] + sh[192+tid]);
}

__device__ __forceinline__ void dev_p1(const BMeta& m, const int* __restrict__ bktCnt,
    int* __restrict__ bktBase, int* __restrict__ bktCur, int* sh){
  int tid = threadIdx.x;
  for (int i = tid; i < 328; i += 256) sh[i] = bktCnt[i];
  __syncthreads();
  if (tid < 10){
    int acc = (tid < 7) ? m.eoff[tid] : m.soff[tid-7];
    for (int b = m.boff[tid]; b < m.boff[tid+1]; ++b){ int v = sh[b]; sh[b] = acc; acc += v; }
  }
  __syncthreads();
  for (int i = tid; i < 328; i += 256){ bktBase[i] = sh[i]; bktCur[i] = sh[i]; }
}

// P2: per-wave hist + per-wave start offsets. sh: 512 ints.
__device__ __forceinline__ void dev_p2(const BMeta& m, int bid, int* __restrict__ bktCur,
    u32* __restrict__ ebuf, u16* __restrict__ ebuf16, int* sh){
  int j = job_of_blk(m, bid);
  int lb = bid - m.pblk[j];
  const int* key = m.key[j];
  int E = m.E[j], r = m.r[j], B = m.B[j];
  int tid = threadIdx.x, wid = tid >> 6;
  int* wh = sh; int* wstart = sh + 256;
  wh[tid] = 0;
  __syncthreads();
  int base = lb*4096 + tid;
  int* mywh = wh + wid*64;
  #pragma unroll
  for (int i = 0; i < 16; ++i){ int e = base + i*256; if (e < E) atomicAdd(&mywh[key[e]/r], 1); }
  __syncthreads();
  if (tid < B){
    int h0 = wh[tid], h1 = wh[64+tid], h2 = wh[128+tid], h3 = wh[192+tid];
    int g = atomicAdd(&bktCur[m.boff[j] + tid], h0+h1+h2+h3);
    wstart[tid] = g;
    wstart[64+tid] = g + h0;
    wstart[128+tid] = g + h0 + h1;
    wstart[192+tid] = g + h0 + h1 + h2;
  }
  __syncthreads();
  int* myst = wstart + wid*64;
  if (j < 7){
    const int* src = m.src[j];
    #pragma unroll
    for (int i = 0; i < 16; ++i){
      int e = base + i*256;
      if (e < E){
        int s = src[e], d = key[e];
        int b = d / r;
        int pos = atomicAdd(&myst[b], 1);
        ebuf[pos] = ((u32)(d - b*r) << 17) | (u32)s;
      }
    }
  } else {
    #pragma unroll
    for (int i = 0; i < 16; ++i){
      int e = base + i*256;
      if (e < E){
        int k = key[e];
        int b = k / r;
        int pos = atomicAdd(&myst[b], 1);
        ebuf16[pos] = (u16)(k - b*r);
      }
    }
  }
}

__device__ __forceinline__ void dev_p3(const BMeta& m, int bb,
    const int* __restrict__ bktCnt, const int* __restrict__ bktBase,
    const u32* __restrict__ ebuf, const u16* __restrict__ ebuf16, int* sh){
  int j = 0;
  #pragma unroll
  for (int t = 1; t < 10; ++t) if (bb >= m.boff[t]) j = t;
  int b = bb - m.boff[j];
  int n = m.n[j], r = m.r[j];
  int node0 = b*r;
  int rr = min(r, n - node0);
  int gbase = bktBase[bb];
  int cnt = bktCnt[bb];
  int tid = threadIdx.x;
  if (j >= 7){
    int* hist = sh;
    for (int i = tid; i < rr; i += 256) hist[i] = 0;
    __syncthreads();
    for (int e = tid; e < cnt; e += 256) atomicAdd(&hist[ebuf16[gbase + e]], 1);
    __syncthreads();
    float* rs = m.rsout[j-7];
    for (int i = tid; i < rr; i += 256) rs[node0 + i] = rsqrtf(fmaxf((float)hist[i], 1.f));
    return;
  }
  int B = m.B[j];
  int* rowp = m.rowp[j]; int* csr = m.csr[j];
  int lbase = gbase - m.eoff[j];
  int* hist = sh; int* aux = sh + 1568;
  for (int i = tid; i < rr; i += 256) hist[i] = 0;
  __syncthreads();
  for (int e = tid; e < cnt; e += 256){ u32 pk = ebuf[gbase + e]; atomicAdd(&hist[pk >> 17], 1); }
  __syncthreads();
  int ch = (rr + 255) >> 8;
  int i0 = tid*ch;
  int s = 0;
  for (int k = 0; k < ch; ++k){ int idx = i0 + k; if (idx < rr){ int t = hist[idx]; hist[idx] = s; s += t; } }
  aux[tid] = s; __syncthreads();
  for (int off = 1; off < 256; off <<= 1){
    int v = aux[tid]; int a = (tid >= off) ? aux[tid - off] : 0;
    __syncthreads();
    aux[tid] = v + a;
    __syncthreads();
  }
  int pre = (tid ? aux[tid-1] : 0) + lbase;
  for (int k = 0; k < ch; ++k){ int idx = i0 + k; if (idx < rr) hist[idx] += pre; }
  __syncthreads();
  for (int i = tid; i < rr; i += 256) rowp[node0 + i] = hist[i];
  if (b == B-1 && tid == 0) rowp[n] = lbase + cnt;
  __syncthreads();
  for (int e = tid; e < cnt; e += 256){
    u32 pk = ebuf[gbase + e];
    int pos = atomicAdd(&hist[pk >> 17], 1);
    csr[pos] = (int)(pk & 0x1FFFFu);
  }
}

// ================= 16-lane gathers, 4-deep pipelined =================
template<int OB16>
__device__ __forceinline__ void dev_attn_gather16(int bid,
    const int* __restrict__ csr, const int* __restrict__ rowp,
    const float* __restrict__ w, const u16* __restrict__ V,
    void* __restrict__ out, int n)
{
  int g = threadIdx.x >> 4, lane = threadIdx.x & 15;
  int row = bid*16 + g;
  if (row >= n) return;
  int st = rowp[row], en = rowp[row+1];
  float a0=0,a1=0,a2=0,a3=0,a4=0,a5=0,a6=0,a7=0;
  if (en > st){
    const uint4* V8 = (const uint4*)V;
    float den = 0.f;
    int e = st;
    for (; e + 4 <= en; e += 4){
      int s0=csr[e], s1=csr[e+1], s2=csr[e+2], s3=csr[e+3];
      float x0=w[s0], x1=w[s1], x2=w[s2], x3=w[s3];
      uint4 v0=V8[(size_t)s0*16+lane], v1=V8[(size_t)s1*16+lane];
      uint4 v2=V8[(size_t)s2*16+lane], v3=V8[(size_t)s3*16+lane];
      den += x0+x1+x2+x3;
      a0=fmaf(x0,blo(v0.x),a0); a1=fmaf(x0,bhi(v0.x),a1); a2=fmaf(x0,blo(v0.y),a2); a3=fmaf(x0,bhi(v0.y),a3);
      a4=fmaf(x0,blo(v0.z),a4); a5=fmaf(x0,bhi(v0.z),a5); a6=fmaf(x0,blo(v0.w),a6); a7=fmaf(x0,bhi(v0.w),a7);
      a0=fmaf(x1,blo(v1.x),a0); a1=fmaf(x1,bhi(v1.x),a1); a2=fmaf(x1,blo(v1.y),a2); a3=fmaf(x1,bhi(v1.y),a3);
      a4=fmaf(x1,blo(v1.z),a4); a5=fmaf(x1,bhi(v1.z),a5); a6=fmaf(x1,blo(v1.w),a6); a7=fmaf(x1,bhi(v1.w),a7);
      a0=fmaf(x2,blo(v2.x),a0); a1=fmaf(x2,bhi(v2.x),a1); a2=fmaf(x2,blo(v2.y),a2); a3=fmaf(x2,bhi(v2.y),a3);
      a4=fmaf(x2,blo(v2.z),a4); a5=fmaf(x2,bhi(v2.z),a5); a6=fmaf(x2,blo(v2.w),a6); a7=fmaf(x2,bhi(v2.w),a7);
      a0=fmaf(x3,blo(v3.x),a0); a1=fmaf(x3,bhi(v3.x),a1); a2=fmaf(x3,blo(v3.y),a2); a3=fmaf(x3,bhi(v3.y),a3);
      a4=fmaf(x3,blo(v3.z),a4); a5=fmaf(x3,bhi(v3.z),a5); a6=fmaf(x3,blo(v3.w),a6); a7=fmaf(x3,bhi(v3.w),a7);
    }
    for (; e < en; ++e){
      int sn = csr[e];
      float x = w[sn];
      uint4 v = V8[(size_t)sn*16 + lane];
      den += x;
      a0=fmaf(x,blo(v.x),a0); a1=fmaf(x,bhi(v.x),a1); a2=fmaf(x,blo(v.y),a2); a3=fmaf(x,bhi(v.y),a3);
      a4=fmaf(x,blo(v.z),a4); a5=fmaf(x,bhi(v.z),a5); a6=fmaf(x,blo(v.w),a6); a7=fmaf(x,bhi(v.w),a7);
    }
    float inv = 1.f/den;
    a0*=inv; a1*=inv; a2*=inv; a3*=inv; a4*=inv; a5*=inv; a6*=inv; a7*=inv;
  }
  if (OB16){
    uint4 o; o.x = pk2(a0,a1); o.y = pk2(a2,a3); o.z = pk2(a4,a5); o.w = pk2(a6,a7);
    ((uint4*)out)[(size_t)row*16 + lane] = o;
  } else {
    float4* o4 = (float4*)out;
    o4[(size_t)row*32 + lane*2]     = make_float4(a0,a1,a2,a3);
    o4[(size_t)row*32 + lane*2 + 1] = make_float4(a4,a5,a6,a7);
  }
}

template<int OB16>
__device__ __forceinline__ void dev_gcn_gather16(int bid,
    const int* __restrict__ csr, const int* __restrict__ rowp,
    const float* __restrict__ rs, const u16* __restrict__ Y,
    const float* __restrict__ bias, void* __restrict__ out, int n)
{
  int g = threadIdx.x >> 4, lane = threadIdx.x & 15;
  int row = bid*16 + g;
  if (row >= n) return;
  int st = rowp[row], en = rowp[row+1];
  float a0=0,a1=0,a2=0,a3=0,a4=0,a5=0,a6=0,a7=0;
  const uint4* Y8 = (const uint4*)Y;
  int e = st;
  for (; e + 4 <= en; e += 4){
    int s0=csr[e], s1=csr[e+1], s2=csr[e+2], s3=csr[e+3];
    float x0=rs[s0], x1=rs[s1], x2=rs[s2], x3=rs[s3];
    uint4 v0=Y8[(size_t)s0*16+lane], v1=Y8[(size_t)s1*16+lane];
    uint4 v2=Y8[(size_t)s2*16+lane], v3=Y8[(size_t)s3*16+lane];
    a0=fmaf(x0,blo(v0.x),a0); a1=fmaf(x0,bhi(v0.x),a1); a2=fmaf(x0,blo(v0.y),a2); a3=fmaf(x0,bhi(v0.y),a3);
    a4=fmaf(x0,blo(v0.z),a4); a5=fmaf(x0,bhi(v0.z),a5); a6=fmaf(x0,blo(v0.w),a6); a7=fmaf(x0,bhi(v0.w),a7);
    a0=fmaf(x1,blo(v1.x),a0); a1=fmaf(x1,bhi(v1.x),a1); a2=fmaf(x1,blo(v1.y),a2); a3=fmaf(x1,bhi(v1.y),a3);
    a4=fmaf(x1,blo(v1.z),a4); a5=fmaf(x1,bhi(v1.z),a5); a6=fmaf(x1,blo(v1.w),a6); a7=fmaf(x1,bhi(v1.w),a7);
    a0=fmaf(x2,blo(v2.x),a0); a1=fmaf(x2,bhi(v2.x),a1); a2=fmaf(x2,blo(v2.y),a2); a3=fmaf(x2,bhi(v2.y),a3);
    a4=fmaf(x2,blo(v2.z),a4); a5=fmaf(x2,bhi(v2.z),a5); a6=fmaf(x2,blo(v2.w),a6); a7=fmaf(x2,bhi(v2.w),a7);
    a0=fmaf(x3,blo(v3.x),a0); a1=fmaf(x3,bhi(v3.x),a1); a2=fmaf(x3,blo(v3.y),a2); a3=fmaf(x3,bhi(v3.y),a3);
    a4=fmaf(x3,blo(v3.z),a4); a5=fmaf(x3,bhi(v3.z),a5); a6=fmaf(x3,blo(v3.w),a6); a7=fmaf(x3,bhi(v3.w),a7);
  }
  for (; e < en; ++e){
    int sn = csr[e];
    float x = rs[sn];
    uint4 v = Y8[(size_t)sn*16 + lane];
    a0=fmaf(x,blo(v.x),a0); a1=fmaf(x,bhi(v.x),a1); a2=fmaf(x,blo(v.y),a2); a3=fmaf(x,bhi(v.y),a3);
    a4=fmaf(x,blo(v.z),a4); a5=fmaf(x,bhi(v.z),a5); a6=fmaf(x,blo(v.w),a6); a7=fmaf(x,bhi(v.w),a7);
  }
  float sc = rsqrtf(fmaxf((float)(en - st), 1.f));
  const float4* b4 = (const float4*)bias;
  float4 ba = b4[lane*2], bb = b4[lane*2+1];
  float o0=fmaf(a0,sc,ba.x), o1=fmaf(a1,sc,ba.y), o2=fmaf(a2,sc,ba.z), o3=fmaf(a3,sc,ba.w);
  float o4v=fmaf(a4,sc,bb.x), o5=fmaf(a5,sc,bb.y), o6=fmaf(a6,sc,bb.z), o7=fmaf(a7,sc,bb.w);
  if (OB16){
    uint4 o; o.x = pk2(o0,o1); o.y = pk2(o2,o3); o.z = pk2(o4v,o5); o.w = pk2(o6,o7);
    ((uint4*)out)[(size_t)row*16 + lane] = o;
  } else {
    float4* o4 = (float4*)out;
    o4[(size_t)row*32 + lane*2]     = make_float4(o0,o1,o2,o3);
    o4[(size_t)row*32 + lane*2 + 1] = make_float4(o4v,o5,o6,o7);
  }
}

template<int GB16, int DB16>
__device__ __forceinline__ void dev_head(int bid, const void* __restrict__ g, const void* __restrict__ dch,
    const float* __restrict__ W, const float* __restrict__ b,
    float* __restrict__ out, int n, int rowOff)
{
  int wid = threadIdx.x >> 6, lane = threadIdx.x & 63;
  int row = bid*4 + wid;
  if (row >= n) return;
  float x0, x1, x2, x3;
  if (GB16){ const u16* gr = (const u16*)g + (size_t)row*FD; x0 = bf2f(gr[lane]); x1 = bf2f(gr[64+lane]); }
  else     { const float* gr = (const float*)g + (size_t)row*FD; x0 = gr[lane]; x1 = gr[64+lane]; }
  if (DB16){ const u16* dr = (const u16*)dch + (size_t)row*FD; x2 = bf2f(dr[lane]); x3 = bf2f(dr[64+lane]); }
  else     { const float* dr = (const float*)dch + (size_t)row*FD; x2 = dr[lane]; x3 = dr[64+lane]; }
  float acc[5];
  #pragma unroll
  for (int o = 0; o < 5; ++o)
    acc[o] = x0*W[lane*5+o] + x1*W[(64+lane)*5+o] + x2*W[(128+lane)*5+o] + x3*W[(192+lane)*5+o];
  #pragma unroll
  for (int o = 0; o < 5; ++o)
    #pragma unroll
    for (int s = 32; s; s >>= 1) acc[o] += __shfl_xor(acc[o], s);
  if (lane == 0){
    float m = -1e30f;
    #pragma unroll
    for (int o = 0; o < 5; ++o){ acc[o] += b[o]; m = fmaxf(m, acc[o]); }
    float sum = 0.f;
    #pragma unroll
    for (int o = 0; o < 5; ++o){ acc[o] = expf(acc[o]-m); sum += acc[o]; }
    float is = 1.0f/sum;
    float* op = out + (size_t)(rowOff+row)*5;
    #pragma unroll
    for (int o = 0; o < 5; ++o) op[o] = acc[o]*is;
  }
}

// ================= kernels =================

__global__ __launch_bounds__(256) void k1_prep(int* __restrict__ zeroBlk, int ntot,
    const float* __restrict__ ekW, const float* __restrict__ ekb, const float* __restrict__ eqb,
    const float* __restrict__ dkW, const float* __restrict__ dkb, const float* __restrict__ dqb,
    float* __restrict__ kv, float inv,
    const float* __restrict__ evW, const float* __restrict__ gW,
    const float* __restrict__ embW, const float* __restrict__ dvW,
    u16* __restrict__ wvt0, u16* __restrict__ wgt0, u16* __restrict__ wvt1, u16* __restrict__ wgt1,
    u16* __restrict__ wembT, u16* __restrict__ wvtd1)
{
  int bid = blockIdx.x;
  if (bid < 4){
    if (threadIdx.x < 128){
      int j = bid;
      const float* kW = (j < 2) ? ekW + j*16384 : dkW + (j-2)*16384;
      const float* kb = (j < 2) ? ekb + j*128   : dkb + (j-2)*128;
      const float* qb = (j < 2) ? eqb + j*128   : dqb + (j-2)*128;
      float* o = kv + j*132;
      int k = threadIdx.x;
      float a = 0.f;
      for (int t = 0; t < 128; ++t) a = fmaf(kW[k*128+t], qb[t], a);
      o[k] = a * inv;
      if (k == 0){
        float c = 0.f;
        for (int t = 0; t < 128; ++t) c = fmaf(kb[t], qb[t], c);
        o[128] = c * inv;
      }
    }
  } else if (bid < 10){
    const float* Ws; u16* Wd;
    if (bid == 4){ Ws = evW;            Wd = wvt0; }
    else if (bid == 5){ Ws = gW;        Wd = wgt0; }
    else if (bid == 6){ Ws = evW+16384; Wd = wvt1; }
    else if (bid == 7){ Ws = gW+16384;  Wd = wgt1; }
    else if (bid == 8){ Ws = embW;      Wd = wembT; }
    else              { Ws = dvW+16384; Wd = wvtd1; }
    for (int i = threadIdx.x; i < 16384; i += 256){
      int k = i >> 7, c = i & 127;
      Wd[c*128 + k] = f2bf(Ws[i]);
    }
  } else {
    int i = (bid-10)*256 + threadIdx.x;
    if (i < ntot) zeroBlk[i] = 0;
  }
}

// K2: P0 || MFMA h0 gemm (f32 A)
__global__ __launch_bounds__(256) void k2_p0_gemm(BMeta m, int* __restrict__ bktCnt,
    const float* __restrict__ X, const u16* __restrict__ wembT, const float* __restrict__ b,
    u16* __restrict__ bh0, int np0)
{
  __shared__ int sh[256];
  int bid = blockIdx.x;
  if (bid < np0) dev_p0(m, bid, bktCnt, sh);
  else dev_single_mfma<1,0>(bid - np0, X, wembT, b, nullptr, nullptr, bh0, N0);
}

// K3: P1
__global__ __launch_bounds__(256) void k3_p1(BMeta m,
    const int* __restrict__ bktCnt, int* __restrict__ bktBase, int* __restrict__ bktCur)
{
  __shared__ int sh[384];
  dev_p1(m, bktCnt, bktBase, bktCur, sh);
}

// K4: P2 || MFMA dual(h0) part 1
__global__ __launch_bounds__(256) void k4_p2_dual(BMeta m, int* __restrict__ bktCur,
    u32* __restrict__ ebuf, u16* __restrict__ ebuf16,
    const u16* __restrict__ bh0,
    const u16* __restrict__ wvt0, const u16* __restrict__ wgt0, const float* __restrict__ evb,
    const float* __restrict__ kvec, float* __restrict__ sS, u16* __restrict__ bV, u16* __restrict__ bY0,
    int np2, int gOff)
{
  __shared__ int sh[512];
  int bid = blockIdx.x;
  if (bid < np2) dev_p2(m, bid, bktCur, ebuf, ebuf16, sh);
  else dev_dual_mfma(gOff + bid - np2, bh0, wvt0, wgt0, evb, kvec, sS, bV, bY0, N0);
}

// K5: P3 || MFMA dual(h0) part 2
__global__ __launch_bounds__(256) void k5_p3_dual(BMeta m,
    const int* __restrict__ bktCnt, const int* __restrict__ bktBase,
    const u32* __restrict__ ebuf, const u16* __restrict__ ebuf16,
    const u16* __restrict__ bh0,
    const u16* __restrict__ wvt0, const u16* __restrict__ wgt0, const float* __restrict__ evb,
    const float* __restrict__ kvec, float* __restrict__ sS, u16* __restrict__ bV, u16* __restrict__ bY0,
    int np3, int gOff)
{
  __shared__ int sh[1824];
  int bid = blockIdx.x;
  if (bid < np3) dev_p3(m, bid, bktCnt, bktBase, ebuf, ebuf16, sh);
  else dev_dual_mfma(gOff + bid - np3, bh0, wvt0, wgt0, evb, kvec, sS, bV, bY0, N0);
}

// K6: attn_gather16(i0)->be1 || g0 slice
__global__ __launch_bounds__(256) void k6_ag_i0(
    const int* __restrict__ csrA, const int* __restrict__ rowpA,
    const float* __restrict__ sS, const u16* __restrict__ bV, u16* __restrict__ be1,
    const int* __restrict__ csr0, const int* __restrict__ rowp0, const float* __restrict__ rs0,
    const u16* __restrict__ bY0, const float* __restrict__ gb, u16* __restrict__ bg0, int nMain, int sBase)
{
  int bid = blockIdx.x;
  if (bid < nMain) dev_attn_gather16<1>(bid, csrA, rowpA, sS, bV, be1, N1);
  else dev_gcn_gather16<1>(sBase + bid - nMain, csr0, rowp0, rs0, bY0, gb, bg0, N0);
}

// K7: MFMA dual(be1 -> V1+score, Y1) || g0 slice
__global__ __launch_bounds__(256) void k7_dual_enc1(
    const u16* __restrict__ be1,
    const u16* __restrict__ wvt1, const u16* __restrict__ wgt1, const float* __restrict__ vb,
    const float* __restrict__ kvec, float* __restrict__ sS, u16* __restrict__ bV, u16* __restrict__ bY1,
    const int* __restrict__ csr0, const int* __restrict__ rowp0, const float* __restrict__ rs0,
    const u16* __restrict__ bY0, const float* __restrict__ gb, u16* __restrict__ bg0, int nMain, int sBase)
{
  int bid = blockIdx.x;
  if (bid < nMain) dev_dual_mfma(bid, be1, wvt1, wgt1, vb, kvec, sS, bV, bY1, N1);
  else dev_gcn_gather16<1>(sBase + bid - nMain, csr0, rowp0, rs0, bY0, gb, bg0, N0);
}

// K8: attn_gather16(i1)->be2(f32) || g0 slice
__global__ __launch_bounds__(256) void k8_ag_i1(
    const int* __restrict__ csrA, const int* __restrict__ rowpA,
    const float* __restrict__ sS, const u16* __restrict__ bV, float* __restrict__ be2,
    const int* __restrict__ csr0, const int* __restrict__ rowp0, const float* __restrict__ rs0,
    const u16* __restrict__ bY0, const float* __restrict__ gb, u16* __restrict__ bg0, int nMain, int sBase)
{
  int bid = blockIdx.x;
  if (bid < nMain) dev_attn_gather16<0>(bid, csrA, rowpA, sS, bV, be2, N2);
  else dev_gcn_gather16<1>(sBase + bid - nMain, csr0, rowp0, rs0, bY0, gb, bg0, N0);
}

// K9: gcn2-Y gemm (f32 A) || gcn_gather16(g1)->bg1 || g0 slice
__global__ __launch_bounds__(256) void k9_y2_g1(
    const float* __restrict__ be2, const float* __restrict__ W2, u16* __restrict__ bY2,
    const int* __restrict__ csr1, const int* __restrict__ rowp1, const float* __restrict__ rs1,
    const u16* __restrict__ bY1, const float* __restrict__ b1, u16* __restrict__ bg1,
    const int* __restrict__ csr0, const int* __restrict__ rowp0, const float* __restrict__ rs0,
    const u16* __restrict__ bY0, const float* __restrict__ gb, u16* __restrict__ bg0,
    int ngemm, int nMain, int sBase)
{
  __shared__ float sm[5120];
  int bid = blockIdx.x;
  if (bid < ngemm) dev_gemm<0,0>(sm, sm+4096, bid, be2, W2, nullptr, nullptr, nullptr, bY2, N2);
  else if (bid < nMain) dev_gcn_gather16<1>(bid - ngemm, csr1, rowp1, rs1, bY1, b1, bg1, N1);
  else dev_gcn_gather16<1>(sBase + bid - nMain, csr0, rowp0, rs0, bY0, gb, bg0, N0);
}

// K10: gcn_gather16(g2)->bg2(f32) || g0 slice
__global__ __launch_bounds__(256) void k10_g2(
    const int* __restrict__ csr2, const int* __restrict__ rowp2, const float* __restrict__ rs2,
    const u16* __restrict__ bY2, const float* __restrict__ b2, float* __restrict__ bg2,
    const int* __restrict__ csr0, const int* __restrict__ rowp0, const float* __restrict__ rs0,
    const u16* __restrict__ bY0, const float* __restrict__ gb, u16* __restrict__ bg0, int nMain, int sBase)
{
  int bid = blockIdx.x;
  if (bid < nMain) dev_gcn_gather16<0>(bid, csr2, rowp2, rs2, bY2, b2, bg2, N2);
  else dev_gcn_gather16<1>(sBase + bid - nMain, csr0, rowp0, rs0, bY0, gb, bg0, N0);
}

// K11: dec0 gemm (f32 A) || head2 || g0 slice
__global__ __launch_bounds__(256) void k11_dec0_head2(
    const float* __restrict__ bg2, const float* __restrict__ vW, const float* __restrict__ vb,
    const float* __restrict__ kvec, float* __restrict__ sS, u16* __restrict__ bV,
    const float* __restrict__ hW, const float* __restrict__ hb, float* __restrict__ out,
    const int* __restrict__ csr0, const int* __restrict__ rowp0, const float* __restrict__ rs0,
    const u16* __restrict__ bY0, const float* __restrict__ gb, u16* __restrict__ bg0,
    int ngemm, int nMain, int sBase)
{
  __shared__ float sm[5120];
  int bid = blockIdx.x;
  if (bid < ngemm) dev_gemm<1,0>(sm, sm+4096, bid, bg2, vW, vb, kvec, sS, bV, N2);
  else if (bid < nMain) dev_head<0,0>(bid - ngemm, bg2, bg2, hW, hb, out, N2, N0+N1);
  else dev_gcn_gather16<1>(sBase + bid - nMain, csr0, rowp0, rs0, bY0, gb, bg0, N0);
}

// K12: attn_gather16(dc0)->be1 (d1) || g0 slice
__global__ __launch_bounds__(256) void k12_ag_d1(
    const int* __restrict__ csrA, const int* __restrict__ rowpA,
    const float* __restrict__ sS, const u16* __restrict__ bV, u16* __restrict__ be1,
    const int* __restrict__ csr0, const int* __restrict__ rowp0, const float* __restrict__ rs0,
    const u16* __restrict__ bY0, const float* __restrict__ gb, u16* __restrict__ bg0, int nMain, int sBase)
{
  int bid = blockIdx.x;
  if (bid < nMain) dev_attn_gather16<1>(bid, csrA, rowpA, sS, bV, be1, N1);
  else dev_gcn_gather16<1>(sBase + bid - nMain, csr0, rowp0, rs0, bY0, gb, bg0, N0);
}

// K13: MFMA dec1 gemm (bf16 A, +score) || head1 || g0 slice
__global__ __launch_bounds__(256) void k13_dec1_head1(
    const u16* __restrict__ be1, const u16* __restrict__ wvtd1, const float* __restrict__ vb,
    const float* __restrict__ kvec, float* __restrict__ sS, u16* __restrict__ bV,
    const u16* __restrict__ bg1, const float* __restrict__ hW, const float* __restrict__ hb,
    float* __restrict__ out,
    const int* __restrict__ csr0, const int* __restrict__ rowp0, const float* __restrict__ rs0,
    const u16* __restrict__ bY0, const float* __restrict__ gb, u16* __restrict__ bg0,
    int ngemm, int nMain, int sBase)
{
  int bid = blockIdx.x;
  if (bid < ngemm) dev_single_mfma<0,1>(bid, be1, wvtd1, vb, kvec, sS, bV, N1);
  else if (bid < nMain) dev_head<1,1>(bid - ngemm, bg1, be1, hW, hb, out, N1, N0);
  else dev_gcn_gather16<1>(sBase + bid - nMain, csr0, rowp0, rs0, bY0, gb, bg0, N0);
}

// K14: fused d0 gather + head0 (16-lane, 4-deep)
__global__ __launch_bounds__(256) void k14_gather_head0(
    const int* __restrict__ csr, const int* __restrict__ rowp,
    const float* __restrict__ w, const u16* __restrict__ V,
    const u16* __restrict__ bg0,
    const float* __restrict__ hW, const float* __restrict__ hb,
    float* __restrict__ out)
{
  int g = threadIdx.x >> 4, lane = threadIdx.x & 15;
  int row = blockIdx.x*16 + g;
  if (row >= N0) return;
  int st = rowp[row], en = rowp[row+1];
  float a0=0,a1=0,a2=0,a3=0,a4=0,a5=0,a6=0,a7=0;
  if (en > st){
    const uint4* V8 = (const uint4*)V;
    float den = 0.f;
    int e = st;
    for (; e + 4 <= en; e += 4){
      int s0=csr[e], s1=csr[e+1], s2=csr[e+2], s3=csr[e+3];
      float x0=w[s0], x1=w[s1], x2=w[s2], x3=w[s3];
      uint4 v0=V8[(size_t)s0*16+lane], v1=V8[(size_t)s1*16+lane];
      uint4 v2=V8[(size_t)s2*16+lane], v3=V8[(size_t)s3*16+lane];
      den += x0+x1+x2+x3;
      a0=fmaf(x0,blo(v0.x),a0); a1=fmaf(x0,bhi(v0.x),a1); a2=fmaf(x0,blo(v0.y),a2); a3=fmaf(x0,bhi(v0.y),a3);
      a4=fmaf(x0,blo(v0.z),a4); a5=fmaf(x0,bhi(v0.z),a5); a6=fmaf(x0,blo(v0.w),a6); a7=fmaf(x0,bhi(v0.w),a7);
      a0=fmaf(x1,blo(v1.x),a0); a1=fmaf(x1,bhi(v1.x),a1); a2=fmaf(x1,blo(v1.y),a2); a3=fmaf(x1,bhi(v1.y),a3);
      a4=fmaf(x1,blo(v1.z),a4); a5=fmaf(x1,bhi(v1.z),a5); a6=fmaf(x1,blo(v1.w),a6); a7=fmaf(x1,bhi(v1.w),a7);
      a0=fmaf(x2,blo(v2.x),a0); a1=fmaf(x2,bhi(v2.x),a1); a2=fmaf(x2,blo(v2.y),a2); a3=fmaf(x2,bhi(v2.y),a3);
      a4=fmaf(x2,blo(v2.z),a4); a5=fmaf(x2,bhi(v2.z),a5); a6=fmaf(x2,blo(v2.w),a6); a7=fmaf(x2,bhi(v2.w),a7);
      a0=fmaf(x3,blo(v3.x),a0); a1=fmaf(x3,bhi(v3.x),a1); a2=fmaf(x3,blo(v3.y),a2); a3=fmaf(x3,bhi(v3.y),a3);
      a4=fmaf(x3,blo(v3.z),a4); a5=fmaf(x3,bhi(v3.z),a5); a6=fmaf(x3,blo(v3.w),a6); a7=fmaf(x3,bhi(v3.w),a7);
    }
    for (; e < en; ++e){
      int sn = csr[e];
      float x = w[sn];
      uint4 v = V8[(size_t)sn*16 + lane];
      den += x;
      a0=fmaf(x,blo(v.x),a0); a1=fmaf(x,bhi(v.x),a1); a2=fmaf(x,blo(v.y),a2); a3=fmaf(x,bhi(v.y),a3);
      a4=fmaf(x,blo(v.z),a4); a5=fmaf(x,bhi(v.z),a5); a6=fmaf(x,blo(v.w),a6); a7=fmaf(x,bhi(v.w),a7);
    }
    float inv = 1.f/den;
    a0*=inv; a1*=inv; a2*=inv; a3*=inv; a4*=inv; a5*=inv; a6*=inv; a7*=inv;
  }
  uint4 gv = ((const uint4*)(bg0 + (size_t)row*FD))[lane];
  float g0 = blo(gv.x), g1 = bhi(gv.x), g2 = blo(gv.y), g3 = bhi(gv.y);
  float g4 = blo(gv.z), g5 = bhi(gv.z), g6 = blo(gv.w), g7 = bhi(gv.w);
  int j = 8*lane;
  float acc[5];
  #pragma unroll
  for (int o = 0; o < 5; ++o){
    acc[o] = g0*hW[(j+0)*5+o] + g1*hW[(j+1)*5+o] + g2*hW[(j+2)*5+o] + g3*hW[(j+3)*5+o]
           + g4*hW[(j+4)*5+o] + g5*hW[(j+5)*5+o] + g6*hW[(j+6)*5+o] + g7*hW[(j+7)*5+o]
           + a0*hW[(128+j+0)*5+o] + a1*hW[(128+j+1)*5+o] + a2*hW[(128+j+2)*5+o] + a3*hW[(128+j+3)*5+o]
           + a4*hW[(128+j+4)*5+o] + a5*hW[(128+j+5)*5+o] + a6*hW[(128+j+6)*5+o] + a7*hW[(128+j+7)*5+o];
  }
  #pragma unroll
  for (int o = 0; o < 5; ++o)
    #pragma unroll
    for (int s = 8; s; s >>= 1) acc[o] += __shfl_xor(acc[o], s, 16);
  if (lane == 0){
    float m = -1e30f;
    #pragma unroll
    for (int o = 0; o < 5; ++o){ acc[o] += hb[o]; m = fmaxf(m, acc[o]); }
    float sum = 0.f;
    #pragma unroll
    for (int o = 0; o < 5; ++o){ acc[o] = expf(acc[o]-m); sum += acc[o]; }
    float is = 1.0f/sum;
    float* op = out + (size_t)row*5;
    #pragma unroll
    for (int o = 0; o < 5; ++o) op[o] = acc[o]*is;
  }
}

// ================= host =================
extern "C" void kernel_launch(void* const* d_in, const int* in_sizes, int n_in,
                              void* d_out, int out_size, void* d_ws, size_t ws_size,
                              hipStream_t stream)
{
  const float* X      = (const float*)d_in[0];
  const float* emb_W  = (const float*)d_in[1];
  const float* emb_b  = (const float*)d_in[2];
  const float* gcn_W  = (const float*)d_in[3];
  const float* gcn_b  = (const float*)d_in[4];
  const float* enc_qb = (const float*)d_in[6];
  const float* enc_kW = (const float*)d_in[7];
  const float* enc_kb = (const float*)d_in[8];
  const float* enc_vW = (const float*)d_in[9];
  const float* enc_vb = (const float*)d_in[10];
  const float* dec_qb = (const float*)d_in[12];
  const float* dec_kW = (const float*)d_in[13];
  const float* dec_kb = (const float*)d_in[14];
  const float* dec_vW = (const float*)d_in[15];
  const float* dec_vb = (const float*)d_in[16];
  const float* head_W = (const float*)d_in[17];
  const float* head_b = (const float*)d_in[18];
  const int* g0s  = (const int*)d_in[19];
  const int* g0d  = (const int*)d_in[20];
  const int* g1s  = (const int*)d_in[21];
  const int* g1d  = (const int*)d_in[22];
  const int* g2s  = (const int*)d_in[23];
  const int* g2d  = (const int*)d_in[24];
  const int* i0s  = (const int*)d_in[25];
  const int* i0d  = (const int*)d_in[26];
  const int* i1s  = (const int*)d_in[27];
  const int* i1d  = (const int*)d_in[28];
  const int* dc0s = (const int*)d_in[29];
  const int* dc0d = (const int*)d_in[30];
  const int* dc1s = (const int*)d_in[31];
  const int* dc1d = (const int*)d_in[32];

  // ---- workspace layout ----
  float* ws = (float*)d_ws;
  float* sS  = ws;                          // N0
  float* kvec = sS + N0;                    // 4*132
  float* be2 = kvec + 4*132;                // N2*FD f32
  float* bg2 = be2 + (size_t)N2*FD;         // N2*FD f32
  float* rs0 = bg2 + (size_t)N2*FD;         // N0
  float* rs1 = rs0 + N0;                    // N1
  float* rs2 = rs1 + N1;                    // N2 (+2 pad)
  u16*  bh0 = (u16*)(rs2 + N2 + 2);         // N0*FD u16
  u16*  be1 = bh0 + (size_t)N0*FD;          // N1*FD u16
  u16*  bg0 = be1 + (size_t)N1*FD;          // N0*FD u16
  u16*  bg1 = bg0 + (size_t)N0*FD;          // N1*FD u16
  u16*  bV  = bg1 + (size_t)N1*FD;          // N0*FD u16 (V tables, time-shared)
  u16*  bY0 = bV  + (size_t)N0*FD;          // N0*FD u16
  u16*  bY1 = bV + 4000000;                 // alias into bV tail
  u16*  bY2 = bV + 8000000;
  int*  bktCnt  = (int*)(bY0 + (size_t)N0*FD);  // 328
  int*  bktBase = bktCnt + 328;                 // 328
  int*  bktCur  = bktBase + 328;                // 328
  int*  rowpBlk = bktCur + 328;                 // 287507
  int*  csrBlk  = rowpBlk + 287507;             // 2,500,000
  u32*  ebuf    = (u32*)(csrBlk + 2500000);     // 2.5M u32
  u16*  ebuf16  = (u16*)(ebuf + 2500000);       // 1.5M u16
  uintptr_t wtp = ((uintptr_t)(ebuf16 + 1500000) + 15) & ~(uintptr_t)15;
  u16* wvt0 = (u16*)wtp;                        // 16384 each
  u16* wgt0 = wvt0 + 16384;
  u16* wvt1 = wgt0 + 16384;
  u16* wgt1 = wvt1 + 16384;
  u16* wembT = wgt1 + 16384;
  u16* wvtd1 = wembT + 16384;

  const int* keyP[10] = {g0d,g1d,g2d,i0d,i1d,dc0d,dc1d, g0s,g1s,g2s};
  const int* srcP[7]  = {g0s,g1s,g2s,i0s,i1s,dc0s,dc1s};
  const int nArr[10] = {N0,N1,N2,N1,N2,N1,N0, N0,N1,N2};
  const int EArr[10] = {1000000,400000,100000,400000,100000,100000,400000, 1000000,400000,100000};
  const int BArr[10] = {64,32,8,32,8,16,64, 64,32,8};
  const int rArr[10] = {1563,782,782,782,782,1563,1563, 1563,782,782};

  BMeta m;
  {
    int eo=0, so=0, bo=0, po=0, ro=0, co=0;
    for (int j=0;j<10;++j){
      m.key[j]=keyP[j];
      m.n[j]=nArr[j]; m.E[j]=EArr[j]; m.B[j]=BArr[j]; m.r[j]=rArr[j];
      m.boff[j]=bo; m.pblk[j]=po;
      bo+=BArr[j]; po+=ceildiv(EArr[j],4096);
      if (j < 7){
        m.src[j]=srcP[j]; m.rowp[j]=rowpBlk+ro; m.csr[j]=csrBlk+co;
        m.eoff[j]=eo; eo+=EArr[j]; ro+=nArr[j]+1; co+=EArr[j];
      } else {
        m.soff[j-7]=so; so+=EArr[j];
      }
    }
    m.eoff[7]=eo; m.soff[3]=so; m.boff[10]=bo; m.pblk[10]=po;
  }
  m.rsout[0]=rs0; m.rsout[1]=rs1; m.rsout[2]=rs2;

  const float invScale = 0.17677669529663687f;
  float* out = (float*)d_out;

  const int NP = m.pblk[10];                // 982
  const int NB = m.boff[10];                // 328
  const int GH0 = ceildiv(N0,32);           // 3125
  const int GH1 = ceildiv(N1,32);           // 782
  const int GH2 = ceildiv(N2,32);           // 196
  const int GS1 = 1900;                     // dual(h0) share in K4
  const int GA1_16 = ceildiv(N1,16);        // 1563
  const int GA2_16 = ceildiv(N2,16);        // 391
  const int G0B16  = ceildiv(N0,16);        // 6250
  const int GH2H = ceildiv(N2,4);           // 1563
  const int GH1H = ceildiv(N1,4);           // 6250

  int ss[9];
  for (int i = 0; i <= 8; ++i) ss[i] = (int)(((long long)G0B16 * i) / 8);

  // K1: kvec || W transposes || zero bktCnt
  k1_prep<<<10 + ceildiv(NB,256), 256, 0, stream>>>(bktCnt, NB,
      enc_kW, enc_kb, enc_qb, dec_kW, dec_kb, dec_qb, kvec, invScale,
      enc_vW, gcn_W, emb_W, dec_vW, wvt0, wgt0, wvt1, wgt1, wembT, wvtd1);
  // K2: P0 || MFMA h0 gemm
  k2_p0_gemm<<<NP + GH0, 256, 0, stream>>>(m, bktCnt, X, wembT, emb_b, bh0, NP);
  // K3: P1
  k3_p1<<<1, 256, 0, stream>>>(m, bktCnt, bktBase, bktCur);
  // K4: P2 || MFMA dual(h0) part 1
  k4_p2_dual<<<NP + GS1, 256, 0, stream>>>(m, bktCur, ebuf, ebuf16,
      bh0, wvt0, wgt0, enc_vb, kvec, sS, bV, bY0, NP, 0);
  // K5: P3 || MFMA dual(h0) part 2
  k5_p3_dual<<<NB + (GH0 - GS1), 256, 0, stream>>>(m, bktCnt, bktBase, ebuf, ebuf16,
      bh0, wvt0, wgt0, enc_vb, kvec, sS, bV, bY0, NB, GS1);
  // K6: attn_gather(i0)->be1 || g0[0]
  k6_ag_i0<<<GA1_16 + (ss[1]-ss[0]), 256, 0, stream>>>(m.csr[3], m.rowp[3], sS, bV, be1,
      m.csr[0], m.rowp[0], rs0, bY0, gcn_b, bg0, GA1_16, ss[0]);
  // K7: MFMA dual(be1 -> V1, Y1) || g0[1]
  k7_dual_enc1<<<GH1 + (ss[2]-ss[1]), 256, 0, stream>>>(be1,
      wvt1, wgt1, enc_vb+128, kvec+132, sS, bV, bY1,
      m.csr[0], m.rowp[0], rs0, bY0, gcn_b, bg0, GH1, ss[1]);
  // K8: attn_gather(i1)->be2 || g0[2]
  k8_ag_i1<<<GA2_16 + (ss[3]-ss[2]), 256, 0, stream>>>(m.csr[4], m.rowp[4], sS, bV, be2,
      m.csr[0], m.rowp[0], rs0, bY0, gcn_b, bg0, GA2_16, ss[2]);
  // K9: gcn2-Y || gather(g1)->bg1 || g0[3]
  k9_y2_g1<<<GH2 + GA1_16 + (ss[4]-ss[3]), 256, 0, stream>>>(be2, gcn_W+32768, bY2,
      m.csr[1], m.rowp[1], rs1, bY1, gcn_b+128, bg1,
      m.csr[0], m.rowp[0], rs0, bY0, gcn_b, bg0, GH2, GH2+GA1_16, ss[3]);
  // K10: gather(g2)->bg2 || g0[4]
  k10_g2<<<GA2_16 + (ss[5]-ss[4]), 256, 0, stream>>>(m.csr[2], m.rowp[2], rs2, bY2, gcn_b+256, bg2,
      m.csr[0], m.rowp[0], rs0, bY0, gcn_b, bg0, GA2_16, ss[4]);
  // K11: dec0 gemm || head2 || g0[5]
  k11_dec0_head2<<<GH2 + GH2H + (ss[6]-ss[5]), 256, 0, stream>>>(bg2, dec_vW, dec_vb, kvec+264, sS, bV,
      head_W+2560, head_b+10, out,
      m.csr[0], m.rowp[0], rs0, bY0, gcn_b, bg0, GH2, GH2+GH2H, ss[5]);
  // K12: attn_gather(dc0)->be1 (d1) || g0[6]
  k12_ag_d1<<<GA1_16 + (ss[7]-ss[6]), 256, 0, stream>>>(m.csr[5], m.rowp[5], sS, bV, be1,
      m.csr[0], m.rowp[0], rs0, bY0, gcn_b, bg0, GA1_16, ss[6]);
  // K13: MFMA dec1 gemm || head1 || g0[7]
  k13_dec1_head1<<<GH1 + GH1H + (ss[8]-ss[7]), 256, 0, stream>>>(be1, wvtd1, dec_vb+128, kvec+396, sS, bV,
      bg1, head_W+1280, head_b+5, out,
      m.csr[0], m.rowp[0], rs0, bY0, gcn_b, bg0, GH1, GH1+GH1H, ss[7]);
  // K14: fused d0 gather + head0
  k14_gather_head0<<<G0B16, 256, 0, stream>>>(m.csr[6], m.rowp[6], sS, bV, bg0,
      head_W, head_b, out);
}

// Round 16
// 386.546 us; speedup vs baseline: 12.8855x; 1.0790x over previous
//
#include <hip/hip_runtime.h>
#include <math.h>
#include <stdint.h>

#define N0 100000
#define N1 25000
#define N2 6250
#define FD 128

typedef unsigned short u16;
typedef unsigned int u32;
typedef short bf16x8 __attribute__((ext_vector_type(8)));
typedef float f32x4 __attribute__((ext_vector_type(4)));

static inline int ceildiv(int a, int b){ return (a + b - 1)/b; }

__device__ __forceinline__ u16 f2bf(float f){
  u32 u = __float_as_uint(f);
  u += 0x7fffu + ((u >> 16) & 1u);
  return (u16)(u >> 16);
}
__device__ __forceinline__ float bf2f(u16 h){
  return __uint_as_float(((u32)h) << 16);
}
__device__ __forceinline__ float blo(u32 u){ return __uint_as_float(u << 16); }
__device__ __forceinline__ float bhi(u32 u){ return __uint_as_float(u & 0xffff0000u); }
__device__ __forceinline__ u32 pk2(float a, float b){ return (u32)f2bf(a) | ((u32)f2bf(b) << 16); }

// ================= bucket metadata: 10 jobs =================
struct BMeta {
  const int* key[10];
  const int* src[7];
  int* rowp[7]; int* csr[7];
  float* rsout[3];
  int n[10], E[10], B[10], r[10];
  int cap[10];
  int ebase[10];
  int boff[11];
  int pblk[11];
};

__device__ __forceinline__ int capbase(const BMeta& m, int bb){
  int j = 0;
  #pragma unroll
  for (int t = 1; t < 10; ++t) if (bb >= m.boff[t]) j = t;
  return m.ebase[j] + (bb - m.boff[j]) * m.cap[j];
}

// ================= FMA GEMM (small cases) =================
__device__ __forceinline__ void mm_inner(const float* Al, const float* Wl, int r0, int c0, float acc[4][4]){
  #pragma unroll
  for (int kq = 0; kq < 8; ++kq) {
    int k0 = kq*4;
    float4 a[4], w[4];
    #pragma unroll
    for (int i=0;i<4;++i) a[i] = *(const float4*)&Al[(r0+i)*32 + k0];
    #pragma unroll
    for (int kk=0;kk<4;++kk) w[kk] = *(const float4*)&Wl[(k0+kk)*128 + c0];
    #pragma unroll
    for (int i=0;i<4;++i){
      acc[i][0] = fmaf(a[i].x,w[0].x, fmaf(a[i].y,w[1].x, fmaf(a[i].z,w[2].x, fmaf(a[i].w,w[3].x, acc[i][0]))));
      acc[i][1] = fmaf(a[i].x,w[0].y, fmaf(a[i].y,w[1].y, fmaf(a[i].z,w[2].y, fmaf(a[i].w,w[3].y, acc[i][1]))));
      acc[i][2] = fmaf(a[i].x,w[0].z, fmaf(a[i].y,w[1].z, fmaf(a[i].z,w[2].z, fmaf(a[i].w,w[3].z, acc[i][2]))));
      acc[i][3] = fmaf(a[i].x,w[0].w, fmaf(a[i].y,w[1].w, fmaf(a[i].z,w[2].w, fmaf(a[i].w,w[3].w, acc[i][3]))));
    }
  }
}

template<int SCORE, int AB16>
__device__ __forceinline__ void dev_gemm(float* Wl, float* Al, int bid,
    const void* __restrict__ Ap,
    const float* __restrict__ W, const float* __restrict__ bias,
    const float* __restrict__ kvec, float* __restrict__ sOut,
    u16* __restrict__ out, int n)
{
  const int tid = threadIdx.x;
  const int row0 = bid * 32;
  const int c0 = (tid & 31) * 4, r0 = (tid >> 5) * 4;
  const int r = tid >> 3, fc = tid & 7;
  const int gr_s = row0 + r;
  float acc[4][4] = {};
  float sacc = 0.f;
  const float4* W4 = (const float4*)W;
  for (int kp = 0; kp < 4; ++kp) {
    float4* Wl4 = (float4*)Wl;
    #pragma unroll
    for (int i = 0; i < 4; ++i) Wl4[tid + 256*i] = W4[kp*1024 + tid + 256*i];
    {
      float4 v = make_float4(0.f,0.f,0.f,0.f);
      if (gr_s < n){
        if (AB16){
          ushort4 h = ((const ushort4*)Ap)[(size_t)gr_s*32 + kp*8 + fc];
          v = make_float4(bf2f(h.x), bf2f(h.y), bf2f(h.z), bf2f(h.w));
        } else {
          v = ((const float4*)Ap)[(size_t)gr_s*32 + kp*8 + fc];
        }
      }
      ((float4*)Al)[tid] = v;
      if (SCORE){
        float4 kv = *(const float4*)&kvec[kp*32 + fc*4];
        sacc += v.x*kv.x + v.y*kv.y + v.z*kv.z + v.w*kv.w;
      }
    }
    __syncthreads();
    mm_inner(Al, Wl, r0, c0, acc);
    __syncthreads();
  }
  if (SCORE){
    sacc += __shfl_xor(sacc, 1);
    sacc += __shfl_xor(sacc, 2);
    sacc += __shfl_xor(sacc, 4);
    if (fc == 0 && gr_s < n) sOut[gr_s] = expf(sacc + kvec[128]);
  }
  float4 bv = make_float4(0.f,0.f,0.f,0.f);
  if (bias) bv = *(const float4*)&bias[c0];
  #pragma unroll
  for (int i=0;i<4;++i){
    int gr = row0 + r0 + i;
    if (gr < n){
      ushort4 o;
      o.x = f2bf(acc[i][0]+bv.x); o.y = f2bf(acc[i][1]+bv.y);
      o.z = f2bf(acc[i][2]+bv.z); o.w = f2bf(acc[i][3]+bv.w);
      *(ushort4*)&out[(size_t)gr*FD + c0] = o;
    }
  }
}

// ================= MFMA GEMMs (LDS-free) =================
__device__ __forceinline__ void dev_dual_mfma(int bid,
    const u16* __restrict__ A, const u16* __restrict__ WvT, const u16* __restrict__ WgT,
    const float* __restrict__ vb, const float* __restrict__ kvec, float* __restrict__ sOut,
    u16* __restrict__ Vout, u16* __restrict__ Yout, int n)
{
  const int tid = threadIdx.x;
  const int wid = tid >> 6, lane = tid & 63;
  const int l15 = lane & 15, lg = lane >> 4;
  const int rt = wid & 1;
  const int cbase = (wid >> 1) * 64;
  const int row0 = bid * 32;
  const int arow = row0 + rt*16 + l15;
  const int arowc = min(arow, n-1);
  f32x4 accV[4] = {{0.f,0.f,0.f,0.f},{0.f,0.f,0.f,0.f},{0.f,0.f,0.f,0.f},{0.f,0.f,0.f,0.f}};
  f32x4 accY[4] = {{0.f,0.f,0.f,0.f},{0.f,0.f,0.f,0.f},{0.f,0.f,0.f,0.f},{0.f,0.f,0.f,0.f}};
  float sacc = 0.f;
  #pragma unroll
  for (int ks = 0; ks < 4; ++ks){
    const int ko = ks*32 + lg*8;
    bf16x8 a = *(const bf16x8*)(A + (size_t)arowc*FD + ko);
    if (wid < 2){
      float4 k0 = *(const float4*)(kvec + ko);
      float4 k1 = *(const float4*)(kvec + ko + 4);
      sacc += bf2f((u16)a[0])*k0.x + bf2f((u16)a[1])*k0.y + bf2f((u16)a[2])*k0.z + bf2f((u16)a[3])*k0.w
            + bf2f((u16)a[4])*k1.x + bf2f((u16)a[5])*k1.y + bf2f((u16)a[6])*k1.z + bf2f((u16)a[7])*k1.w;
    }
    #pragma unroll
    for (int ct = 0; ct < 4; ++ct){
      const int col = cbase + ct*16 + l15;
      bf16x8 bv = *(const bf16x8*)(WvT + (size_t)col*FD + ko);
      bf16x8 bg = *(const bf16x8*)(WgT + (size_t)col*FD + ko);
      accV[ct] = __builtin_amdgcn_mfma_f32_16x16x32_bf16(a, bv, accV[ct], 0, 0, 0);
      accY[ct] = __builtin_amdgcn_mfma_f32_16x16x32_bf16(a, bg, accY[ct], 0, 0, 0);
    }
  }
  if (wid < 2){
    sacc += __shfl_xor(sacc, 16);
    sacc += __shfl_xor(sacc, 32);
    if (lane < 16 && arow < n) sOut[arow] = expf(sacc + kvec[128]);
  }
  #pragma unroll
  for (int ct = 0; ct < 4; ++ct){
    const int col = cbase + ct*16 + l15;
    const float bvv = vb[col];
    #pragma unroll
    for (int i = 0; i < 4; ++i){
      int gr = row0 + rt*16 + lg*4 + i;
      if (gr < n){
        Vout[(size_t)gr*FD + col] = f2bf(accV[ct][i] + bvv);
        Yout[(size_t)gr*FD + col] = f2bf(accY[ct][i]);
      }
    }
  }
}

template<int AF32, int SCORE>
__device__ __forceinline__ void dev_single_mfma(int bid,
    const void* __restrict__ Ap, const u16* __restrict__ WT,
    const float* __restrict__ bias,
    const float* __restrict__ kvec, float* __restrict__ sOut,
    u16* __restrict__ out, int n)
{
  const int tid = threadIdx.x;
  const int wid = tid >> 6, lane = tid & 63;
  const int l15 = lane & 15, lg = lane >> 4;
  const int rt = wid & 1;
  const int cbase = (wid >> 1) * 64;
  const int row0 = bid * 32;
  const int arow = row0 + rt*16 + l15;
  const int arowc = min(arow, n-1);
  f32x4 acc[4] = {{0.f,0.f,0.f,0.f},{0.f,0.f,0.f,0.f},{0.f,0.f,0.f,0.f},{0.f,0.f,0.f,0.f}};
  float sacc = 0.f;
  #pragma unroll
  for (int ks = 0; ks < 4; ++ks){
    const int ko = ks*32 + lg*8;
    bf16x8 a;
    if (AF32){
      const float* Af = (const float*)Ap + (size_t)arowc*FD + ko;
      float4 f0 = *(const float4*)Af;
      float4 f1 = *(const float4*)(Af + 4);
      a[0]=(short)f2bf(f0.x); a[1]=(short)f2bf(f0.y); a[2]=(short)f2bf(f0.z); a[3]=(short)f2bf(f0.w);
      a[4]=(short)f2bf(f1.x); a[5]=(short)f2bf(f1.y); a[6]=(short)f2bf(f1.z); a[7]=(short)f2bf(f1.w);
      if (SCORE && wid < 2){
        float4 k0 = *(const float4*)(kvec + ko);
        float4 k1 = *(const float4*)(kvec + ko + 4);
        sacc += f0.x*k0.x + f0.y*k0.y + f0.z*k0.z + f0.w*k0.w
              + f1.x*k1.x + f1.y*k1.y + f1.z*k1.z + f1.w*k1.w;
      }
    } else {
      a = *(const bf16x8*)((const u16*)Ap + (size_t)arowc*FD + ko);
      if (SCORE && wid < 2){
        float4 k0 = *(const float4*)(kvec + ko);
        float4 k1 = *(const float4*)(kvec + ko + 4);
        sacc += bf2f((u16)a[0])*k0.x + bf2f((u16)a[1])*k0.y + bf2f((u16)a[2])*k0.z + bf2f((u16)a[3])*k0.w
              + bf2f((u16)a[4])*k1.x + bf2f((u16)a[5])*k1.y + bf2f((u16)a[6])*k1.z + bf2f((u16)a[7])*k1.w;
      }
    }
    #pragma unroll
    for (int ct = 0; ct < 4; ++ct){
      const int col = cbase + ct*16 + l15;
      bf16x8 bv = *(const bf16x8*)(WT + (size_t)col*FD + ko);
      acc[ct] = __builtin_amdgcn_mfma_f32_16x16x32_bf16(a, bv, acc[ct], 0, 0, 0);
    }
  }
  if (SCORE && wid < 2){
    sacc += __shfl_xor(sacc, 16);
    sacc += __shfl_xor(sacc, 32);
    if (lane < 16 && arow < n) sOut[arow] = expf(sacc + kvec[128]);
  }
  #pragma unroll
  for (int ct = 0; ct < 4; ++ct){
    const int col = cbase + ct*16 + l15;
    const float bvv = bias[col];
    #pragma unroll
    for (int i = 0; i < 4; ++i){
      int gr = row0 + rt*16 + lg*4 + i;
      if (gr < n) out[(size_t)gr*FD + col] = f2bf(acc[ct][i] + bvv);
    }
  }
}

// ================= bucket passes =================
__device__ __forceinline__ int job_of_blk(const BMeta& m, int bid){
  int j = 0;
  #pragma unroll
  for (int t = 1; t < 10; ++t) if (bid >= m.pblk[t]) j = t;
  return j;
}

__device__ __forceinline__ void dev_p2(const BMeta& m, int bid, int* __restrict__ bktCur,
    u32* __restrict__ ebuf, u16* __restrict__ ebuf16, int* sh){
  int j = job_of_blk(m, bid);
  int lb = bid - m.pblk[j];
  const int* key = m.key[j];
  int E = m.E[j], r = m.r[j], B = m.B[j];
  int tid = threadIdx.x, wid = tid >> 6;
  int* wh = sh; int* wstart = sh + 256;
  wh[tid] = 0;
  __syncthreads();
  int base = lb*4096 + tid;
  int* mywh = wh + wid*64;
  #pragma unroll
  for (int i = 0; i < 16; ++i){ int e = base + i*256; if (e < E) atomicAdd(&mywh[key[e]/r], 1); }
  __syncthreads();
  if (tid < B){
    int h0 = wh[tid], h1 = wh[64+tid], h2 = wh[128+tid], h3 = wh[192+tid];
    int g = atomicAdd(&bktCur[m.boff[j] + tid], h0+h1+h2+h3);
    wstart[tid] = g;
    wstart[64+tid] = g + h0;
    wstart[128+tid] = g + h0 + h1;
    wstart[192+tid] = g + h0 + h1 + h2;
  }
  __syncthreads();
  int* myst = wstart + wid*64;
  if (j < 7){
    const int* src = m.src[j];
    #pragma unroll
    for (int i = 0; i < 16; ++i){
      int e = base + i*256;
      if (e < E){
        int s = src[e], d = key[e];
        int b = d / r;
        int pos = atomicAdd(&myst[b], 1);
        ebuf[pos] = ((u32)(d - b*r) << 17) | (u32)s;
      }
    }
  } else {
    #pragma unroll
    for (int i = 0; i < 16; ++i){
      int e = base + i*256;
      if (e < E){
        int k = key[e];
        int b = k / r;
        int pos = atomicAdd(&myst[b], 1);
        ebuf16[pos] = (u16)(k - b*r);
      }
    }
  }
}

__device__ __forceinline__ void dev_p3(const BMeta& m, int bb,
    const int* __restrict__ bktCnt, const int* __restrict__ bktBase,
    const u32* __restrict__ ebuf, const u16* __restrict__ ebuf16, int* sh){
  int j = 0;
  #pragma unroll
  for (int t = 1; t < 10; ++t) if (bb >= m.boff[t]) j = t;
  int b = bb - m.boff[j];
  int n = m.n[j], r = m.r[j];
  int node0 = b*r;
  int rr = min(r, n - node0);
  int gbase = m.ebase[j] + b * m.cap[j];
  int cnt = bktCnt[bb];
  int tid = threadIdx.x;
  if (j >= 7){
    int* hist = sh;
    for (int i = tid; i < rr; i += 256) hist[i] = 0;
    __syncthreads();
    for (int e = tid; e < cnt; e += 256) atomicAdd(&hist[ebuf16[gbase + e]], 1);
    __syncthreads();
    float* rs = m.rsout[j-7];
    for (int i = tid; i < rr; i += 256) rs[node0 + i] = rsqrtf(fmaxf((float)hist[i], 1.f));
    return;
  }
  int B = m.B[j];
  int* rowp = m.rowp[j]; int* csr = m.csr[j];
  int lbase = bktBase[bb];
  int* hist = sh; int* aux = sh + 1568;
  for (int i = tid; i < rr; i += 256) hist[i] = 0;
  __syncthreads();
  for (int e = tid; e < cnt; e += 256){ u32 pk = ebuf[gbase + e]; atomicAdd(&hist[pk >> 17], 1); }
  __syncthreads();
  int ch = (rr + 255) >> 8;
  int i0 = tid*ch;
  int s = 0;
  for (int k = 0; k < ch; ++k){ int idx = i0 + k; if (idx < rr){ int t = hist[idx]; hist[idx] = s; s += t; } }
  aux[tid] = s; __syncthreads();
  for (int off = 1; off < 256; off <<= 1){
    int v = aux[tid]; int a = (tid >= off) ? aux[tid - off] : 0;
    __syncthreads();
    aux[tid] = v + a;
    __syncthreads();
  }
  int pre = (tid ? aux[tid-1] : 0) + lbase;
  for (int k = 0; k < ch; ++k){ int idx = i0 + k; if (idx < rr) hist[idx] += pre; }
  __syncthreads();
  for (int i = tid; i < rr; i += 256) rowp[node0 + i] = hist[i];
  if (b == B-1 && tid == 0) rowp[n] = lbase + cnt;
  __syncthreads();
  for (int e = tid; e < cnt; e += 256){
    u32 pk = ebuf[gbase + e];
    int pos = atomicAdd(&hist[pk >> 17], 1);
    csr[pos] = (int)(pk & 0x1FFFFu);
  }
}

// ================= 16-lane gathers, 4-deep pipelined =================
template<int OB16>
__device__ __forceinline__ void dev_attn_gather16(int bid,
    const int* __restrict__ csr, const int* __restrict__ rowp,
    const float* __restrict__ w, const u16* __restrict__ V,
    void* __restrict__ out, int n)
{
  int g = threadIdx.x >> 4, lane = threadIdx.x & 15;
  int row = bid*16 + g;
  if (row >= n) return;
  int st = rowp[row], en = rowp[row+1];
  float a0=0,a1=0,a2=0,a3=0,a4=0,a5=0,a6=0,a7=0;
  if (en > st){
    const uint4* V8 = (const uint4*)V;
    float den = 0.f;
    int e = st;
    for (; e + 4 <= en; e += 4){
      int s0=csr[e], s1=csr[e+1], s2=csr[e+2], s3=csr[e+3];
      float x0=w[s0], x1=w[s1], x2=w[s2], x3=w[s3];
      uint4 v0=V8[(size_t)s0*16+lane], v1=V8[(size_t)s1*16+lane];
      uint4 v2=V8[(size_t)s2*16+lane], v3=V8[(size_t)s3*16+lane];
      den += x0+x1+x2+x3;
      a0=fmaf(x0,blo(v0.x),a0); a1=fmaf(x0,bhi(v0.x),a1); a2=fmaf(x0,blo(v0.y),a2); a3=fmaf(x0,bhi(v0.y),a3);
      a4=fmaf(x0,blo(v0.z),a4); a5=fmaf(x0,bhi(v0.z),a5); a6=fmaf(x0,blo(v0.w),a6); a7=fmaf(x0,bhi(v0.w),a7);
      a0=fmaf(x1,blo(v1.x),a0); a1=fmaf(x1,bhi(v1.x),a1); a2=fmaf(x1,blo(v1.y),a2); a3=fmaf(x1,bhi(v1.y),a3);
      a4=fmaf(x1,blo(v1.z),a4); a5=fmaf(x1,bhi(v1.z),a5); a6=fmaf(x1,blo(v1.w),a6); a7=fmaf(x1,bhi(v1.w),a7);
      a0=fmaf(x2,blo(v2.x),a0); a1=fmaf(x2,bhi(v2.x),a1); a2=fmaf(x2,blo(v2.y),a2); a3=fmaf(x2,bhi(v2.y),a3);
      a4=fmaf(x2,blo(v2.z),a4); a5=fmaf(x2,bhi(v2.z),a5); a6=fmaf(x2,blo(v2.w),a6); a7=fmaf(x2,bhi(v2.w),a7);
      a0=fmaf(x3,blo(v3.x),a0); a1=fmaf(x3,bhi(v3.x),a1); a2=fmaf(x3,blo(v3.y),a2); a3=fmaf(x3,bhi(v3.y),a3);
      a4=fmaf(x3,blo(v3.z),a4); a5=fmaf(x3,bhi(v3.z),a5); a6=fmaf(x3,blo(v3.w),a6); a7=fmaf(x3,bhi(v3.w),a7);
    }
    for (; e < en; ++e){
      int sn = csr[e];
      float x = w[sn];
      uint4 v = V8[(size_t)sn*16 + lane];
      den += x;
      a0=fmaf(x,blo(v.x),a0); a1=fmaf(x,bhi(v.x),a1); a2=fmaf(x,blo(v.y),a2); a3=fmaf(x,bhi(v.y),a3);
      a4=fmaf(x,blo(v.z),a4); a5=fmaf(x,bhi(v.z),a5); a6=fmaf(x,blo(v.w),a6); a7=fmaf(x,bhi(v.w),a7);
    }
    float inv = 1.f/den;
    a0*=inv; a1*=inv; a2*=inv; a3*=inv; a4*=inv; a5*=inv; a6*=inv; a7*=inv;
  }
  if (OB16){
    uint4 o; o.x = pk2(a0,a1); o.y = pk2(a2,a3); o.z = pk2(a4,a5); o.w = pk2(a6,a7);
    ((uint4*)out)[(size_t)row*16 + lane] = o;
  } else {
    float4* o4 = (float4*)out;
    o4[(size_t)row*32 + lane*2]     = make_float4(a0,a1,a2,a3);
    o4[(size_t)row*32 + lane*2 + 1] = make_float4(a4,a5,a6,a7);
  }
}

template<int OB16>
__device__ __forceinline__ void dev_gcn_gather16(int bid,
    const int* __restrict__ csr, const int* __restrict__ rowp,
    const float* __restrict__ rs, const u16* __restrict__ Y,
    const float* __restrict__ bias, void* __restrict__ out, int n)
{
  int g = threadIdx.x >> 4, lane = threadIdx.x & 15;
  int row = bid*16 + g;
  if (row >= n) return;
  int st = rowp[row], en = rowp[row+1];
  float a0=0,a1=0,a2=0,a3=0,a4=0,a5=0,a6=0,a7=0;
  const uint4* Y8 = (const uint4*)Y;
  int e = st;
  for (; e + 4 <= en; e += 4){
    int s0=csr[e], s1=csr[e+1], s2=csr[e+2], s3=csr[e+3];
    float x0=rs[s0], x1=rs[s1], x2=rs[s2], x3=rs[s3];
    uint4 v0=Y8[(size_t)s0*16+lane], v1=Y8[(size_t)s1*16+lane];
    uint4 v2=Y8[(size_t)s2*16+lane], v3=Y8[(size_t)s3*16+lane];
    a0=fmaf(x0,blo(v0.x),a0); a1=fmaf(x0,bhi(v0.x),a1); a2=fmaf(x0,blo(v0.y),a2); a3=fmaf(x0,bhi(v0.y),a3);
    a4=fmaf(x0,blo(v0.z),a4); a5=fmaf(x0,bhi(v0.z),a5); a6=fmaf(x0,blo(v0.w),a6); a7=fmaf(x0,bhi(v0.w),a7);
    a0=fmaf(x1,blo(v1.x),a0); a1=fmaf(x1,bhi(v1.x),a1); a2=fmaf(x1,blo(v1.y),a2); a3=fmaf(x1,bhi(v1.y),a3);
    a4=fmaf(x1,blo(v1.z),a4); a5=fmaf(x1,bhi(v1.z),a5); a6=fmaf(x1,blo(v1.w),a6); a7=fmaf(x1,bhi(v1.w),a7);
    a0=fmaf(x2,blo(v2.x),a0); a1=fmaf(x2,bhi(v2.x),a1); a2=fmaf(x2,blo(v2.y),a2); a3=fmaf(x2,bhi(v2.y),a3);
    a4=fmaf(x2,blo(v2.z),a4); a5=fmaf(x2,bhi(v2.z),a5); a6=fmaf(x2,blo(v2.w),a6); a7=fmaf(x2,bhi(v2.w),a7);
    a0=fmaf(x3,blo(v3.x),a0); a1=fmaf(x3,bhi(v3.x),a1); a2=fmaf(x3,blo(v3.y),a2); a3=fmaf(x3,bhi(v3.y),a3);
    a4=fmaf(x3,blo(v3.z),a4); a5=fmaf(x3,bhi(v3.z),a5); a6=fmaf(x3,blo(v3.w),a6); a7=fmaf(x3,bhi(v3.w),a7);
  }
  for (; e < en; ++e){
    int sn = csr[e];
    float x = rs[sn];
    uint4 v = Y8[(size_t)sn*16 + lane];
    a0=fmaf(x,blo(v.x),a0); a1=fmaf(x,bhi(v.x),a1); a2=fmaf(x,blo(v.y),a2); a3=fmaf(x,bhi(v.y),a3);
    a4=fmaf(x,blo(v.z),a4); a5=fmaf(x,bhi(v.z),a5); a6=fmaf(x,blo(v.w),a6); a7=fmaf(x,bhi(v.w),a7);
  }
  float sc = rsqrtf(fmaxf((float)(en - st), 1.f));
  const float4* b4 = (const float4*)bias;
  float4 ba = b4[lane*2], bb = b4[lane*2+1];
  float o0=fmaf(a0,sc,ba.x), o1=fmaf(a1,sc,ba.y), o2=fmaf(a2,sc,ba.z), o3=fmaf(a3,sc,ba.w);
  float o4v=fmaf(a4,sc,bb.x), o5=fmaf(a5,sc,bb.y), o6=fmaf(a6,sc,bb.z), o7=fmaf(a7,sc,bb.w);
  if (OB16){
    uint4 o; o.x = pk2(o0,o1); o.y = pk2(o2,o3); o.z = pk2(o4v,o5); o.w = pk2(o6,o7);
    ((uint4*)out)[(size_t)row*16 + lane] = o;
  } else {
    float4* o4 = (float4*)out;
    o4[(size_t)row*32 + lane*2]     = make_float4(o0,o1,o2,o3);
    o4[(size_t)row*32 + lane*2 + 1] = make_float4(o4v,o5,o6,o7);
  }
}

template<int GB16, int DB16>
__device__ __forceinline__ void dev_head(int bid, const void* __restrict__ g, const void* __restrict__ dch,
    const float* __restrict__ W, const float* __restrict__ b,
    float* __restrict__ out, int n, int rowOff)
{
  int wid = threadIdx.x >> 6, lane = threadIdx.x & 63;
  int row = bid*4 + wid;
  if (row >= n) return;
  float x0, x1, x2, x3;
  if (GB16){ const u16* gr = (const u16*)g + (size_t)row*FD; x0 = bf2f(gr[lane]); x1 = bf2f(gr[64+lane]); }
  else     { const float* gr = (const float*)g + (size_t)row*FD; x0 = gr[lane]; x1 = gr[64+lane]; }
  if (DB16){ const u16* dr = (const u16*)dch + (size_t)row*FD; x2 = bf2f(dr[lane]); x3 = bf2f(dr[64+lane]); }
  else     { const float* dr = (const float*)dch + (size_t)row*FD; x2 = dr[lane]; x3 = dr[64+lane]; }
  float acc[5];
  #pragma unroll
  for (int o = 0; o < 5; ++o)
    acc[o] = x0*W[lane*5+o] + x1*W[(64+lane)*5+o] + x2*W[(128+lane)*5+o] + x3*W[(192+lane)*5+o];
  #pragma unroll
  for (int o = 0; o < 5; ++o)
    #pragma unroll
    for (int s = 32; s; s >>= 1) acc[o] += __shfl_xor(acc[o], s);
  if (lane == 0){
    float m = -1e30f;
    #pragma unroll
    for (int o = 0; o < 5; ++o){ acc[o] += b[o]; m = fmaxf(m, acc[o]); }
    float sum = 0.f;
    #pragma unroll
    for (int o = 0; o < 5; ++o){ acc[o] = expf(acc[o]-m); sum += acc[o]; }
    float is = 1.0f/sum;
    float* op = out + (size_t)(rowOff+row)*5;
    #pragma unroll
    for (int o = 0; o < 5; ++o) op[o] = acc[o]*is;
  }
}

// ================= kernels =================

__global__ __launch_bounds__(256) void k1_prep(BMeta m, int* __restrict__ bktCur,
    const float* __restrict__ ekW, const float* __restrict__ ekb, const float* __restrict__ eqb,
    const float* __restrict__ dkW, const float* __restrict__ dkb, const float* __restrict__ dqb,
    float* __restrict__ kv, float inv,
    const float* __restrict__ evW, const float* __restrict__ gW,
    const float* __restrict__ embW, const float* __restrict__ dvW,
    u16* __restrict__ wvt0, u16* __restrict__ wgt0, u16* __restrict__ wvt1, u16* __restrict__ wgt1,
    u16* __restrict__ wembT, u16* __restrict__ wvtd1)
{
  int bid = blockIdx.x;
  if (bid < 4){
    if (threadIdx.x < 128){
      int j = bid;
      const float* kW = (j < 2) ? ekW + j*16384 : dkW + (j-2)*16384;
      const float* kb = (j < 2) ? ekb + j*128   : dkb + (j-2)*128;
      const float* qb = (j < 2) ? eqb + j*128   : dqb + (j-2)*128;
      float* o = kv + j*132;
      int k = threadIdx.x;
      float a = 0.f;
      for (int t = 0; t < 128; ++t) a = fmaf(kW[k*128+t], qb[t], a);
      o[k] = a * inv;
      if (k == 0){
        float c = 0.f;
        for (int t = 0; t < 128; ++t) c = fmaf(kb[t], qb[t], c);
        o[128] = c * inv;
      }
    }
  } else if (bid < 10){
    const float* Ws; u16* Wd;
    if (bid == 4){ Ws = evW;            Wd = wvt0; }
    else if (bid == 5){ Ws = gW;        Wd = wgt0; }
    else if (bid == 6){ Ws = evW+16384; Wd = wvt1; }
    else if (bid == 7){ Ws = gW+16384;  Wd = wgt1; }
    else if (bid == 8){ Ws = embW;      Wd = wembT; }
    else              { Ws = dvW+16384; Wd = wvtd1; }
    for (int i = threadIdx.x; i < 16384; i += 256){
      int k = i >> 7, c = i & 127;
      Wd[c*128 + k] = f2bf(Ws[i]);
    }
  } else {
    for (int i = threadIdx.x; i < 328; i += 256) bktCur[i] = capbase(m, i);
  }
}

// K2: P2 || MFMA h0 gemm (f32 A)
__global__ __launch_bounds__(256) void k2_p2_gemm(BMeta m, int* __restrict__ bktCur,
    u32* __restrict__ ebuf, u16* __restrict__ ebuf16,
    const float* __restrict__ X, const u16* __restrict__ wembT, const float* __restrict__ b,
    u16* __restrict__ bh0, int np2)
{
  __shared__ int sh[512];
  int bid = blockIdx.x;
  if (bid < np2) dev_p2(m, bid, bktCur, ebuf, ebuf16, sh);
  else dev_single_mfma<1,0>(bid - np2, X, wembT, b, nullptr, nullptr, bh0, N0);
}

// K3: derive counts + per-job exclusive scan (1 block)
__global__ __launch_bounds__(256) void k3_p1(BMeta m, const int* __restrict__ bktCur,
    int* __restrict__ bktCnt, int* __restrict__ bktBase)
{
  __shared__ int sh[384];
  int tid = threadIdx.x;
  for (int i = tid; i < 328; i += 256){
    int cnt = bktCur[i] - capbase(m, i);
    bktCnt[i] = cnt;
    sh[i] = cnt;
  }
  __syncthreads();
  if (tid < 7){
    int acc = 0;
    for (int b = m.boff[tid]; b < m.boff[tid+1]; ++b){ int v = sh[b]; sh[b] = acc; acc += v; }
  }
  __syncthreads();
  for (int i = tid; i < 328; i += 256) bktBase[i] = sh[i];
}

// K4: P3 || MFMA dual(h0) full
__global__ __launch_bounds__(256) void k4_p3_dual(BMeta m,
    const int* __restrict__ bktCnt, const int* __restrict__ bktBase,
    const u32* __restrict__ ebuf, const u16* __restrict__ ebuf16,
    const u16* __restrict__ bh0,
    const u16* __restrict__ wvt0, const u16* __restrict__ wgt0, const float* __restrict__ evb,
    const float* __restrict__ kvec, float* __restrict__ sS, u16* __restrict__ bV, u16* __restrict__ bY0,
    int np3)
{
  __shared__ int sh[1824];
  int bid = blockIdx.x;
  if (bid < np3) dev_p3(m, bid, bktCnt, bktBase, ebuf, ebuf16, sh);
  else dev_dual_mfma(bid - np3, bh0, wvt0, wgt0, evb, kvec, sS, bV, bY0, N0);
}

// K5: attn_gather16(i0)->be1 || g0 slice
__global__ __launch_bounds__(256) void k5_ag_i0(
    const int* __restrict__ csrA, const int* __restrict__ rowpA,
    const float* __restrict__ sS, const u16* __restrict__ bV, u16* __restrict__ be1,
    const int* __restrict__ csr0, const int* __restrict__ rowp0, const float* __restrict__ rs0,
    const u16* __restrict__ bY0, const float* __restrict__ gb, u16* __restrict__ bg0, int nMain, int sBase)
{
  int bid = blockIdx.x;
  if (bid < nMain) dev_attn_gather16<1>(bid, csrA, rowpA, sS, bV, be1, N1);
  else dev_gcn_gather16<1>(sBase + bid - nMain, csr0, rowp0, rs0, bY0, gb, bg0, N0);
}

// K6: MFMA dual(be1 -> V1+score, Y1) || g0 slice
__global__ __launch_bounds__(256) void k6_dual_enc1(
    const u16* __restrict__ be1,
    const u16* __restrict__ wvt1, const u16* __restrict__ wgt1, const float* __restrict__ vb,
    const float* __restrict__ kvec, float* __restrict__ sS, u16* __restrict__ bV, u16* __restrict__ bY1,
    const int* __restrict__ csr0, const int* __restrict__ rowp0, const float* __restrict__ rs0,
    const u16* __restrict__ bY0, const float* __restrict__ gb, u16* __restrict__ bg0, int nMain, int sBase)
{
  int bid = blockIdx.x;
  if (bid < nMain) dev_dual_mfma(bid, be1, wvt1, wgt1, vb, kvec, sS, bV, bY1, N1);
  else dev_gcn_gather16<1>(sBase + bid - nMain, csr0, rowp0, rs0, bY0, gb, bg0, N0);
}

// K7: attn_gather16(i1)->be2(f32) || g0 slice
__global__ __launch_bounds__(256) void k7_ag_i1(
    const int* __restrict__ csrA, const int* __restrict__ rowpA,
    const float* __restrict__ sS, const u16* __restrict__ bV, float* __restrict__ be2,
    const int* __restrict__ csr0, const int* __restrict__ rowp0, const float* __restrict__ rs0,
    const u16* __restrict__ bY0, const float* __restrict__ gb, u16* __restrict__ bg0, int nMain, int sBase)
{
  int bid = blockIdx.x;
  if (bid < nMain) dev_attn_gather16<0>(bid, csrA, rowpA, sS, bV, be2, N2);
  else dev_gcn_gather16<1>(sBase + bid - nMain, csr0, rowp0, rs0, bY0, gb, bg0, N0);
}

// K8: gcn2-Y gemm (f32 A) || gcn_gather16(g1)->bg1 || g0 slice
__global__ __launch_bounds__(256) void k8_y2_g1(
    const float* __restrict__ be2, const float* __restrict__ W2, u16* __restrict__ bY2,
    const int* __restrict__ csr1, const int* __restrict__ rowp1, const float* __restrict__ rs1,
    const u16* __restrict__ bY1, const float* __restrict__ b1, u16* __restrict__ bg1,
    const int* __restrict__ csr0, const int* __restrict__ rowp0, const float* __restrict__ rs0,
    const u16* __restrict__ bY0, const float* __restrict__ gb, u16* __restrict__ bg0,
    int ngemm, int nMain, int sBase)
{
  __shared__ float sm[5120];
  int bid = blockIdx.x;
  if (bid < ngemm) dev_gemm<0,0>(sm, sm+4096, bid, be2, W2, nullptr, nullptr, nullptr, bY2, N2);
  else if (bid < nMain) dev_gcn_gather16<1>(bid - ngemm, csr1, rowp1, rs1, bY1, b1, bg1, N1);
  else dev_gcn_gather16<1>(sBase + bid - nMain, csr0, rowp0, rs0, bY0, gb, bg0, N0);
}

// K9: gcn_gather16(g2)->bg2(f32) || g0 slice
__global__ __launch_bounds__(256) void k9_g2(
    const int* __restrict__ csr2, const int* __restrict__ rowp2, const float* __restrict__ rs2,
    const u16* __restrict__ bY2, const float* __restrict__ b2, float* __restrict__ bg2,
    const int* __restrict__ csr0, const int* __restrict__ rowp0, const float* __restrict__ rs0,
    const u16* __restrict__ bY0, const float* __restrict__ gb, u16* __restrict__ bg0, int nMain, int sBase)
{
  int bid = blockIdx.x;
  if (bid < nMain) dev_gcn_gather16<0>(bid, csr2, rowp2, rs2, bY2, b2, bg2, N2);
  else dev_gcn_gather16<1>(sBase + bid - nMain, csr0, rowp0, rs0, bY0, gb, bg0, N0);
}

// K10: dec0 gemm (f32 A) || head2 || g0 slice
__global__ __launch_bounds__(256) void k10_dec0_head2(
    const float* __restrict__ bg2, const float* __restrict__ vW, const float* __restrict__ vb,
    const float* __restrict__ kvec, float* __restrict__ sS, u16* __restrict__ bV,
    const float* __restrict__ hW, const float* __restrict__ hb, float* __restrict__ out,
    const int* __restrict__ csr0, const int* __restrict__ rowp0, const float* __restrict__ rs0,
    const u16* __restrict__ bY0, const float* __restrict__ gb, u16* __restrict__ bg0,
    int ngemm, int nMain, int sBase)
{
  __shared__ float sm[5120];
  int bid = blockIdx.x;
  if (bid < ngemm) dev_gemm<1,0>(sm, sm+4096, bid, bg2, vW, vb, kvec, sS, bV, N2);
  else if (bid < nMain) dev_head<0,0>(bid - ngemm, bg2, bg2, hW, hb, out, N2, N0+N1);
  else dev_gcn_gather16<1>(sBase + bid - nMain, csr0, rowp0, rs0, bY0, gb, bg0, N0);
}

// K11: attn_gather16(dc0)->be1 (d1) || g0 slice
__global__ __launch_bounds__(256) void k11_ag_d1(
    const int* __restrict__ csrA, const int* __restrict__ rowpA,
    const float* __restrict__ sS, const u16* __restrict__ bV, u16* __restrict__ be1,
    const int* __restrict__ csr0, const int* __restrict__ rowp0, const float* __restrict__ rs0,
    const u16* __restrict__ bY0, const float* __restrict__ gb, u16* __restrict__ bg0, int nMain, int sBase)
{
  int bid = blockIdx.x;
  if (bid < nMain) dev_attn_gather16<1>(bid, csrA, rowpA, sS, bV, be1, N1);
  else dev_gcn_gather16<1>(sBase + bid - nMain, csr0, rowp0, rs0, bY0, gb, bg0, N0);
}

// K12: MFMA dec1 gemm (bf16 A, +score) || head1 || g0 slice
__global__ __launch_bounds__(256) void k12_dec1_head1(
    const u16* __restrict__ be1, const u16* __restrict__ wvtd1, const float* __restrict__ vb,
    const float* __restrict__ kvec, float* __restrict__ sS, u16* __restrict__ bV,
    const u16* __restrict__ bg1, const float* __restrict__ hW, const float* __restrict__ hb,
    float* __restrict__ out,
    const int* __restrict__ csr0, const int* __restrict__ rowp0, const float* __restrict__ rs0,
    const u16* __restrict__ bY0, const float* __restrict__ gb, u16* __restrict__ bg0,
    int ngemm, int nMain, int sBase)
{
  int bid = blockIdx.x;
  if (bid < ngemm) dev_single_mfma<0,1>(bid, be1, wvtd1, vb, kvec, sS, bV, N1);
  else if (bid < nMain) dev_head<1,1>(bid - ngemm, bg1, be1, hW, hb, out, N1, N0);
  else dev_gcn_gather16<1>(sBase + bid - nMain, csr0, rowp0, rs0, bY0, gb, bg0, N0);
}

// K13: fused d0 gather + head0 (16-lane, 4-deep)
__global__ __launch_bounds__(256) void k13_gather_head0(
    const int* __restrict__ csr, const int* __restrict__ rowp,
    const float* __restrict__ w, const u16* __restrict__ V,
    const u16* __restrict__ bg0,
    const float* __restrict__ hW, const float* __restrict__ hb,
    float* __restrict__ out)
{
  int g = threadIdx.x >> 4, lane = threadIdx.x & 15;
  int row = blockIdx.x*16 + g;
  if (row >= N0) return;
  int st = rowp[row], en = rowp[row+1];
  float a0=0,a1=0,a2=0,a3=0,a4=0,a5=0,a6=0,a7=0;
  if (en > st){
    const uint4* V8 = (const uint4*)V;
    float den = 0.f;
    int e = st;
    for (; e + 4 <= en; e += 4){
      int s0=csr[e], s1=csr[e+1], s2=csr[e+2], s3=csr[e+3];
      float x0=w[s0], x1=w[s1], x2=w[s2], x3=w[s3];
      uint4 v0=V8[(size_t)s0*16+lane], v1=V8[(size_t)s1*16+lane];
      uint4 v2=V8[(size_t)s2*16+lane], v3=V8[(size_t)s3*16+lane];
      den += x0+x1+x2+x3;
      a0=fmaf(x0,blo(v0.x),a0); a1=fmaf(x0,bhi(v0.x),a1); a2=fmaf(x0,blo(v0.y),a2); a3=fmaf(x0,bhi(v0.y),a3);
      a4=fmaf(x0,blo(v0.z),a4); a5=fmaf(x0,bhi(v0.z),a5); a6=fmaf(x0,blo(v0.w),a6); a7=fmaf(x0,bhi(v0.w),a7);
      a0=fmaf(x1,blo(v1.x),a0); a1=fmaf(x1,bhi(v1.x),a1); a2=fmaf(x1,blo(v1.y),a2); a3=fmaf(x1,bhi(v1.y),a3);
      a4=fmaf(x1,blo(v1.z),a4); a5=fmaf(x1,bhi(v1.z),a5); a6=fmaf(x1,blo(v1.w),a6); a7=fmaf(x1,bhi(v1.w),a7);
      a0=fmaf(x2,blo(v2.x),a0); a1=fmaf(x2,bhi(v2.x),a1); a2=fmaf(x2,blo(v2.y),a2); a3=fmaf(x2,bhi(v2.y),a3);
      a4=fmaf(x2,blo(v2.z),a4); a5=fmaf(x2,bhi(v2.z),a5); a6=fmaf(x2,blo(v2.w),a6); a7=fmaf(x2,bhi(v2.w),a7);
      a0=fmaf(x3,blo(v3.x),a0); a1=fmaf(x3,bhi(v3.x),a1); a2=fmaf(x3,blo(v3.y),a2); a3=fmaf(x3,bhi(v3.y),a3);
      a4=fmaf(x3,blo(v3.z),a4); a5=fmaf(x3,bhi(v3.z),a5); a6=fmaf(x3,blo(v3.w),a6); a7=fmaf(x3,bhi(v3.w),a7);
    }
    for (; e < en; ++e){
      int sn = csr[e];
      float x = w[sn];
      uint4 v = V8[(size_t)sn*16 + lane];
      den += x;
      a0=fmaf(x,blo(v.x),a0); a1=fmaf(x,bhi(v.x),a1); a2=fmaf(x,blo(v.y),a2); a3=fmaf(x,bhi(v.y),a3);
      a4=fmaf(x,blo(v.z),a4); a5=fmaf(x,bhi(v.z),a5); a6=fmaf(x,blo(v.w),a6); a7=fmaf(x,bhi(v.w),a7);
    }
    float inv = 1.f/den;
    a0*=inv; a1*=inv; a2*=inv; a3*=inv; a4*=inv; a5*=inv; a6*=inv; a7*=inv;
  }
  uint4 gv = ((const uint4*)(bg0 + (size_t)row*FD))[lane];
  float g0 = blo(gv.x), g1 = bhi(gv.x), g2 = blo(gv.y), g3 = bhi(gv.y);
  float g4 = blo(gv.z), g5 = bhi(gv.z), g6 = blo(gv.w), g7 = bhi(gv.w);
  int j = 8*lane;
  float acc[5];
  #pragma unroll
  for (int o = 0; o < 5; ++o){
    acc[o] = g0*hW[(j+0)*5+o] + g1*hW[(j+1)*5+o] + g2*hW[(j+2)*5+o] + g3*hW[(j+3)*5+o]
           + g4*hW[(j+4)*5+o] + g5*hW[(j+5)*5+o] + g6*hW[(j+6)*5+o] + g7*hW[(j+7)*5+o]
           + a0*hW[(128+j+0)*5+o] + a1*hW[(128+j+1)*5+o] + a2*hW[(128+j+2)*5+o] + a3*hW[(128+j+3)*5+o]
           + a4*hW[(128+j+4)*5+o] + a5*hW[(128+j+5)*5+o] + a6*hW[(128+j+6)*5+o] + a7*hW[(128+j+7)*5+o];
  }
  #pragma unroll
  for (int o = 0; o < 5; ++o)
    #pragma unroll
    for (int s = 8; s; s >>= 1) acc[o] += __shfl_xor(acc[o], s, 16);
  if (lane == 0){
    float m = -1e30f;
    #pragma unroll
    for (int o = 0; o < 5; ++o){ acc[o] += hb[o]; m = fmaxf(m, acc[o]); }
    float sum = 0.f;
    #pragma unroll
    for (int o = 0; o < 5; ++o){ acc[o] = expf(acc[o]-m); sum += acc[o]; }
    float is = 1.0f/sum;
    float* op = out + (size_t)row*5;
    #pragma unroll
    for (int o = 0; o < 5; ++o) op[o] = acc[o]*is;
  }
}

// ================= host =================
extern "C" void kernel_launch(void* const* d_in, const int* in_sizes, int n_in,
                              void* d_out, int out_size, void* d_ws, size_t ws_size,
                              hipStream_t stream)
{
  const float* X      = (const float*)d_in[0];
  const float* emb_W  = (const float*)d_in[1];
  const float* emb_b  = (const float*)d_in[2];
  const float* gcn_W  = (const float*)d_in[3];
  const float* gcn_b  = (const float*)d_in[4];
  const float* enc_qb = (const float*)d_in[6];
  const float* enc_kW = (const float*)d_in[7];
  const float* enc_kb = (const float*)d_in[8];
  const float* enc_vW = (const float*)d_in[9];
  const float* enc_vb = (const float*)d_in[10];
  const float* dec_qb = (const float*)d_in[12];
  const float* dec_kW = (const float*)d_in[13];
  const float* dec_kb = (const float*)d_in[14];
  const float* dec_vW = (const float*)d_in[15];
  const float* dec_vb = (const float*)d_in[16];
  const float* head_W = (const float*)d_in[17];
  const float* head_b = (const float*)d_in[18];
  const int* g0s  = (const int*)d_in[19];
  const int* g0d  = (const int*)d_in[20];
  const int* g1s  = (const int*)d_in[21];
  const int* g1d  = (const int*)d_in[22];
  const int* g2s  = (const int*)d_in[23];
  const int* g2d  = (const int*)d_in[24];
  const int* i0s  = (const int*)d_in[25];
  const int* i0d  = (const int*)d_in[26];
  const int* i1s  = (const int*)d_in[27];
  const int* i1d  = (const int*)d_in[28];
  const int* dc0s = (const int*)d_in[29];
  const int* dc0d = (const int*)d_in[30];
  const int* dc1s = (const int*)d_in[31];
  const int* dc1d = (const int*)d_in[32];

  // ---- workspace layout ----
  float* ws = (float*)d_ws;
  float* sS  = ws;                          // N0
  float* kvec = sS + N0;                    // 4*132
  float* be2 = kvec + 4*132;                // N2*FD f32
  float* bg2 = be2 + (size_t)N2*FD;         // N2*FD f32
  float* rs0 = bg2 + (size_t)N2*FD;         // N0
  float* rs1 = rs0 + N0;                    // N1
  float* rs2 = rs1 + N1;                    // N2 (+2 pad)
  u16*  bh0 = (u16*)(rs2 + N2 + 2);         // N0*FD u16
  u16*  be1 = bh0 + (size_t)N0*FD;          // N1*FD u16
  u16*  bg0 = be1 + (size_t)N1*FD;          // N0*FD u16
  u16*  bg1 = bg0 + (size_t)N0*FD;          // N1*FD u16
  u16*  bV  = bg1 + (size_t)N1*FD;          // N0*FD u16 (V tables, time-shared)
  u16*  bY0 = bV  + (size_t)N0*FD;          // N0*FD u16
  u16*  bY1 = bV + 4000000;                 // alias into bV tail
  u16*  bY2 = bV + 8000000;
  int*  bktCnt  = (int*)(bY0 + (size_t)N0*FD);  // 328
  int*  bktBase = bktCnt + 328;                 // 328
  int*  bktCur  = bktBase + 328;                // 328
  int*  rowpBlk = bktCur + 328;                 // 287507
  int*  csrBlk  = rowpBlk + 287507;             // 2,500,000
  u32*  ebuf    = (u32*)(csrBlk + 2500000);     // 2,880,000 u32 (capacity-padded)
  u16*  ebuf16  = (u16*)(ebuf + 2880000);       // 1,712,000 u16
  uintptr_t wtp = ((uintptr_t)(ebuf16 + 1712000) + 15) & ~(uintptr_t)15;
  u16* wvt0 = (u16*)wtp;                        // 16384 each
  u16* wgt0 = wvt0 + 16384;
  u16* wvt1 = wgt0 + 16384;
  u16* wgt1 = wvt1 + 16384;
  u16* wembT = wgt1 + 16384;
  u16* wvtd1 = wembT + 16384;

  const int* keyP[10] = {g0d,g1d,g2d,i0d,i1d,dc0d,dc1d, g0s,g1s,g2s};
  const int* srcP[7]  = {g0s,g1s,g2s,i0s,i1s,dc0s,dc1s};
  const int nArr[10] = {N0,N1,N2,N1,N2,N1,N0, N0,N1,N2};
  const int EArr[10] = {1000000,400000,100000,400000,100000,100000,400000, 1000000,400000,100000};
  const int BArr[10] = {64,32,8,32,8,16,64, 64,32,8};
  const int rArr[10] = {1563,782,782,782,782,1563,1563, 1563,782,782};
  const int capArr[10] = {18000,14000,14000,14000,14000,7600,7600, 18000,14000,14000};

  BMeta m;
  {
    int bo=0, po=0, ro=0, co=0;
    int eb32=0, eb16=0;
    for (int j=0;j<10;++j){
      m.key[j]=keyP[j];
      m.n[j]=nArr[j]; m.E[j]=EArr[j]; m.B[j]=BArr[j]; m.r[j]=rArr[j];
      m.cap[j]=capArr[j];
      m.boff[j]=bo; m.pblk[j]=po;
      bo+=BArr[j]; po+=ceildiv(EArr[j],4096);
      if (j < 7){
        m.src[j]=srcP[j]; m.rowp[j]=rowpBlk+ro; m.csr[j]=csrBlk+co;
        m.ebase[j]=eb32; eb32 += BArr[j]*capArr[j];
        ro+=nArr[j]+1; co+=EArr[j];
      } else {
        m.ebase[j]=eb16; eb16 += BArr[j]*capArr[j];
      }
    }
    m.boff[10]=bo; m.pblk[10]=po;   // 328 / 982
  }
  m.rsout[0]=rs0; m.rsout[1]=rs1; m.rsout[2]=rs2;

  const float invScale = 0.17677669529663687f;
  float* out = (float*)d_out;

  const int NP = m.pblk[10];                // 982
  const int NB = m.boff[10];                // 328
  const int GH0 = ceildiv(N0,32);           // 3125
  const int GH1 = ceildiv(N1,32);           // 782
  const int GH2 = ceildiv(N2,32);           // 196
  const int GA1_16 = ceildiv(N1,16);        // 1563
  const int GA2_16 = ceildiv(N2,16);        // 391
  const int G0B16  = ceildiv(N0,16);        // 6250
  const int GH2H = ceildiv(N2,4);           // 1563
  const int GH1H = ceildiv(N1,4);           // 6250

  int ss[9];
  for (int i = 0; i <= 8; ++i) ss[i] = (int)(((long long)G0B16 * i) / 8);

  // K1: kvec || W transposes || init bktCur
  k1_prep<<<11, 256, 0, stream>>>(m, bktCur,
      enc_kW, enc_kb, enc_qb, dec_kW, dec_kb, dec_qb, kvec, invScale,
      enc_vW, gcn_W, emb_W, dec_vW, wvt0, wgt0, wvt1, wgt1, wembT, wvtd1);
  // K2: P2 || MFMA h0 gemm
  k2_p2_gemm<<<NP + GH0, 256, 0, stream>>>(m, bktCur, ebuf, ebuf16,
      X, wembT, emb_b, bh0, NP);
  // K3: counts + scan
  k3_p1<<<1, 256, 0, stream>>>(m, bktCur, bktCnt, bktBase);
  // K4: P3 || MFMA dual(h0)
  k4_p3_dual<<<NB + GH0, 256, 0, stream>>>(m, bktCnt, bktBase, ebuf, ebuf16,
      bh0, wvt0, wgt0, enc_vb, kvec, sS, bV, bY0, NB);
  // K5: attn_gather(i0)->be1 || g0[0]
  k5_ag_i0<<<GA1_16 + (ss[1]-ss[0]), 256, 0, stream>>>(m.csr[3], m.rowp[3], sS, bV, be1,
      m.csr[0], m.rowp[0], rs0, bY0, gcn_b, bg0, GA1_16, ss[0]);
  // K6: dual(be1 -> V1, Y1) || g0[1]
  k6_dual_enc1<<<GH1 + (ss[2]-ss[1]), 256, 0, stream>>>(be1,
      wvt1, wgt1, enc_vb+128, kvec+132, sS, bV, bY1,
      m.csr[0], m.rowp[0], rs0, bY0, gcn_b, bg0, GH1, ss[1]);
  // K7: attn_gather(i1)->be2 || g0[2]
  k7_ag_i1<<<GA2_16 + (ss[3]-ss[2]), 256, 0, stream>>>(m.csr[4], m.rowp[4], sS, bV, be2,
      m.csr[0], m.rowp[0], rs0, bY0, gcn_b, bg0, GA2_16, ss[2]);
  // K8: gcn2-Y || gather(g1)->bg1 || g0[3]
  k8_y2_g1<<<GH2 + GA1_16 + (ss[4]-ss[3]), 256, 0, stream>>>(be2, gcn_W+32768, bY2,
      m.csr[1], m.rowp[1], rs1, bY1, gcn_b+128, bg1,
      m.csr[0], m.rowp[0], rs0, bY0, gcn_b, bg0, GH2, GH2+GA1_16, ss[3]);
  // K9: gather(g2)->bg2 || g0[4]
  k9_g2<<<GA2_16 + (ss[5]-ss[4]), 256, 0, stream>>>(m.csr[2], m.rowp[2], rs2, bY2, gcn_b+256, bg2,
      m.csr[0], m.rowp[0], rs0, bY0, gcn_b, bg0, GA2_16, ss[4]);
  // K10: dec0 gemm || head2 || g0[5]
  k10_dec0_head2<<<GH2 + GH2H + (ss[6]-ss[5]), 256, 0, stream>>>(bg2, dec_vW, dec_vb, kvec+264, sS, bV,
      head_W+2560, head_b+10, out,
      m.csr[0], m.rowp[0], rs0, bY0, gcn_b, bg0, GH2, GH2+GH2H, ss[5]);
  // K11: attn_gather(dc0)->be1 (d1) || g0[6]
  k11_ag_d1<<<GA1_16 + (ss[7]-ss[6]), 256, 0, stream>>>(m.csr[5], m.rowp[5], sS, bV, be1,
      m.csr[0], m.rowp[0], rs0, bY0, gcn_b, bg0, GA1_16, ss[6]);
  // K12: dec1 gemm || head1 || g0[7]
  k12_dec1_head1<<<GH1 + GH1H + (ss[8]-ss[7]), 256, 0, stream>>>(be1, wvtd1, dec_vb+128, kvec+396, sS, bV,
      bg1, head_W+1280, head_b+5, out,
      m.csr[0], m.rowp[0], rs0, bY0, gcn_b, bg0, GH1, GH1H+GH1, ss[7]);
  // K13: fused d0 gather + head0
  k13_gather_head0<<<G0B16, 256, 0, stream>>>(m.csr[6], m.rowp[6], sS, bV, bg0,
      head_W, head_b, out);
}